// Round 14
// baseline (2361.767 us; speedup 1.0000x reference)
//
#include <hip/hip_runtime.h>

typedef unsigned short u16;
typedef __attribute__((ext_vector_type(4))) float f32x4;
typedef __attribute__((ext_vector_type(8))) __bf16 bf16x8;
typedef __attribute__((ext_vector_type(8))) _Float16 f16x8;
typedef __attribute__((ext_vector_type(4))) unsigned short u16x4;
typedef __attribute__((ext_vector_type(8))) unsigned short u16x8;

constexpr int kT = 1024, kD = 1024, kH = 16, kHD = 64, kL = 3, kE = 8;
constexpr int kFF = 4096, kV = 32000, kBT = 2048, kSLOTS = 5120;

__device__ __forceinline__ u16 f2bf(float f) {
  union { float f; unsigned u; } v; v.f = f;
  unsigned r = v.u + 0x7FFFu + ((v.u >> 16) & 1u);   // RNE
  return (u16)(r >> 16);
}
__device__ __forceinline__ u16 f2h(float x) {
  _Float16 h = (_Float16)x;
  union { _Float16 h; u16 u; } v; v.h = h; return v.u;
}
// uniform-scale fp16 split-2: 64*x = hi + mid + O(2^-11 * |64x - hi|)
__device__ __forceinline__ void split2s(float x, u16& h, u16& m) {
  float xs = x * 64.0f;
  _Float16 hh = (_Float16)xs;
  union { _Float16 h; u16 u; } v; v.h = hh; h = v.u;
  float r = xs - (float)hh;
  union { _Float16 h; u16 u; } w; w.h = (_Float16)r; m = w.u;
}

__device__ __forceinline__ void ld_lds16(const void* g, void* l) {
  __builtin_amdgcn_global_load_lds((const __attribute__((address_space(1))) void*)g,
                                   (__attribute__((address_space(3))) void*)l, 16, 0, 0);
}

#define MFMA16(a, b, c) __builtin_amdgcn_mfma_f32_16x16x32_bf16(a, b, c, 0, 0, 0)
#define MFMAH(a, b, c)  __builtin_amdgcn_mfma_f32_16x16x32_f16(a, b, c, 0, 0, 0)

__device__ __forceinline__ float blockReduceSum256(float v) {
  #pragma unroll
  for (int m = 32; m >= 1; m >>= 1) v += __shfl_xor(v, m);
  __shared__ float sh_[4];
  int w = threadIdx.x >> 6;
  if ((threadIdx.x & 63) == 0) sh_[w] = v;
  __syncthreads();
  v = (sh_[0] + sh_[1]) + (sh_[2] + sh_[3]);
  __syncthreads();
  return v;
}

// ---------------- elementwise / small kernels ----------------

__global__ __launch_bounds__(256) void cast_bf16_k(const float* __restrict__ in,
                                                   u16* __restrict__ out, long n4) {
  long i = (long)blockIdx.x * 256 + threadIdx.x;
  long stride = (long)gridDim.x * 256;
  for (; i < n4; i += stride) {
    f32x4 v = ((const f32x4*)in)[i];
    u16x4 o; o[0] = f2bf(v[0]); o[1] = f2bf(v[1]); o[2] = f2bf(v[2]); o[3] = f2bf(v[3]);
    ((u16x4*)out)[i] = o;
  }
}

__global__ __launch_bounds__(256) void cast_h_k(const float* __restrict__ in,
                                                u16* __restrict__ out, long n4) {
  long i = (long)blockIdx.x * 256 + threadIdx.x;
  long stride = (long)gridDim.x * 256;
  for (; i < n4; i += stride) {
    f32x4 v = ((const f32x4*)in)[i];
    u16x4 o; o[0] = f2h(v[0]); o[1] = f2h(v[1]); o[2] = f2h(v[2]); o[3] = f2h(v[3]);
    ((u16x4*)out)[i] = o;
  }
}

// two tensors f32 -> f16 in one launch
__global__ __launch_bounds__(256) void cast_h2_k(
    const float* __restrict__ in0, u16* __restrict__ out0,
    const float* __restrict__ in1, u16* __restrict__ out1, long n4) {
  long i = (long)blockIdx.x * 256 + threadIdx.x;
  long stride = (long)gridDim.x * 256;
  for (; i < 2 * n4; i += stride) {
    const float* s; u16* d; long j;
    if (i < n4) { s = in0; d = out0; j = i; } else { s = in1; d = out1; j = i - n4; }
    f32x4 v = ((const f32x4*)s)[j];
    u16x4 o; o[0] = f2h(v[0]); o[1] = f2h(v[1]); o[2] = f2h(v[2]); o[3] = f2h(v[3]);
    ((u16x4*)d)[j] = o;
  }
}

// f32 -> 2 fp16 planes (uniform x64 scale)
__global__ __launch_bounds__(256) void split2h_k(const float* __restrict__ in,
    u16* __restrict__ out, long planeStride, long n4) {
  long i = (long)blockIdx.x * 256 + threadIdx.x;
  long stride = (long)gridDim.x * 256;
  u16* o1 = out + planeStride;
  for (; i < n4; i += stride) {
    f32x4 v = ((const f32x4*)in)[i];
    u16x4 a, b;
    #pragma unroll
    for (int j = 0; j < 4; ++j) {
      u16 h, m; split2s(v[j], h, m);
      a[j] = h; b[j] = m;
    }
    ((u16x4*)out)[i] = a; ((u16x4*)o1)[i] = b;
  }
}

// qkv = p0 + p1 -> 2 fp16 planes (x64 scale)
__global__ __launch_bounds__(256) void qkvcomb_k(const float* __restrict__ a,
    const float* __restrict__ b, u16* __restrict__ oP, long plane, long n4) {
  long i = (long)blockIdx.x * 256 + threadIdx.x;
  long stride = (long)gridDim.x * 256;
  for (; i < n4; i += stride) {
    f32x4 v = ((const f32x4*)a)[i] + ((const f32x4*)b)[i];
    u16x4 hh, mm;
    #pragma unroll
    for (int j = 0; j < 4; ++j) {
      u16 h, m; split2s(v[j], h, m);
      hh[j] = h; mm[j] = m;
    }
    ((u16x4*)oP)[i] = hh;
    ((u16x4*)(oP + plane))[i] = mm;
  }
}

// two tensors -> split-2 planes in one launch
__global__ __launch_bounds__(256) void split2h2_k(
    const float* __restrict__ in0, u16* __restrict__ out0,
    const float* __restrict__ in1, u16* __restrict__ out1,
    long planeStride, long n4) {
  long i = (long)blockIdx.x * 256 + threadIdx.x;
  long stride = (long)gridDim.x * 256;
  for (; i < 2 * n4; i += stride) {
    const float* s; u16* d; long j;
    if (i < n4) { s = in0; d = out0; j = i; } else { s = in1; d = out1; j = i - n4; }
    f32x4 v = ((const f32x4*)s)[j];
    u16x4 a, b;
    #pragma unroll
    for (int jj = 0; jj < 4; ++jj) {
      u16 h, m; split2s(v[jj], h, m);
      a[jj] = h; b[jj] = m;
    }
    ((u16x4*)d)[j] = a; ((u16x4*)(d + planeStride))[j] = b;
  }
}

__global__ __launch_bounds__(256) void embed_rms_k(const int* __restrict__ idx,
    const float* __restrict__ wte, const float* __restrict__ wpe, float* __restrict__ x) {
  int tok = blockIdx.x, t = threadIdx.x;
  int id = idx[tok];
  int tt = tok & (kT - 1);
  f32x4 a = ((const f32x4*)(wte + (long)id * kD))[t];
  f32x4 p = ((const f32x4*)(wpe + (long)tt * kD))[t];
  f32x4 vv = a + p;
  float ss = vv[0]*vv[0] + vv[1]*vv[1] + vv[2]*vv[2] + vv[3]*vv[3];
  ss = blockReduceSum256(ss);
  float sc = rsqrtf(ss * (1.0f / kD) + 1e-5f);
  vv *= sc;
  ((f32x4*)(x + (long)tok * kD))[t] = vv;
}

// rmsnorm -> f32 + bf16 (fallback path)
__global__ __launch_bounds__(256) void rmsnorm2_k(const float* __restrict__ x,
    float* __restrict__ xnf, u16* __restrict__ xnb) {
  int tok = blockIdx.x, t = threadIdx.x;
  f32x4 vv = ((const f32x4*)(x + (long)tok * kD))[t];
  float ss = blockReduceSum256(vv[0]*vv[0] + vv[1]*vv[1] + vv[2]*vv[2] + vv[3]*vv[3]);
  float sc = rsqrtf(ss * (1.0f / kD) + 1e-5f);
  vv *= sc;
  ((f32x4*)(xnf + (long)tok * kD))[t] = vv;
  u16x4 o;
  o[0] = f2bf(vv[0]); o[1] = f2bf(vv[1]); o[2] = f2bf(vv[2]); o[3] = f2bf(vv[3]);
  ((u16x4*)(xnb + (long)tok * kD))[t] = o;
}

// rmsnorm -> 2 fp16 planes (fast path, x64 scale)
__global__ __launch_bounds__(256) void rmsnorm2h_k(const float* __restrict__ x,
    u16* __restrict__ xnP, long plane) {
  int tok = blockIdx.x, t = threadIdx.x;
  f32x4 vv = ((const f32x4*)(x + (long)tok * kD))[t];
  float ss = blockReduceSum256(vv[0]*vv[0] + vv[1]*vv[1] + vv[2]*vv[2] + vv[3]*vv[3]);
  float sc = rsqrtf(ss * (1.0f / kD) + 1e-5f);
  vv *= sc;
  u16x4 a, b;
  #pragma unroll
  for (int j = 0; j < 4; ++j) {
    u16 h, m; split2s(vv[j], h, m);
    a[j] = h; b[j] = m;
  }
  long o = (long)tok * kD / 4 + t;
  ((u16x4*)xnP)[o] = a;
  ((u16x4*)(xnP + plane))[o] = b;
}

// x += sum of 4 K-partials; write x; rmsnorm -> 2 fp16 planes
__global__ __launch_bounds__(256) void resid4_rms2h_k(float* __restrict__ x,
    const float* __restrict__ parts, long plane, u16* __restrict__ xnP, long xplane) {
  int tok = blockIdx.x, t = threadIdx.x;
  long o = (long)tok * (kD / 4) + t;
  f32x4 xv = ((f32x4*)x)[o];
  #pragma unroll
  for (int p = 0; p < 4; ++p) xv += ((const f32x4*)(parts + p * plane))[o];
  ((f32x4*)x)[o] = xv;
  float ss = blockReduceSum256(xv[0]*xv[0] + xv[1]*xv[1] + xv[2]*xv[2] + xv[3]*xv[3]);
  float sc = rsqrtf(ss * (1.0f / kD) + 1e-5f);
  f32x4 vv = xv * sc;
  u16x4 a, b;
  #pragma unroll
  for (int j = 0; j < 4; ++j) {
    u16 h, m; split2s(vv[j], h, m);
    a[j] = h; b[j] = m;
  }
  ((u16x4*)xnP)[o] = a;
  ((u16x4*)(xnP + xplane))[o] = b;
}

// x += moe combine (4 K-partials, 2 experts); write x; rmsnorm -> 2 fp16 planes
__global__ __launch_bounds__(256) void moe4_rms2h_k(float* __restrict__ x,
    const float* __restrict__ outsP, long plane, const int* __restrict__ slotOf,
    const float* __restrict__ top2w, u16* __restrict__ xnP, long xplane) {
  int tok = blockIdx.x, t = threadIdx.x;
  int s0 = slotOf[tok*2], s1 = slotOf[tok*2+1];
  float w0 = top2w[tok*2], w1 = top2w[tok*2+1];
  f32x4 a = {0.f,0.f,0.f,0.f}, b = a;
  #pragma unroll
  for (int p = 0; p < 4; ++p) {
    a += ((const f32x4*)(outsP + p * plane + (long)s0 * kD))[t];
    b += ((const f32x4*)(outsP + p * plane + (long)s1 * kD))[t];
  }
  long o = (long)tok * (kD / 4) + t;
  f32x4 xv = ((f32x4*)x)[o];
  xv += a * w0 + b * w1;
  ((f32x4*)x)[o] = xv;
  float ss = blockReduceSum256(xv[0]*xv[0] + xv[1]*xv[1] + xv[2]*xv[2] + xv[3]*xv[3]);
  float sc = rsqrtf(ss * (1.0f / kD) + 1e-5f);
  f32x4 vv = xv * sc;
  u16x4 ha, hb;
  #pragma unroll
  for (int j = 0; j < 4; ++j) {
    u16 h, m; split2s(vv[j], h, m);
    ha[j] = h; hb[j] = m;
  }
  ((u16x4*)xnP)[o] = ha;
  ((u16x4*)(xnP + xplane))[o] = hb;
}

// last layer: x += moe combine; write f16 (unscaled) plane for lm_head
__global__ __launch_bounds__(256) void moe4_cast_h_k(float* __restrict__ x,
    const float* __restrict__ outsP, long plane, const int* __restrict__ slotOf,
    const float* __restrict__ top2w, u16* __restrict__ xn) {
  int tok = blockIdx.x, t = threadIdx.x;
  int s0 = slotOf[tok*2], s1 = slotOf[tok*2+1];
  float w0 = top2w[tok*2], w1 = top2w[tok*2+1];
  f32x4 a = {0.f,0.f,0.f,0.f}, b = a;
  #pragma unroll
  for (int p = 0; p < 4; ++p) {
    a += ((const f32x4*)(outsP + p * plane + (long)s0 * kD))[t];
    b += ((const f32x4*)(outsP + p * plane + (long)s1 * kD))[t];
  }
  long o = (long)tok * (kD / 4) + t;
  f32x4 xv = ((f32x4*)x)[o];
  xv += a * w0 + b * w1;
  u16x4 hv;
  #pragma unroll
  for (int j = 0; j < 4; ++j) hv[j] = f2h(xv[j]);
  ((u16x4*)xn)[o] = hv;
}

// gating in f32 (bf16 would flip top-2 selections on near-ties)
__global__ __launch_bounds__(256) void gate_topk_k(const float* __restrict__ x,
    const float* __restrict__ gate_l, float* __restrict__ probs, int* __restrict__ top2e,
    float* __restrict__ top2w, int* __restrict__ counts) {
  int tok = blockIdx.x, t = threadIdx.x;
  f32x4 xv = ((const f32x4*)(x + (long)tok * kD))[t];
  float ss = blockReduceSum256(xv[0]*xv[0] + xv[1]*xv[1] + xv[2]*xv[2] + xv[3]*xv[3]);
  float sc = rsqrtf(ss * (1.0f / kD) + 1e-5f);
  float a[kE];
  #pragma unroll
  for (int e = 0; e < kE; ++e) {
    f32x4 gv = ((const f32x4*)(gate_l + (long)e * kD))[t];
    a[e] = xv[0]*gv[0] + xv[1]*gv[1] + xv[2]*gv[2] + xv[3]*gv[3];
  }
  __shared__ float sh8[kE][4];
  int w = t >> 6, l = t & 63;
  #pragma unroll
  for (int e = 0; e < kE; ++e) {
    float v = a[e];
    #pragma unroll
    for (int m = 32; m >= 1; m >>= 1) v += __shfl_xor(v, m);
    if (l == 0) sh8[e][w] = v;
  }
  __syncthreads();
  if (t == 0) {
    float lg[kE], mx = -1e30f;
    #pragma unroll
    for (int e = 0; e < kE; ++e) {
      lg[e] = (sh8[e][0] + sh8[e][1] + sh8[e][2] + sh8[e][3]) * sc;
      mx = fmaxf(mx, lg[e]);
    }
    float pe[kE], s = 0.f;
    #pragma unroll
    for (int e = 0; e < kE; ++e) { pe[e] = __expf(lg[e] - mx); s += pe[e]; }
    float inv = 1.f / s;
    int i1 = 0;
    #pragma unroll
    for (int e = 1; e < kE; ++e) if (lg[e] > lg[i1]) i1 = e;
    int i2 = (i1 == 0) ? 1 : 0;
    #pragma unroll
    for (int e = 0; e < kE; ++e) if (e != i1 && lg[e] > lg[i2]) i2 = e;
    #pragma unroll
    for (int e = 0; e < kE; ++e) probs[(long)tok * kE + e] = pe[e] * inv;
    float p1 = pe[i1] * inv, p2 = pe[i2] * inv;
    float wn = p1 + p2;
    top2e[tok*2] = i1; top2e[tok*2+1] = i2;
    top2w[tok*2] = p1 / wn; top2w[tok*2+1] = p2 / wn;
    atomicAdd(&counts[i1], 1); atomicAdd(&counts[i2], 1);
  }
}

// 128-aligned expert offsets
__global__ void calc_offsets_k(const int* __restrict__ counts, int* __restrict__ offsets) {
  if (threadIdx.x == 0) {
    int o = 0;
    #pragma unroll
    for (int e = 0; e < kE; ++e) { offsets[e] = o; o += (counts[e] + 127) & ~127; }
    offsets[kE] = o;
  }
}

__global__ __launch_bounds__(256) void fill_slots_k(const int* __restrict__ top2e,
    const int* __restrict__ offsets, int* __restrict__ cursors,
    int* __restrict__ rows, int* __restrict__ slotOf) {
  int tok = blockIdx.x * 256 + threadIdx.x;
  if (tok >= kBT) return;
  #pragma unroll
  for (int j = 0; j < 2; ++j) {
    int e = top2e[tok*2 + j];
    int pos = atomicAdd(&cursors[e], 1);
    int slot = offsets[e] + pos;
    rows[slot] = tok;
    slotOf[tok*2 + j] = slot;
  }
}

// fallback combine (4 partials; unused planes zeroed)
__global__ __launch_bounds__(256) void moe_combine4_k(float* __restrict__ x,
    const float* __restrict__ outsP, long plane, const int* __restrict__ slotOf,
    const float* __restrict__ top2w) {
  int tok = blockIdx.x, t = threadIdx.x;
  int s0 = slotOf[tok*2], s1 = slotOf[tok*2+1];
  float w0 = top2w[tok*2], w1 = top2w[tok*2+1];
  f32x4 a = {0.f,0.f,0.f,0.f}, b = a;
  #pragma unroll
  for (int p = 0; p < 4; ++p) {
    a += ((const f32x4*)(outsP + p * plane + (long)s0 * kD))[t];
    b += ((const f32x4*)(outsP + p * plane + (long)s1 * kD))[t];
  }
  f32x4 xv = ((f32x4*)(x + (long)tok * kD))[t];
  xv += a * w0 + b * w1;
  ((f32x4*)(x + (long)tok * kD))[t] = xv;
}

__global__ __launch_bounds__(256) void aux_reduce_k(const float* __restrict__ probs,
                                                    float* __restrict__ aux) {
  int t = threadIdx.x;
  float part[kE] = {};
  for (int i = t; i < kBT; i += 256) {
    #pragma unroll
    for (int e = 0; e < kE; ++e) part[e] += probs[(long)i * kE + e];
  }
  __shared__ float sh8[kE][4];
  int w = t >> 6, l = t & 63;
  #pragma unroll
  for (int e = 0; e < kE; ++e) {
    float v = part[e];
    #pragma unroll
    for (int m = 32; m >= 1; m >>= 1) v += __shfl_xor(v, m);
    if (l == 0) sh8[e][w] = v;
  }
  __syncthreads();
  if (t == 0) {
    float acc = 0.f;
    #pragma unroll
    for (int e = 0; e < kE; ++e) {
      float frac = (sh8[e][0] + sh8[e][1] + sh8[e][2] + sh8[e][3]) * (1.0f / kBT);
      acc += frac * frac;
    }
    aux[0] += (float)kE * acc;
  }
}

__global__ void write_aux_k(const float* __restrict__ aux, float* __restrict__ out) {
  if (threadIdx.x == 0) out[0] = 0.01f * aux[0] / (float)kL;
}

enum { P_BF16 = 0, P_BF16_RELU = 1, P_F32 = 2, P_F32_RESID = 3, P_F32_RELU = 4,
       P_SPLIT2_RELU = 5, P_F16_RELU = 6 };

__device__ __forceinline__ int clamp_row(int rv) {
  return ((unsigned)rv < (unsigned)kBT) ? rv : 0;
}

template <bool MPART>
__device__ __forceinline__ void block_mn(int lin, int base, int mArg, int& mb, int& nb) {
  int xcd = lin & 7, c = lin >> 3;
  if (MPART) {
    mb = xcd * mArg + (c % mArg);
    nb = c / mArg;
  } else {
    int swz = xcd * (base >> 3) + c;
    mb = swz % mArg;
    nb = swz / mArg;
  }
}

// ------- fused fp16 split-2 MFMA GEMM (128x128, 256 thr), single accumulator -------

template <int POST, bool GATHER, bool EXPERT, bool MPART>
__global__ __launch_bounds__(256) void gemm2h_bt_k(
    const u16* __restrict__ A0, long planeA,
    const u16* __restrict__ B0, long planeB,
    void* __restrict__ C, long planeC,
    const float* __restrict__ resid,
    const int* __restrict__ rows, const int* __restrict__ offsets,
    int N, int K, int lda, long eBstride, int mArg,
    int kParts, int base, long cPart) {
  constexpr int BM = 128, BK = 32;
  int part = blockIdx.x / base;
  int lin = blockIdx.x % base;
  int mb, nb;
  block_mn<MPART>(lin, base, mArg, mb, nb);
  int m0 = mb * BM, n0 = nb * BM;
  if (EXPERT) {
    int total = offsets[kE];
    if (m0 >= total) return;
    int e = 0;
    while (offsets[e + 1] <= m0) ++e;
    B0 += (long)e * eBstride;
  }
  __shared__ __align__(16) u16 Ac[BM][64];
  __shared__ __align__(16) u16 Bc[BM][64];
  int t = threadIdx.x;
  int l = t & 63, lr = l & 15, lg = l >> 4;
  int wid = t >> 6;
  int wm = (wid >> 1) * 64, wn = (wid & 1) * 64;

  long asrc[4], bsrc[4];
  int ldst[4];
  #pragma unroll
  for (int it = 0; it < 4; ++it) {
    int d = it * 256 + t;
    int row = d >> 3, pc = d & 7;
    int lc = pc ^ (row & 7);
    int p = lc >> 2, c = lc & 3;
    int grow = GATHER ? clamp_row(rows[m0 + row]) : (m0 + row);
    asrc[it] = (long)p * planeA + (long)grow * lda + c * 8;
    bsrc[it] = (long)p * planeB + (long)(n0 + row) * K + c * 8;
    ldst[it] = (it * 256 + (t & ~63)) * 8;
  }
  int sa = lr & 7;
  int cH = (lg ^ sa) * 8;
  int cM = ((4 + lg) ^ sa) * 8;

  f32x4 acc[4][4];
  #pragma unroll
  for (int i = 0; i < 4; ++i)
    #pragma unroll
    for (int j = 0; j < 4; ++j) acc[i][j] = 0.f;

  int kStep = K / kParts;
  int kLo = part * kStep, kHi = kLo + kStep;
  for (int k0 = kLo; k0 < kHi; k0 += BK) {
    #pragma unroll
    for (int it = 0; it < 4; ++it) {
      ld_lds16(A0 + asrc[it] + k0, &Ac[0][0] + ldst[it]);
      ld_lds16(B0 + bsrc[it] + k0, &Bc[0][0] + ldst[it]);
    }
    __syncthreads();
    f16x8 ah[4], am[4];
    #pragma unroll
    for (int i = 0; i < 4; ++i) {
      ah[i] = *(const f16x8*)&Ac[wm + i*16 + lr][cH];
      am[i] = *(const f16x8*)&Ac[wm + i*16 + lr][cM];
    }
    #pragma unroll
    for (int j = 0; j < 4; ++j) {
      f16x8 bh = *(const f16x8*)&Bc[wn + j*16 + lr][cH];
      f16x8 bm = *(const f16x8*)&Bc[wn + j*16 + lr][cM];
      #pragma unroll
      for (int i = 0; i < 4; ++i) {
        acc[i][j] = MFMAH(ah[i], bh, acc[i][j]);
        acc[i][j] = MFMAH(am[i], bh, acc[i][j]);
        acc[i][j] = MFMAH(ah[i], bm, acc[i][j]);
      }
    }
    __syncthreads();
  }
  float* Cf = (float*)C + (long)part * cPart;
  #pragma unroll
  for (int i = 0; i < 4; ++i) {
    #pragma unroll
    for (int r = 0; r < 4; ++r) {
      long m = m0 + wm + i*16 + lg*4 + r;
      #pragma unroll
      for (int j = 0; j < 4; ++j) {
        int n = n0 + wn + j*16 + lr;
        float val = acc[i][j][r] * (1.0f / 4096.0f);
        if (POST == P_F32) {
          Cf[m * N + n] = val;
        } else if (POST == P_F32_RESID) {
          ((float*)C)[m * N + n] = val + resid[m * N + n];
        } else if (POST == P_SPLIT2_RELU) {
          val = fmaxf(val, 0.f);
          u16 h, mm; split2s(val, h, mm);
          u16* Cp = (u16*)C;
          Cp[m * N + n] = h;
          Cp[planeC + m * N + n] = mm;
        }
      }
    }
  }
}

// ------- wide fused fp16 split-2 GEMM: 128x256 tile, 512 threads, 2m x 4n waves -------
// optional split-K: grid = kParts*base; P_F32 part p writes C + p*cPart.

template <int POST, bool GATHER, bool EXPERT>
__global__ __launch_bounds__(512) void gemm2hW_bt_k(
    const u16* __restrict__ A0, long planeA,
    const u16* __restrict__ B0, long planeB,
    void* __restrict__ C, long planeC,
    const int* __restrict__ rows, const int* __restrict__ offsets,
    int N, int K, int lda, long eBstride, int mPerX,
    int kParts, int base, long cPart) {
  constexpr int BM = 128, BN = 256, BK = 32;
  int part = blockIdx.x / base;
  int lin = blockIdx.x % base;
  int xcd = lin & 7, c0 = lin >> 3;
  int m0 = (xcd * mPerX + (c0 % mPerX)) * BM;
  int n0 = (c0 / mPerX) * BN;
  if (EXPERT) {
    int total = offsets[kE];
    if (m0 >= total) return;
    int e = 0;
    while (offsets[e + 1] <= m0) ++e;
    B0 += (long)e * eBstride;
  }
  __shared__ __align__(16) u16 Ac[BM][64];
  __shared__ __align__(16) u16 Bc[BN][64];
  int t = threadIdx.x;
  int l = t & 63, lr = l & 15, lg = l >> 4;
  int wid = t >> 6;
  int wm = (wid >> 2) * 64;
  int wn = (wid & 3) * 64;

  long asrc[2], bsrc[4];
  int aldst[2], bldst[4];
  #pragma unroll
  for (int it = 0; it < 2; ++it) {
    int d = it * 512 + t;
    int row = d >> 3, pc = d & 7;
    int lc = pc ^ (row & 7);
    int p = lc >> 2, cc = lc & 3;
    int grow = GATHER ? clamp_row(rows[m0 + row]) : (m0 + row);
    asrc[it] = (long)p * planeA + (long)grow * lda + cc * 8;
    aldst[it] = (it * 512 + (t & ~63)) * 8;
  }
  #pragma unroll
  for (int it = 0; it < 4; ++it) {
    int d = it * 512 + t;
    int row = d >> 3, pc = d & 7;
    int lc = pc ^ (row & 7);
    int p = lc >> 2, cc = lc & 3;
    bsrc[it] = (long)p * planeB + (long)(n0 + row) * K + cc * 8;
    bldst[it] = (it * 512 + (t & ~63)) * 8;
  }
  int sa = lr & 7;
  int cH = (lg ^ sa) * 8;
  int cM = ((4 + lg) ^ sa) * 8;

  f32x4 acc[4][4];
  #pragma unroll
  for (int i = 0; i < 4; ++i)
    #pragma unroll
    for (int j = 0; j < 4; ++j) acc[i][j] = 0.f;

  int kStep = K / kParts;
  int kLo = part * kStep, kHi = kLo + kStep;
  for (int k0 = kLo; k0 < kHi; k0 += BK) {
    #pragma unroll
    for (int it = 0; it < 2; ++it)
      ld_lds16(A0 + asrc[it] + k0, &Ac[0][0] + aldst[it]);
    #pragma unroll
    for (int it = 0; it < 4; ++it)
      ld_lds16(B0 + bsrc[it] + k0, &Bc[0][0] + bldst[it]);
    __syncthreads();
    f16x8 ah[4], am[4];
    #pragma unroll
    for (int i = 0; i < 4; ++i) {
      ah[i] = *(const f16x8*)&Ac[wm + i*16 + lr][cH];
      am[i] = *(const f16x8*)&Ac[wm + i*16 + lr][cM];
    }
    #pragma unroll
    for (int j = 0; j < 4; ++j) {
      f16x8 bh = *(const f16x8*)&Bc[wn + j*16 + lr][cH];
      f16x8 bm = *(const f16x8*)&Bc[wn + j*16 + lr][cM];
      #pragma unroll
      for (int i = 0; i < 4; ++i) {
        acc[i][j] = MFMAH(ah[i], bh, acc[i][j]);
        acc[i][j] = MFMAH(am[i], bh, acc[i][j]);
        acc[i][j] = MFMAH(ah[i], bm, acc[i][j]);
      }
    }
    __syncthreads();
  }
  float* Cf = (float*)C + (long)part * cPart;
  #pragma unroll
  for (int i = 0; i < 4; ++i) {
    #pragma unroll
    for (int r = 0; r < 4; ++r) {
      long m = m0 + wm + i*16 + lg*4 + r;
      #pragma unroll
      for (int j = 0; j < 4; ++j) {
        int n = n0 + wn + j*16 + lr;
        float val = acc[i][j][r] * (1.0f / 4096.0f);
        if (POST == P_F32) {
          Cf[m * N + n] = val;
        } else if (POST == P_SPLIT2_RELU) {
          val = fmaxf(val, 0.f);
          u16 h, mm; split2s(val, h, mm);
          u16* Cp = (u16*)C;
          Cp[m * N + n] = h;
          Cp[planeC + m * N + n] = mm;
        }
      }
    }
  }
}

// ---------------- single-plane MFMA GEMM (with optional split-K) ----------------

template <int POST, bool EXPERT, bool GATHER, bool HALF, bool BCONV, bool MPART>
__global__ __launch_bounds__(256) void gemm_bt_k(
    const u16* __restrict__ A, const void* __restrict__ Bv, void* __restrict__ C,
    const int* __restrict__ rows, const int* __restrict__ offsets,
    int N, int K, int lda, long eBstride, float oscale, int mArg,
    int kParts, int base, long cPart) {
  constexpr int BM = 128, BK = 64;
  int part = blockIdx.x / base;
  int lin = blockIdx.x % base;
  int mb, nb;
  block_mn<MPART>(lin, base, mArg, mb, nb);
  int m0 = mb * BM, n0 = nb * BM;
  const float* Bf = (const float*)Bv;
  const u16*   Bh = (const u16*)Bv;
  if (EXPERT) {
    int total = offsets[kE];
    if (m0 >= total) return;
    int e = 0;
    while (offsets[e + 1] <= m0) ++e;
    if (BCONV) Bf += (long)e * eBstride; else Bh += (long)e * eBstride;
  }
  __shared__ __align__(16) u16 As[BM][BK];
  __shared__ __align__(16) u16 Bs[BM][BK + (BCONV ? 8 : 0)];
  int t = threadIdx.x;
  int l = t & 63, lr = l & 15, lg = l >> 4;
  int wid = t >> 6;
  int wm = (wid >> 1) * 64, wn = (wid & 1) * 64;

  long asrc[4], bsrc[4];
  int ldst[4];
  #pragma unroll
  for (int it = 0; it < 4; ++it) {
    int d = it * 256 + t;
    int row = d >> 3, pc = d & 7;
    int c = pc ^ (row & 7);
    int grow = GATHER ? clamp_row(rows[m0 + row]) : (m0 + row);
    asrc[it] = (long)grow * lda + c * 8;
    bsrc[it] = (long)(n0 + row) * K + c * 8;
    ldst[it] = (it * 256 + (t & ~63)) * 8;
  }
  f32x4 acc[4][4];
  #pragma unroll
  for (int i = 0; i < 4; ++i)
    #pragma unroll
    for (int j = 0; j < 4; ++j) acc[i][j] = 0.f;

  int kStep = K / kParts;
  int kLo = part * kStep, kHi = kLo + kStep;
  for (int k0 = kLo; k0 < kHi; k0 += BK) {
    #pragma unroll
    for (int it = 0; it < 4; ++it)
      ld_lds16(A + asrc[it] + k0, &As[0][0] + ldst[it]);
    if (!BCONV) {
      #pragma unroll
      for (int it = 0; it < 4; ++it)
        ld_lds16(Bh + bsrc[it] + k0, &Bs[0][0] + ldst[it]);
    } else {
      #pragma unroll
      for (int it = 0; it < 8; ++it) {
        int c = it * 256 + t;
        int row = c >> 4, col = (c & 15) * 4;
        f32x4 v = *(const f32x4*)(Bf + (long)(n0 + row) * K + k0 + col);
        u16x4 o;
        #pragma unroll
        for (int j = 0; j < 4; ++j) o[j] = HALF ? f2h(v[j]) : f2bf(v[j]);
        *(u16x4*)&Bs[row][col] = o;
      }
    }
    __syncthreads();
    #pragma unroll
    for (int kk = 0; kk < 2; ++kk) {
      int ca = ((kk * 4 + lg) ^ (lr & 7)) * 8;
      int cb = BCONV ? (kk * 32 + lg * 8) : ca;
      #pragma unroll
      for (int i = 0; i < 4; ++i)
        #pragma unroll
        for (int j = 0; j < 4; ++j) {
          if (HALF) {
            f16x8 af = *(const f16x8*)&As[wm + i*16 + lr][ca];
            f16x8 bq = *(const f16x8*)&Bs[wn + j*16 + lr][cb];
            acc[i][j] = MFMAH(af, bq, acc[i][j]);
          } else {
            bf16x8 af = *(const bf16x8*)&As[wm + i*16 + lr][ca];
            bf16x8 bq = *(const bf16x8*)&Bs[wn + j*16 + lr][cb];
            acc[i][j] = MFMA16(af, bq, acc[i][j]);
          }
        }
    }
    __syncthreads();
  }
  #pragma unroll
  for (int i = 0; i < 4; ++i) {
    #pragma unroll
    for (int r = 0; r < 4; ++r) {
      long m = m0 + wm + i*16 + lg*4 + r;
      #pragma unroll
      for (int j = 0; j < 4; ++j) {
        int n = n0 + wn + j*16 + lr;
        float val = acc[i][j][r] * oscale;
        if (POST == P_BF16_RELU)       ((u16*)C)[m * N + n] = f2bf(fmaxf(val, 0.f));
        else if (POST == P_F16_RELU)   ((u16*)C)[m * N + n] = f2h(fmaxf(val, 0.f));
        else if (POST == P_F32)        ((float*)C + (long)part * cPart)[m * N + n] = val;
      }
    }
  }
}

// ---------------- f32 SGEMM (fallback path only) ----------------

template <int POST, bool GATHER, bool EXPERT>
__global__ __launch_bounds__(256) void sgemm_bt_k(
    const float* __restrict__ A, const float* __restrict__ B, float* __restrict__ C,
    const float* __restrict__ resid, const int* __restrict__ rows,
    const int* __restrict__ offsets, int N, int K, int lda, long eBstride) {
  constexpr int BM = 128, BN = 128, BK = 32;
  int m0 = blockIdx.x * BM, n0 = blockIdx.y * BN;
  if (EXPERT) {
    int total = offsets[kE];
    if (m0 >= total) return;
    int e = 0;
    while (offsets[e + 1] <= m0) ++e;
    B += (long)e * eBstride;
  }
  __shared__ float Ast[BK][BM];
  __shared__ float Bst[BK][BN];
  int t = threadIdx.x, tx = t & 15, ty = t >> 4;
  long asrc[4], bsrc[4];
  #pragma unroll
  for (int it = 0; it < 4; ++it) {
    int c = it * 256 + t;
    int row = c >> 3, kc = (c & 7) * 4;
    int gr = GATHER ? clamp_row(rows[m0 + row]) : (m0 + row);
    asrc[it] = (long)gr * lda + kc;
    bsrc[it] = (long)(n0 + row) * K + kc;
  }
  f32x4 accv[8][2];
  #pragma unroll
  for (int i = 0; i < 8; ++i) { accv[i][0] = 0.f; accv[i][1] = 0.f; }

  for (int k0 = 0; k0 < K; k0 += BK) {
    #pragma unroll
    for (int it = 0; it < 4; ++it) {
      int c = it * 256 + t;
      int row = c >> 3, kc = (c & 7) * 4;
      f32x4 av = *(const f32x4*)(A + asrc[it] + k0);
      f32x4 bv = *(const f32x4*)(B + bsrc[it] + k0);
      #pragma unroll
      for (int j = 0; j < 4; ++j) { Ast[kc + j][row] = av[j]; Bst[kc + j][row] = bv[j]; }
    }
    __syncthreads();
    #pragma unroll
    for (int kk = 0; kk < BK; ++kk) {
      f32x4 a0 = *(const f32x4*)&Ast[kk][ty * 4];
      f32x4 a1 = *(const f32x4*)&Ast[kk][64 + ty * 4];
      f32x4 b0 = *(const f32x4*)&Bst[kk][tx * 4];
      f32x4 b1 = *(const f32x4*)&Bst[kk][64 + tx * 4];
      float as[8] = {a0[0], a0[1], a0[2], a0[3], a1[0], a1[1], a1[2], a1[3]};
      #pragma unroll
      for (int i = 0; i < 8; ++i) {
        accv[i][0] += b0 * as[i];
        accv[i][1] += b1 * as[i];
      }
    }
    __syncthreads();
  }
  #pragma unroll
  for (int ih = 0; ih < 2; ++ih)
    #pragma unroll
    for (int i = 0; i < 4; ++i) {
      long m = m0 + ih * 64 + ty * 4 + i;
      #pragma unroll
      for (int jh = 0; jh < 2; ++jh) {
        long n = n0 + jh * 64 + tx * 4;
        f32x4 val = accv[ih * 4 + i][jh];
        if (POST == P_F32_RELU) {
          #pragma unroll
          for (int j = 0; j < 4; ++j) val[j] = fmaxf(val[j], 0.f);
        }
        if (POST == P_F32_RESID) val += *(const f32x4*)&resid[m * N + n];
        *(f32x4*)&C[m * N + n] = val;
      }
    }
}

// ------- MFMA split-2 attention (f32-equivalent accuracy) -------

__global__ __launch_bounds__(256) void attn2h_k(
    const u16* __restrict__ qkvP, long qplane,
    u16* __restrict__ oP, long oplane) {
  int qt = blockIdx.x;                 // 0..15
  int bh = blockIdx.y;                 // 0..31
  int b = bh >> 4, h = bh & 15;
  const int ldq = 3 * kD;
  long hbq = (long)b * kT * ldq + h * kHD;
  long hbo = (long)b * kT * kD + h * kHD;
  int t = threadIdx.x, w = t >> 6, l = t & 63;
  int lr = l & 15, lg = l >> 4;

  __shared__ __align__(16) u16 Ks[2][64][72];
  __shared__ __align__(16) u16 Vt[2][64][72];
  __shared__ __align__(16) u16 Ps[2][4][16][72];

  f16x8 qf0[2], qf1[2];
  {
    long qrow = qt * 64 + w * 16 + lr;
    const u16* qp = qkvP + hbq + qrow * ldq;
    #pragma unroll
    for (int kc = 0; kc < 2; ++kc) {
      qf0[kc] = *(const f16x8*)(qp + kc * 32 + lg * 8);
      qf1[kc] = *(const f16x8*)(qp + qplane + kc * 32 + lg * 8);
    }
  }
  int qg = qt * 64 + w * 16 + lg * 4;

  float mrow[4], lsum[4];
  f32x4 accO[4];
  #pragma unroll
  for (int r = 0; r < 4; ++r) { mrow[r] = -1e30f; lsum[r] = 0.f; }
  #pragma unroll
  for (int j = 0; j < 4; ++j) accO[j] = 0.f;

  for (int it = 0; it <= qt; ++it) {
    #pragma unroll
    for (int p = 0; p < 2; ++p) {
      #pragma unroll
      for (int s = 0; s < 2; ++s) {
        int c = s * 256 + t;
        int row = c >> 3, col = (c & 7) * 8;
        long gi = (long)p * qplane + hbq + (long)(it * 64 + row) * ldq + col;
        *(u16x8*)&Ks[p][row][col] = *(const u16x8*)(qkvP + kD + gi);
        u16x8 vv = *(const u16x8*)(qkvP + 2 * kD + gi);
        #pragma unroll
        for (int j = 0; j < 8; ++j) Vt[p][col + j][row] = vv[j];
      }
    }
    __syncthreads();

    f32x4 s4[4];
    #pragma unroll
    for (int j = 0; j < 4; ++j) {
      f32x4 z = {0.f, 0.f, 0.f, 0.f};
      #pragma unroll
      for (int kc = 0; kc < 2; ++kc) {
        f16x8 kh = *(const f16x8*)&Ks[0][j*16 + lr][kc*32 + lg*8];
        f16x8 km = *(const f16x8*)&Ks[1][j*16 + lr][kc*32 + lg*8];
        z = MFMAH(qf0[kc], kh, z);
        z = MFMAH(qf1[kc], kh, z);
        z = MFMAH(qf0[kc], km, z);
      }
      s4[j] = z;
    }
    #pragma unroll
    for (int j = 0; j < 4; ++j)
      #pragma unroll
      for (int r = 0; r < 4; ++r) {
        float sv = s4[j][r] * (0.125f / 4096.0f);
        if (it * 64 + j * 16 + lr > qg + r) sv = -1e30f;
        s4[j][r] = sv;
      }
    float alpha[4];
    #pragma unroll
    for (int r = 0; r < 4; ++r) {
      float mx = fmaxf(fmaxf(s4[0][r], s4[1][r]), fmaxf(s4[2][r], s4[3][r]));
      mx = fmaxf(mx, __shfl_xor(mx, 1));
      mx = fmaxf(mx, __shfl_xor(mx, 2));
      mx = fmaxf(mx, __shfl_xor(mx, 4));
      mx = fmaxf(mx, __shfl_xor(mx, 8));
      float mi = fmaxf(mrow[r], mx);
      alpha[r] = __expf(mrow[r] - mi);
      mrow[r] = mi;
    }
    float rs[4] = {0.f, 0.f, 0.f, 0.f};
    #pragma unroll
    for (int j = 0; j < 4; ++j)
      #pragma unroll
      for (int r = 0; r < 4; ++r) {
        float p = __expf(s4[j][r] - mrow[r]);
        rs[r] += p;
        u16 hh, mm; split2s(p, hh, mm);
        Ps[0][w][lg*4 + r][j*16 + lr] = hh;
        Ps[1][w][lg*4 + r][j*16 + lr] = mm;
      }
    #pragma unroll
    for (int r = 0; r < 4; ++r) {
      float x2 = rs[r];
      x2 += __shfl_xor(x2, 1);
      x2 += __shfl_xor(x2, 2);
      x2 += __shfl_xor(x2, 4);
      x2 += __shfl_xor(x2, 8);
      lsum[r] = lsum[r] * alpha[r] + x2;
    }
    #pragma unroll
    for (int j = 0; j < 4; ++j)
      #pragma unroll
      for (int r = 0; r < 4; ++r) accO[j][r] *= alpha[r];
    __syncthreads();

    f16x8 ph[2], pm[2];
    #pragma unroll
    for (int kc = 0; kc < 2; ++kc) {
      ph[kc] = *(const f16x8*)&Ps[0][w][lr][kc*32 + lg*8];
      pm[kc] = *(const f16x8*)&Ps[1][w][lr][kc*32 + lg*8];
    }
    #pragma unroll
    for (int j2 = 0; j2 < 4; ++j2) {
      #pragma unroll
      for (int kc = 0; kc < 2; ++kc) {
        f16x8 vh = *(const f16x8*)&Vt[0][j2*16 + lr][kc*32 + lg*8];
        f16x8 vm = *(const f16x8*)&Vt[1][j2*16 + lr][kc*32 + lg*8];
        accO[j2] = MFMAH(ph[kc], vh, accO[j2]);
        accO[j2] = MFMAH(pm[kc], vh, accO[j2]);
        accO[j2] = MFMAH(ph[kc], vm, accO[j2]);
      }
    }
    __syncthreads();
  }
  #pragma unroll
  for (int j2 = 0; j2 < 4; ++j2)
    #pragma unroll
    for (int r = 0; r < 4; ++r) {
      float ov = accO[j2][r] * (1.0f / 4096.0f) / lsum[r];
      long row = qt * 64 + w * 16 + lg * 4 + r;
      long idx = hbo + row * kD + j2 * 16 + lr;
      u16 hh, mm; split2s(ov, hh, mm);
      oP[idx] = hh;
      oP[oplane + idx] = mm;
    }
}

// ---------------- f32 attention (fallback path) ----------------

__global__ __launch_bounds__(256) void attn_f32_k(
    const float* __restrict__ qkv, float* __restrict__ of32, int ldq) {
  int qt = blockIdx.x;
  int bh = blockIdx.y;
  int b = bh >> 4, h = bh & 15;
  long hbq = (long)b * kT * ldq + h * kHD;
  long hbo = (long)b * kT * kD + h * kHD;
  int t = threadIdx.x, qr = t >> 2, sub = t & 3;

  __shared__ float Qs[64][68], Ks[64][68], Vs[64][68], Ps[64][68];

  const float* q = qkv;
  const float* k = qkv + kD;
  const float* v = qkv + 2 * kD;

  #pragma unroll
  for (int it = 0; it < 4; ++it) {
    int c = it * 256 + t, row = c >> 4, c4 = (c & 15) * 4;
    f32x4 qv = *(const f32x4*)(q + hbq + (long)(qt * 64 + row) * ldq + c4);
    #pragma unroll
    for (int j = 0; j < 4; ++j) Qs[row][c4 + j] = qv[j];
  }
  __syncthreads();
  f32x4 qreg[16];
  #pragma unroll
  for (int d4 = 0; d4 < 16; ++d4) qreg[d4] = *(const f32x4*)&Qs[qr][d4 * 4];
  int qg = qt * 64 + qr;

  float mrow = -1e30f, lsum = 0.f;
  f32x4 accO[4];
  #pragma unroll
  for (int i = 0; i < 4; ++i) accO[i] = 0.f;

  for (int itl = 0; itl <= qt; ++itl) {
    #pragma unroll
    for (int it = 0; it < 4; ++it) {
      int c = it * 256 + t, row = c >> 4, c4 = (c & 15) * 4;
      long gi = hbq + (long)(itl * 64 + row) * ldq + c4;
      f32x4 kv = *(const f32x4*)(k + gi);
      f32x4 vv = *(const f32x4*)(v + gi);
      #pragma unroll
      for (int j = 0; j < 4; ++j) { Ks[row][c4 + j] = kv[j]; Vs[row][c4 + j] = vv[j]; }
    }
    __syncthreads();

    float s[16];
    #pragma unroll
    for (int kk = 0; kk < 16; ++kk) {
      int key = kk * 4 + sub;
      f32x4 a = {0.f, 0.f, 0.f, 0.f};
      #pragma unroll
      for (int d4 = 0; d4 < 16; ++d4) a += qreg[d4] * *(const f32x4*)&Ks[key][d4 * 4];
      float sv = (a[0] + a[1] + a[2] + a[3]) * 0.125f;
      if (itl * 64 + key > qg) sv = -1e30f;
      s[kk] = sv;
    }
    float mx = s[0];
    #pragma unroll
    for (int kk = 1; kk < 16; ++kk) mx = fmaxf(mx, s[kk]);
    mx = fmaxf(mx, __shfl_xor(mx, 1));
    mx = fmaxf(mx, __shfl_xor(mx, 2));
    float mi = fmaxf(mrow, mx);
    float alpha = __expf(mrow - mi);
    mrow = mi;
    float rs = 0.f;
    #pragma unroll
    for (int kk = 0; kk < 16; ++kk) {
      float p = __expf(s[kk] - mi);
      rs += p;
      Ps[qr][kk * 4 + sub] = p;
    }
    rs += __shfl_xor(rs, 1);
    rs += __shfl_xor(rs, 2);
    lsum = lsum * alpha + rs;
    #pragma unroll
    for (int i = 0; i < 4; ++i) accO[i] *= alpha;
    #pragma unroll
    for (int key2 = 0; key2 < 64; ++key2) {
      float p = Ps[qr][key2];
      #pragma unroll
      for (int i4 = 0; i4 < 4; ++i4)
        accO[i4] += p * *(const f32x4*)&Vs[key2][sub * 16 + i4 * 4];
    }
    __syncthreads();
  }
  float inv = 1.f / lsum;
  #pragma unroll
  for (int i4 = 0; i4 < 4; ++i4) {
    f32x4 ov = accO[i4] * inv;
    *(f32x4*)(of32 + hbo + (long)qg * kD + sub * 16 + i4 * 4) = ov;
  }
}

// ---------------- host ----------------

extern "C" void kernel_launch(void* const* d_in, const int* in_sizes, int n_in,
                              void* d_out, int out_size, void* d_ws, size_t ws_size,
                              hipStream_t stream) {
  const int*   idx  = (const int*)  d_in[0];
  const float* wte  = (const float*)d_in[1];
  const float* wpe  = (const float*)d_in[2];
  const float* wq   = (const float*)d_in[3];
  const float* wk   = (const float*)d_in[4];
  const float* wv   = (const float*)d_in[5];
  const float* wo   = (const float*)d_in[6];
  const float* gate = (const float*)d_in[7];
  const float* f1   = (const float*)d_in[8];
  const float* f2   = (const float*)d_in[9];
  const float* lmh  = (const float*)d_in[10];
  float* out = (float*)d_out;

  char* ws = (char*)d_ws;
  size_t off = 0;
  auto alloc = [&](size_t b) -> char* {
    char* p = ws + off;
    off += (b + 255) & ~(size_t)255;
    return p;
  };

  constexpr long PLN_XN = (long)kBT * kD;
  constexpr long PLN_Q3 = (long)kBT * 3 * kD;
  constexpr long PLN_QKV = (long)3 * kD * kD;
  constexpr long PLN_WO = (long)kD * kD;
  constexpr long PLN_FF = (long)kE * kFF * kD;
  constexpr long PLN_H = (long)kSLOTS * kFF;
  constexpr long PLN_OUTS = (long)kSLOTS * kD;

  // shared small buffers
  float* x     = (float*)alloc((size_t)kBT * kD * 4);
  float* outs  = (float*)alloc((size_t)4 * PLN_OUTS * 4);   // 4 K-partials
  float* probs = (float*)alloc((size_t)kBT * kE * 4);
  int*   top2e = (int*)  alloc((size_t)kBT * 2 * 4);
  float* top2w = (float*)alloc((size_t)kBT * 2 * 4);
  int*   meta  = (int*)  alloc(64 * 4);
  int* counts = meta; int* cursors = meta + 8; int* offs = meta + 16;
  int*   rows  = (int*)  alloc((size_t)kSLOTS * 4);
  int*   slotOf= (int*)  alloc((size_t)kBT * 2 * 4);
  float* aux   = (float*)alloc(256);
  size_t off_shared = off;

  // fast-path buffers
  u16*   xnP   = (u16*)  alloc((size_t)2 * PLN_XN * 2);
  float* qkvf  = (float*)alloc((size_t)PLN_Q3 * 4);
  u16*   qkvP  = (u16*)  alloc((size_t)2 * PLN_Q3 * 2);
  u16*   ofP   = (u16*)  alloc((size_t)2 * PLN_XN * 2);
  u16*   hP    = (u16*)  alloc((size_t)2 * PLN_H * 2);
  u16*   wqkvP = (u16*)  alloc((size_t)kL * 2 * PLN_QKV * 2);
  u16*   woP   = (u16*)  alloc((size_t)kL * 2 * PLN_WO * 2);
  u16*   f1P   = (u16*)  alloc((size_t)2 * PLN_FF * 2);   // reused per layer
  u16*   f2P   = (u16*)  alloc((size_t)2 * PLN_FF * 2);
  u16*   lmb   = (u16*)  alloc((size_t)kV * kD * 2);
  bool fast = (off <= ws_size);
  float* qkvp1 = (float*)hP;          // alias: hP idle during QKV+attn phase

  dim3 gAttn(kT / 64, 2 * kH);
  // wide-kernel bases (all % 8 == 0)
  int bQKVw = (kBT / 128) * (3 * kD / 256);      // 16*12 = 192, mPerX=2, kParts=2
  int bWOw  = (kBT / 128) * (kD / 256);          // 16*4  = 64,  mPerX=2, kParts=4
  int nF1W  = (kSLOTS / 128) * (kFF / 256);      // 40*16 = 640, mPerX=5
  int bF2w  = (kSLOTS / 128) * (kD / 256);       // 40*4  = 160, mPerX=5, kParts=4
  int bF2   = (kSLOTS / 128) * (kD / 128);       // 320 (li=2 single-plane, kParts=4)
  int nF1s  = (kSLOTS / 128) * (kFF / 128);      // 1280, MPART mPerX=5
  int nLM   = (kBT / 128) * (kV / 128);          // 4000, mBlocks=16

  if (fast) {
    for (int li = 0; li < kL; ++li) {
      u16* dst = wqkvP + (size_t)li * 2 * PLN_QKV;
      split2h_k<<<1024, 256, 0, stream>>>(wq + (size_t)li * kD * kD, dst, PLN_QKV, (long)kD * kD / 4);
      split2h_k<<<1024, 256, 0, stream>>>(wk + (size_t)li * kD * kD, dst + (long)kD * kD, PLN_QKV, (long)kD * kD / 4);
      split2h_k<<<1024, 256, 0, stream>>>(wv + (size_t)li * kD * kD, dst + (long)2 * kD * kD, PLN_QKV, (long)kD * kD / 4);
      split2h_k<<<1024, 256, 0, stream>>>(wo + (size_t)li * kD * kD, woP + (size_t)li * 2 * PLN_WO, PLN_WO, (long)kD * kD / 4);
    }
    cast_h_k<<<4096, 256, 0, stream>>>(lmh, lmb, (long)kV * kD / 4);
    hipMemsetAsync(aux, 0, 4, stream);
    embed_rms_k<<<kBT, 256, 0, stream>>>(idx, wte, wpe, x);
    rmsnorm2h_k<<<kBT, 256, 0, stream>>>(x, xnP, PLN_XN);   // layer-0 QKV input

    for (int li = 0; li < kL; ++li) {
      // QKV: wide kernel, split-K x2 -> qkvf + qkvp1; combine into split-2 planes
      gemm2hW_bt_k<P_F32, false, false><<<2 * bQKVw, 512, 0, stream>>>(
          xnP, PLN_XN, wqkvP + (size_t)li * 2 * PLN_QKV, PLN_QKV,
          qkvf, 0, nullptr, nullptr, 3 * kD, kD, kD, 0, 2,
          2, bQKVw, (long)(qkvp1 - qkvf));
      qkvcomb_k<<<2048, 256, 0, stream>>>(qkvf, qkvp1, qkvP, PLN_Q3, PLN_Q3 / 4);
      attn2h_k<<<gAttn, 256, 0, stream>>>(qkvP, PLN_Q3, ofP, PLN_XN);
      // WO: wide kernel, split-K x4 into outs partials; fused residual+rms+split
      gemm2hW_bt_k<P_F32, false, false><<<4 * bWOw, 512, 0, stream>>>(
          ofP, PLN_XN, woP + (size_t)li * 2 * PLN_WO, PLN_WO,
          outs, 0, nullptr, nullptr, kD, kD, kD, 0, 2,
          4, bWOw, PLN_OUTS);
      resid4_rms2h_k<<<kBT, 256, 0, stream>>>(x, outs, PLN_OUTS, xnP, PLN_XN);
      hipMemsetAsync(meta, 0, 64, stream);
      gate_topk_k<<<kBT, 256, 0, stream>>>(x, gate + (size_t)li * kE * kD,
                                           probs, top2e, top2w, counts);
      calc_offsets_k<<<1, 64, 0, stream>>>(counts, offs);
      fill_slots_k<<<kBT / 256, 256, 0, stream>>>(top2e, offs, cursors, rows, slotOf);
      size_t fd = (size_t)li * PLN_FF;
      if (li < 2) {
        split2h2_k<<<8192, 256, 0, stream>>>(f1 + fd, f1P, f2 + fd, f2P,
                                             PLN_FF, PLN_FF / 4);
        gemm2hW_bt_k<P_SPLIT2_RELU, true, true><<<nF1W, 512, 0, stream>>>(
            xnP, PLN_XN, f1P, PLN_FF, hP, PLN_H, rows, offs,
            kFF, kD, kD, (long)kFF * kD, kSLOTS / 128 / 8,
            1, nF1W, 0);
        gemm2hW_bt_k<P_F32, false, true><<<4 * bF2w, 512, 0, stream>>>(
            hP, PLN_H, f2P, PLN_FF, outs, 0, nullptr, offs,
            kD, kFF, kFF, (long)kD * kFF, kSLOTS / 128 / 8,
            4, bF2w, PLN_OUTS);
        moe4_rms2h_k<<<kBT, 256, 0, stream>>>(x, outs, PLN_OUTS, slotOf, top2w,
                                              xnP, PLN_XN);
      } else {
        cast_h2_k<<<8192, 256, 0, stream>>>(f1 + fd, f1P, f2 + fd, f2P, PLN_FF / 4);
        gemm_bt_k<P_F16_RELU, true, true, true, false, true><<<nF1s, 256, 0, stream>>>(
            xnP, f1P, hP, rows, offs, kFF, kD, kD, (long)kFF * kD,
            1.0f / 64.0f, kSLOTS / 128 / 8, 1, nF1s, 0);
        gemm_bt_k<P_F32, true, false, true, false, true><<<4 * bF2, 256, 0, stream>>>(
            hP, f2P, outs, nullptr, offs, kD, kFF, kFF, (long)kD * kFF,
            1.0f, kSLOTS / 128 / 8, 4, bF2, PLN_OUTS);
        moe4_cast_h_k<<<kBT, 256, 0, stream>>>(x, outs, PLN_OUTS, slotOf, top2w, xnP);
      }
      aux_reduce_k<<<1, 256, 0, stream>>>(probs, aux);
    }
    gemm_bt_k<P_F32, false, false, true, false, false><<<nLM, 256, 0, stream>>>(
        xnP, lmb, out, nullptr, nullptr, kV, kD, kD, 0, 1.0f, kBT / 128,
        1, nLM, 0);
    write_aux_k<<<1, 64, 0, stream>>>(aux, out + (size_t)kBT * kV);
    return;
  }

  // ---------- fallback: f32 path ----------
  off = off_shared;
  float* xnf   = (float*)alloc((size_t)kBT * kD * 4);
  u16*   xnb   = (u16*)  alloc((size_t)kBT * kD * 2);
  float* qkvf32= (float*)alloc((size_t)kBT * 3 * kD * 4);
  float* off32 = (float*)alloc((size_t)kBT * kD * 4);
  float* hbuf  = (float*)alloc((size_t)kSLOTS * kFF * 4);
  u16* hbuf16 = (u16*)hbuf;

  hipMemsetAsync(aux, 0, 4, stream);
  embed_rms_k<<<kBT, 256, 0, stream>>>(idx, wte, wpe, x);
  dim3 gF1s(kSLOTS / 128, kFF / 128);
  dim3 gF2s(kSLOTS / 128, kD / 128);
  for (int li = 0; li < kL; ++li) {
    size_t dd = (size_t)li * kD * kD;
    rmsnorm2_k<<<kBT, 256, 0, stream>>>(x, xnf, xnb);
    dim3 gP(kBT / 128, kD / 128);
    sgemm_bt_k<P_F32, false, false><<<gP, 256, 0, stream>>>(
        xnf, wq + dd, qkvf32, nullptr, nullptr, nullptr, 3 * kD, kD, kD, 0);
    sgemm_bt_k<P_F32, false, false><<<gP, 256, 0, stream>>>(
        xnf, wk + dd, qkvf32 + kD, nullptr, nullptr, nullptr, 3 * kD, kD, kD, 0);
    sgemm_bt_k<P_F32, false, false><<<gP, 256, 0, stream>>>(
        xnf, wv + dd, qkvf32 + 2 * kD, nullptr, nullptr, nullptr, 3 * kD, kD, kD, 0);
    attn_f32_k<<<gAttn, 256, 0, stream>>>(qkvf32, off32, 3 * kD);
    sgemm_bt_k<P_F32_RESID, false, false><<<gP, 256, 0, stream>>>(
        off32, wo + dd, x, x, nullptr, nullptr, kD, kD, kD, 0);
    rmsnorm2_k<<<kBT, 256, 0, stream>>>(x, xnf, xnb);
    hipMemsetAsync(meta, 0, 64, stream);
    gate_topk_k<<<kBT, 256, 0, stream>>>(x, gate + (size_t)li * kE * kD,
                                         probs, top2e, top2w, counts);
    calc_offsets_k<<<1, 64, 0, stream>>>(counts, offs);
    fill_slots_k<<<kBT / 256, 256, 0, stream>>>(top2e, offs, cursors, rows, slotOf);
    size_t fd = (size_t)li * kE * kFF * kD;
    if (li < 2) {
      sgemm_bt_k<P_F32_RELU, true, true><<<gF1s, 256, 0, stream>>>(
          xnf, f1 + fd, hbuf, nullptr, rows, offs, kFF, kD, kD, (long)kFF * kD);
      sgemm_bt_k<P_F32, false, true><<<gF2s, 256, 0, stream>>>(
          hbuf, f2 + fd, outs, nullptr, nullptr, offs, kD, kFF, kFF, (long)kD * kFF);
    } else {
      gemm_bt_k<P_BF16_RELU, true, true, false, true, false><<<nF1s, 256, 0, stream>>>(
          xnb, f1 + fd, hbuf16, rows, offs, kFF, kD, kD, (long)kFF * kD,
          1.0f, kSLOTS / 128, 1, nF1s, 0);
      gemm_bt_k<P_F32, true, false, false, true, false><<<bF2, 256, 0, stream>>>(
          hbuf16, f2 + fd, outs, nullptr, offs, kD, kFF, kFF, (long)kD * kFF,
          1.0f, kSLOTS / 128, 1, bF2, 0);
    }
    hipMemsetAsync(outs + PLN_OUTS, 0, 3 * PLN_OUTS * 4, stream);
    moe_combine4_k<<<kBT, 256, 0, stream>>>(x, outs, PLN_OUTS, slotOf, top2w);
    aux_reduce_k<<<1, 256, 0, stream>>>(probs, aux);
  }
  cast_bf16_k<<<2048, 256, 0, stream>>>(x, xnb, (long)kBT * kD / 4);
  gemm_bt_k<P_F32, false, false, false, true, false><<<nLM, 256, 0, stream>>>(
      xnb, lmh, out, nullptr, nullptr, kV, kD, kD, 0, 1.0f, kBT / 128,
      1, nLM, 0);
  write_aux_k<<<1, 64, 0, stream>>>(aux, out + (size_t)kBT * kV);
}

// Round 15
// 2273.909 us; speedup vs baseline: 1.0386x; 1.0386x over previous
//
#include <hip/hip_runtime.h>

typedef unsigned short u16;
typedef __attribute__((ext_vector_type(4))) float f32x4;
typedef __attribute__((ext_vector_type(8))) __bf16 bf16x8;
typedef __attribute__((ext_vector_type(8))) _Float16 f16x8;
typedef __attribute__((ext_vector_type(4))) unsigned short u16x4;
typedef __attribute__((ext_vector_type(8))) unsigned short u16x8;

constexpr int kT = 1024, kD = 1024, kH = 16, kHD = 64, kL = 3, kE = 8;
constexpr int kFF = 4096, kV = 32000, kBT = 2048, kSLOTS = 5120;

__device__ __forceinline__ u16 f2bf(float f) {
  union { float f; unsigned u; } v; v.f = f;
  unsigned r = v.u + 0x7FFFu + ((v.u >> 16) & 1u);   // RNE
  return (u16)(r >> 16);
}
__device__ __forceinline__ u16 f2h(float x) {
  _Float16 h = (_Float16)x;
  union { _Float16 h; u16 u; } v; v.h = h; return v.u;
}
// uniform-scale fp16 split-2: 64*x = hi + mid + O(2^-11 * |64x - hi|)
__device__ __forceinline__ void split2s(float x, u16& h, u16& m) {
  float xs = x * 64.0f;
  _Float16 hh = (_Float16)xs;
  union { _Float16 h; u16 u; } v; v.h = hh; h = v.u;
  float r = xs - (float)hh;
  union { _Float16 h; u16 u; } w; w.h = (_Float16)r; m = w.u;
}

__device__ __forceinline__ void ld_lds16(const void* g, void* l) {
  __builtin_amdgcn_global_load_lds((const __attribute__((address_space(1))) void*)g,
                                   (__attribute__((address_space(3))) void*)l, 16, 0, 0);
}

#define MFMA16(a, b, c) __builtin_amdgcn_mfma_f32_16x16x32_bf16(a, b, c, 0, 0, 0)
#define MFMAH(a, b, c)  __builtin_amdgcn_mfma_f32_16x16x32_f16(a, b, c, 0, 0, 0)

__device__ __forceinline__ float blockReduceSum256(float v) {
  #pragma unroll
  for (int m = 32; m >= 1; m >>= 1) v += __shfl_xor(v, m);
  __shared__ float sh_[4];
  int w = threadIdx.x >> 6;
  if ((threadIdx.x & 63) == 0) sh_[w] = v;
  __syncthreads();
  v = (sh_[0] + sh_[1]) + (sh_[2] + sh_[3]);
  __syncthreads();
  return v;
}

// ---------------- elementwise / small kernels ----------------

__global__ __launch_bounds__(256) void cast_bf16_k(const float* __restrict__ in,
                                                   u16* __restrict__ out, long n4) {
  long i = (long)blockIdx.x * 256 + threadIdx.x;
  long stride = (long)gridDim.x * 256;
  for (; i < n4; i += stride) {
    f32x4 v = ((const f32x4*)in)[i];
    u16x4 o; o[0] = f2bf(v[0]); o[1] = f2bf(v[1]); o[2] = f2bf(v[2]); o[3] = f2bf(v[3]);
    ((u16x4*)out)[i] = o;
  }
}

__global__ __launch_bounds__(256) void cast_h_k(const float* __restrict__ in,
                                                u16* __restrict__ out, long n4) {
  long i = (long)blockIdx.x * 256 + threadIdx.x;
  long stride = (long)gridDim.x * 256;
  for (; i < n4; i += stride) {
    f32x4 v = ((const f32x4*)in)[i];
    u16x4 o; o[0] = f2h(v[0]); o[1] = f2h(v[1]); o[2] = f2h(v[2]); o[3] = f2h(v[3]);
    ((u16x4*)out)[i] = o;
  }
}

// two tensors f32 -> f16 in one launch
__global__ __launch_bounds__(256) void cast_h2_k(
    const float* __restrict__ in0, u16* __restrict__ out0,
    const float* __restrict__ in1, u16* __restrict__ out1, long n4) {
  long i = (long)blockIdx.x * 256 + threadIdx.x;
  long stride = (long)gridDim.x * 256;
  for (; i < 2 * n4; i += stride) {
    const float* s; u16* d; long j;
    if (i < n4) { s = in0; d = out0; j = i; } else { s = in1; d = out1; j = i - n4; }
    f32x4 v = ((const f32x4*)s)[j];
    u16x4 o; o[0] = f2h(v[0]); o[1] = f2h(v[1]); o[2] = f2h(v[2]); o[3] = f2h(v[3]);
    ((u16x4*)d)[j] = o;
  }
}

// f32 -> 2 fp16 planes (uniform x64 scale)
__global__ __launch_bounds__(256) void split2h_k(const float* __restrict__ in,
    u16* __restrict__ out, long planeStride, long n4) {
  long i = (long)blockIdx.x * 256 + threadIdx.x;
  long stride = (long)gridDim.x * 256;
  u16* o1 = out + planeStride;
  for (; i < n4; i += stride) {
    f32x4 v = ((const f32x4*)in)[i];
    u16x4 a, b;
    #pragma unroll
    for (int j = 0; j < 4; ++j) {
      u16 h, m; split2s(v[j], h, m);
      a[j] = h; b[j] = m;
    }
    ((u16x4*)out)[i] = a; ((u16x4*)o1)[i] = b;
  }
}

// qkv = p0 + p1 -> 2 fp16 planes (x64 scale)
__global__ __launch_bounds__(256) void qkvcomb_k(const float* __restrict__ a,
    const float* __restrict__ b, u16* __restrict__ oP, long plane, long n4) {
  long i = (long)blockIdx.x * 256 + threadIdx.x;
  long stride = (long)gridDim.x * 256;
  for (; i < n4; i += stride) {
    f32x4 v = ((const f32x4*)a)[i] + ((const f32x4*)b)[i];
    u16x4 hh, mm;
    #pragma unroll
    for (int j = 0; j < 4; ++j) {
      u16 h, m; split2s(v[j], h, m);
      hh[j] = h; mm[j] = m;
    }
    ((u16x4*)oP)[i] = hh;
    ((u16x4*)(oP + plane))[i] = mm;
  }
}

// two tensors -> split-2 planes in one launch
__global__ __launch_bounds__(256) void split2h2_k(
    const float* __restrict__ in0, u16* __restrict__ out0,
    const float* __restrict__ in1, u16* __restrict__ out1,
    long planeStride, long n4) {
  long i = (long)blockIdx.x * 256 + threadIdx.x;
  long stride = (long)gridDim.x * 256;
  for (; i < 2 * n4; i += stride) {
    const float* s; u16* d; long j;
    if (i < n4) { s = in0; d = out0; j = i; } else { s = in1; d = out1; j = i - n4; }
    f32x4 v = ((const f32x4*)s)[j];
    u16x4 a, b;
    #pragma unroll
    for (int jj = 0; jj < 4; ++jj) {
      u16 h, m; split2s(v[jj], h, m);
      a[jj] = h; b[jj] = m;
    }
    ((u16x4*)d)[j] = a; ((u16x4*)(d + planeStride))[j] = b;
  }
}

__global__ __launch_bounds__(256) void embed_rms_k(const int* __restrict__ idx,
    const float* __restrict__ wte, const float* __restrict__ wpe, float* __restrict__ x) {
  int tok = blockIdx.x, t = threadIdx.x;
  int id = idx[tok];
  int tt = tok & (kT - 1);
  f32x4 a = ((const f32x4*)(wte + (long)id * kD))[t];
  f32x4 p = ((const f32x4*)(wpe + (long)tt * kD))[t];
  f32x4 vv = a + p;
  float ss = vv[0]*vv[0] + vv[1]*vv[1] + vv[2]*vv[2] + vv[3]*vv[3];
  ss = blockReduceSum256(ss);
  float sc = rsqrtf(ss * (1.0f / kD) + 1e-5f);
  vv *= sc;
  ((f32x4*)(x + (long)tok * kD))[t] = vv;
}

// rmsnorm -> f32 + bf16 (fallback path)
__global__ __launch_bounds__(256) void rmsnorm2_k(const float* __restrict__ x,
    float* __restrict__ xnf, u16* __restrict__ xnb) {
  int tok = blockIdx.x, t = threadIdx.x;
  f32x4 vv = ((const f32x4*)(x + (long)tok * kD))[t];
  float ss = blockReduceSum256(vv[0]*vv[0] + vv[1]*vv[1] + vv[2]*vv[2] + vv[3]*vv[3]);
  float sc = rsqrtf(ss * (1.0f / kD) + 1e-5f);
  vv *= sc;
  ((f32x4*)(xnf + (long)tok * kD))[t] = vv;
  u16x4 o;
  o[0] = f2bf(vv[0]); o[1] = f2bf(vv[1]); o[2] = f2bf(vv[2]); o[3] = f2bf(vv[3]);
  ((u16x4*)(xnb + (long)tok * kD))[t] = o;
}

// rmsnorm -> 2 fp16 planes (fast path, x64 scale)
__global__ __launch_bounds__(256) void rmsnorm2h_k(const float* __restrict__ x,
    u16* __restrict__ xnP, long plane) {
  int tok = blockIdx.x, t = threadIdx.x;
  f32x4 vv = ((const f32x4*)(x + (long)tok * kD))[t];
  float ss = blockReduceSum256(vv[0]*vv[0] + vv[1]*vv[1] + vv[2]*vv[2] + vv[3]*vv[3]);
  float sc = rsqrtf(ss * (1.0f / kD) + 1e-5f);
  vv *= sc;
  u16x4 a, b;
  #pragma unroll
  for (int j = 0; j < 4; ++j) {
    u16 h, m; split2s(vv[j], h, m);
    a[j] = h; b[j] = m;
  }
  long o = (long)tok * kD / 4 + t;
  ((u16x4*)xnP)[o] = a;
  ((u16x4*)(xnP + plane))[o] = b;
}

// x += sum of 4 K-partials; write x; rmsnorm -> 2 fp16 planes
__global__ __launch_bounds__(256) void resid4_rms2h_k(float* __restrict__ x,
    const float* __restrict__ parts, long plane, u16* __restrict__ xnP, long xplane) {
  int tok = blockIdx.x, t = threadIdx.x;
  long o = (long)tok * (kD / 4) + t;
  f32x4 xv = ((f32x4*)x)[o];
  #pragma unroll
  for (int p = 0; p < 4; ++p) xv += ((const f32x4*)(parts + p * plane))[o];
  ((f32x4*)x)[o] = xv;
  float ss = blockReduceSum256(xv[0]*xv[0] + xv[1]*xv[1] + xv[2]*xv[2] + xv[3]*xv[3]);
  float sc = rsqrtf(ss * (1.0f / kD) + 1e-5f);
  f32x4 vv = xv * sc;
  u16x4 a, b;
  #pragma unroll
  for (int j = 0; j < 4; ++j) {
    u16 h, m; split2s(vv[j], h, m);
    a[j] = h; b[j] = m;
  }
  ((u16x4*)xnP)[o] = a;
  ((u16x4*)(xnP + xplane))[o] = b;
}

// x += moe combine (4 K-partials, 2 experts); write x; rmsnorm -> 2 fp16 planes
__global__ __launch_bounds__(256) void moe4_rms2h_k(float* __restrict__ x,
    const float* __restrict__ outsP, long plane, const int* __restrict__ slotOf,
    const float* __restrict__ top2w, u16* __restrict__ xnP, long xplane) {
  int tok = blockIdx.x, t = threadIdx.x;
  int s0 = slotOf[tok*2], s1 = slotOf[tok*2+1];
  float w0 = top2w[tok*2], w1 = top2w[tok*2+1];
  f32x4 a = {0.f,0.f,0.f,0.f}, b = a;
  #pragma unroll
  for (int p = 0; p < 4; ++p) {
    a += ((const f32x4*)(outsP + p * plane + (long)s0 * kD))[t];
    b += ((const f32x4*)(outsP + p * plane + (long)s1 * kD))[t];
  }
  long o = (long)tok * (kD / 4) + t;
  f32x4 xv = ((f32x4*)x)[o];
  xv += a * w0 + b * w1;
  ((f32x4*)x)[o] = xv;
  float ss = blockReduceSum256(xv[0]*xv[0] + xv[1]*xv[1] + xv[2]*xv[2] + xv[3]*xv[3]);
  float sc = rsqrtf(ss * (1.0f / kD) + 1e-5f);
  f32x4 vv = xv * sc;
  u16x4 ha, hb;
  #pragma unroll
  for (int j = 0; j < 4; ++j) {
    u16 h, m; split2s(vv[j], h, m);
    ha[j] = h; hb[j] = m;
  }
  ((u16x4*)xnP)[o] = ha;
  ((u16x4*)(xnP + xplane))[o] = hb;
}

// last layer: x += moe combine; write f16 (unscaled) plane for lm_head
__global__ __launch_bounds__(256) void moe4_cast_h_k(float* __restrict__ x,
    const float* __restrict__ outsP, long plane, const int* __restrict__ slotOf,
    const float* __restrict__ top2w, u16* __restrict__ xn) {
  int tok = blockIdx.x, t = threadIdx.x;
  int s0 = slotOf[tok*2], s1 = slotOf[tok*2+1];
  float w0 = top2w[tok*2], w1 = top2w[tok*2+1];
  f32x4 a = {0.f,0.f,0.f,0.f}, b = a;
  #pragma unroll
  for (int p = 0; p < 4; ++p) {
    a += ((const f32x4*)(outsP + p * plane + (long)s0 * kD))[t];
    b += ((const f32x4*)(outsP + p * plane + (long)s1 * kD))[t];
  }
  long o = (long)tok * (kD / 4) + t;
  f32x4 xv = ((f32x4*)x)[o];
  xv += a * w0 + b * w1;
  u16x4 hv;
  #pragma unroll
  for (int j = 0; j < 4; ++j) hv[j] = f2h(xv[j]);
  ((u16x4*)xn)[o] = hv;
}

// gating in f32 (bf16 would flip top-2 selections on near-ties)
__global__ __launch_bounds__(256) void gate_topk_k(const float* __restrict__ x,
    const float* __restrict__ gate_l, float* __restrict__ probs, int* __restrict__ top2e,
    float* __restrict__ top2w, int* __restrict__ counts) {
  int tok = blockIdx.x, t = threadIdx.x;
  f32x4 xv = ((const f32x4*)(x + (long)tok * kD))[t];
  float ss = blockReduceSum256(xv[0]*xv[0] + xv[1]*xv[1] + xv[2]*xv[2] + xv[3]*xv[3]);
  float sc = rsqrtf(ss * (1.0f / kD) + 1e-5f);
  float a[kE];
  #pragma unroll
  for (int e = 0; e < kE; ++e) {
    f32x4 gv = ((const f32x4*)(gate_l + (long)e * kD))[t];
    a[e] = xv[0]*gv[0] + xv[1]*gv[1] + xv[2]*gv[2] + xv[3]*gv[3];
  }
  __shared__ float sh8[kE][4];
  int w = t >> 6, l = t & 63;
  #pragma unroll
  for (int e = 0; e < kE; ++e) {
    float v = a[e];
    #pragma unroll
    for (int m = 32; m >= 1; m >>= 1) v += __shfl_xor(v, m);
    if (l == 0) sh8[e][w] = v;
  }
  __syncthreads();
  if (t == 0) {
    float lg[kE], mx = -1e30f;
    #pragma unroll
    for (int e = 0; e < kE; ++e) {
      lg[e] = (sh8[e][0] + sh8[e][1] + sh8[e][2] + sh8[e][3]) * sc;
      mx = fmaxf(mx, lg[e]);
    }
    float pe[kE], s = 0.f;
    #pragma unroll
    for (int e = 0; e < kE; ++e) { pe[e] = __expf(lg[e] - mx); s += pe[e]; }
    float inv = 1.f / s;
    int i1 = 0;
    #pragma unroll
    for (int e = 1; e < kE; ++e) if (lg[e] > lg[i1]) i1 = e;
    int i2 = (i1 == 0) ? 1 : 0;
    #pragma unroll
    for (int e = 0; e < kE; ++e) if (e != i1 && lg[e] > lg[i2]) i2 = e;
    #pragma unroll
    for (int e = 0; e < kE; ++e) probs[(long)tok * kE + e] = pe[e] * inv;
    float p1 = pe[i1] * inv, p2 = pe[i2] * inv;
    float wn = p1 + p2;
    top2e[tok*2] = i1; top2e[tok*2+1] = i2;
    top2w[tok*2] = p1 / wn; top2w[tok*2+1] = p2 / wn;
    atomicAdd(&counts[i1], 1); atomicAdd(&counts[i2], 1);
  }
}

// 128-aligned expert offsets
__global__ void calc_offsets_k(const int* __restrict__ counts, int* __restrict__ offsets) {
  if (threadIdx.x == 0) {
    int o = 0;
    #pragma unroll
    for (int e = 0; e < kE; ++e) { offsets[e] = o; o += (counts[e] + 127) & ~127; }
    offsets[kE] = o;
  }
}

__global__ __launch_bounds__(256) void fill_slots_k(const int* __restrict__ top2e,
    const int* __restrict__ offsets, int* __restrict__ cursors,
    int* __restrict__ rows, int* __restrict__ slotOf) {
  int tok = blockIdx.x * 256 + threadIdx.x;
  if (tok >= kBT) return;
  #pragma unroll
  for (int j = 0; j < 2; ++j) {
    int e = top2e[tok*2 + j];
    int pos = atomicAdd(&cursors[e], 1);
    int slot = offsets[e] + pos;
    rows[slot] = tok;
    slotOf[tok*2 + j] = slot;
  }
}

// fallback combine (4 partials; unused planes zeroed)
__global__ __launch_bounds__(256) void moe_combine4_k(float* __restrict__ x,
    const float* __restrict__ outsP, long plane, const int* __restrict__ slotOf,
    const float* __restrict__ top2w) {
  int tok = blockIdx.x, t = threadIdx.x;
  int s0 = slotOf[tok*2], s1 = slotOf[tok*2+1];
  float w0 = top2w[tok*2], w1 = top2w[tok*2+1];
  f32x4 a = {0.f,0.f,0.f,0.f}, b = a;
  #pragma unroll
  for (int p = 0; p < 4; ++p) {
    a += ((const f32x4*)(outsP + p * plane + (long)s0 * kD))[t];
    b += ((const f32x4*)(outsP + p * plane + (long)s1 * kD))[t];
  }
  f32x4 xv = ((f32x4*)(x + (long)tok * kD))[t];
  xv += a * w0 + b * w1;
  ((f32x4*)(x + (long)tok * kD))[t] = xv;
}

__global__ __launch_bounds__(256) void aux_reduce_k(const float* __restrict__ probs,
                                                    float* __restrict__ aux) {
  int t = threadIdx.x;
  float part[kE] = {};
  for (int i = t; i < kBT; i += 256) {
    #pragma unroll
    for (int e = 0; e < kE; ++e) part[e] += probs[(long)i * kE + e];
  }
  __shared__ float sh8[kE][4];
  int w = t >> 6, l = t & 63;
  #pragma unroll
  for (int e = 0; e < kE; ++e) {
    float v = part[e];
    #pragma unroll
    for (int m = 32; m >= 1; m >>= 1) v += __shfl_xor(v, m);
    if (l == 0) sh8[e][w] = v;
  }
  __syncthreads();
  if (t == 0) {
    float acc = 0.f;
    #pragma unroll
    for (int e = 0; e < kE; ++e) {
      float frac = (sh8[e][0] + sh8[e][1] + sh8[e][2] + sh8[e][3]) * (1.0f / kBT);
      acc += frac * frac;
    }
    aux[0] += (float)kE * acc;
  }
}

__global__ void write_aux_k(const float* __restrict__ aux, float* __restrict__ out) {
  if (threadIdx.x == 0) out[0] = 0.01f * aux[0] / (float)kL;
}

enum { P_BF16 = 0, P_BF16_RELU = 1, P_F32 = 2, P_F32_RESID = 3, P_F32_RELU = 4,
       P_SPLIT2_RELU = 5, P_F16_RELU = 6 };

__device__ __forceinline__ int clamp_row(int rv) {
  return ((unsigned)rv < (unsigned)kBT) ? rv : 0;
}

template <bool MPART>
__device__ __forceinline__ void block_mn(int lin, int base, int mArg, int& mb, int& nb) {
  int xcd = lin & 7, c = lin >> 3;
  if (MPART) {
    mb = xcd * mArg + (c % mArg);
    nb = c / mArg;
  } else {
    int swz = xcd * (base >> 3) + c;
    mb = swz % mArg;
    nb = swz / mArg;
  }
}

// ------- fused fp16 split-2 MFMA GEMM (128x128, 256 thr), single accumulator -------

template <int POST, bool GATHER, bool EXPERT, bool MPART>
__global__ __launch_bounds__(256) void gemm2h_bt_k(
    const u16* __restrict__ A0, long planeA,
    const u16* __restrict__ B0, long planeB,
    void* __restrict__ C, long planeC,
    const float* __restrict__ resid,
    const int* __restrict__ rows, const int* __restrict__ offsets,
    int N, int K, int lda, long eBstride, int mArg,
    int kParts, int base, long cPart) {
  constexpr int BM = 128, BK = 32;
  int part = blockIdx.x / base;
  int lin = blockIdx.x % base;
  int mb, nb;
  block_mn<MPART>(lin, base, mArg, mb, nb);
  int m0 = mb * BM, n0 = nb * BM;
  if (EXPERT) {
    int total = offsets[kE];
    if (m0 >= total) return;
    int e = 0;
    while (offsets[e + 1] <= m0) ++e;
    B0 += (long)e * eBstride;
  }
  __shared__ __align__(16) u16 Ac[BM][64];
  __shared__ __align__(16) u16 Bc[BM][64];
  int t = threadIdx.x;
  int l = t & 63, lr = l & 15, lg = l >> 4;
  int wid = t >> 6;
  int wm = (wid >> 1) * 64, wn = (wid & 1) * 64;

  long asrc[4], bsrc[4];
  int ldst[4];
  #pragma unroll
  for (int it = 0; it < 4; ++it) {
    int d = it * 256 + t;
    int row = d >> 3, pc = d & 7;
    int lc = pc ^ (row & 7);
    int p = lc >> 2, c = lc & 3;
    int grow = GATHER ? clamp_row(rows[m0 + row]) : (m0 + row);
    asrc[it] = (long)p * planeA + (long)grow * lda + c * 8;
    bsrc[it] = (long)p * planeB + (long)(n0 + row) * K + c * 8;
    ldst[it] = (it * 256 + (t & ~63)) * 8;
  }
  int sa = lr & 7;
  int cH = (lg ^ sa) * 8;
  int cM = ((4 + lg) ^ sa) * 8;

  f32x4 acc[4][4];
  #pragma unroll
  for (int i = 0; i < 4; ++i)
    #pragma unroll
    for (int j = 0; j < 4; ++j) acc[i][j] = 0.f;

  int kStep = K / kParts;
  int kLo = part * kStep, kHi = kLo + kStep;
  for (int k0 = kLo; k0 < kHi; k0 += BK) {
    #pragma unroll
    for (int it = 0; it < 4; ++it) {
      ld_lds16(A0 + asrc[it] + k0, &Ac[0][0] + ldst[it]);
      ld_lds16(B0 + bsrc[it] + k0, &Bc[0][0] + ldst[it]);
    }
    __syncthreads();
    f16x8 ah[4], am[4];
    #pragma unroll
    for (int i = 0; i < 4; ++i) {
      ah[i] = *(const f16x8*)&Ac[wm + i*16 + lr][cH];
      am[i] = *(const f16x8*)&Ac[wm + i*16 + lr][cM];
    }
    #pragma unroll
    for (int j = 0; j < 4; ++j) {
      f16x8 bh = *(const f16x8*)&Bc[wn + j*16 + lr][cH];
      f16x8 bm = *(const f16x8*)&Bc[wn + j*16 + lr][cM];
      #pragma unroll
      for (int i = 0; i < 4; ++i) {
        acc[i][j] = MFMAH(ah[i], bh, acc[i][j]);
        acc[i][j] = MFMAH(am[i], bh, acc[i][j]);
        acc[i][j] = MFMAH(ah[i], bm, acc[i][j]);
      }
    }
    __syncthreads();
  }
  float* Cf = (float*)C + (long)part * cPart;
  #pragma unroll
  for (int i = 0; i < 4; ++i) {
    #pragma unroll
    for (int r = 0; r < 4; ++r) {
      long m = m0 + wm + i*16 + lg*4 + r;
      #pragma unroll
      for (int j = 0; j < 4; ++j) {
        int n = n0 + wn + j*16 + lr;
        float val = acc[i][j][r] * (1.0f / 4096.0f);
        if (POST == P_F32) {
          Cf[m * N + n] = val;
        } else if (POST == P_F32_RESID) {
          ((float*)C)[m * N + n] = val + resid[m * N + n];
        } else if (POST == P_SPLIT2_RELU) {
          val = fmaxf(val, 0.f);
          u16 h, mm; split2s(val, h, mm);
          u16* Cp = (u16*)C;
          Cp[m * N + n] = h;
          Cp[planeC + m * N + n] = mm;
        }
      }
    }
  }
}

// ------- wide fused fp16 split-2 GEMM: 128x256 tile, 512 threads, 2m x 4n waves -------

template <int POST, bool GATHER, bool EXPERT>
__global__ __launch_bounds__(512) void gemm2hW_bt_k(
    const u16* __restrict__ A0, long planeA,
    const u16* __restrict__ B0, long planeB,
    void* __restrict__ C, long planeC,
    const int* __restrict__ rows, const int* __restrict__ offsets,
    int N, int K, int lda, long eBstride, int mPerX,
    int kParts, int base, long cPart) {
  constexpr int BM = 128, BN = 256, BK = 32;
  int part = blockIdx.x / base;
  int lin = blockIdx.x % base;
  int xcd = lin & 7, c0 = lin >> 3;
  int m0 = (xcd * mPerX + (c0 % mPerX)) * BM;
  int n0 = (c0 / mPerX) * BN;
  if (EXPERT) {
    int total = offsets[kE];
    if (m0 >= total) return;
    int e = 0;
    while (offsets[e + 1] <= m0) ++e;
    B0 += (long)e * eBstride;
  }
  __shared__ __align__(16) u16 Ac[BM][64];
  __shared__ __align__(16) u16 Bc[BN][64];
  int t = threadIdx.x;
  int l = t & 63, lr = l & 15, lg = l >> 4;
  int wid = t >> 6;
  int wm = (wid >> 2) * 64;
  int wn = (wid & 3) * 64;

  long asrc[2], bsrc[4];
  int aldst[2], bldst[4];
  #pragma unroll
  for (int it = 0; it < 2; ++it) {
    int d = it * 512 + t;
    int row = d >> 3, pc = d & 7;
    int lc = pc ^ (row & 7);
    int p = lc >> 2, cc = lc & 3;
    int grow = GATHER ? clamp_row(rows[m0 + row]) : (m0 + row);
    asrc[it] = (long)p * planeA + (long)grow * lda + cc * 8;
    aldst[it] = (it * 512 + (t & ~63)) * 8;
  }
  #pragma unroll
  for (int it = 0; it < 4; ++it) {
    int d = it * 512 + t;
    int row = d >> 3, pc = d & 7;
    int lc = pc ^ (row & 7);
    int p = lc >> 2, cc = lc & 3;
    bsrc[it] = (long)p * planeB + (long)(n0 + row) * K + cc * 8;
    bldst[it] = (it * 512 + (t & ~63)) * 8;
  }
  int sa = lr & 7;
  int cH = (lg ^ sa) * 8;
  int cM = ((4 + lg) ^ sa) * 8;

  f32x4 acc[4][4];
  #pragma unroll
  for (int i = 0; i < 4; ++i)
    #pragma unroll
    for (int j = 0; j < 4; ++j) acc[i][j] = 0.f;

  int kStep = K / kParts;
  int kLo = part * kStep, kHi = kLo + kStep;
  for (int k0 = kLo; k0 < kHi; k0 += BK) {
    #pragma unroll
    for (int it = 0; it < 2; ++it)
      ld_lds16(A0 + asrc[it] + k0, &Ac[0][0] + aldst[it]);
    #pragma unroll
    for (int it = 0; it < 4; ++it)
      ld_lds16(B0 + bsrc[it] + k0, &Bc[0][0] + bldst[it]);
    __syncthreads();
    f16x8 ah[4], am[4];
    #pragma unroll
    for (int i = 0; i < 4; ++i) {
      ah[i] = *(const f16x8*)&Ac[wm + i*16 + lr][cH];
      am[i] = *(const f16x8*)&Ac[wm + i*16 + lr][cM];
    }
    #pragma unroll
    for (int j = 0; j < 4; ++j) {
      f16x8 bh = *(const f16x8*)&Bc[wn + j*16 + lr][cH];
      f16x8 bm = *(const f16x8*)&Bc[wn + j*16 + lr][cM];
      #pragma unroll
      for (int i = 0; i < 4; ++i) {
        acc[i][j] = MFMAH(ah[i], bh, acc[i][j]);
        acc[i][j] = MFMAH(am[i], bh, acc[i][j]);
        acc[i][j] = MFMAH(ah[i], bm, acc[i][j]);
      }
    }
    __syncthreads();
  }
  float* Cf = (float*)C + (long)part * cPart;
  #pragma unroll
  for (int i = 0; i < 4; ++i) {
    #pragma unroll
    for (int r = 0; r < 4; ++r) {
      long m = m0 + wm + i*16 + lg*4 + r;
      #pragma unroll
      for (int j = 0; j < 4; ++j) {
        int n = n0 + wn + j*16 + lr;
        float val = acc[i][j][r] * (1.0f / 4096.0f);
        if (POST == P_F32) {
          Cf[m * N + n] = val;
        } else if (POST == P_SPLIT2_RELU) {
          val = fmaxf(val, 0.f);
          u16 h, mm; split2s(val, h, mm);
          u16* Cp = (u16*)C;
          Cp[m * N + n] = h;
          Cp[planeC + m * N + n] = mm;
        }
      }
    }
  }
}

// ---------------- single-plane MFMA GEMM (with optional split-K) ----------------

template <int POST, bool EXPERT, bool GATHER, bool HALF, bool BCONV, bool MPART>
__global__ __launch_bounds__(256) void gemm_bt_k(
    const u16* __restrict__ A, const void* __restrict__ Bv, void* __restrict__ C,
    const int* __restrict__ rows, const int* __restrict__ offsets,
    int N, int K, int lda, long eBstride, float oscale, int mArg,
    int kParts, int base, long cPart) {
  constexpr int BM = 128, BK = 64;
  int part = blockIdx.x / base;
  int lin = blockIdx.x % base;
  int mb, nb;
  block_mn<MPART>(lin, base, mArg, mb, nb);
  int m0 = mb * BM, n0 = nb * BM;
  const float* Bf = (const float*)Bv;
  const u16*   Bh = (const u16*)Bv;
  if (EXPERT) {
    int total = offsets[kE];
    if (m0 >= total) return;
    int e = 0;
    while (offsets[e + 1] <= m0) ++e;
    if (BCONV) Bf += (long)e * eBstride; else Bh += (long)e * eBstride;
  }
  __shared__ __align__(16) u16 As[BM][BK];
  __shared__ __align__(16) u16 Bs[BM][BK + (BCONV ? 8 : 0)];
  int t = threadIdx.x;
  int l = t & 63, lr = l & 15, lg = l >> 4;
  int wid = t >> 6;
  int wm = (wid >> 1) * 64, wn = (wid & 1) * 64;

  long asrc[4], bsrc[4];
  int ldst[4];
  #pragma unroll
  for (int it = 0; it < 4; ++it) {
    int d = it * 256 + t;
    int row = d >> 3, pc = d & 7;
    int c = pc ^ (row & 7);
    int grow = GATHER ? clamp_row(rows[m0 + row]) : (m0 + row);
    asrc[it] = (long)grow * lda + c * 8;
    bsrc[it] = (long)(n0 + row) * K + c * 8;
    ldst[it] = (it * 256 + (t & ~63)) * 8;
  }
  f32x4 acc[4][4];
  #pragma unroll
  for (int i = 0; i < 4; ++i)
    #pragma unroll
    for (int j = 0; j < 4; ++j) acc[i][j] = 0.f;

  int kStep = K / kParts;
  int kLo = part * kStep, kHi = kLo + kStep;
  for (int k0 = kLo; k0 < kHi; k0 += BK) {
    #pragma unroll
    for (int it = 0; it < 4; ++it)
      ld_lds16(A + asrc[it] + k0, &As[0][0] + ldst[it]);
    if (!BCONV) {
      #pragma unroll
      for (int it = 0; it < 4; ++it)
        ld_lds16(Bh + bsrc[it] + k0, &Bs[0][0] + ldst[it]);
    } else {
      #pragma unroll
      for (int it = 0; it < 8; ++it) {
        int c = it * 256 + t;
        int row = c >> 4, col = (c & 15) * 4;
        f32x4 v = *(const f32x4*)(Bf + (long)(n0 + row) * K + k0 + col);
        u16x4 o;
        #pragma unroll
        for (int j = 0; j < 4; ++j) o[j] = HALF ? f2h(v[j]) : f2bf(v[j]);
        *(u16x4*)&Bs[row][col] = o;
      }
    }
    __syncthreads();
    #pragma unroll
    for (int kk = 0; kk < 2; ++kk) {
      int ca = ((kk * 4 + lg) ^ (lr & 7)) * 8;
      int cb = BCONV ? (kk * 32 + lg * 8) : ca;
      #pragma unroll
      for (int i = 0; i < 4; ++i)
        #pragma unroll
        for (int j = 0; j < 4; ++j) {
          if (HALF) {
            f16x8 af = *(const f16x8*)&As[wm + i*16 + lr][ca];
            f16x8 bq = *(const f16x8*)&Bs[wn + j*16 + lr][cb];
            acc[i][j] = MFMAH(af, bq, acc[i][j]);
          } else {
            bf16x8 af = *(const bf16x8*)&As[wm + i*16 + lr][ca];
            bf16x8 bq = *(const bf16x8*)&Bs[wn + j*16 + lr][cb];
            acc[i][j] = MFMA16(af, bq, acc[i][j]);
          }
        }
    }
    __syncthreads();
  }
  #pragma unroll
  for (int i = 0; i < 4; ++i) {
    #pragma unroll
    for (int r = 0; r < 4; ++r) {
      long m = m0 + wm + i*16 + lg*4 + r;
      #pragma unroll
      for (int j = 0; j < 4; ++j) {
        int n = n0 + wn + j*16 + lr;
        float val = acc[i][j][r] * oscale;
        if (POST == P_BF16_RELU)       ((u16*)C)[m * N + n] = f2bf(fmaxf(val, 0.f));
        else if (POST == P_F16_RELU)   ((u16*)C)[m * N + n] = f2h(fmaxf(val, 0.f));
        else if (POST == P_F32)        ((float*)C + (long)part * cPart)[m * N + n] = val;
      }
    }
  }
}

// ---------------- f32 SGEMM (fallback path only) ----------------

template <int POST, bool GATHER, bool EXPERT>
__global__ __launch_bounds__(256) void sgemm_bt_k(
    const float* __restrict__ A, const float* __restrict__ B, float* __restrict__ C,
    const float* __restrict__ resid, const int* __restrict__ rows,
    const int* __restrict__ offsets, int N, int K, int lda, long eBstride) {
  constexpr int BM = 128, BN = 128, BK = 32;
  int m0 = blockIdx.x * BM, n0 = blockIdx.y * BN;
  if (EXPERT) {
    int total = offsets[kE];
    if (m0 >= total) return;
    int e = 0;
    while (offsets[e + 1] <= m0) ++e;
    B += (long)e * eBstride;
  }
  __shared__ float Ast[BK][BM];
  __shared__ float Bst[BK][BN];
  int t = threadIdx.x, tx = t & 15, ty = t >> 4;
  long asrc[4], bsrc[4];
  #pragma unroll
  for (int it = 0; it < 4; ++it) {
    int c = it * 256 + t;
    int row = c >> 3, kc = (c & 7) * 4;
    int gr = GATHER ? clamp_row(rows[m0 + row]) : (m0 + row);
    asrc[it] = (long)gr * lda + kc;
    bsrc[it] = (long)(n0 + row) * K + kc;
  }
  f32x4 accv[8][2];
  #pragma unroll
  for (int i = 0; i < 8; ++i) { accv[i][0] = 0.f; accv[i][1] = 0.f; }

  for (int k0 = 0; k0 < K; k0 += BK) {
    #pragma unroll
    for (int it = 0; it < 4; ++it) {
      int c = it * 256 + t;
      int row = c >> 3, kc = (c & 7) * 4;
      f32x4 av = *(const f32x4*)(A + asrc[it] + k0);
      f32x4 bv = *(const f32x4*)(B + bsrc[it] + k0);
      #pragma unroll
      for (int j = 0; j < 4; ++j) { Ast[kc + j][row] = av[j]; Bst[kc + j][row] = bv[j]; }
    }
    __syncthreads();
    #pragma unroll
    for (int kk = 0; kk < BK; ++kk) {
      f32x4 a0 = *(const f32x4*)&Ast[kk][ty * 4];
      f32x4 a1 = *(const f32x4*)&Ast[kk][64 + ty * 4];
      f32x4 b0 = *(const f32x4*)&Bst[kk][tx * 4];
      f32x4 b1 = *(const f32x4*)&Bst[kk][64 + tx * 4];
      float as[8] = {a0[0], a0[1], a0[2], a0[3], a1[0], a1[1], a1[2], a1[3]};
      #pragma unroll
      for (int i = 0; i < 8; ++i) {
        accv[i][0] += b0 * as[i];
        accv[i][1] += b1 * as[i];
      }
    }
    __syncthreads();
  }
  #pragma unroll
  for (int ih = 0; ih < 2; ++ih)
    #pragma unroll
    for (int i = 0; i < 4; ++i) {
      long m = m0 + ih * 64 + ty * 4 + i;
      #pragma unroll
      for (int jh = 0; jh < 2; ++jh) {
        long n = n0 + jh * 64 + tx * 4;
        f32x4 val = accv[ih * 4 + i][jh];
        if (POST == P_F32_RELU) {
          #pragma unroll
          for (int j = 0; j < 4; ++j) val[j] = fmaxf(val[j], 0.f);
        }
        if (POST == P_F32_RESID) val += *(const f32x4*)&resid[m * N + n];
        *(f32x4*)&C[m * N + n] = val;
      }
    }
}

// ------- MFMA split-2 attention (f32-equivalent accuracy) -------
// longest-first: qt = 15 - blockIdx.x so heavy blocks dispatch first.

__global__ __launch_bounds__(256) void attn2h_k(
    const u16* __restrict__ qkvP, long qplane,
    u16* __restrict__ oP, long oplane) {
  int qt = (int)gridDim.x - 1 - (int)blockIdx.x;   // 15..0, heavy first
  int bh = blockIdx.y;
  int b = bh >> 4, h = bh & 15;
  const int ldq = 3 * kD;
  long hbq = (long)b * kT * ldq + h * kHD;
  long hbo = (long)b * kT * kD + h * kHD;
  int t = threadIdx.x, w = t >> 6, l = t & 63;
  int lr = l & 15, lg = l >> 4;

  __shared__ __align__(16) u16 Ks[2][64][72];
  __shared__ __align__(16) u16 Vt[2][64][72];
  __shared__ __align__(16) u16 Ps[2][4][16][72];

  f16x8 qf0[2], qf1[2];
  {
    long qrow = qt * 64 + w * 16 + lr;
    const u16* qp = qkvP + hbq + qrow * ldq;
    #pragma unroll
    for (int kc = 0; kc < 2; ++kc) {
      qf0[kc] = *(const f16x8*)(qp + kc * 32 + lg * 8);
      qf1[kc] = *(const f16x8*)(qp + qplane + kc * 32 + lg * 8);
    }
  }
  int qg = qt * 64 + w * 16 + lg * 4;

  float mrow[4], lsum[4];
  f32x4 accO[4];
  #pragma unroll
  for (int r = 0; r < 4; ++r) { mrow[r] = -1e30f; lsum[r] = 0.f; }
  #pragma unroll
  for (int j = 0; j < 4; ++j) accO[j] = 0.f;

  for (int it = 0; it <= qt; ++it) {
    #pragma unroll
    for (int p = 0; p < 2; ++p) {
      #pragma unroll
      for (int s = 0; s < 2; ++s) {
        int c = s * 256 + t;
        int row = c >> 3, col = (c & 7) * 8;
        long gi = (long)p * qplane + hbq + (long)(it * 64 + row) * ldq + col;
        *(u16x8*)&Ks[p][row][col] = *(const u16x8*)(qkvP + kD + gi);
        u16x8 vv = *(const u16x8*)(qkvP + 2 * kD + gi);
        #pragma unroll
        for (int j = 0; j < 8; ++j) Vt[p][col + j][row] = vv[j];
      }
    }
    __syncthreads();

    f32x4 s4[4];
    #pragma unroll
    for (int j = 0; j < 4; ++j) {
      f32x4 z = {0.f, 0.f, 0.f, 0.f};
      #pragma unroll
      for (int kc = 0; kc < 2; ++kc) {
        f16x8 kh = *(const f16x8*)&Ks[0][j*16 + lr][kc*32 + lg*8];
        f16x8 km = *(const f16x8*)&Ks[1][j*16 + lr][kc*32 + lg*8];
        z = MFMAH(qf0[kc], kh, z);
        z = MFMAH(qf1[kc], kh, z);
        z = MFMAH(qf0[kc], km, z);
      }
      s4[j] = z;
    }
    #pragma unroll
    for (int j = 0; j < 4; ++j)
      #pragma unroll
      for (int r = 0; r < 4; ++r) {
        float sv = s4[j][r] * (0.125f / 4096.0f);
        if (it * 64 + j * 16 + lr > qg + r) sv = -1e30f;
        s4[j][r] = sv;
      }
    float alpha[4];
    #pragma unroll
    for (int r = 0; r < 4; ++r) {
      float mx = fmaxf(fmaxf(s4[0][r], s4[1][r]), fmaxf(s4[2][r], s4[3][r]));
      mx = fmaxf(mx, __shfl_xor(mx, 1));
      mx = fmaxf(mx, __shfl_xor(mx, 2));
      mx = fmaxf(mx, __shfl_xor(mx, 4));
      mx = fmaxf(mx, __shfl_xor(mx, 8));
      float mi = fmaxf(mrow[r], mx);
      alpha[r] = __expf(mrow[r] - mi);
      mrow[r] = mi;
    }
    float rs[4] = {0.f, 0.f, 0.f, 0.f};
    #pragma unroll
    for (int j = 0; j < 4; ++j)
      #pragma unroll
      for (int r = 0; r < 4; ++r) {
        float p = __expf(s4[j][r] - mrow[r]);
        rs[r] += p;
        u16 hh, mm; split2s(p, hh, mm);
        Ps[0][w][lg*4 + r][j*16 + lr] = hh;
        Ps[1][w][lg*4 + r][j*16 + lr] = mm;
      }
    #pragma unroll
    for (int r = 0; r < 4; ++r) {
      float x2 = rs[r];
      x2 += __shfl_xor(x2, 1);
      x2 += __shfl_xor(x2, 2);
      x2 += __shfl_xor(x2, 4);
      x2 += __shfl_xor(x2, 8);
      lsum[r] = lsum[r] * alpha[r] + x2;
    }
    #pragma unroll
    for (int j = 0; j < 4; ++j)
      #pragma unroll
      for (int r = 0; r < 4; ++r) accO[j][r] *= alpha[r];
    __syncthreads();

    f16x8 ph[2], pm[2];
    #pragma unroll
    for (int kc = 0; kc < 2; ++kc) {
      ph[kc] = *(const f16x8*)&Ps[0][w][lr][kc*32 + lg*8];
      pm[kc] = *(const f16x8*)&Ps[1][w][lr][kc*32 + lg*8];
    }
    #pragma unroll
    for (int j2 = 0; j2 < 4; ++j2) {
      #pragma unroll
      for (int kc = 0; kc < 2; ++kc) {
        f16x8 vh = *(const f16x8*)&Vt[0][j2*16 + lr][kc*32 + lg*8];
        f16x8 vm = *(const f16x8*)&Vt[1][j2*16 + lr][kc*32 + lg*8];
        accO[j2] = MFMAH(ph[kc], vh, accO[j2]);
        accO[j2] = MFMAH(pm[kc], vh, accO[j2]);
        accO[j2] = MFMAH(ph[kc], vm, accO[j2]);
      }
    }
    __syncthreads();
  }
  #pragma unroll
  for (int j2 = 0; j2 < 4; ++j2)
    #pragma unroll
    for (int r = 0; r < 4; ++r) {
      float ov = accO[j2][r] * (1.0f / 4096.0f) / lsum[r];
      long row = qt * 64 + w * 16 + lg * 4 + r;
      long idx = hbo + row * kD + j2 * 16 + lr;
      u16 hh, mm; split2s(ov, hh, mm);
      oP[idx] = hh;
      oP[oplane + idx] = mm;
    }
}

// ---------------- f32 attention (fallback path) ----------------

__global__ __launch_bounds__(256) void attn_f32_k(
    const float* __restrict__ qkv, float* __restrict__ of32, int ldq) {
  int qt = blockIdx.x;
  int bh = blockIdx.y;
  int b = bh >> 4, h = bh & 15;
  long hbq = (long)b * kT * ldq + h * kHD;
  long hbo = (long)b * kT * kD + h * kHD;
  int t = threadIdx.x, qr = t >> 2, sub = t & 3;

  __shared__ float Qs[64][68], Ks[64][68], Vs[64][68], Ps[64][68];

  const float* q = qkv;
  const float* k = qkv + kD;
  const float* v = qkv + 2 * kD;

  #pragma unroll
  for (int it = 0; it < 4; ++it) {
    int c = it * 256 + t, row = c >> 4, c4 = (c & 15) * 4;
    f32x4 qv = *(const f32x4*)(q + hbq + (long)(qt * 64 + row) * ldq + c4);
    #pragma unroll
    for (int j = 0; j < 4; ++j) Qs[row][c4 + j] = qv[j];
  }
  __syncthreads();
  f32x4 qreg[16];
  #pragma unroll
  for (int d4 = 0; d4 < 16; ++d4) qreg[d4] = *(const f32x4*)&Qs[qr][d4 * 4];
  int qg = qt * 64 + qr;

  float mrow = -1e30f, lsum = 0.f;
  f32x4 accO[4];
  #pragma unroll
  for (int i = 0; i < 4; ++i) accO[i] = 0.f;

  for (int itl = 0; itl <= qt; ++itl) {
    #pragma unroll
    for (int it = 0; it < 4; ++it) {
      int c = it * 256 + t, row = c >> 4, c4 = (c & 15) * 4;
      long gi = hbq + (long)(itl * 64 + row) * ldq + c4;
      f32x4 kv = *(const f32x4*)(k + gi);
      f32x4 vv = *(const f32x4*)(v + gi);
      #pragma unroll
      for (int j = 0; j < 4; ++j) { Ks[row][c4 + j] = kv[j]; Vs[row][c4 + j] = vv[j]; }
    }
    __syncthreads();

    float s[16];
    #pragma unroll
    for (int kk = 0; kk < 16; ++kk) {
      int key = kk * 4 + sub;
      f32x4 a = {0.f, 0.f, 0.f, 0.f};
      #pragma unroll
      for (int d4 = 0; d4 < 16; ++d4) a += qreg[d4] * *(const f32x4*)&Ks[key][d4 * 4];
      float sv = (a[0] + a[1] + a[2] + a[3]) * 0.125f;
      if (itl * 64 + key > qg) sv = -1e30f;
      s[kk] = sv;
    }
    float mx = s[0];
    #pragma unroll
    for (int kk = 1; kk < 16; ++kk) mx = fmaxf(mx, s[kk]);
    mx = fmaxf(mx, __shfl_xor(mx, 1));
    mx = fmaxf(mx, __shfl_xor(mx, 2));
    float mi = fmaxf(mrow, mx);
    float alpha = __expf(mrow - mi);
    mrow = mi;
    float rs = 0.f;
    #pragma unroll
    for (int kk = 0; kk < 16; ++kk) {
      float p = __expf(s[kk] - mi);
      rs += p;
      Ps[qr][kk * 4 + sub] = p;
    }
    rs += __shfl_xor(rs, 1);
    rs += __shfl_xor(rs, 2);
    lsum = lsum * alpha + rs;
    #pragma unroll
    for (int i = 0; i < 4; ++i) accO[i] *= alpha;
    #pragma unroll
    for (int key2 = 0; key2 < 64; ++key2) {
      float p = Ps[qr][key2];
      #pragma unroll
      for (int i4 = 0; i4 < 4; ++i4)
        accO[i4] += p * *(const f32x4*)&Vs[key2][sub * 16 + i4 * 4];
    }
    __syncthreads();
  }
  float inv = 1.f / lsum;
  #pragma unroll
  for (int i4 = 0; i4 < 4; ++i4) {
    f32x4 ov = accO[i4] * inv;
    *(f32x4*)(of32 + hbo + (long)qg * kD + sub * 16 + i4 * 4) = ov;
  }
}

// ---------------- host ----------------

extern "C" void kernel_launch(void* const* d_in, const int* in_sizes, int n_in,
                              void* d_out, int out_size, void* d_ws, size_t ws_size,
                              hipStream_t stream) {
  const int*   idx  = (const int*)  d_in[0];
  const float* wte  = (const float*)d_in[1];
  const float* wpe  = (const float*)d_in[2];
  const float* wq   = (const float*)d_in[3];
  const float* wk   = (const float*)d_in[4];
  const float* wv   = (const float*)d_in[5];
  const float* wo   = (const float*)d_in[6];
  const float* gate = (const float*)d_in[7];
  const float* f1   = (const float*)d_in[8];
  const float* f2   = (const float*)d_in[9];
  const float* lmh  = (const float*)d_in[10];
  float* out = (float*)d_out;

  char* ws = (char*)d_ws;
  size_t off = 0;
  auto alloc = [&](size_t b) -> char* {
    char* p = ws + off;
    off += (b + 255) & ~(size_t)255;
    return p;
  };

  constexpr long PLN_XN = (long)kBT * kD;
  constexpr long PLN_Q3 = (long)kBT * 3 * kD;
  constexpr long PLN_QKV = (long)3 * kD * kD;
  constexpr long PLN_WO = (long)kD * kD;
  constexpr long PLN_FF = (long)kE * kFF * kD;
  constexpr long PLN_H = (long)kSLOTS * kFF;
  constexpr long PLN_OUTS = (long)kSLOTS * kD;

  // shared small buffers
  float* x     = (float*)alloc((size_t)kBT * kD * 4);
  float* outs  = (float*)alloc((size_t)4 * PLN_OUTS * 4);   // 4 K-partials
  float* probs = (float*)alloc((size_t)kBT * kE * 4);
  int*   top2e = (int*)  alloc((size_t)kBT * 2 * 4);
  float* top2w = (float*)alloc((size_t)kBT * 2 * 4);
  int*   meta  = (int*)  alloc(64 * 4);
  int* counts = meta; int* cursors = meta + 8; int* offs = meta + 16;
  int*   rows  = (int*)  alloc((size_t)kSLOTS * 4);
  int*   slotOf= (int*)  alloc((size_t)kBT * 2 * 4);
  float* aux   = (float*)alloc(256);
  size_t off_shared = off;

  // fast-path buffers
  u16*   xnP   = (u16*)  alloc((size_t)2 * PLN_XN * 2);
  float* qkvf  = (float*)alloc((size_t)PLN_Q3 * 4);
  u16*   qkvP  = (u16*)  alloc((size_t)2 * PLN_Q3 * 2);
  u16*   ofP   = (u16*)  alloc((size_t)2 * PLN_XN * 2);
  u16*   hP    = (u16*)  alloc((size_t)2 * PLN_H * 2);
  u16*   wqkvP = (u16*)  alloc((size_t)kL * 2 * PLN_QKV * 2);
  u16*   woP   = (u16*)  alloc((size_t)kL * 2 * PLN_WO * 2);
  u16*   f1P   = (u16*)  alloc((size_t)2 * PLN_FF * 2);   // reused per layer
  u16*   f2P   = (u16*)  alloc((size_t)2 * PLN_FF * 2);
  u16*   lmb   = (u16*)  alloc((size_t)kV * kD * 2);
  bool fast = (off <= ws_size);
  float* qkvp1 = (float*)hP;          // alias: hP idle during QKV+attn phase

  dim3 gAttn(kT / 64, 2 * kH);
  // base grids (all % 8 == 0) — round-13 proven configuration
  int bQKV = (kBT / 128) * (3 * kD / 128);       // 384,  MPART mPerX=2, kParts=2
  int bWO  = (kBT / 128) * (kD / 128);           // 128,  MPART mPerX=2, kParts=4
  int nF1W = (kSLOTS / 128) * (kFF / 256);       // 640,  W kernel mPerX=5
  int bF2  = (kSLOTS / 128) * (kD / 128);        // 320,  MPART mPerX=5, kParts=4
  int nF1s = (kSLOTS / 128) * (kFF / 128);       // 1280, MPART mPerX=5
  int nLM  = (kBT / 128) * (kV / 128);           // 4000, mBlocks=16

  if (fast) {
    for (int li = 0; li < kL; ++li) {
      u16* dst = wqkvP + (size_t)li * 2 * PLN_QKV;
      split2h_k<<<1024, 256, 0, stream>>>(wq + (size_t)li * kD * kD, dst, PLN_QKV, (long)kD * kD / 4);
      split2h_k<<<1024, 256, 0, stream>>>(wk + (size_t)li * kD * kD, dst + (long)kD * kD, PLN_QKV, (long)kD * kD / 4);
      split2h_k<<<1024, 256, 0, stream>>>(wv + (size_t)li * kD * kD, dst + (long)2 * kD * kD, PLN_QKV, (long)kD * kD / 4);
      split2h_k<<<1024, 256, 0, stream>>>(wo + (size_t)li * kD * kD, woP + (size_t)li * 2 * PLN_WO, PLN_WO, (long)kD * kD / 4);
    }
    cast_h_k<<<4096, 256, 0, stream>>>(lmh, lmb, (long)kV * kD / 4);
    hipMemsetAsync(aux, 0, 4, stream);
    embed_rms_k<<<kBT, 256, 0, stream>>>(idx, wte, wpe, x);
    rmsnorm2h_k<<<kBT, 256, 0, stream>>>(x, xnP, PLN_XN);   // layer-0 QKV input

    for (int li = 0; li < kL; ++li) {
      // QKV: 128^2 kernel, split-K x2 -> qkvf + qkvp1; combine into split-2 planes
      gemm2h_bt_k<P_F32, false, false, true><<<2 * bQKV, 256, 0, stream>>>(
          xnP, PLN_XN, wqkvP + (size_t)li * 2 * PLN_QKV, PLN_QKV,
          qkvf, 0, nullptr, nullptr, nullptr, 3 * kD, kD, kD, 0, 2,
          2, bQKV, (long)(qkvp1 - qkvf));
      qkvcomb_k<<<2048, 256, 0, stream>>>(qkvf, qkvp1, qkvP, PLN_Q3, PLN_Q3 / 4);
      attn2h_k<<<gAttn, 256, 0, stream>>>(qkvP, PLN_Q3, ofP, PLN_XN);
      // WO: 128^2 kernel, split-K x4 into outs partials; fused residual+rms+split
      gemm2h_bt_k<P_F32, false, false, true><<<4 * bWO, 256, 0, stream>>>(
          ofP, PLN_XN, woP + (size_t)li * 2 * PLN_WO, PLN_WO,
          outs, 0, nullptr, nullptr, nullptr, kD, kD, kD, 0, 2,
          4, bWO, PLN_OUTS);
      resid4_rms2h_k<<<kBT, 256, 0, stream>>>(x, outs, PLN_OUTS, xnP, PLN_XN);
      hipMemsetAsync(meta, 0, 64, stream);
      gate_topk_k<<<kBT, 256, 0, stream>>>(x, gate + (size_t)li * kE * kD,
                                           probs, top2e, top2w, counts);
      calc_offsets_k<<<1, 64, 0, stream>>>(counts, offs);
      fill_slots_k<<<kBT / 256, 256, 0, stream>>>(top2e, offs, cursors, rows, slotOf);
      size_t fd = (size_t)li * PLN_FF;
      if (li < 2) {
        split2h2_k<<<8192, 256, 0, stream>>>(f1 + fd, f1P, f2 + fd, f2P,
                                             PLN_FF, PLN_FF / 4);
        gemm2hW_bt_k<P_SPLIT2_RELU, true, true><<<nF1W, 512, 0, stream>>>(
            xnP, PLN_XN, f1P, PLN_FF, hP, PLN_H, rows, offs,
            kFF, kD, kD, (long)kFF * kD, kSLOTS / 128 / 8,
            1, nF1W, 0);
        gemm2h_bt_k<P_F32, false, true, true><<<4 * bF2, 256, 0, stream>>>(
            hP, PLN_H, f2P, PLN_FF, outs, 0, nullptr, nullptr, offs,
            kD, kFF, kFF, (long)kD * kFF, kSLOTS / 128 / 8,
            4, bF2, PLN_OUTS);
        moe4_rms2h_k<<<kBT, 256, 0, stream>>>(x, outs, PLN_OUTS, slotOf, top2w,
                                              xnP, PLN_XN);
      } else {
        cast_h2_k<<<8192, 256, 0, stream>>>(f1 + fd, f1P, f2 + fd, f2P, PLN_FF / 4);
        gemm_bt_k<P_F16_RELU, true, true, true, false, true><<<nF1s, 256, 0, stream>>>(
            xnP, f1P, hP, rows, offs, kFF, kD, kD, (long)kFF * kD,
            1.0f / 64.0f, kSLOTS / 128 / 8, 1, nF1s, 0);
        gemm_bt_k<P_F32, true, false, true, false, true><<<4 * bF2, 256, 0, stream>>>(
            hP, f2P, outs, nullptr, offs, kD, kFF, kFF, (long)kD * kFF,
            1.0f, kSLOTS / 128 / 8, 4, bF2, PLN_OUTS);
        moe4_cast_h_k<<<kBT, 256, 0, stream>>>(x, outs, PLN_OUTS, slotOf, top2w, xnP);
      }
      aux_reduce_k<<<1, 256, 0, stream>>>(probs, aux);
    }
    gemm_bt_k<P_F32, false, false, true, false, false><<<nLM, 256, 0, stream>>>(
        xnP, lmb, out, nullptr, nullptr, kV, kD, kD, 0, 1.0f, kBT / 128,
        1, nLM, 0);
    write_aux_k<<<1, 64, 0, stream>>>(aux, out + (size_t)kBT * kV);
    return;
  }

  // ---------- fallback: f32 path ----------
  off = off_shared;
  float* xnf   = (float*)alloc((size_t)kBT * kD * 4);
  u16*   xnb   = (u16*)  alloc((size_t)kBT * kD * 2);
  float* qkvf32= (float*)alloc((size_t)kBT * 3 * kD * 4);
  float* off32 = (float*)alloc((size_t)kBT * kD * 4);
  float* hbuf  = (float*)alloc((size_t)kSLOTS * kFF * 4);
  u16* hbuf16 = (u16*)hbuf;

  hipMemsetAsync(aux, 0, 4, stream);
  embed_rms_k<<<kBT, 256, 0, stream>>>(idx, wte, wpe, x);
  dim3 gF1s(kSLOTS / 128, kFF / 128);
  dim3 gF2s(kSLOTS / 128, kD / 128);
  for (int li = 0; li < kL; ++li) {
    size_t dd = (size_t)li * kD * kD;
    rmsnorm2_k<<<kBT, 256, 0, stream>>>(x, xnf, xnb);
    dim3 gP(kBT / 128, kD / 128);
    sgemm_bt_k<P_F32, false, false><<<gP, 256, 0, stream>>>(
        xnf, wq + dd, qkvf32, nullptr, nullptr, nullptr, 3 * kD, kD, kD, 0);
    sgemm_bt_k<P_F32, false, false><<<gP, 256, 0, stream>>>(
        xnf, wk + dd, qkvf32 + kD, nullptr, nullptr, nullptr, 3 * kD, kD, kD, 0);
    sgemm_bt_k<P_F32, false, false><<<gP, 256, 0, stream>>>(
        xnf, wv + dd, qkvf32 + 2 * kD, nullptr, nullptr, nullptr, 3 * kD, kD, kD, 0);
    attn_f32_k<<<gAttn, 256, 0, stream>>>(qkvf32, off32, 3 * kD);
    sgemm_bt_k<P_F32_RESID, false, false><<<gP, 256, 0, stream>>>(
        off32, wo + dd, x, x, nullptr, nullptr, kD, kD, kD, 0);
    rmsnorm2_k<<<kBT, 256, 0, stream>>>(x, xnf, xnb);
    hipMemsetAsync(meta, 0, 64, stream);
    gate_topk_k<<<kBT, 256, 0, stream>>>(x, gate + (size_t)li * kE * kD,
                                         probs, top2e, top2w, counts);
    calc_offsets_k<<<1, 64, 0, stream>>>(counts, offs);
    fill_slots_k<<<kBT / 256, 256, 0, stream>>>(top2e, offs, cursors, rows, slotOf);
    size_t fd = (size_t)li * kE * kFF * kD;
    if (li < 2) {
      sgemm_bt_k<P_F32_RELU, true, true><<<gF1s, 256, 0, stream>>>(
          xnf, f1 + fd, hbuf, nullptr, rows, offs, kFF, kD, kD, (long)kFF * kD);
      sgemm_bt_k<P_F32, false, true><<<gF2s, 256, 0, stream>>>(
          hbuf, f2 + fd, outs, nullptr, nullptr, offs, kD, kFF, kFF, (long)kD * kFF);
    } else {
      gemm_bt_k<P_BF16_RELU, true, true, false, true, false><<<nF1s, 256, 0, stream>>>(
          xnb, f1 + fd, hbuf16, rows, offs, kFF, kD, kD, (long)kFF * kD,
          1.0f, kSLOTS / 128, 1, nF1s, 0);
      gemm_bt_k<P_F32, true, false, false, true, false><<<bF2, 256, 0, stream>>>(
          hbuf16, f2 + fd, outs, nullptr, offs, kD, kFF, kFF, (long)kD * kFF,
          1.0f, kSLOTS / 128, 1, bF2, 0);
    }
    hipMemsetAsync(outs + PLN_OUTS, 0, 3 * PLN_OUTS * 4, stream);
    moe_combine4_k<<<kBT, 256, 0, stream>>>(x, outs, PLN_OUTS, slotOf, top2w);
    aux_reduce_k<<<1, 256, 0, stream>>>(probs, aux);
  }
  cast_bf16_k<<<2048, 256, 0, stream>>>(x, xnb, (long)kBT * kD / 4);
  gemm_bt_k<P_F32, false, false, false, true, false><<<nLM, 256, 0, stream>>>(
      xnb, lmh, out, nullptr, nullptr, kV, kD, kD, 0, 1.0f, kBT / 128,
      1, nLM, 0);
  write_aux_k<<<1, 64, 0, stream>>>(aux, out + (size_t)kBT * kV);
}

// Round 16
// 2076.239 us; speedup vs baseline: 1.1375x; 1.0952x over previous
//
#include <hip/hip_runtime.h>

typedef unsigned short u16;
typedef __attribute__((ext_vector_type(4))) float f32x4;
typedef __attribute__((ext_vector_type(8))) __bf16 bf16x8;
typedef __attribute__((ext_vector_type(8))) _Float16 f16x8;
typedef __attribute__((ext_vector_type(4))) unsigned short u16x4;
typedef __attribute__((ext_vector_type(8))) unsigned short u16x8;

constexpr int kT = 1024, kD = 1024, kH = 16, kHD = 64, kL = 3, kE = 8;
constexpr int kFF = 4096, kV = 32000, kBT = 2048, kSLOTS = 5120;

__device__ __forceinline__ u16 f2bf(float f) {
  union { float f; unsigned u; } v; v.f = f;
  unsigned r = v.u + 0x7FFFu + ((v.u >> 16) & 1u);   // RNE
  return (u16)(r >> 16);
}
__device__ __forceinline__ u16 f2h(float x) {
  _Float16 h = (_Float16)x;
  union { _Float16 h; u16 u; } v; v.h = h; return v.u;
}
// uniform-scale fp16 split-2: 64*x = hi + mid + O(2^-11 * |64x - hi|)
__device__ __forceinline__ void split2s(float x, u16& h, u16& m) {
  float xs = x * 64.0f;
  _Float16 hh = (_Float16)xs;
  union { _Float16 h; u16 u; } v; v.h = hh; h = v.u;
  float r = xs - (float)hh;
  union { _Float16 h; u16 u; } w; w.h = (_Float16)r; m = w.u;
}

__device__ __forceinline__ void ld_lds16(const void* g, void* l) {
  __builtin_amdgcn_global_load_lds((const __attribute__((address_space(1))) void*)g,
                                   (__attribute__((address_space(3))) void*)l, 16, 0, 0);
}

#define MFMA16(a, b, c) __builtin_amdgcn_mfma_f32_16x16x32_bf16(a, b, c, 0, 0, 0)
#define MFMAH(a, b, c)  __builtin_amdgcn_mfma_f32_16x16x32_f16(a, b, c, 0, 0, 0)

__device__ __forceinline__ float blockReduceSum256(float v) {
  #pragma unroll
  for (int m = 32; m >= 1; m >>= 1) v += __shfl_xor(v, m);
  __shared__ float sh_[4];
  int w = threadIdx.x >> 6;
  if ((threadIdx.x & 63) == 0) sh_[w] = v;
  __syncthreads();
  v = (sh_[0] + sh_[1]) + (sh_[2] + sh_[3]);
  __syncthreads();
  return v;
}

// ---------------- elementwise / small kernels ----------------

__global__ __launch_bounds__(256) void cast_bf16_k(const float* __restrict__ in,
                                                   u16* __restrict__ out, long n4) {
  long i = (long)blockIdx.x * 256 + threadIdx.x;
  long stride = (long)gridDim.x * 256;
  for (; i < n4; i += stride) {
    f32x4 v = ((const f32x4*)in)[i];
    u16x4 o; o[0] = f2bf(v[0]); o[1] = f2bf(v[1]); o[2] = f2bf(v[2]); o[3] = f2bf(v[3]);
    ((u16x4*)out)[i] = o;
  }
}

__global__ __launch_bounds__(256) void cast_h_k(const float* __restrict__ in,
                                                u16* __restrict__ out, long n4) {
  long i = (long)blockIdx.x * 256 + threadIdx.x;
  long stride = (long)gridDim.x * 256;
  for (; i < n4; i += stride) {
    f32x4 v = ((const f32x4*)in)[i];
    u16x4 o; o[0] = f2h(v[0]); o[1] = f2h(v[1]); o[2] = f2h(v[2]); o[3] = f2h(v[3]);
    ((u16x4*)out)[i] = o;
  }
}

// f32 -> 2 fp16 planes (uniform x64 scale)
__global__ __launch_bounds__(256) void split2h_k(const float* __restrict__ in,
    u16* __restrict__ out, long planeStride, long n4) {
  long i = (long)blockIdx.x * 256 + threadIdx.x;
  long stride = (long)gridDim.x * 256;
  u16* o1 = out + planeStride;
  for (; i < n4; i += stride) {
    f32x4 v = ((const f32x4*)in)[i];
    u16x4 a, b;
    #pragma unroll
    for (int j = 0; j < 4; ++j) {
      u16 h, m; split2s(v[j], h, m);
      a[j] = h; b[j] = m;
    }
    ((u16x4*)out)[i] = a; ((u16x4*)o1)[i] = b;
  }
}

// qkv = p0 + p1 -> 2 fp16 planes (x64 scale)
__global__ __launch_bounds__(256) void qkvcomb_k(const float* __restrict__ a,
    const float* __restrict__ b, u16* __restrict__ oP, long plane, long n4) {
  long i = (long)blockIdx.x * 256 + threadIdx.x;
  long stride = (long)gridDim.x * 256;
  for (; i < n4; i += stride) {
    f32x4 v = ((const f32x4*)a)[i] + ((const f32x4*)b)[i];
    u16x4 hh, mm;
    #pragma unroll
    for (int j = 0; j < 4; ++j) {
      u16 h, m; split2s(v[j], h, m);
      hh[j] = h; mm[j] = m;
    }
    ((u16x4*)oP)[i] = hh;
    ((u16x4*)(oP + plane))[i] = mm;
  }
}

__global__ __launch_bounds__(256) void embed_rms_k(const int* __restrict__ idx,
    const float* __restrict__ wte, const float* __restrict__ wpe, float* __restrict__ x) {
  int tok = blockIdx.x, t = threadIdx.x;
  int id = idx[tok];
  int tt = tok & (kT - 1);
  f32x4 a = ((const f32x4*)(wte + (long)id * kD))[t];
  f32x4 p = ((const f32x4*)(wpe + (long)tt * kD))[t];
  f32x4 vv = a + p;
  float ss = vv[0]*vv[0] + vv[1]*vv[1] + vv[2]*vv[2] + vv[3]*vv[3];
  ss = blockReduceSum256(ss);
  float sc = rsqrtf(ss * (1.0f / kD) + 1e-5f);
  vv *= sc;
  ((f32x4*)(x + (long)tok * kD))[t] = vv;
}

// rmsnorm -> f32 + bf16 (fallback path)
__global__ __launch_bounds__(256) void rmsnorm2_k(const float* __restrict__ x,
    float* __restrict__ xnf, u16* __restrict__ xnb) {
  int tok = blockIdx.x, t = threadIdx.x;
  f32x4 vv = ((const f32x4*)(x + (long)tok * kD))[t];
  float ss = blockReduceSum256(vv[0]*vv[0] + vv[1]*vv[1] + vv[2]*vv[2] + vv[3]*vv[3]);
  float sc = rsqrtf(ss * (1.0f / kD) + 1e-5f);
  vv *= sc;
  ((f32x4*)(xnf + (long)tok * kD))[t] = vv;
  u16x4 o;
  o[0] = f2bf(vv[0]); o[1] = f2bf(vv[1]); o[2] = f2bf(vv[2]); o[3] = f2bf(vv[3]);
  ((u16x4*)(xnb + (long)tok * kD))[t] = o;
}

// rmsnorm -> 2 fp16 planes (fast path, x64 scale)
__global__ __launch_bounds__(256) void rmsnorm2h_k(const float* __restrict__ x,
    u16* __restrict__ xnP, long plane) {
  int tok = blockIdx.x, t = threadIdx.x;
  f32x4 vv = ((const f32x4*)(x + (long)tok * kD))[t];
  float ss = blockReduceSum256(vv[0]*vv[0] + vv[1]*vv[1] + vv[2]*vv[2] + vv[3]*vv[3]);
  float sc = rsqrtf(ss * (1.0f / kD) + 1e-5f);
  vv *= sc;
  u16x4 a, b;
  #pragma unroll
  for (int j = 0; j < 4; ++j) {
    u16 h, m; split2s(vv[j], h, m);
    a[j] = h; b[j] = m;
  }
  long o = (long)tok * kD / 4 + t;
  ((u16x4*)xnP)[o] = a;
  ((u16x4*)(xnP + plane))[o] = b;
}

// x += sum of 4 K-partials; write x; rmsnorm -> 2 fp16 planes
__global__ __launch_bounds__(256) void resid4_rms2h_k(float* __restrict__ x,
    const float* __restrict__ parts, long plane, u16* __restrict__ xnP, long xplane) {
  int tok = blockIdx.x, t = threadIdx.x;
  long o = (long)tok * (kD / 4) + t;
  f32x4 xv = ((f32x4*)x)[o];
  #pragma unroll
  for (int p = 0; p < 4; ++p) xv += ((const f32x4*)(parts + p * plane))[o];
  ((f32x4*)x)[o] = xv;
  float ss = blockReduceSum256(xv[0]*xv[0] + xv[1]*xv[1] + xv[2]*xv[2] + xv[3]*xv[3]);
  float sc = rsqrtf(ss * (1.0f / kD) + 1e-5f);
  f32x4 vv = xv * sc;
  u16x4 a, b;
  #pragma unroll
  for (int j = 0; j < 4; ++j) {
    u16 h, m; split2s(vv[j], h, m);
    a[j] = h; b[j] = m;
  }
  ((u16x4*)xnP)[o] = a;
  ((u16x4*)(xnP + xplane))[o] = b;
}

// x += moe combine (4 K-partials, 2 experts); write x; rmsnorm -> 2 fp16 planes
__global__ __launch_bounds__(256) void moe4_rms2h_k(float* __restrict__ x,
    const float* __restrict__ outsP, long plane, const int* __restrict__ slotOf,
    const float* __restrict__ top2w, u16* __restrict__ xnP, long xplane) {
  int tok = blockIdx.x, t = threadIdx.x;
  int s0 = slotOf[tok*2], s1 = slotOf[tok*2+1];
  float w0 = top2w[tok*2], w1 = top2w[tok*2+1];
  f32x4 a = {0.f,0.f,0.f,0.f}, b = a;
  #pragma unroll
  for (int p = 0; p < 4; ++p) {
    a += ((const f32x4*)(outsP + p * plane + (long)s0 * kD))[t];
    b += ((const f32x4*)(outsP + p * plane + (long)s1 * kD))[t];
  }
  long o = (long)tok * (kD / 4) + t;
  f32x4 xv = ((f32x4*)x)[o];
  xv += a * w0 + b * w1;
  ((f32x4*)x)[o] = xv;
  float ss = blockReduceSum256(xv[0]*xv[0] + xv[1]*xv[1] + xv[2]*xv[2] + xv[3]*xv[3]);
  float sc = rsqrtf(ss * (1.0f / kD) + 1e-5f);
  f32x4 vv = xv * sc;
  u16x4 ha, hb;
  #pragma unroll
  for (int j = 0; j < 4; ++j) {
    u16 h, m; split2s(vv[j], h, m);
    ha[j] = h; hb[j] = m;
  }
  ((u16x4*)xnP)[o] = ha;
  ((u16x4*)(xnP + xplane))[o] = hb;
}

// last layer: x += moe combine; write f16 (unscaled) plane for lm_head
__global__ __launch_bounds__(256) void moe4_cast_h_k(float* __restrict__ x,
    const float* __restrict__ outsP, long plane, const int* __restrict__ slotOf,
    const float* __restrict__ top2w, u16* __restrict__ xn) {
  int tok = blockIdx.x, t = threadIdx.x;
  int s0 = slotOf[tok*2], s1 = slotOf[tok*2+1];
  float w0 = top2w[tok*2], w1 = top2w[tok*2+1];
  f32x4 a = {0.f,0.f,0.f,0.f}, b = a;
  #pragma unroll
  for (int p = 0; p < 4; ++p) {
    a += ((const f32x4*)(outsP + p * plane + (long)s0 * kD))[t];
    b += ((const f32x4*)(outsP + p * plane + (long)s1 * kD))[t];
  }
  long o = (long)tok * (kD / 4) + t;
  f32x4 xv = ((f32x4*)x)[o];
  xv += a * w0 + b * w1;
  u16x4 hv;
  #pragma unroll
  for (int j = 0; j < 4; ++j) hv[j] = f2h(xv[j]);
  ((u16x4*)xn)[o] = hv;
}

// gating in f32 (bf16 would flip top-2 selections on near-ties)
__global__ __launch_bounds__(256) void gate_topk_k(const float* __restrict__ x,
    const float* __restrict__ gate_l, float* __restrict__ probs, int* __restrict__ top2e,
    float* __restrict__ top2w, int* __restrict__ counts) {
  int tok = blockIdx.x, t = threadIdx.x;
  f32x4 xv = ((const f32x4*)(x + (long)tok * kD))[t];
  float ss = blockReduceSum256(xv[0]*xv[0] + xv[1]*xv[1] + xv[2]*xv[2] + xv[3]*xv[3]);
  float sc = rsqrtf(ss * (1.0f / kD) + 1e-5f);
  float a[kE];
  #pragma unroll
  for (int e = 0; e < kE; ++e) {
    f32x4 gv = ((const f32x4*)(gate_l + (long)e * kD))[t];
    a[e] = xv[0]*gv[0] + xv[1]*gv[1] + xv[2]*gv[2] + xv[3]*gv[3];
  }
  __shared__ float sh8[kE][4];
  int w = t >> 6, l = t & 63;
  #pragma unroll
  for (int e = 0; e < kE; ++e) {
    float v = a[e];
    #pragma unroll
    for (int m = 32; m >= 1; m >>= 1) v += __shfl_xor(v, m);
    if (l == 0) sh8[e][w] = v;
  }
  __syncthreads();
  if (t == 0) {
    float lg[kE], mx = -1e30f;
    #pragma unroll
    for (int e = 0; e < kE; ++e) {
      lg[e] = (sh8[e][0] + sh8[e][1] + sh8[e][2] + sh8[e][3]) * sc;
      mx = fmaxf(mx, lg[e]);
    }
    float pe[kE], s = 0.f;
    #pragma unroll
    for (int e = 0; e < kE; ++e) { pe[e] = __expf(lg[e] - mx); s += pe[e]; }
    float inv = 1.f / s;
    int i1 = 0;
    #pragma unroll
    for (int e = 1; e < kE; ++e) if (lg[e] > lg[i1]) i1 = e;
    int i2 = (i1 == 0) ? 1 : 0;
    #pragma unroll
    for (int e = 0; e < kE; ++e) if (e != i1 && lg[e] > lg[i2]) i2 = e;
    #pragma unroll
    for (int e = 0; e < kE; ++e) probs[(long)tok * kE + e] = pe[e] * inv;
    float p1 = pe[i1] * inv, p2 = pe[i2] * inv;
    float wn = p1 + p2;
    top2e[tok*2] = i1; top2e[tok*2+1] = i2;
    top2w[tok*2] = p1 / wn; top2w[tok*2+1] = p2 / wn;
    atomicAdd(&counts[i1], 1); atomicAdd(&counts[i2], 1);
  }
}

// 128-aligned expert offsets
__global__ void calc_offsets_k(const int* __restrict__ counts, int* __restrict__ offsets) {
  if (threadIdx.x == 0) {
    int o = 0;
    #pragma unroll
    for (int e = 0; e < kE; ++e) { offsets[e] = o; o += (counts[e] + 127) & ~127; }
    offsets[kE] = o;
  }
}

__global__ __launch_bounds__(256) void fill_slots_k(const int* __restrict__ top2e,
    const int* __restrict__ offsets, int* __restrict__ cursors,
    int* __restrict__ rows, int* __restrict__ slotOf) {
  int tok = blockIdx.x * 256 + threadIdx.x;
  if (tok >= kBT) return;
  #pragma unroll
  for (int j = 0; j < 2; ++j) {
    int e = top2e[tok*2 + j];
    int pos = atomicAdd(&cursors[e], 1);
    int slot = offsets[e] + pos;
    rows[slot] = tok;
    slotOf[tok*2 + j] = slot;
  }
}

// fallback combine (4 partials; unused planes zeroed)
__global__ __launch_bounds__(256) void moe_combine4_k(float* __restrict__ x,
    const float* __restrict__ outsP, long plane, const int* __restrict__ slotOf,
    const float* __restrict__ top2w) {
  int tok = blockIdx.x, t = threadIdx.x;
  int s0 = slotOf[tok*2], s1 = slotOf[tok*2+1];
  float w0 = top2w[tok*2], w1 = top2w[tok*2+1];
  f32x4 a = {0.f,0.f,0.f,0.f}, b = a;
  #pragma unroll
  for (int p = 0; p < 4; ++p) {
    a += ((const f32x4*)(outsP + p * plane + (long)s0 * kD))[t];
    b += ((const f32x4*)(outsP + p * plane + (long)s1 * kD))[t];
  }
  f32x4 xv = ((f32x4*)(x + (long)tok * kD))[t];
  xv += a * w0 + b * w1;
  ((f32x4*)(x + (long)tok * kD))[t] = xv;
}

__global__ __launch_bounds__(256) void aux_reduce_k(const float* __restrict__ probs,
                                                    float* __restrict__ aux) {
  int t = threadIdx.x;
  float part[kE] = {};
  for (int i = t; i < kBT; i += 256) {
    #pragma unroll
    for (int e = 0; e < kE; ++e) part[e] += probs[(long)i * kE + e];
  }
  __shared__ float sh8[kE][4];
  int w = t >> 6, l = t & 63;
  #pragma unroll
  for (int e = 0; e < kE; ++e) {
    float v = part[e];
    #pragma unroll
    for (int m = 32; m >= 1; m >>= 1) v += __shfl_xor(v, m);
    if (l == 0) sh8[e][w] = v;
  }
  __syncthreads();
  if (t == 0) {
    float acc = 0.f;
    #pragma unroll
    for (int e = 0; e < kE; ++e) {
      float frac = (sh8[e][0] + sh8[e][1] + sh8[e][2] + sh8[e][3]) * (1.0f / kBT);
      acc += frac * frac;
    }
    aux[0] += (float)kE * acc;
  }
}

__global__ void write_aux_k(const float* __restrict__ aux, float* __restrict__ out) {
  if (threadIdx.x == 0) out[0] = 0.01f * aux[0] / (float)kL;
}

enum { P_BF16 = 0, P_BF16_RELU = 1, P_F32 = 2, P_F32_RESID = 3, P_F32_RELU = 4,
       P_SPLIT2_RELU = 5, P_F16_RELU = 6 };

__device__ __forceinline__ int clamp_row(int rv) {
  return ((unsigned)rv < (unsigned)kBT) ? rv : 0;
}

template <bool MPART>
__device__ __forceinline__ void block_mn(int lin, int base, int mArg, int& mb, int& nb) {
  int xcd = lin & 7, c = lin >> 3;
  if (MPART) {
    mb = xcd * mArg + (c % mArg);
    nb = c / mArg;
  } else {
    int swz = xcd * (base >> 3) + c;
    mb = swz % mArg;
    nb = swz / mArg;
  }
}

// ------- fused fp16 split-2 MFMA GEMM (128x128, 256 thr), single accumulator -------
// BF32: B is f32; staged via in-register split2s + swizzled ds_write (bit-identical
// to pre-converted planes; B read once from HBM, no conversion kernel needed).

template <int POST, bool GATHER, bool EXPERT, bool MPART, bool BF32>
__global__ __launch_bounds__(256) void gemm2h_bt_k(
    const u16* __restrict__ A0, long planeA,
    const void* __restrict__ Bv, long planeB,
    void* __restrict__ C, long planeC,
    const float* __restrict__ resid,
    const int* __restrict__ rows, const int* __restrict__ offsets,
    int N, int K, int lda, long eBstride, int mArg,
    int kParts, int base, long cPart) {
  constexpr int BM = 128, BK = 32;
  int part = blockIdx.x / base;
  int lin = blockIdx.x % base;
  int mb, nb;
  block_mn<MPART>(lin, base, mArg, mb, nb);
  int m0 = mb * BM, n0 = nb * BM;
  const u16* B0 = (const u16*)Bv;
  const float* Bf = (const float*)Bv;
  if (EXPERT) {
    int total = offsets[kE];
    if (m0 >= total) return;
    int e = 0;
    while (offsets[e + 1] <= m0) ++e;
    if (BF32) Bf += (long)e * eBstride; else B0 += (long)e * eBstride;
  }
  __shared__ __align__(16) u16 Ac[BM][64];
  __shared__ __align__(16) u16 Bc[BM][64];
  int t = threadIdx.x;
  int l = t & 63, lr = l & 15, lg = l >> 4;
  int wid = t >> 6;
  int wm = (wid >> 1) * 64, wn = (wid & 1) * 64;

  long asrc[4], bsrc[4];
  int ldst[4];
  #pragma unroll
  for (int it = 0; it < 4; ++it) {
    int d = it * 256 + t;
    int row = d >> 3, pc = d & 7;
    int lc = pc ^ (row & 7);
    int p = lc >> 2, c = lc & 3;
    int grow = GATHER ? clamp_row(rows[m0 + row]) : (m0 + row);
    asrc[it] = (long)p * planeA + (long)grow * lda + c * 8;
    if (!BF32) bsrc[it] = (long)p * planeB + (long)(n0 + row) * K + c * 8;
    ldst[it] = (it * 256 + (t & ~63)) * 8;
  }
  long bsrcF[2];
  int brow[2], bc[2];
  if (BF32) {
    #pragma unroll
    for (int it = 0; it < 2; ++it) {
      int d = it * 256 + t;            // 0..511 = 128 rows x 4 k-chunks
      brow[it] = d >> 2; bc[it] = d & 3;
      bsrcF[it] = (long)(n0 + brow[it]) * K + bc[it] * 8;
    }
  }
  int sa = lr & 7;
  int cH = (lg ^ sa) * 8;
  int cM = ((4 + lg) ^ sa) * 8;

  f32x4 acc[4][4];
  #pragma unroll
  for (int i = 0; i < 4; ++i)
    #pragma unroll
    for (int j = 0; j < 4; ++j) acc[i][j] = 0.f;

  int kStep = K / kParts;
  int kLo = part * kStep, kHi = kLo + kStep;
  for (int k0 = kLo; k0 < kHi; k0 += BK) {
    #pragma unroll
    for (int it = 0; it < 4; ++it) {
      ld_lds16(A0 + asrc[it] + k0, &Ac[0][0] + ldst[it]);
      if (!BF32) ld_lds16(B0 + bsrc[it] + k0, &Bc[0][0] + ldst[it]);
    }
    if (BF32) {
      #pragma unroll
      for (int it = 0; it < 2; ++it) {
        const float* src = Bf + bsrcF[it] + k0;
        f32x4 v0 = *(const f32x4*)src;
        f32x4 v1 = *(const f32x4*)(src + 4);
        u16x8 hi, mi;
        #pragma unroll
        for (int j = 0; j < 4; ++j) {
          u16 h, m; split2s(v0[j], h, m); hi[j] = h; mi[j] = m;
        }
        #pragma unroll
        for (int j = 0; j < 4; ++j) {
          u16 h, m; split2s(v1[j], h, m); hi[4 + j] = h; mi[4 + j] = m;
        }
        int r7 = brow[it] & 7;
        *(u16x8*)&Bc[brow[it]][(bc[it] ^ r7) * 8] = hi;
        *(u16x8*)&Bc[brow[it]][((4 + bc[it]) ^ r7) * 8] = mi;
      }
    }
    __syncthreads();
    f16x8 ah[4], am[4];
    #pragma unroll
    for (int i = 0; i < 4; ++i) {
      ah[i] = *(const f16x8*)&Ac[wm + i*16 + lr][cH];
      am[i] = *(const f16x8*)&Ac[wm + i*16 + lr][cM];
    }
    #pragma unroll
    for (int j = 0; j < 4; ++j) {
      f16x8 bh = *(const f16x8*)&Bc[wn + j*16 + lr][cH];
      f16x8 bm = *(const f16x8*)&Bc[wn + j*16 + lr][cM];
      #pragma unroll
      for (int i = 0; i < 4; ++i) {
        acc[i][j] = MFMAH(ah[i], bh, acc[i][j]);
        acc[i][j] = MFMAH(am[i], bh, acc[i][j]);
        acc[i][j] = MFMAH(ah[i], bm, acc[i][j]);
      }
    }
    __syncthreads();
  }
  float* Cf = (float*)C + (long)part * cPart;
  #pragma unroll
  for (int i = 0; i < 4; ++i) {
    #pragma unroll
    for (int r = 0; r < 4; ++r) {
      long m = m0 + wm + i*16 + lg*4 + r;
      #pragma unroll
      for (int j = 0; j < 4; ++j) {
        int n = n0 + wn + j*16 + lr;
        float val = acc[i][j][r] * (1.0f / 4096.0f);
        if (POST == P_F32) {
          Cf[m * N + n] = val;
        } else if (POST == P_F32_RESID) {
          ((float*)C)[m * N + n] = val + resid[m * N + n];
        } else if (POST == P_SPLIT2_RELU) {
          val = fmaxf(val, 0.f);
          u16 h, mm; split2s(val, h, mm);
          u16* Cp = (u16*)C;
          Cp[m * N + n] = h;
          Cp[planeC + m * N + n] = mm;
        }
      }
    }
  }
}

// ------- wide fused fp16 split-2 GEMM: 128x256 tile, 512 threads, 2m x 4n waves -------

template <int POST, bool GATHER, bool EXPERT, bool BF32>
__global__ __launch_bounds__(512) void gemm2hW_bt_k(
    const u16* __restrict__ A0, long planeA,
    const void* __restrict__ Bv, long planeB,
    void* __restrict__ C, long planeC,
    const int* __restrict__ rows, const int* __restrict__ offsets,
    int N, int K, int lda, long eBstride, int mPerX,
    int kParts, int base, long cPart) {
  constexpr int BM = 128, BN = 256, BK = 32;
  int part = blockIdx.x / base;
  int lin = blockIdx.x % base;
  int xcd = lin & 7, c0 = lin >> 3;
  int m0 = (xcd * mPerX + (c0 % mPerX)) * BM;
  int n0 = (c0 / mPerX) * BN;
  const u16* B0 = (const u16*)Bv;
  const float* Bf = (const float*)Bv;
  if (EXPERT) {
    int total = offsets[kE];
    if (m0 >= total) return;
    int e = 0;
    while (offsets[e + 1] <= m0) ++e;
    if (BF32) Bf += (long)e * eBstride; else B0 += (long)e * eBstride;
  }
  __shared__ __align__(16) u16 Ac[BM][64];
  __shared__ __align__(16) u16 Bc[BN][64];
  int t = threadIdx.x;
  int l = t & 63, lr = l & 15, lg = l >> 4;
  int wid = t >> 6;
  int wm = (wid >> 2) * 64;
  int wn = (wid & 3) * 64;

  long asrc[2], bsrc[4];
  int aldst[2], bldst[4];
  #pragma unroll
  for (int it = 0; it < 2; ++it) {
    int d = it * 512 + t;
    int row = d >> 3, pc = d & 7;
    int lc = pc ^ (row & 7);
    int p = lc >> 2, cc = lc & 3;
    int grow = GATHER ? clamp_row(rows[m0 + row]) : (m0 + row);
    asrc[it] = (long)p * planeA + (long)grow * lda + cc * 8;
    aldst[it] = (it * 512 + (t & ~63)) * 8;
  }
  long bsrcF[2];
  int brow[2], bcc[2];
  if (!BF32) {
    #pragma unroll
    for (int it = 0; it < 4; ++it) {
      int d = it * 512 + t;
      int row = d >> 3, pc = d & 7;
      int lc = pc ^ (row & 7);
      int p = lc >> 2, cc = lc & 3;
      bsrc[it] = (long)p * planeB + (long)(n0 + row) * K + cc * 8;
      bldst[it] = (it * 512 + (t & ~63)) * 8;
    }
  } else {
    #pragma unroll
    for (int it = 0; it < 2; ++it) {
      int d = it * 512 + t;            // 0..1023 = 256 rows x 4 k-chunks
      brow[it] = d >> 2; bcc[it] = d & 3;
      bsrcF[it] = (long)(n0 + brow[it]) * K + bcc[it] * 8;
    }
  }
  int sa = lr & 7;
  int cH = (lg ^ sa) * 8;
  int cM = ((4 + lg) ^ sa) * 8;

  f32x4 acc[4][4];
  #pragma unroll
  for (int i = 0; i < 4; ++i)
    #pragma unroll
    for (int j = 0; j < 4; ++j) acc[i][j] = 0.f;

  int kStep = K / kParts;
  int kLo = part * kStep, kHi = kLo + kStep;
  for (int k0 = kLo; k0 < kHi; k0 += BK) {
    #pragma unroll
    for (int it = 0; it < 2; ++it)
      ld_lds16(A0 + asrc[it] + k0, &Ac[0][0] + aldst[it]);
    if (!BF32) {
      #pragma unroll
      for (int it = 0; it < 4; ++it)
        ld_lds16(B0 + bsrc[it] + k0, &Bc[0][0] + bldst[it]);
    } else {
      #pragma unroll
      for (int it = 0; it < 2; ++it) {
        const float* src = Bf + bsrcF[it] + k0;
        f32x4 v0 = *(const f32x4*)src;
        f32x4 v1 = *(const f32x4*)(src + 4);
        u16x8 hi, mi;
        #pragma unroll
        for (int j = 0; j < 4; ++j) {
          u16 h, m; split2s(v0[j], h, m); hi[j] = h; mi[j] = m;
        }
        #pragma unroll
        for (int j = 0; j < 4; ++j) {
          u16 h, m; split2s(v1[j], h, m); hi[4 + j] = h; mi[4 + j] = m;
        }
        int r7 = brow[it] & 7;
        *(u16x8*)&Bc[brow[it]][(bcc[it] ^ r7) * 8] = hi;
        *(u16x8*)&Bc[brow[it]][((4 + bcc[it]) ^ r7) * 8] = mi;
      }
    }
    __syncthreads();
    f16x8 ah[4], am[4];
    #pragma unroll
    for (int i = 0; i < 4; ++i) {
      ah[i] = *(const f16x8*)&Ac[wm + i*16 + lr][cH];
      am[i] = *(const f16x8*)&Ac[wm + i*16 + lr][cM];
    }
    #pragma unroll
    for (int j = 0; j < 4; ++j) {
      f16x8 bh = *(const f16x8*)&Bc[wn + j*16 + lr][cH];
      f16x8 bm = *(const f16x8*)&Bc[wn + j*16 + lr][cM];
      #pragma unroll
      for (int i = 0; i < 4; ++i) {
        acc[i][j] = MFMAH(ah[i], bh, acc[i][j]);
        acc[i][j] = MFMAH(am[i], bh, acc[i][j]);
        acc[i][j] = MFMAH(ah[i], bm, acc[i][j]);
      }
    }
    __syncthreads();
  }
  float* Cf = (float*)C + (long)part * cPart;
  #pragma unroll
  for (int i = 0; i < 4; ++i) {
    #pragma unroll
    for (int r = 0; r < 4; ++r) {
      long m = m0 + wm + i*16 + lg*4 + r;
      #pragma unroll
      for (int j = 0; j < 4; ++j) {
        int n = n0 + wn + j*16 + lr;
        float val = acc[i][j][r] * (1.0f / 4096.0f);
        if (POST == P_F32) {
          Cf[m * N + n] = val;
        } else if (POST == P_SPLIT2_RELU) {
          val = fmaxf(val, 0.f);
          u16 h, mm; split2s(val, h, mm);
          u16* Cp = (u16*)C;
          Cp[m * N + n] = h;
          Cp[planeC + m * N + n] = mm;
        }
      }
    }
  }
}

// ---------------- single-plane MFMA GEMM (with optional split-K) ----------------

template <int POST, bool EXPERT, bool GATHER, bool HALF, bool BCONV, bool MPART>
__global__ __launch_bounds__(256) void gemm_bt_k(
    const u16* __restrict__ A, const void* __restrict__ Bv, void* __restrict__ C,
    const int* __restrict__ rows, const int* __restrict__ offsets,
    int N, int K, int lda, long eBstride, float oscale, int mArg,
    int kParts, int base, long cPart) {
  constexpr int BM = 128, BK = 64;
  int part = blockIdx.x / base;
  int lin = blockIdx.x % base;
  int mb, nb;
  block_mn<MPART>(lin, base, mArg, mb, nb);
  int m0 = mb * BM, n0 = nb * BM;
  const float* Bf = (const float*)Bv;
  const u16*   Bh = (const u16*)Bv;
  if (EXPERT) {
    int total = offsets[kE];
    if (m0 >= total) return;
    int e = 0;
    while (offsets[e + 1] <= m0) ++e;
    if (BCONV) Bf += (long)e * eBstride; else Bh += (long)e * eBstride;
  }
  __shared__ __align__(16) u16 As[BM][BK];
  __shared__ __align__(16) u16 Bs[BM][BK + (BCONV ? 8 : 0)];
  int t = threadIdx.x;
  int l = t & 63, lr = l & 15, lg = l >> 4;
  int wid = t >> 6;
  int wm = (wid >> 1) * 64, wn = (wid & 1) * 64;

  long asrc[4], bsrc[4];
  int ldst[4];
  #pragma unroll
  for (int it = 0; it < 4; ++it) {
    int d = it * 256 + t;
    int row = d >> 3, pc = d & 7;
    int c = pc ^ (row & 7);
    int grow = GATHER ? clamp_row(rows[m0 + row]) : (m0 + row);
    asrc[it] = (long)grow * lda + c * 8;
    bsrc[it] = (long)(n0 + row) * K + c * 8;
    ldst[it] = (it * 256 + (t & ~63)) * 8;
  }
  f32x4 acc[4][4];
  #pragma unroll
  for (int i = 0; i < 4; ++i)
    #pragma unroll
    for (int j = 0; j < 4; ++j) acc[i][j] = 0.f;

  int kStep = K / kParts;
  int kLo = part * kStep, kHi = kLo + kStep;
  for (int k0 = kLo; k0 < kHi; k0 += BK) {
    #pragma unroll
    for (int it = 0; it < 4; ++it)
      ld_lds16(A + asrc[it] + k0, &As[0][0] + ldst[it]);
    if (!BCONV) {
      #pragma unroll
      for (int it = 0; it < 4; ++it)
        ld_lds16(Bh + bsrc[it] + k0, &Bs[0][0] + ldst[it]);
    } else {
      #pragma unroll
      for (int it = 0; it < 8; ++it) {
        int c = it * 256 + t;
        int row = c >> 4, col = (c & 15) * 4;
        f32x4 v = *(const f32x4*)(Bf + (long)(n0 + row) * K + k0 + col);
        u16x4 o;
        #pragma unroll
        for (int j = 0; j < 4; ++j) o[j] = HALF ? f2h(v[j]) : f2bf(v[j]);
        *(u16x4*)&Bs[row][col] = o;
      }
    }
    __syncthreads();
    #pragma unroll
    for (int kk = 0; kk < 2; ++kk) {
      int ca = ((kk * 4 + lg) ^ (lr & 7)) * 8;
      int cb = BCONV ? (kk * 32 + lg * 8) : ca;
      #pragma unroll
      for (int i = 0; i < 4; ++i)
        #pragma unroll
        for (int j = 0; j < 4; ++j) {
          if (HALF) {
            f16x8 af = *(const f16x8*)&As[wm + i*16 + lr][ca];
            f16x8 bq = *(const f16x8*)&Bs[wn + j*16 + lr][cb];
            acc[i][j] = MFMAH(af, bq, acc[i][j]);
          } else {
            bf16x8 af = *(const bf16x8*)&As[wm + i*16 + lr][ca];
            bf16x8 bq = *(const bf16x8*)&Bs[wn + j*16 + lr][cb];
            acc[i][j] = MFMA16(af, bq, acc[i][j]);
          }
        }
    }
    __syncthreads();
  }
  #pragma unroll
  for (int i = 0; i < 4; ++i) {
    #pragma unroll
    for (int r = 0; r < 4; ++r) {
      long m = m0 + wm + i*16 + lg*4 + r;
      #pragma unroll
      for (int j = 0; j < 4; ++j) {
        int n = n0 + wn + j*16 + lr;
        float val = acc[i][j][r] * oscale;
        if (POST == P_BF16_RELU)       ((u16*)C)[m * N + n] = f2bf(fmaxf(val, 0.f));
        else if (POST == P_F16_RELU)   ((u16*)C)[m * N + n] = f2h(fmaxf(val, 0.f));
        else if (POST == P_F32)        ((float*)C + (long)part * cPart)[m * N + n] = val;
      }
    }
  }
}

// ---------------- f32 SGEMM (fallback path only) ----------------

template <int POST, bool GATHER, bool EXPERT>
__global__ __launch_bounds__(256) void sgemm_bt_k(
    const float* __restrict__ A, const float* __restrict__ B, float* __restrict__ C,
    const float* __restrict__ resid, const int* __restrict__ rows,
    const int* __restrict__ offsets, int N, int K, int lda, long eBstride) {
  constexpr int BM = 128, BN = 128, BK = 32;
  int m0 = blockIdx.x * BM, n0 = blockIdx.y * BN;
  if (EXPERT) {
    int total = offsets[kE];
    if (m0 >= total) return;
    int e = 0;
    while (offsets[e + 1] <= m0) ++e;
    B += (long)e * eBstride;
  }
  __shared__ float Ast[BK][BM];
  __shared__ float Bst[BK][BN];
  int t = threadIdx.x, tx = t & 15, ty = t >> 4;
  long asrc[4], bsrc[4];
  #pragma unroll
  for (int it = 0; it < 4; ++it) {
    int c = it * 256 + t;
    int row = c >> 3, kc = (c & 7) * 4;
    int gr = GATHER ? clamp_row(rows[m0 + row]) : (m0 + row);
    asrc[it] = (long)gr * lda + kc;
    bsrc[it] = (long)(n0 + row) * K + kc;
  }
  f32x4 accv[8][2];
  #pragma unroll
  for (int i = 0; i < 8; ++i) { accv[i][0] = 0.f; accv[i][1] = 0.f; }

  for (int k0 = 0; k0 < K; k0 += BK) {
    #pragma unroll
    for (int it = 0; it < 4; ++it) {
      int c = it * 256 + t;
      int row = c >> 3, kc = (c & 7) * 4;
      f32x4 av = *(const f32x4*)(A + asrc[it] + k0);
      f32x4 bv = *(const f32x4*)(B + bsrc[it] + k0);
      #pragma unroll
      for (int j = 0; j < 4; ++j) { Ast[kc + j][row] = av[j]; Bst[kc + j][row] = bv[j]; }
    }
    __syncthreads();
    #pragma unroll
    for (int kk = 0; kk < BK; ++kk) {
      f32x4 a0 = *(const f32x4*)&Ast[kk][ty * 4];
      f32x4 a1 = *(const f32x4*)&Ast[kk][64 + ty * 4];
      f32x4 b0 = *(const f32x4*)&Bst[kk][tx * 4];
      f32x4 b1 = *(const f32x4*)&Bst[kk][64 + tx * 4];
      float as[8] = {a0[0], a0[1], a0[2], a0[3], a1[0], a1[1], a1[2], a1[3]};
      #pragma unroll
      for (int i = 0; i < 8; ++i) {
        accv[i][0] += b0 * as[i];
        accv[i][1] += b1 * as[i];
      }
    }
    __syncthreads();
  }
  #pragma unroll
  for (int ih = 0; ih < 2; ++ih)
    #pragma unroll
    for (int i = 0; i < 4; ++i) {
      long m = m0 + ih * 64 + ty * 4 + i;
      #pragma unroll
      for (int jh = 0; jh < 2; ++jh) {
        long n = n0 + jh * 64 + tx * 4;
        f32x4 val = accv[ih * 4 + i][jh];
        if (POST == P_F32_RELU) {
          #pragma unroll
          for (int j = 0; j < 4; ++j) val[j] = fmaxf(val[j], 0.f);
        }
        if (POST == P_F32_RESID) val += *(const f32x4*)&resid[m * N + n];
        *(f32x4*)&C[m * N + n] = val;
      }
    }
}

// ------- MFMA split-2 attention (f32-equivalent accuracy) -------

__global__ __launch_bounds__(256) void attn2h_k(
    const u16* __restrict__ qkvP, long qplane,
    u16* __restrict__ oP, long oplane) {
  int qt = (int)gridDim.x - 1 - (int)blockIdx.x;   // heavy first
  int bh = blockIdx.y;
  int b = bh >> 4, h = bh & 15;
  const int ldq = 3 * kD;
  long hbq = (long)b * kT * ldq + h * kHD;
  long hbo = (long)b * kT * kD + h * kHD;
  int t = threadIdx.x, w = t >> 6, l = t & 63;
  int lr = l & 15, lg = l >> 4;

  __shared__ __align__(16) u16 Ks[2][64][72];
  __shared__ __align__(16) u16 Vt[2][64][72];
  __shared__ __align__(16) u16 Ps[2][4][16][72];

  f16x8 qf0[2], qf1[2];
  {
    long qrow = qt * 64 + w * 16 + lr;
    const u16* qp = qkvP + hbq + qrow * ldq;
    #pragma unroll
    for (int kc = 0; kc < 2; ++kc) {
      qf0[kc] = *(const f16x8*)(qp + kc * 32 + lg * 8);
      qf1[kc] = *(const f16x8*)(qp + qplane + kc * 32 + lg * 8);
    }
  }
  int qg = qt * 64 + w * 16 + lg * 4;

  float mrow[4], lsum[4];
  f32x4 accO[4];
  #pragma unroll
  for (int r = 0; r < 4; ++r) { mrow[r] = -1e30f; lsum[r] = 0.f; }
  #pragma unroll
  for (int j = 0; j < 4; ++j) accO[j] = 0.f;

  for (int it = 0; it <= qt; ++it) {
    #pragma unroll
    for (int p = 0; p < 2; ++p) {
      #pragma unroll
      for (int s = 0; s < 2; ++s) {
        int c = s * 256 + t;
        int row = c >> 3, col = (c & 7) * 8;
        long gi = (long)p * qplane + hbq + (long)(it * 64 + row) * ldq + col;
        *(u16x8*)&Ks[p][row][col] = *(const u16x8*)(qkvP + kD + gi);
        u16x8 vv = *(const u16x8*)(qkvP + 2 * kD + gi);
        #pragma unroll
        for (int j = 0; j < 8; ++j) Vt[p][col + j][row] = vv[j];
      }
    }
    __syncthreads();

    f32x4 s4[4];
    #pragma unroll
    for (int j = 0; j < 4; ++j) {
      f32x4 z = {0.f, 0.f, 0.f, 0.f};
      #pragma unroll
      for (int kc = 0; kc < 2; ++kc) {
        f16x8 kh = *(const f16x8*)&Ks[0][j*16 + lr][kc*32 + lg*8];
        f16x8 km = *(const f16x8*)&Ks[1][j*16 + lr][kc*32 + lg*8];
        z = MFMAH(qf0[kc], kh, z);
        z = MFMAH(qf1[kc], kh, z);
        z = MFMAH(qf0[kc], km, z);
      }
      s4[j] = z;
    }
    #pragma unroll
    for (int j = 0; j < 4; ++j)
      #pragma unroll
      for (int r = 0; r < 4; ++r) {
        float sv = s4[j][r] * (0.125f / 4096.0f);
        if (it * 64 + j * 16 + lr > qg + r) sv = -1e30f;
        s4[j][r] = sv;
      }
    float alpha[4];
    #pragma unroll
    for (int r = 0; r < 4; ++r) {
      float mx = fmaxf(fmaxf(s4[0][r], s4[1][r]), fmaxf(s4[2][r], s4[3][r]));
      mx = fmaxf(mx, __shfl_xor(mx, 1));
      mx = fmaxf(mx, __shfl_xor(mx, 2));
      mx = fmaxf(mx, __shfl_xor(mx, 4));
      mx = fmaxf(mx, __shfl_xor(mx, 8));
      float mi = fmaxf(mrow[r], mx);
      alpha[r] = __expf(mrow[r] - mi);
      mrow[r] = mi;
    }
    float rs[4] = {0.f, 0.f, 0.f, 0.f};
    #pragma unroll
    for (int j = 0; j < 4; ++j)
      #pragma unroll
      for (int r = 0; r < 4; ++r) {
        float p = __expf(s4[j][r] - mrow[r]);
        rs[r] += p;
        u16 hh, mm; split2s(p, hh, mm);
        Ps[0][w][lg*4 + r][j*16 + lr] = hh;
        Ps[1][w][lg*4 + r][j*16 + lr] = mm;
      }
    #pragma unroll
    for (int r = 0; r < 4; ++r) {
      float x2 = rs[r];
      x2 += __shfl_xor(x2, 1);
      x2 += __shfl_xor(x2, 2);
      x2 += __shfl_xor(x2, 4);
      x2 += __shfl_xor(x2, 8);
      lsum[r] = lsum[r] * alpha[r] + x2;
    }
    #pragma unroll
    for (int j = 0; j < 4; ++j)
      #pragma unroll
      for (int r = 0; r < 4; ++r) accO[j][r] *= alpha[r];
    __syncthreads();

    f16x8 ph[2], pm[2];
    #pragma unroll
    for (int kc = 0; kc < 2; ++kc) {
      ph[kc] = *(const f16x8*)&Ps[0][w][lr][kc*32 + lg*8];
      pm[kc] = *(const f16x8*)&Ps[1][w][lr][kc*32 + lg*8];
    }
    #pragma unroll
    for (int j2 = 0; j2 < 4; ++j2) {
      #pragma unroll
      for (int kc = 0; kc < 2; ++kc) {
        f16x8 vh = *(const f16x8*)&Vt[0][j2*16 + lr][kc*32 + lg*8];
        f16x8 vm = *(const f16x8*)&Vt[1][j2*16 + lr][kc*32 + lg*8];
        accO[j2] = MFMAH(ph[kc], vh, accO[j2]);
        accO[j2] = MFMAH(pm[kc], vh, accO[j2]);
        accO[j2] = MFMAH(ph[kc], vm, accO[j2]);
      }
    }
    __syncthreads();
  }
  #pragma unroll
  for (int j2 = 0; j2 < 4; ++j2)
    #pragma unroll
    for (int r = 0; r < 4; ++r) {
      float ov = accO[j2][r] * (1.0f / 4096.0f) / lsum[r];
      long row = qt * 64 + w * 16 + lg * 4 + r;
      long idx = hbo + row * kD + j2 * 16 + lr;
      u16 hh, mm; split2s(ov, hh, mm);
      oP[idx] = hh;
      oP[oplane + idx] = mm;
    }
}

// ---------------- f32 attention (fallback path) ----------------

__global__ __launch_bounds__(256) void attn_f32_k(
    const float* __restrict__ qkv, float* __restrict__ of32, int ldq) {
  int qt = blockIdx.x;
  int bh = blockIdx.y;
  int b = bh >> 4, h = bh & 15;
  long hbq = (long)b * kT * ldq + h * kHD;
  long hbo = (long)b * kT * kD + h * kHD;
  int t = threadIdx.x, qr = t >> 2, sub = t & 3;

  __shared__ float Qs[64][68], Ks[64][68], Vs[64][68], Ps[64][68];

  const float* q = qkv;
  const float* k = qkv + kD;
  const float* v = qkv + 2 * kD;

  #pragma unroll
  for (int it = 0; it < 4; ++it) {
    int c = it * 256 + t, row = c >> 4, c4 = (c & 15) * 4;
    f32x4 qv = *(const f32x4*)(q + hbq + (long)(qt * 64 + row) * ldq + c4);
    #pragma unroll
    for (int j = 0; j < 4; ++j) Qs[row][c4 + j] = qv[j];
  }
  __syncthreads();
  f32x4 qreg[16];
  #pragma unroll
  for (int d4 = 0; d4 < 16; ++d4) qreg[d4] = *(const f32x4*)&Qs[qr][d4 * 4];
  int qg = qt * 64 + qr;

  float mrow = -1e30f, lsum = 0.f;
  f32x4 accO[4];
  #pragma unroll
  for (int i = 0; i < 4; ++i) accO[i] = 0.f;

  for (int itl = 0; itl <= qt; ++itl) {
    #pragma unroll
    for (int it = 0; it < 4; ++it) {
      int c = it * 256 + t, row = c >> 4, c4 = (c & 15) * 4;
      long gi = hbq + (long)(itl * 64 + row) * ldq + c4;
      f32x4 kv = *(const f32x4*)(k + gi);
      f32x4 vv = *(const f32x4*)(v + gi);
      #pragma unroll
      for (int j = 0; j < 4; ++j) { Ks[row][c4 + j] = kv[j]; Vs[row][c4 + j] = vv[j]; }
    }
    __syncthreads();

    float s[16];
    #pragma unroll
    for (int kk = 0; kk < 16; ++kk) {
      int key = kk * 4 + sub;
      f32x4 a = {0.f, 0.f, 0.f, 0.f};
      #pragma unroll
      for (int d4 = 0; d4 < 16; ++d4) a += qreg[d4] * *(const f32x4*)&Ks[key][d4 * 4];
      float sv = (a[0] + a[1] + a[2] + a[3]) * 0.125f;
      if (itl * 64 + key > qg) sv = -1e30f;
      s[kk] = sv;
    }
    float mx = s[0];
    #pragma unroll
    for (int kk = 1; kk < 16; ++kk) mx = fmaxf(mx, s[kk]);
    mx = fmaxf(mx, __shfl_xor(mx, 1));
    mx = fmaxf(mx, __shfl_xor(mx, 2));
    float mi = fmaxf(mrow, mx);
    float alpha = __expf(mrow - mi);
    mrow = mi;
    float rs = 0.f;
    #pragma unroll
    for (int kk = 0; kk < 16; ++kk) {
      float p = __expf(s[kk] - mi);
      rs += p;
      Ps[qr][kk * 4 + sub] = p;
    }
    rs += __shfl_xor(rs, 1);
    rs += __shfl_xor(rs, 2);
    lsum = lsum * alpha + rs;
    #pragma unroll
    for (int i = 0; i < 4; ++i) accO[i] *= alpha;
    #pragma unroll
    for (int key2 = 0; key2 < 64; ++key2) {
      float p = Ps[qr][key2];
      #pragma unroll
      for (int i4 = 0; i4 < 4; ++i4)
        accO[i4] += p * *(const f32x4*)&Vs[key2][sub * 16 + i4 * 4];
    }
    __syncthreads();
  }
  float inv = 1.f / lsum;
  #pragma unroll
  for (int i4 = 0; i4 < 4; ++i4) {
    f32x4 ov = accO[i4] * inv;
    *(f32x4*)(of32 + hbo + (long)qg * kD + sub * 16 + i4 * 4) = ov;
  }
}

// ---------------- host ----------------

extern "C" void kernel_launch(void* const* d_in, const int* in_sizes, int n_in,
                              void* d_out, int out_size, void* d_ws, size_t ws_size,
                              hipStream_t stream) {
  const int*   idx  = (const int*)  d_in[0];
  const float* wte  = (const float*)d_in[1];
  const float* wpe  = (const float*)d_in[2];
  const float* wq   = (const float*)d_in[3];
  const float* wk   = (const float*)d_in[4];
  const float* wv   = (const float*)d_in[5];
  const float* wo   = (const float*)d_in[6];
  const float* gate = (const float*)d_in[7];
  const float* f1   = (const float*)d_in[8];
  const float* f2   = (const float*)d_in[9];
  const float* lmh  = (const float*)d_in[10];
  float* out = (float*)d_out;

  char* ws = (char*)d_ws;
  size_t off = 0;
  auto alloc = [&](size_t b) -> char* {
    char* p = ws + off;
    off += (b + 255) & ~(size_t)255;
    return p;
  };

  constexpr long PLN_XN = (long)kBT * kD;
  constexpr long PLN_Q3 = (long)kBT * 3 * kD;
  constexpr long PLN_QKV = (long)3 * kD * kD;
  constexpr long PLN_WO = (long)kD * kD;
  constexpr long PLN_FF = (long)kE * kFF * kD;
  constexpr long PLN_H = (long)kSLOTS * kFF;
  constexpr long PLN_OUTS = (long)kSLOTS * kD;

  // shared small buffers
  float* x     = (float*)alloc((size_t)kBT * kD * 4);
  float* outs  = (float*)alloc((size_t)4 * PLN_OUTS * 4);   // 4 K-partials
  float* probs = (float*)alloc((size_t)kBT * kE * 4);
  int*   top2e = (int*)  alloc((size_t)kBT * 2 * 4);
  float* top2w = (float*)alloc((size_t)kBT * 2 * 4);
  int*   meta  = (int*)  alloc(64 * 4);
  int* counts = meta; int* cursors = meta + 8; int* offs = meta + 16;
  int*   rows  = (int*)  alloc((size_t)kSLOTS * 4);
  int*   slotOf= (int*)  alloc((size_t)kBT * 2 * 4);
  float* aux   = (float*)alloc(256);
  size_t off_shared = off;

  // fast-path buffers
  u16*   xnP   = (u16*)  alloc((size_t)2 * PLN_XN * 2);
  float* qkvf  = (float*)alloc((size_t)PLN_Q3 * 4);
  u16*   qkvP  = (u16*)  alloc((size_t)2 * PLN_Q3 * 2);
  u16*   ofP   = (u16*)  alloc((size_t)2 * PLN_XN * 2);
  u16*   hP    = (u16*)  alloc((size_t)2 * PLN_H * 2);
  u16*   wqkvP = (u16*)  alloc((size_t)kL * 2 * PLN_QKV * 2);
  u16*   woP   = (u16*)  alloc((size_t)kL * 2 * PLN_WO * 2);
  bool fast = (off <= ws_size);
  float* qkvp1 = (float*)hP;          // alias: hP idle during QKV+attn phase

  dim3 gAttn(kT / 64, 2 * kH);
  // base grids (all % 8 == 0)
  int bQKV = (kBT / 128) * (3 * kD / 128);       // 384,  MPART mPerX=2, kParts=2
  int bWO  = (kBT / 128) * (kD / 128);           // 128,  MPART mPerX=2, kParts=4
  int nF1W = (kSLOTS / 128) * (kFF / 256);       // 640,  W kernel mPerX=5
  int bF2  = (kSLOTS / 128) * (kD / 128);        // 320,  MPART mPerX=5, kParts=4
  int nF1s = (kSLOTS / 128) * (kFF / 128);       // 1280, MPART mPerX=5
  int nLM  = (kBT / 128) * (kV / 128);           // 4000, mBlocks=16

  if (fast) {
    for (int li = 0; li < kL; ++li) {
      u16* dst = wqkvP + (size_t)li * 2 * PLN_QKV;
      split2h_k<<<1024, 256, 0, stream>>>(wq + (size_t)li * kD * kD, dst, PLN_QKV, (long)kD * kD / 4);
      split2h_k<<<1024, 256, 0, stream>>>(wk + (size_t)li * kD * kD, dst + (long)kD * kD, PLN_QKV, (long)kD * kD / 4);
      split2h_k<<<1024, 256, 0, stream>>>(wv + (size_t)li * kD * kD, dst + (long)2 * kD * kD, PLN_QKV, (long)kD * kD / 4);
      split2h_k<<<1024, 256, 0, stream>>>(wo + (size_t)li * kD * kD, woP + (size_t)li * 2 * PLN_WO, PLN_WO, (long)kD * kD / 4);
    }
    hipMemsetAsync(aux, 0, 4, stream);
    embed_rms_k<<<kBT, 256, 0, stream>>>(idx, wte, wpe, x);
    rmsnorm2h_k<<<kBT, 256, 0, stream>>>(x, xnP, PLN_XN);   // layer-0 QKV input

    for (int li = 0; li < kL; ++li) {
      // QKV: split-K x2 -> qkvf + qkvp1; combine into split-2 planes
      gemm2h_bt_k<P_F32, false, false, true, false><<<2 * bQKV, 256, 0, stream>>>(
          xnP, PLN_XN, wqkvP + (size_t)li * 2 * PLN_QKV, PLN_QKV,
          qkvf, 0, nullptr, nullptr, nullptr, 3 * kD, kD, kD, 0, 2,
          2, bQKV, (long)(qkvp1 - qkvf));
      qkvcomb_k<<<2048, 256, 0, stream>>>(qkvf, qkvp1, qkvP, PLN_Q3, PLN_Q3 / 4);
      attn2h_k<<<gAttn, 256, 0, stream>>>(qkvP, PLN_Q3, ofP, PLN_XN);
      // WO: split-K x4 into outs partials; fused residual+rms+split
      gemm2h_bt_k<P_F32, false, false, true, false><<<4 * bWO, 256, 0, stream>>>(
          ofP, PLN_XN, woP + (size_t)li * 2 * PLN_WO, PLN_WO,
          outs, 0, nullptr, nullptr, nullptr, kD, kD, kD, 0, 2,
          4, bWO, PLN_OUTS);
      resid4_rms2h_k<<<kBT, 256, 0, stream>>>(x, outs, PLN_OUTS, xnP, PLN_XN);
      hipMemsetAsync(meta, 0, 64, stream);
      gate_topk_k<<<kBT, 256, 0, stream>>>(x, gate + (size_t)li * kE * kD,
                                           probs, top2e, top2w, counts);
      calc_offsets_k<<<1, 64, 0, stream>>>(counts, offs);
      fill_slots_k<<<kBT / 256, 256, 0, stream>>>(top2e, offs, cursors, rows, slotOf);
      size_t fd = (size_t)li * PLN_FF;
      if (li < 2) {
        // f1: wide kernel, B = f32 weights converted in staging (BF32)
        gemm2hW_bt_k<P_SPLIT2_RELU, true, true, true><<<nF1W, 512, 0, stream>>>(
            xnP, PLN_XN, f1 + fd, 0, hP, PLN_H, rows, offs,
            kFF, kD, kD, (long)kFF * kD, kSLOTS / 128 / 8,
            1, nF1W, 0);
        // f2: 128^2 kernel, split-K x4, B = f32 weights in-staging (BF32)
        gemm2h_bt_k<P_F32, false, true, true, true><<<4 * bF2, 256, 0, stream>>>(
            hP, PLN_H, f2 + fd, 0, outs, 0, nullptr, nullptr, offs,
            kD, kFF, kFF, (long)kD * kFF, kSLOTS / 128 / 8,
            4, bF2, PLN_OUTS);
        moe4_rms2h_k<<<kBT, 256, 0, stream>>>(x, outs, PLN_OUTS, slotOf, top2w,
                                              xnP, PLN_XN);
      } else {
        // last layer: single-f16, B = f32 converted in staging (BCONV)
        gemm_bt_k<P_F16_RELU, true, true, true, true, true><<<nF1s, 256, 0, stream>>>(
            xnP, f1 + fd, hP, rows, offs, kFF, kD, kD, (long)kFF * kD,
            1.0f / 64.0f, kSLOTS / 128 / 8, 1, nF1s, 0);
        gemm_bt_k<P_F32, true, false, true, true, true><<<4 * bF2, 256, 0, stream>>>(
            hP, f2 + fd, outs, nullptr, offs, kD, kFF, kFF, (long)kD * kFF,
            1.0f, kSLOTS / 128 / 8, 4, bF2, PLN_OUTS);
        moe4_cast_h_k<<<kBT, 256, 0, stream>>>(x, outs, PLN_OUTS, slotOf, top2w, xnP);
      }
      aux_reduce_k<<<1, 256, 0, stream>>>(probs, aux);
    }
    // lm_head: B = f32 converted in staging (BCONV)
    gemm_bt_k<P_F32, false, false, true, true, false><<<nLM, 256, 0, stream>>>(
        xnP, lmh, out, nullptr, nullptr, kV, kD, kD, 0, 1.0f, kBT / 128,
        1, nLM, 0);
    write_aux_k<<<1, 64, 0, stream>>>(aux, out + (size_t)kBT * kV);
    return;
  }

  // ---------- fallback: f32 path ----------
  off = off_shared;
  float* xnf   = (float*)alloc((size_t)kBT * kD * 4);
  u16*   xnb   = (u16*)  alloc((size_t)kBT * kD * 2);
  float* qkvf32= (float*)alloc((size_t)kBT * 3 * kD * 4);
  float* off32 = (float*)alloc((size_t)kBT * kD * 4);
  float* hbuf  = (float*)alloc((size_t)kSLOTS * kFF * 4);
  u16* hbuf16 = (u16*)hbuf;

  hipMemsetAsync(aux, 0, 4, stream);
  embed_rms_k<<<kBT, 256, 0, stream>>>(idx, wte, wpe, x);
  dim3 gF1s(kSLOTS / 128, kFF / 128);
  dim3 gF2s(kSLOTS / 128, kD / 128);
  for (int li = 0; li < kL; ++li) {
    size_t dd = (size_t)li * kD * kD;
    rmsnorm2_k<<<kBT, 256, 0, stream>>>(x, xnf, xnb);
    dim3 gP(kBT / 128, kD / 128);
    sgemm_bt_k<P_F32, false, false><<<gP, 256, 0, stream>>>(
        xnf, wq + dd, qkvf32, nullptr, nullptr, nullptr, 3 * kD, kD, kD, 0);
    sgemm_bt_k<P_F32, false, false><<<gP, 256, 0, stream>>>(
        xnf, wk + dd, qkvf32 + kD, nullptr, nullptr, nullptr, 3 * kD, kD, kD, 0);
    sgemm_bt_k<P_F32, false, false><<<gP, 256, 0, stream>>>(
        xnf, wv + dd, qkvf32 + 2 * kD, nullptr, nullptr, nullptr, 3 * kD, kD, kD, 0);
    attn_f32_k<<<gAttn, 256, 0, stream>>>(qkvf32, off32, 3 * kD);
    sgemm_bt_k<P_F32_RESID, false, false><<<gP, 256, 0, stream>>>(
        off32, wo + dd, x, x, nullptr, nullptr, kD, kD, kD, 0);
    rmsnorm2_k<<<kBT, 256, 0, stream>>>(x, xnf, xnb);
    hipMemsetAsync(meta, 0, 64, stream);
    gate_topk_k<<<kBT, 256, 0, stream>>>(x, gate + (size_t)li * kE * kD,
                                         probs, top2e, top2w, counts);
    calc_offsets_k<<<1, 64, 0, stream>>>(counts, offs);
    fill_slots_k<<<kBT / 256, 256, 0, stream>>>(top2e, offs, cursors, rows, slotOf);
    size_t fd = (size_t)li * kE * kFF * kD;
    if (li < 2) {
      sgemm_bt_k<P_F32_RELU, true, true><<<gF1s, 256, 0, stream>>>(
          xnf, f1 + fd, hbuf, nullptr, rows, offs, kFF, kD, kD, (long)kFF * kD);
      sgemm_bt_k<P_F32, false, true><<<gF2s, 256, 0, stream>>>(
          hbuf, f2 + fd, outs, nullptr, nullptr, offs, kD, kFF, kFF, (long)kD * kFF);
    } else {
      gemm_bt_k<P_BF16_RELU, true, true, false, true, false><<<nF1s, 256, 0, stream>>>(
          xnb, f1 + fd, hbuf16, rows, offs, kFF, kD, kD, (long)kFF * kD,
          1.0f, kSLOTS / 128, 1, nF1s, 0);
      gemm_bt_k<P_F32, true, false, false, true, false><<<bF2, 256, 0, stream>>>(
          hbuf16, f2 + fd, outs, nullptr, offs, kD, kFF, kFF, (long)kD * kFF,
          1.0f, kSLOTS / 128, 1, bF2, 0);
    }
    hipMemsetAsync(outs + PLN_OUTS, 0, 3 * PLN_OUTS * 4, stream);
    moe_combine4_k<<<kBT, 256, 0, stream>>>(x, outs, PLN_OUTS, slotOf, top2w);
    aux_reduce_k<<<1, 256, 0, stream>>>(probs, aux);
  }
  cast_bf16_k<<<2048, 256, 0, stream>>>(x, xnb, (long)kBT * kD / 4);
  gemm_bt_k<P_F32, false, false, false, true, false><<<nLM, 256, 0, stream>>>(
      xnb, lmh, out, nullptr, nullptr, kV, kD, kD, 0, 1.0f, kBT / 128,
      1, nLM, 0);
  write_aux_k<<<1, 64, 0, stream>>>(aux, out + (size_t)kBT * kV);
}

// Round 17
// 2027.107 us; speedup vs baseline: 1.1651x; 1.0242x over previous
//
#include <hip/hip_runtime.h>

typedef unsigned short u16;
typedef __attribute__((ext_vector_type(4))) float f32x4;
typedef __attribute__((ext_vector_type(8))) __bf16 bf16x8;
typedef __attribute__((ext_vector_type(8))) _Float16 f16x8;
typedef __attribute__((ext_vector_type(4))) unsigned short u16x4;
typedef __attribute__((ext_vector_type(8))) unsigned short u16x8;

constexpr int kT = 1024, kD = 1024, kH = 16, kHD = 64, kL = 3, kE = 8;
constexpr int kFF = 4096, kV = 32000, kBT = 2048, kSLOTS = 5120;

__device__ __forceinline__ u16 f2bf(float f) {
  union { float f; unsigned u; } v; v.f = f;
  unsigned r = v.u + 0x7FFFu + ((v.u >> 16) & 1u);   // RNE
  return (u16)(r >> 16);
}
__device__ __forceinline__ u16 f2h(float x) {
  _Float16 h = (_Float16)x;
  union { _Float16 h; u16 u; } v; v.h = h; return v.u;
}
// uniform-scale fp16 split-2: 64*x = hi + mid + O(2^-11 * |64x - hi|)
__device__ __forceinline__ void split2s(float x, u16& h, u16& m) {
  float xs = x * 64.0f;
  _Float16 hh = (_Float16)xs;
  union { _Float16 h; u16 u; } v; v.h = hh; h = v.u;
  float r = xs - (float)hh;
  union { _Float16 h; u16 u; } w; w.h = (_Float16)r; m = w.u;
}

__device__ __forceinline__ void ld_lds16(const void* g, void* l) {
  __builtin_amdgcn_global_load_lds((const __attribute__((address_space(1))) void*)g,
                                   (__attribute__((address_space(3))) void*)l, 16, 0, 0);
}

#define MFMA16(a, b, c) __builtin_amdgcn_mfma_f32_16x16x32_bf16(a, b, c, 0, 0, 0)
#define MFMAH(a, b, c)  __builtin_amdgcn_mfma_f32_16x16x32_f16(a, b, c, 0, 0, 0)

__device__ __forceinline__ float blockReduceSum256(float v) {
  #pragma unroll
  for (int m = 32; m >= 1; m >>= 1) v += __shfl_xor(v, m);
  __shared__ float sh_[4];
  int w = threadIdx.x >> 6;
  if ((threadIdx.x & 63) == 0) sh_[w] = v;
  __syncthreads();
  v = (sh_[0] + sh_[1]) + (sh_[2] + sh_[3]);
  __syncthreads();
  return v;
}

// ---------------- elementwise / small kernels ----------------

__global__ __launch_bounds__(256) void cast_bf16_k(const float* __restrict__ in,
                                                   u16* __restrict__ out, long n4) {
  long i = (long)blockIdx.x * 256 + threadIdx.x;
  long stride = (long)gridDim.x * 256;
  for (; i < n4; i += stride) {
    f32x4 v = ((const f32x4*)in)[i];
    u16x4 o; o[0] = f2bf(v[0]); o[1] = f2bf(v[1]); o[2] = f2bf(v[2]); o[3] = f2bf(v[3]);
    ((u16x4*)out)[i] = o;
  }
}

__global__ __launch_bounds__(256) void cast_h_k(const float* __restrict__ in,
                                                u16* __restrict__ out, long n4) {
  long i = (long)blockIdx.x * 256 + threadIdx.x;
  long stride = (long)gridDim.x * 256;
  for (; i < n4; i += stride) {
    f32x4 v = ((const f32x4*)in)[i];
    u16x4 o; o[0] = f2h(v[0]); o[1] = f2h(v[1]); o[2] = f2h(v[2]); o[3] = f2h(v[3]);
    ((u16x4*)out)[i] = o;
  }
}

// f32 -> 2 fp16 planes (uniform x64 scale)
__global__ __launch_bounds__(256) void split2h_k(const float* __restrict__ in,
    u16* __restrict__ out, long planeStride, long n4) {
  long i = (long)blockIdx.x * 256 + threadIdx.x;
  long stride = (long)gridDim.x * 256;
  u16* o1 = out + planeStride;
  for (; i < n4; i += stride) {
    f32x4 v = ((const f32x4*)in)[i];
    u16x4 a, b;
    #pragma unroll
    for (int j = 0; j < 4; ++j) {
      u16 h, m; split2s(v[j], h, m);
      a[j] = h; b[j] = m;
    }
    ((u16x4*)out)[i] = a; ((u16x4*)o1)[i] = b;
  }
}

// qkv = p0 + p1 -> 2 fp16 planes (x64 scale)
__global__ __launch_bounds__(256) void qkvcomb_k(const float* __restrict__ a,
    const float* __restrict__ b, u16* __restrict__ oP, long plane, long n4) {
  long i = (long)blockIdx.x * 256 + threadIdx.x;
  long stride = (long)gridDim.x * 256;
  for (; i < n4; i += stride) {
    f32x4 v = ((const f32x4*)a)[i] + ((const f32x4*)b)[i];
    u16x4 hh, mm;
    #pragma unroll
    for (int j = 0; j < 4; ++j) {
      u16 h, m; split2s(v[j], h, m);
      hh[j] = h; mm[j] = m;
    }
    ((u16x4*)oP)[i] = hh;
    ((u16x4*)(oP + plane))[i] = mm;
  }
}

__global__ __launch_bounds__(256) void embed_rms_k(const int* __restrict__ idx,
    const float* __restrict__ wte, const float* __restrict__ wpe, float* __restrict__ x) {
  int tok = blockIdx.x, t = threadIdx.x;
  int id = idx[tok];
  int tt = tok & (kT - 1);
  f32x4 a = ((const f32x4*)(wte + (long)id * kD))[t];
  f32x4 p = ((const f32x4*)(wpe + (long)tt * kD))[t];
  f32x4 vv = a + p;
  float ss = vv[0]*vv[0] + vv[1]*vv[1] + vv[2]*vv[2] + vv[3]*vv[3];
  ss = blockReduceSum256(ss);
  float sc = rsqrtf(ss * (1.0f / kD) + 1e-5f);
  vv *= sc;
  ((f32x4*)(x + (long)tok * kD))[t] = vv;
}

// rmsnorm -> f32 + bf16 (fallback path)
__global__ __launch_bounds__(256) void rmsnorm2_k(const float* __restrict__ x,
    float* __restrict__ xnf, u16* __restrict__ xnb) {
  int tok = blockIdx.x, t = threadIdx.x;
  f32x4 vv = ((const f32x4*)(x + (long)tok * kD))[t];
  float ss = blockReduceSum256(vv[0]*vv[0] + vv[1]*vv[1] + vv[2]*vv[2] + vv[3]*vv[3]);
  float sc = rsqrtf(ss * (1.0f / kD) + 1e-5f);
  vv *= sc;
  ((f32x4*)(xnf + (long)tok * kD))[t] = vv;
  u16x4 o;
  o[0] = f2bf(vv[0]); o[1] = f2bf(vv[1]); o[2] = f2bf(vv[2]); o[3] = f2bf(vv[3]);
  ((u16x4*)(xnb + (long)tok * kD))[t] = o;
}

// rmsnorm -> 2 fp16 planes (fast path, x64 scale)
__global__ __launch_bounds__(256) void rmsnorm2h_k(const float* __restrict__ x,
    u16* __restrict__ xnP, long plane) {
  int tok = blockIdx.x, t = threadIdx.x;
  f32x4 vv = ((const f32x4*)(x + (long)tok * kD))[t];
  float ss = blockReduceSum256(vv[0]*vv[0] + vv[1]*vv[1] + vv[2]*vv[2] + vv[3]*vv[3]);
  float sc = rsqrtf(ss * (1.0f / kD) + 1e-5f);
  vv *= sc;
  u16x4 a, b;
  #pragma unroll
  for (int j = 0; j < 4; ++j) {
    u16 h, m; split2s(vv[j], h, m);
    a[j] = h; b[j] = m;
  }
  long o = (long)tok * kD / 4 + t;
  ((u16x4*)xnP)[o] = a;
  ((u16x4*)(xnP + plane))[o] = b;
}

// x += sum of 4 K-partials; write x; rmsnorm -> 2 fp16 planes
__global__ __launch_bounds__(256) void resid4_rms2h_k(float* __restrict__ x,
    const float* __restrict__ parts, long plane, u16* __restrict__ xnP, long xplane) {
  int tok = blockIdx.x, t = threadIdx.x;
  long o = (long)tok * (kD / 4) + t;
  f32x4 xv = ((f32x4*)x)[o];
  #pragma unroll
  for (int p = 0; p < 4; ++p) xv += ((const f32x4*)(parts + p * plane))[o];
  ((f32x4*)x)[o] = xv;
  float ss = blockReduceSum256(xv[0]*xv[0] + xv[1]*xv[1] + xv[2]*xv[2] + xv[3]*xv[3]);
  float sc = rsqrtf(ss * (1.0f / kD) + 1e-5f);
  f32x4 vv = xv * sc;
  u16x4 a, b;
  #pragma unroll
  for (int j = 0; j < 4; ++j) {
    u16 h, m; split2s(vv[j], h, m);
    a[j] = h; b[j] = m;
  }
  ((u16x4*)xnP)[o] = a;
  ((u16x4*)(xnP + xplane))[o] = b;
}

// x += moe combine (4 K-partials, 2 experts); write x; rmsnorm -> 2 fp16 planes
__global__ __launch_bounds__(256) void moe4_rms2h_k(float* __restrict__ x,
    const float* __restrict__ outsP, long plane, const int* __restrict__ slotOf,
    const float* __restrict__ top2w, u16* __restrict__ xnP, long xplane) {
  int tok = blockIdx.x, t = threadIdx.x;
  int s0 = slotOf[tok*2], s1 = slotOf[tok*2+1];
  float w0 = top2w[tok*2], w1 = top2w[tok*2+1];
  f32x4 a = {0.f,0.f,0.f,0.f}, b = a;
  #pragma unroll
  for (int p = 0; p < 4; ++p) {
    a += ((const f32x4*)(outsP + p * plane + (long)s0 * kD))[t];
    b += ((const f32x4*)(outsP + p * plane + (long)s1 * kD))[t];
  }
  long o = (long)tok * (kD / 4) + t;
  f32x4 xv = ((f32x4*)x)[o];
  xv += a * w0 + b * w1;
  ((f32x4*)x)[o] = xv;
  float ss = blockReduceSum256(xv[0]*xv[0] + xv[1]*xv[1] + xv[2]*xv[2] + xv[3]*xv[3]);
  float sc = rsqrtf(ss * (1.0f / kD) + 1e-5f);
  f32x4 vv = xv * sc;
  u16x4 ha, hb;
  #pragma unroll
  for (int j = 0; j < 4; ++j) {
    u16 h, m; split2s(vv[j], h, m);
    ha[j] = h; hb[j] = m;
  }
  ((u16x4*)xnP)[o] = ha;
  ((u16x4*)(xnP + xplane))[o] = hb;
}

// last layer: x += moe combine; write f16 (unscaled) plane for lm_head
__global__ __launch_bounds__(256) void moe4_cast_h_k(float* __restrict__ x,
    const float* __restrict__ outsP, long plane, const int* __restrict__ slotOf,
    const float* __restrict__ top2w, u16* __restrict__ xn) {
  int tok = blockIdx.x, t = threadIdx.x;
  int s0 = slotOf[tok*2], s1 = slotOf[tok*2+1];
  float w0 = top2w[tok*2], w1 = top2w[tok*2+1];
  f32x4 a = {0.f,0.f,0.f,0.f}, b = a;
  #pragma unroll
  for (int p = 0; p < 4; ++p) {
    a += ((const f32x4*)(outsP + p * plane + (long)s0 * kD))[t];
    b += ((const f32x4*)(outsP + p * plane + (long)s1 * kD))[t];
  }
  long o = (long)tok * (kD / 4) + t;
  f32x4 xv = ((f32x4*)x)[o];
  xv += a * w0 + b * w1;
  u16x4 hv;
  #pragma unroll
  for (int j = 0; j < 4; ++j) hv[j] = f2h(xv[j]);
  ((u16x4*)xn)[o] = hv;
}

// gating in f32 (bf16 would flip top-2 selections on near-ties)
__global__ __launch_bounds__(256) void gate_topk_k(const float* __restrict__ x,
    const float* __restrict__ gate_l, float* __restrict__ probs, int* __restrict__ top2e,
    float* __restrict__ top2w, int* __restrict__ counts) {
  int tok = blockIdx.x, t = threadIdx.x;
  f32x4 xv = ((const f32x4*)(x + (long)tok * kD))[t];
  float ss = blockReduceSum256(xv[0]*xv[0] + xv[1]*xv[1] + xv[2]*xv[2] + xv[3]*xv[3]);
  float sc = rsqrtf(ss * (1.0f / kD) + 1e-5f);
  float a[kE];
  #pragma unroll
  for (int e = 0; e < kE; ++e) {
    f32x4 gv = ((const f32x4*)(gate_l + (long)e * kD))[t];
    a[e] = xv[0]*gv[0] + xv[1]*gv[1] + xv[2]*gv[2] + xv[3]*gv[3];
  }
  __shared__ float sh8[kE][4];
  int w = t >> 6, l = t & 63;
  #pragma unroll
  for (int e = 0; e < kE; ++e) {
    float v = a[e];
    #pragma unroll
    for (int m = 32; m >= 1; m >>= 1) v += __shfl_xor(v, m);
    if (l == 0) sh8[e][w] = v;
  }
  __syncthreads();
  if (t == 0) {
    float lg[kE], mx = -1e30f;
    #pragma unroll
    for (int e = 0; e < kE; ++e) {
      lg[e] = (sh8[e][0] + sh8[e][1] + sh8[e][2] + sh8[e][3]) * sc;
      mx = fmaxf(mx, lg[e]);
    }
    float pe[kE], s = 0.f;
    #pragma unroll
    for (int e = 0; e < kE; ++e) { pe[e] = __expf(lg[e] - mx); s += pe[e]; }
    float inv = 1.f / s;
    int i1 = 0;
    #pragma unroll
    for (int e = 1; e < kE; ++e) if (lg[e] > lg[i1]) i1 = e;
    int i2 = (i1 == 0) ? 1 : 0;
    #pragma unroll
    for (int e = 0; e < kE; ++e) if (e != i1 && lg[e] > lg[i2]) i2 = e;
    #pragma unroll
    for (int e = 0; e < kE; ++e) probs[(long)tok * kE + e] = pe[e] * inv;
    float p1 = pe[i1] * inv, p2 = pe[i2] * inv;
    float wn = p1 + p2;
    top2e[tok*2] = i1; top2e[tok*2+1] = i2;
    top2w[tok*2] = p1 / wn; top2w[tok*2+1] = p2 / wn;
    atomicAdd(&counts[i1], 1); atomicAdd(&counts[i2], 1);
  }
}

// 128-aligned expert offsets
__global__ void calc_offsets_k(const int* __restrict__ counts, int* __restrict__ offsets) {
  if (threadIdx.x == 0) {
    int o = 0;
    #pragma unroll
    for (int e = 0; e < kE; ++e) { offsets[e] = o; o += (counts[e] + 127) & ~127; }
    offsets[kE] = o;
  }
}

__global__ __launch_bounds__(256) void fill_slots_k(const int* __restrict__ top2e,
    const int* __restrict__ offsets, int* __restrict__ cursors,
    int* __restrict__ rows, int* __restrict__ slotOf) {
  int tok = blockIdx.x * 256 + threadIdx.x;
  if (tok >= kBT) return;
  #pragma unroll
  for (int j = 0; j < 2; ++j) {
    int e = top2e[tok*2 + j];
    int pos = atomicAdd(&cursors[e], 1);
    int slot = offsets[e] + pos;
    rows[slot] = tok;
    slotOf[tok*2 + j] = slot;
  }
}

// fallback combine (4 partials; unused planes zeroed)
__global__ __launch_bounds__(256) void moe_combine4_k(float* __restrict__ x,
    const float* __restrict__ outsP, long plane, const int* __restrict__ slotOf,
    const float* __restrict__ top2w) {
  int tok = blockIdx.x, t = threadIdx.x;
  int s0 = slotOf[tok*2], s1 = slotOf[tok*2+1];
  float w0 = top2w[tok*2], w1 = top2w[tok*2+1];
  f32x4 a = {0.f,0.f,0.f,0.f}, b = a;
  #pragma unroll
  for (int p = 0; p < 4; ++p) {
    a += ((const f32x4*)(outsP + p * plane + (long)s0 * kD))[t];
    b += ((const f32x4*)(outsP + p * plane + (long)s1 * kD))[t];
  }
  f32x4 xv = ((f32x4*)(x + (long)tok * kD))[t];
  xv += a * w0 + b * w1;
  ((f32x4*)(x + (long)tok * kD))[t] = xv;
}

__global__ __launch_bounds__(256) void aux_reduce_k(const float* __restrict__ probs,
                                                    float* __restrict__ aux) {
  int t = threadIdx.x;
  float part[kE] = {};
  for (int i = t; i < kBT; i += 256) {
    #pragma unroll
    for (int e = 0; e < kE; ++e) part[e] += probs[(long)i * kE + e];
  }
  __shared__ float sh8[kE][4];
  int w = t >> 6, l = t & 63;
  #pragma unroll
  for (int e = 0; e < kE; ++e) {
    float v = part[e];
    #pragma unroll
    for (int m = 32; m >= 1; m >>= 1) v += __shfl_xor(v, m);
    if (l == 0) sh8[e][w] = v;
  }
  __syncthreads();
  if (t == 0) {
    float acc = 0.f;
    #pragma unroll
    for (int e = 0; e < kE; ++e) {
      float frac = (sh8[e][0] + sh8[e][1] + sh8[e][2] + sh8[e][3]) * (1.0f / kBT);
      acc += frac * frac;
    }
    aux[0] += (float)kE * acc;
  }
}

__global__ void write_aux_k(const float* __restrict__ aux, float* __restrict__ out) {
  if (threadIdx.x == 0) out[0] = 0.01f * aux[0] / (float)kL;
}

enum { P_BF16 = 0, P_BF16_RELU = 1, P_F32 = 2, P_F32_RESID = 3, P_F32_RELU = 4,
       P_SPLIT2_RELU = 5, P_F16_RELU = 6 };

__device__ __forceinline__ int clamp_row(int rv) {
  return ((unsigned)rv < (unsigned)kBT) ? rv : 0;
}

template <bool MPART>
__device__ __forceinline__ void block_mn(int lin, int base, int mArg, int& mb, int& nb) {
  int xcd = lin & 7, c = lin >> 3;
  if (MPART) {
    mb = xcd * mArg + (c % mArg);
    nb = c / mArg;
  } else {
    int swz = xcd * (base >> 3) + c;
    mb = swz % mArg;
    nb = swz / mArg;
  }
}

// ------- fused fp16 split-2 MFMA GEMM (128x128, 256 thr), single accumulator -------
// BF32: B is f32; staged via in-register split2s + swizzled ds_write.

template <int POST, bool GATHER, bool EXPERT, bool MPART, bool BF32>
__global__ __launch_bounds__(256) void gemm2h_bt_k(
    const u16* __restrict__ A0, long planeA,
    const void* __restrict__ Bv, long planeB,
    void* __restrict__ C, long planeC,
    const float* __restrict__ resid,
    const int* __restrict__ rows, const int* __restrict__ offsets,
    int N, int K, int lda, long eBstride, int mArg,
    int kParts, int base, long cPart) {
  constexpr int BM = 128, BK = 32;
  int part = blockIdx.x / base;
  int lin = blockIdx.x % base;
  int mb, nb;
  block_mn<MPART>(lin, base, mArg, mb, nb);
  int m0 = mb * BM, n0 = nb * BM;
  const u16* B0 = (const u16*)Bv;
  const float* Bf = (const float*)Bv;
  if (EXPERT) {
    int total = offsets[kE];
    if (m0 >= total) return;
    int e = 0;
    while (offsets[e + 1] <= m0) ++e;
    if (BF32) Bf += (long)e * eBstride; else B0 += (long)e * eBstride;
  }
  __shared__ __align__(16) u16 Ac[BM][64];
  __shared__ __align__(16) u16 Bc[BM][64];
  int t = threadIdx.x;
  int l = t & 63, lr = l & 15, lg = l >> 4;
  int wid = t >> 6;
  int wm = (wid >> 1) * 64, wn = (wid & 1) * 64;

  long asrc[4], bsrc[4];
  int ldst[4];
  #pragma unroll
  for (int it = 0; it < 4; ++it) {
    int d = it * 256 + t;
    int row = d >> 3, pc = d & 7;
    int lc = pc ^ (row & 7);
    int p = lc >> 2, c = lc & 3;
    int grow = GATHER ? clamp_row(rows[m0 + row]) : (m0 + row);
    asrc[it] = (long)p * planeA + (long)grow * lda + c * 8;
    if (!BF32) bsrc[it] = (long)p * planeB + (long)(n0 + row) * K + c * 8;
    ldst[it] = (it * 256 + (t & ~63)) * 8;
  }
  long bsrcF[2];
  int brow[2], bc[2];
  if (BF32) {
    #pragma unroll
    for (int it = 0; it < 2; ++it) {
      int d = it * 256 + t;            // 0..511 = 128 rows x 4 k-chunks
      brow[it] = d >> 2; bc[it] = d & 3;
      bsrcF[it] = (long)(n0 + brow[it]) * K + bc[it] * 8;
    }
  }
  int sa = lr & 7;
  int cH = (lg ^ sa) * 8;
  int cM = ((4 + lg) ^ sa) * 8;

  f32x4 acc[4][4];
  #pragma unroll
  for (int i = 0; i < 4; ++i)
    #pragma unroll
    for (int j = 0; j < 4; ++j) acc[i][j] = 0.f;

  int kStep = K / kParts;
  int kLo = part * kStep, kHi = kLo + kStep;
  for (int k0 = kLo; k0 < kHi; k0 += BK) {
    #pragma unroll
    for (int it = 0; it < 4; ++it) {
      ld_lds16(A0 + asrc[it] + k0, &Ac[0][0] + ldst[it]);
      if (!BF32) ld_lds16(B0 + bsrc[it] + k0, &Bc[0][0] + ldst[it]);
    }
    if (BF32) {
      #pragma unroll
      for (int it = 0; it < 2; ++it) {
        const float* src = Bf + bsrcF[it] + k0;
        f32x4 v0 = *(const f32x4*)src;
        f32x4 v1 = *(const f32x4*)(src + 4);
        u16x8 hi, mi;
        #pragma unroll
        for (int j = 0; j < 4; ++j) {
          u16 h, m; split2s(v0[j], h, m); hi[j] = h; mi[j] = m;
        }
        #pragma unroll
        for (int j = 0; j < 4; ++j) {
          u16 h, m; split2s(v1[j], h, m); hi[4 + j] = h; mi[4 + j] = m;
        }
        int r7 = brow[it] & 7;
        *(u16x8*)&Bc[brow[it]][(bc[it] ^ r7) * 8] = hi;
        *(u16x8*)&Bc[brow[it]][((4 + bc[it]) ^ r7) * 8] = mi;
      }
    }
    __syncthreads();
    f16x8 ah[4], am[4];
    #pragma unroll
    for (int i = 0; i < 4; ++i) {
      ah[i] = *(const f16x8*)&Ac[wm + i*16 + lr][cH];
      am[i] = *(const f16x8*)&Ac[wm + i*16 + lr][cM];
    }
    #pragma unroll
    for (int j = 0; j < 4; ++j) {
      f16x8 bh = *(const f16x8*)&Bc[wn + j*16 + lr][cH];
      f16x8 bm = *(const f16x8*)&Bc[wn + j*16 + lr][cM];
      #pragma unroll
      for (int i = 0; i < 4; ++i) {
        acc[i][j] = MFMAH(ah[i], bh, acc[i][j]);
        acc[i][j] = MFMAH(am[i], bh, acc[i][j]);
        acc[i][j] = MFMAH(ah[i], bm, acc[i][j]);
      }
    }
    __syncthreads();
  }
  float* Cf = (float*)C + (long)part * cPart;
  #pragma unroll
  for (int i = 0; i < 4; ++i) {
    #pragma unroll
    for (int r = 0; r < 4; ++r) {
      long m = m0 + wm + i*16 + lg*4 + r;
      #pragma unroll
      for (int j = 0; j < 4; ++j) {
        int n = n0 + wn + j*16 + lr;
        float val = acc[i][j][r] * (1.0f / 4096.0f);
        if (POST == P_F32) {
          Cf[m * N + n] = val;
        } else if (POST == P_F32_RESID) {
          ((float*)C)[m * N + n] = val + resid[m * N + n];
        } else if (POST == P_SPLIT2_RELU) {
          val = fmaxf(val, 0.f);
          u16 h, mm; split2s(val, h, mm);
          u16* Cp = (u16*)C;
          Cp[m * N + n] = h;
          Cp[planeC + m * N + n] = mm;
        }
      }
    }
  }
}

// ------- wide fused fp16 split-2 GEMM: 128x256 tile, 512 threads, 2m x 4n waves -------

template <int POST, bool GATHER, bool EXPERT, bool BF32>
__global__ __launch_bounds__(512) void gemm2hW_bt_k(
    const u16* __restrict__ A0, long planeA,
    const void* __restrict__ Bv, long planeB,
    void* __restrict__ C, long planeC,
    const int* __restrict__ rows, const int* __restrict__ offsets,
    int N, int K, int lda, long eBstride, int mPerX,
    int kParts, int base, long cPart) {
  constexpr int BM = 128, BN = 256, BK = 32;
  int part = blockIdx.x / base;
  int lin = blockIdx.x % base;
  int xcd = lin & 7, c0 = lin >> 3;
  int m0 = (xcd * mPerX + (c0 % mPerX)) * BM;
  int n0 = (c0 / mPerX) * BN;
  const u16* B0 = (const u16*)Bv;
  const float* Bf = (const float*)Bv;
  if (EXPERT) {
    int total = offsets[kE];
    if (m0 >= total) return;
    int e = 0;
    while (offsets[e + 1] <= m0) ++e;
    if (BF32) Bf += (long)e * eBstride; else B0 += (long)e * eBstride;
  }
  __shared__ __align__(16) u16 Ac[BM][64];
  __shared__ __align__(16) u16 Bc[BN][64];
  int t = threadIdx.x;
  int l = t & 63, lr = l & 15, lg = l >> 4;
  int wid = t >> 6;
  int wm = (wid >> 2) * 64;
  int wn = (wid & 3) * 64;

  long asrc[2], bsrc[4];
  int aldst[2], bldst[4];
  #pragma unroll
  for (int it = 0; it < 2; ++it) {
    int d = it * 512 + t;
    int row = d >> 3, pc = d & 7;
    int lc = pc ^ (row & 7);
    int p = lc >> 2, cc = lc & 3;
    int grow = GATHER ? clamp_row(rows[m0 + row]) : (m0 + row);
    asrc[it] = (long)p * planeA + (long)grow * lda + cc * 8;
    aldst[it] = (it * 512 + (t & ~63)) * 8;
  }
  long bsrcF[2];
  int brow[2], bcc[2];
  if (!BF32) {
    #pragma unroll
    for (int it = 0; it < 4; ++it) {
      int d = it * 512 + t;
      int row = d >> 3, pc = d & 7;
      int lc = pc ^ (row & 7);
      int p = lc >> 2, cc = lc & 3;
      bsrc[it] = (long)p * planeB + (long)(n0 + row) * K + cc * 8;
      bldst[it] = (it * 512 + (t & ~63)) * 8;
    }
  } else {
    #pragma unroll
    for (int it = 0; it < 2; ++it) {
      int d = it * 512 + t;            // 0..1023 = 256 rows x 4 k-chunks
      brow[it] = d >> 2; bcc[it] = d & 3;
      bsrcF[it] = (long)(n0 + brow[it]) * K + bcc[it] * 8;
    }
  }
  int sa = lr & 7;
  int cH = (lg ^ sa) * 8;
  int cM = ((4 + lg) ^ sa) * 8;

  f32x4 acc[4][4];
  #pragma unroll
  for (int i = 0; i < 4; ++i)
    #pragma unroll
    for (int j = 0; j < 4; ++j) acc[i][j] = 0.f;

  int kStep = K / kParts;
  int kLo = part * kStep, kHi = kLo + kStep;
  for (int k0 = kLo; k0 < kHi; k0 += BK) {
    #pragma unroll
    for (int it = 0; it < 2; ++it)
      ld_lds16(A0 + asrc[it] + k0, &Ac[0][0] + aldst[it]);
    if (!BF32) {
      #pragma unroll
      for (int it = 0; it < 4; ++it)
        ld_lds16(B0 + bsrc[it] + k0, &Bc[0][0] + bldst[it]);
    } else {
      #pragma unroll
      for (int it = 0; it < 2; ++it) {
        const float* src = Bf + bsrcF[it] + k0;
        f32x4 v0 = *(const f32x4*)src;
        f32x4 v1 = *(const f32x4*)(src + 4);
        u16x8 hi, mi;
        #pragma unroll
        for (int j = 0; j < 4; ++j) {
          u16 h, m; split2s(v0[j], h, m); hi[j] = h; mi[j] = m;
        }
        #pragma unroll
        for (int j = 0; j < 4; ++j) {
          u16 h, m; split2s(v1[j], h, m); hi[4 + j] = h; mi[4 + j] = m;
        }
        int r7 = brow[it] & 7;
        *(u16x8*)&Bc[brow[it]][(bcc[it] ^ r7) * 8] = hi;
        *(u16x8*)&Bc[brow[it]][((4 + bcc[it]) ^ r7) * 8] = mi;
      }
    }
    __syncthreads();
    f16x8 ah[4], am[4];
    #pragma unroll
    for (int i = 0; i < 4; ++i) {
      ah[i] = *(const f16x8*)&Ac[wm + i*16 + lr][cH];
      am[i] = *(const f16x8*)&Ac[wm + i*16 + lr][cM];
    }
    #pragma unroll
    for (int j = 0; j < 4; ++j) {
      f16x8 bh = *(const f16x8*)&Bc[wn + j*16 + lr][cH];
      f16x8 bm = *(const f16x8*)&Bc[wn + j*16 + lr][cM];
      #pragma unroll
      for (int i = 0; i < 4; ++i) {
        acc[i][j] = MFMAH(ah[i], bh, acc[i][j]);
        acc[i][j] = MFMAH(am[i], bh, acc[i][j]);
        acc[i][j] = MFMAH(ah[i], bm, acc[i][j]);
      }
    }
    __syncthreads();
  }
  float* Cf = (float*)C + (long)part * cPart;
  #pragma unroll
  for (int i = 0; i < 4; ++i) {
    #pragma unroll
    for (int r = 0; r < 4; ++r) {
      long m = m0 + wm + i*16 + lg*4 + r;
      #pragma unroll
      for (int j = 0; j < 4; ++j) {
        int n = n0 + wn + j*16 + lr;
        float val = acc[i][j][r] * (1.0f / 4096.0f);
        if (POST == P_F32) {
          Cf[m * N + n] = val;
        } else if (POST == P_SPLIT2_RELU) {
          val = fmaxf(val, 0.f);
          u16 h, mm; split2s(val, h, mm);
          u16* Cp = (u16*)C;
          Cp[m * N + n] = h;
          Cp[planeC + m * N + n] = mm;
        }
      }
    }
  }
}

// ---------------- single-plane MFMA GEMM (with optional split-K) ----------------
// BCONV staging now uses 16B chunks with the same XOR-8 swizzle as A (reg-staged
// ds_write at physical chunk lc^(row&7); reads use the swizzled column for both).

template <int POST, bool EXPERT, bool GATHER, bool HALF, bool BCONV, bool MPART>
__global__ __launch_bounds__(256) void gemm_bt_k(
    const u16* __restrict__ A, const void* __restrict__ Bv, void* __restrict__ C,
    const int* __restrict__ rows, const int* __restrict__ offsets,
    int N, int K, int lda, long eBstride, float oscale, int mArg,
    int kParts, int base, long cPart) {
  constexpr int BM = 128, BK = 64;
  int part = blockIdx.x / base;
  int lin = blockIdx.x % base;
  int mb, nb;
  block_mn<MPART>(lin, base, mArg, mb, nb);
  int m0 = mb * BM, n0 = nb * BM;
  const float* Bf = (const float*)Bv;
  const u16*   Bh = (const u16*)Bv;
  if (EXPERT) {
    int total = offsets[kE];
    if (m0 >= total) return;
    int e = 0;
    while (offsets[e + 1] <= m0) ++e;
    if (BCONV) Bf += (long)e * eBstride; else Bh += (long)e * eBstride;
  }
  __shared__ __align__(16) u16 As[BM][BK];
  __shared__ __align__(16) u16 Bs[BM][BK];
  int t = threadIdx.x;
  int l = t & 63, lr = l & 15, lg = l >> 4;
  int wid = t >> 6;
  int wm = (wid >> 1) * 64, wn = (wid & 1) * 64;

  long asrc[4], bsrc[4];
  int ldst[4];
  #pragma unroll
  for (int it = 0; it < 4; ++it) {
    int d = it * 256 + t;
    int row = d >> 3, pc = d & 7;
    int c = pc ^ (row & 7);
    int grow = GATHER ? clamp_row(rows[m0 + row]) : (m0 + row);
    asrc[it] = (long)grow * lda + c * 8;
    if (!BCONV) bsrc[it] = (long)(n0 + row) * K + c * 8;
    ldst[it] = (it * 256 + (t & ~63)) * 8;
  }
  long bsrcC[4];
  int bdst[4];
  if (BCONV) {
    #pragma unroll
    for (int it = 0; it < 4; ++it) {
      int d = it * 256 + t;               // 128 rows x 8 logical chunks
      int row = d >> 3, lc = d & 7;
      bsrcC[it] = (long)(n0 + row) * K + lc * 8;   // f32 source of logical chunk
      bdst[it] = row * BK + (lc ^ (row & 7)) * 8;  // swizzled physical chunk (u16)
    }
  }
  f32x4 acc[4][4];
  #pragma unroll
  for (int i = 0; i < 4; ++i)
    #pragma unroll
    for (int j = 0; j < 4; ++j) acc[i][j] = 0.f;

  int kStep = K / kParts;
  int kLo = part * kStep, kHi = kLo + kStep;
  for (int k0 = kLo; k0 < kHi; k0 += BK) {
    #pragma unroll
    for (int it = 0; it < 4; ++it)
      ld_lds16(A + asrc[it] + k0, &As[0][0] + ldst[it]);
    if (!BCONV) {
      #pragma unroll
      for (int it = 0; it < 4; ++it)
        ld_lds16(Bh + bsrc[it] + k0, &Bs[0][0] + ldst[it]);
    } else {
      #pragma unroll
      for (int it = 0; it < 4; ++it) {
        const float* src = Bf + bsrcC[it] + k0;
        f32x4 v0 = *(const f32x4*)src;
        f32x4 v1 = *(const f32x4*)(src + 4);
        u16x8 o;
        #pragma unroll
        for (int j = 0; j < 4; ++j) {
          o[j] = HALF ? f2h(v0[j]) : f2bf(v0[j]);
          o[4 + j] = HALF ? f2h(v1[j]) : f2bf(v1[j]);
        }
        *(u16x8*)(&Bs[0][0] + bdst[it]) = o;
      }
    }
    __syncthreads();
    #pragma unroll
    for (int kk = 0; kk < 2; ++kk) {
      int ca = ((kk * 4 + lg) ^ (lr & 7)) * 8;
      #pragma unroll
      for (int i = 0; i < 4; ++i)
        #pragma unroll
        for (int j = 0; j < 4; ++j) {
          if (HALF) {
            f16x8 af = *(const f16x8*)&As[wm + i*16 + lr][ca];
            f16x8 bq = *(const f16x8*)&Bs[wn + j*16 + lr][ca];
            acc[i][j] = MFMAH(af, bq, acc[i][j]);
          } else {
            bf16x8 af = *(const bf16x8*)&As[wm + i*16 + lr][ca];
            bf16x8 bq = *(const bf16x8*)&Bs[wn + j*16 + lr][ca];
            acc[i][j] = MFMA16(af, bq, acc[i][j]);
          }
        }
    }
    __syncthreads();
  }
  #pragma unroll
  for (int i = 0; i < 4; ++i) {
    #pragma unroll
    for (int r = 0; r < 4; ++r) {
      long m = m0 + wm + i*16 + lg*4 + r;
      #pragma unroll
      for (int j = 0; j < 4; ++j) {
        int n = n0 + wn + j*16 + lr;
        float val = acc[i][j][r] * oscale;
        if (POST == P_BF16_RELU)       ((u16*)C)[m * N + n] = f2bf(fmaxf(val, 0.f));
        else if (POST == P_F16_RELU)   ((u16*)C)[m * N + n] = f2h(fmaxf(val, 0.f));
        else if (POST == P_F32)        ((float*)C + (long)part * cPart)[m * N + n] = val;
      }
    }
  }
}

// ---------------- f32 SGEMM (fallback path only) ----------------

template <int POST, bool GATHER, bool EXPERT>
__global__ __launch_bounds__(256) void sgemm_bt_k(
    const float* __restrict__ A, const float* __restrict__ B, float* __restrict__ C,
    const float* __restrict__ resid, const int* __restrict__ rows,
    const int* __restrict__ offsets, int N, int K, int lda, long eBstride) {
  constexpr int BM = 128, BN = 128, BK = 32;
  int m0 = blockIdx.x * BM, n0 = blockIdx.y * BN;
  if (EXPERT) {
    int total = offsets[kE];
    if (m0 >= total) return;
    int e = 0;
    while (offsets[e + 1] <= m0) ++e;
    B += (long)e * eBstride;
  }
  __shared__ float Ast[BK][BM];
  __shared__ float Bst[BK][BN];
  int t = threadIdx.x, tx = t & 15, ty = t >> 4;
  long asrc[4], bsrc[4];
  #pragma unroll
  for (int it = 0; it < 4; ++it) {
    int c = it * 256 + t;
    int row = c >> 3, kc = (c & 7) * 4;
    int gr = GATHER ? clamp_row(rows[m0 + row]) : (m0 + row);
    asrc[it] = (long)gr * lda + kc;
    bsrc[it] = (long)(n0 + row) * K + kc;
  }
  f32x4 accv[8][2];
  #pragma unroll
  for (int i = 0; i < 8; ++i) { accv[i][0] = 0.f; accv[i][1] = 0.f; }

  for (int k0 = 0; k0 < K; k0 += BK) {
    #pragma unroll
    for (int it = 0; it < 4; ++it) {
      int c = it * 256 + t;
      int row = c >> 3, kc = (c & 7) * 4;
      f32x4 av = *(const f32x4*)(A + asrc[it] + k0);
      f32x4 bv = *(const f32x4*)(B + bsrc[it] + k0);
      #pragma unroll
      for (int j = 0; j < 4; ++j) { Ast[kc + j][row] = av[j]; Bst[kc + j][row] = bv[j]; }
    }
    __syncthreads();
    #pragma unroll
    for (int kk = 0; kk < BK; ++kk) {
      f32x4 a0 = *(const f32x4*)&Ast[kk][ty * 4];
      f32x4 a1 = *(const f32x4*)&Ast[kk][64 + ty * 4];
      f32x4 b0 = *(const f32x4*)&Bst[kk][tx * 4];
      f32x4 b1 = *(const f32x4*)&Bst[kk][64 + tx * 4];
      float as[8] = {a0[0], a0[1], a0[2], a0[3], a1[0], a1[1], a1[2], a1[3]};
      #pragma unroll
      for (int i = 0; i < 8; ++i) {
        accv[i][0] += b0 * as[i];
        accv[i][1] += b1 * as[i];
      }
    }
    __syncthreads();
  }
  #pragma unroll
  for (int ih = 0; ih < 2; ++ih)
    #pragma unroll
    for (int i = 0; i < 4; ++i) {
      long m = m0 + ih * 64 + ty * 4 + i;
      #pragma unroll
      for (int jh = 0; jh < 2; ++jh) {
        long n = n0 + jh * 64 + tx * 4;
        f32x4 val = accv[ih * 4 + i][jh];
        if (POST == P_F32_RELU) {
          #pragma unroll
          for (int j = 0; j < 4; ++j) val[j] = fmaxf(val[j], 0.f);
        }
        if (POST == P_F32_RESID) val += *(const f32x4*)&resid[m * N + n];
        *(f32x4*)&C[m * N + n] = val;
      }
    }
}

// ------- MFMA split-2 attention (f32-equivalent accuracy) -------

__global__ __launch_bounds__(256) void attn2h_k(
    const u16* __restrict__ qkvP, long qplane,
    u16* __restrict__ oP, long oplane) {
  int qt = (int)gridDim.x - 1 - (int)blockIdx.x;   // heavy first
  int bh = blockIdx.y;
  int b = bh >> 4, h = bh & 15;
  const int ldq = 3 * kD;
  long hbq = (long)b * kT * ldq + h * kHD;
  long hbo = (long)b * kT * kD + h * kHD;
  int t = threadIdx.x, w = t >> 6, l = t & 63;
  int lr = l & 15, lg = l >> 4;

  __shared__ __align__(16) u16 Ks[2][64][72];
  __shared__ __align__(16) u16 Vt[2][64][72];
  __shared__ __align__(16) u16 Ps[2][4][16][72];

  f16x8 qf0[2], qf1[2];
  {
    long qrow = qt * 64 + w * 16 + lr;
    const u16* qp = qkvP + hbq + qrow * ldq;
    #pragma unroll
    for (int kc = 0; kc < 2; ++kc) {
      qf0[kc] = *(const f16x8*)(qp + kc * 32 + lg * 8);
      qf1[kc] = *(const f16x8*)(qp + qplane + kc * 32 + lg * 8);
    }
  }
  int qg = qt * 64 + w * 16 + lg * 4;

  float mrow[4], lsum[4];
  f32x4 accO[4];
  #pragma unroll
  for (int r = 0; r < 4; ++r) { mrow[r] = -1e30f; lsum[r] = 0.f; }
  #pragma unroll
  for (int j = 0; j < 4; ++j) accO[j] = 0.f;

  for (int it = 0; it <= qt; ++it) {
    #pragma unroll
    for (int p = 0; p < 2; ++p) {
      #pragma unroll
      for (int s = 0; s < 2; ++s) {
        int c = s * 256 + t;
        int row = c >> 3, col = (c & 7) * 8;
        long gi = (long)p * qplane + hbq + (long)(it * 64 + row) * ldq + col;
        *(u16x8*)&Ks[p][row][col] = *(const u16x8*)(qkvP + kD + gi);
        u16x8 vv = *(const u16x8*)(qkvP + 2 * kD + gi);
        #pragma unroll
        for (int j = 0; j < 8; ++j) Vt[p][col + j][row] = vv[j];
      }
    }
    __syncthreads();

    f32x4 s4[4];
    #pragma unroll
    for (int j = 0; j < 4; ++j) {
      f32x4 z = {0.f, 0.f, 0.f, 0.f};
      #pragma unroll
      for (int kc = 0; kc < 2; ++kc) {
        f16x8 kh = *(const f16x8*)&Ks[0][j*16 + lr][kc*32 + lg*8];
        f16x8 km = *(const f16x8*)&Ks[1][j*16 + lr][kc*32 + lg*8];
        z = MFMAH(qf0[kc], kh, z);
        z = MFMAH(qf1[kc], kh, z);
        z = MFMAH(qf0[kc], km, z);
      }
      s4[j] = z;
    }
    #pragma unroll
    for (int j = 0; j < 4; ++j)
      #pragma unroll
      for (int r = 0; r < 4; ++r) {
        float sv = s4[j][r] * (0.125f / 4096.0f);
        if (it * 64 + j * 16 + lr > qg + r) sv = -1e30f;
        s4[j][r] = sv;
      }
    float alpha[4];
    #pragma unroll
    for (int r = 0; r < 4; ++r) {
      float mx = fmaxf(fmaxf(s4[0][r], s4[1][r]), fmaxf(s4[2][r], s4[3][r]));
      mx = fmaxf(mx, __shfl_xor(mx, 1));
      mx = fmaxf(mx, __shfl_xor(mx, 2));
      mx = fmaxf(mx, __shfl_xor(mx, 4));
      mx = fmaxf(mx, __shfl_xor(mx, 8));
      float mi = fmaxf(mrow[r], mx);
      alpha[r] = __expf(mrow[r] - mi);
      mrow[r] = mi;
    }
    float rs[4] = {0.f, 0.f, 0.f, 0.f};
    #pragma unroll
    for (int j = 0; j < 4; ++j)
      #pragma unroll
      for (int r = 0; r < 4; ++r) {
        float p = __expf(s4[j][r] - mrow[r]);
        rs[r] += p;
        u16 hh, mm; split2s(p, hh, mm);
        Ps[0][w][lg*4 + r][j*16 + lr] = hh;
        Ps[1][w][lg*4 + r][j*16 + lr] = mm;
      }
    #pragma unroll
    for (int r = 0; r < 4; ++r) {
      float x2 = rs[r];
      x2 += __shfl_xor(x2, 1);
      x2 += __shfl_xor(x2, 2);
      x2 += __shfl_xor(x2, 4);
      x2 += __shfl_xor(x2, 8);
      lsum[r] = lsum[r] * alpha[r] + x2;
    }
    #pragma unroll
    for (int j = 0; j < 4; ++j)
      #pragma unroll
      for (int r = 0; r < 4; ++r) accO[j][r] *= alpha[r];
    __syncthreads();

    f16x8 ph[2], pm[2];
    #pragma unroll
    for (int kc = 0; kc < 2; ++kc) {
      ph[kc] = *(const f16x8*)&Ps[0][w][lr][kc*32 + lg*8];
      pm[kc] = *(const f16x8*)&Ps[1][w][lr][kc*32 + lg*8];
    }
    #pragma unroll
    for (int j2 = 0; j2 < 4; ++j2) {
      #pragma unroll
      for (int kc = 0; kc < 2; ++kc) {
        f16x8 vh = *(const f16x8*)&Vt[0][j2*16 + lr][kc*32 + lg*8];
        f16x8 vm = *(const f16x8*)&Vt[1][j2*16 + lr][kc*32 + lg*8];
        accO[j2] = MFMAH(ph[kc], vh, accO[j2]);
        accO[j2] = MFMAH(pm[kc], vh, accO[j2]);
        accO[j2] = MFMAH(ph[kc], vm, accO[j2]);
      }
    }
    __syncthreads();
  }
  #pragma unroll
  for (int j2 = 0; j2 < 4; ++j2)
    #pragma unroll
    for (int r = 0; r < 4; ++r) {
      float ov = accO[j2][r] * (1.0f / 4096.0f) / lsum[r];
      long row = qt * 64 + w * 16 + lg * 4 + r;
      long idx = hbo + row * kD + j2 * 16 + lr;
      u16 hh, mm; split2s(ov, hh, mm);
      oP[idx] = hh;
      oP[oplane + idx] = mm;
    }
}

// ---------------- f32 attention (fallback path) ----------------

__global__ __launch_bounds__(256) void attn_f32_k(
    const float* __restrict__ qkv, float* __restrict__ of32, int ldq) {
  int qt = blockIdx.x;
  int bh = blockIdx.y;
  int b = bh >> 4, h = bh & 15;
  long hbq = (long)b * kT * ldq + h * kHD;
  long hbo = (long)b * kT * kD + h * kHD;
  int t = threadIdx.x, qr = t >> 2, sub = t & 3;

  __shared__ float Qs[64][68], Ks[64][68], Vs[64][68], Ps[64][68];

  const float* q = qkv;
  const float* k = qkv + kD;
  const float* v = qkv + 2 * kD;

  #pragma unroll
  for (int it = 0; it < 4; ++it) {
    int c = it * 256 + t, row = c >> 4, c4 = (c & 15) * 4;
    f32x4 qv = *(const f32x4*)(q + hbq + (long)(qt * 64 + row) * ldq + c4);
    #pragma unroll
    for (int j = 0; j < 4; ++j) Qs[row][c4 + j] = qv[j];
  }
  __syncthreads();
  f32x4 qreg[16];
  #pragma unroll
  for (int d4 = 0; d4 < 16; ++d4) qreg[d4] = *(const f32x4*)&Qs[qr][d4 * 4];
  int qg = qt * 64 + qr;

  float mrow = -1e30f, lsum = 0.f;
  f32x4 accO[4];
  #pragma unroll
  for (int i = 0; i < 4; ++i) accO[i] = 0.f;

  for (int itl = 0; itl <= qt; ++itl) {
    #pragma unroll
    for (int it = 0; it < 4; ++it) {
      int c = it * 256 + t, row = c >> 4, c4 = (c & 15) * 4;
      long gi = hbq + (long)(itl * 64 + row) * ldq + c4;
      f32x4 kv = *(const f32x4*)(k + gi);
      f32x4 vv = *(const f32x4*)(v + gi);
      #pragma unroll
      for (int j = 0; j < 4; ++j) { Ks[row][c4 + j] = kv[j]; Vs[row][c4 + j] = vv[j]; }
    }
    __syncthreads();

    float s[16];
    #pragma unroll
    for (int kk = 0; kk < 16; ++kk) {
      int key = kk * 4 + sub;
      f32x4 a = {0.f, 0.f, 0.f, 0.f};
      #pragma unroll
      for (int d4 = 0; d4 < 16; ++d4) a += qreg[d4] * *(const f32x4*)&Ks[key][d4 * 4];
      float sv = (a[0] + a[1] + a[2] + a[3]) * 0.125f;
      if (itl * 64 + key > qg) sv = -1e30f;
      s[kk] = sv;
    }
    float mx = s[0];
    #pragma unroll
    for (int kk = 1; kk < 16; ++kk) mx = fmaxf(mx, s[kk]);
    mx = fmaxf(mx, __shfl_xor(mx, 1));
    mx = fmaxf(mx, __shfl_xor(mx, 2));
    float mi = fmaxf(mrow, mx);
    float alpha = __expf(mrow - mi);
    mrow = mi;
    float rs = 0.f;
    #pragma unroll
    for (int kk = 0; kk < 16; ++kk) {
      float p = __expf(s[kk] - mi);
      rs += p;
      Ps[qr][kk * 4 + sub] = p;
    }
    rs += __shfl_xor(rs, 1);
    rs += __shfl_xor(rs, 2);
    lsum = lsum * alpha + rs;
    #pragma unroll
    for (int i = 0; i < 4; ++i) accO[i] *= alpha;
    #pragma unroll
    for (int key2 = 0; key2 < 64; ++key2) {
      float p = Ps[qr][key2];
      #pragma unroll
      for (int i4 = 0; i4 < 4; ++i4)
        accO[i4] += p * *(const f32x4*)&Vs[key2][sub * 16 + i4 * 4];
    }
    __syncthreads();
  }
  float inv = 1.f / lsum;
  #pragma unroll
  for (int i4 = 0; i4 < 4; ++i4) {
    f32x4 ov = accO[i4] * inv;
    *(f32x4*)(of32 + hbo + (long)qg * kD + sub * 16 + i4 * 4) = ov;
  }
}

// ---------------- host ----------------

extern "C" void kernel_launch(void* const* d_in, const int* in_sizes, int n_in,
                              void* d_out, int out_size, void* d_ws, size_t ws_size,
                              hipStream_t stream) {
  const int*   idx  = (const int*)  d_in[0];
  const float* wte  = (const float*)d_in[1];
  const float* wpe  = (const float*)d_in[2];
  const float* wq   = (const float*)d_in[3];
  const float* wk   = (const float*)d_in[4];
  const float* wv   = (const float*)d_in[5];
  const float* wo   = (const float*)d_in[6];
  const float* gate = (const float*)d_in[7];
  const float* f1   = (const float*)d_in[8];
  const float* f2   = (const float*)d_in[9];
  const float* lmh  = (const float*)d_in[10];
  float* out = (float*)d_out;

  char* ws = (char*)d_ws;
  size_t off = 0;
  auto alloc = [&](size_t b) -> char* {
    char* p = ws + off;
    off += (b + 255) & ~(size_t)255;
    return p;
  };

  constexpr long PLN_XN = (long)kBT * kD;
  constexpr long PLN_Q3 = (long)kBT * 3 * kD;
  constexpr long PLN_QKV = (long)3 * kD * kD;
  constexpr long PLN_WO = (long)kD * kD;
  constexpr long PLN_FF = (long)kE * kFF * kD;
  constexpr long PLN_H = (long)kSLOTS * kFF;
  constexpr long PLN_OUTS = (long)kSLOTS * kD;

  // shared small buffers
  float* x     = (float*)alloc((size_t)kBT * kD * 4);
  float* outs  = (float*)alloc((size_t)4 * PLN_OUTS * 4);   // 4 K-partials
  float* probs = (float*)alloc((size_t)kBT * kE * 4);
  int*   top2e = (int*)  alloc((size_t)kBT * 2 * 4);
  float* top2w = (float*)alloc((size_t)kBT * 2 * 4);
  int*   meta  = (int*)  alloc(64 * 4);
  int* counts = meta; int* cursors = meta + 8; int* offs = meta + 16;
  int*   rows  = (int*)  alloc((size_t)kSLOTS * 4);
  int*   slotOf= (int*)  alloc((size_t)kBT * 2 * 4);
  float* aux   = (float*)alloc(256);
  size_t off_shared = off;

  // fast-path buffers
  u16*   xnP   = (u16*)  alloc((size_t)2 * PLN_XN * 2);
  float* qkvf  = (float*)alloc((size_t)PLN_Q3 * 4);
  u16*   qkvP  = (u16*)  alloc((size_t)2 * PLN_Q3 * 2);
  u16*   ofP   = (u16*)  alloc((size_t)2 * PLN_XN * 2);
  u16*   hP    = (u16*)  alloc((size_t)2 * PLN_H * 2);
  u16*   wqkvP = (u16*)  alloc((size_t)kL * 2 * PLN_QKV * 2);
  u16*   woP   = (u16*)  alloc((size_t)kL * 2 * PLN_WO * 2);
  u16*   lmb   = (u16*)  alloc((size_t)kV * kD * 2);      // f16 lm_head weights
  bool fast = (off <= ws_size);
  float* qkvp1 = (float*)hP;          // alias: hP idle during QKV+attn phase

  dim3 gAttn(kT / 64, 2 * kH);
  // base grids (all % 8 == 0)
  int bQKV = (kBT / 128) * (3 * kD / 128);       // 384,  MPART mPerX=2, kParts=2
  int bWO  = (kBT / 128) * (kD / 128);           // 128,  MPART mPerX=2, kParts=4
  int nF1W = (kSLOTS / 128) * (kFF / 256);       // 640,  W kernel mPerX=5
  int bF2  = (kSLOTS / 128) * (kD / 128);        // 320,  MPART mPerX=5, kParts=4
  int nF1s = (kSLOTS / 128) * (kFF / 128);       // 1280, MPART mPerX=5
  int nLM  = (kBT / 128) * (kV / 128);           // 4000, mBlocks=16

  if (fast) {
    for (int li = 0; li < kL; ++li) {
      u16* dst = wqkvP + (size_t)li * 2 * PLN_QKV;
      split2h_k<<<1024, 256, 0, stream>>>(wq + (size_t)li * kD * kD, dst, PLN_QKV, (long)kD * kD / 4);
      split2h_k<<<1024, 256, 0, stream>>>(wk + (size_t)li * kD * kD, dst + (long)kD * kD, PLN_QKV, (long)kD * kD / 4);
      split2h_k<<<1024, 256, 0, stream>>>(wv + (size_t)li * kD * kD, dst + (long)2 * kD * kD, PLN_QKV, (long)kD * kD / 4);
      split2h_k<<<1024, 256, 0, stream>>>(wo + (size_t)li * kD * kD, woP + (size_t)li * 2 * PLN_WO, PLN_WO, (long)kD * kD / 4);
    }
    cast_h_k<<<4096, 256, 0, stream>>>(lmh, lmb, (long)kV * kD / 4);
    hipMemsetAsync(aux, 0, 4, stream);
    embed_rms_k<<<kBT, 256, 0, stream>>>(idx, wte, wpe, x);
    rmsnorm2h_k<<<kBT, 256, 0, stream>>>(x, xnP, PLN_XN);   // layer-0 QKV input

    for (int li = 0; li < kL; ++li) {
      // QKV: split-K x2 -> qkvf + qkvp1; combine into split-2 planes
      gemm2h_bt_k<P_F32, false, false, true, false><<<2 * bQKV, 256, 0, stream>>>(
          xnP, PLN_XN, wqkvP + (size_t)li * 2 * PLN_QKV, PLN_QKV,
          qkvf, 0, nullptr, nullptr, nullptr, 3 * kD, kD, kD, 0, 2,
          2, bQKV, (long)(qkvp1 - qkvf));
      qkvcomb_k<<<2048, 256, 0, stream>>>(qkvf, qkvp1, qkvP, PLN_Q3, PLN_Q3 / 4);
      attn2h_k<<<gAttn, 256, 0, stream>>>(qkvP, PLN_Q3, ofP, PLN_XN);
      // WO: split-K x4 into outs partials; fused residual+rms+split
      gemm2h_bt_k<P_F32, false, false, true, false><<<4 * bWO, 256, 0, stream>>>(
          ofP, PLN_XN, woP + (size_t)li * 2 * PLN_WO, PLN_WO,
          outs, 0, nullptr, nullptr, nullptr, kD, kD, kD, 0, 2,
          4, bWO, PLN_OUTS);
      resid4_rms2h_k<<<kBT, 256, 0, stream>>>(x, outs, PLN_OUTS, xnP, PLN_XN);
      hipMemsetAsync(meta, 0, 64, stream);
      gate_topk_k<<<kBT, 256, 0, stream>>>(x, gate + (size_t)li * kE * kD,
                                           probs, top2e, top2w, counts);
      calc_offsets_k<<<1, 64, 0, stream>>>(counts, offs);
      fill_slots_k<<<kBT / 256, 256, 0, stream>>>(top2e, offs, cursors, rows, slotOf);
      size_t fd = (size_t)li * PLN_FF;
      if (li < 2) {
        // f1: wide kernel, B = f32 weights converted in staging (BF32)
        gemm2hW_bt_k<P_SPLIT2_RELU, true, true, true><<<nF1W, 512, 0, stream>>>(
            xnP, PLN_XN, f1 + fd, 0, hP, PLN_H, rows, offs,
            kFF, kD, kD, (long)kFF * kD, kSLOTS / 128 / 8,
            1, nF1W, 0);
        // f2: 128^2 kernel, split-K x4, B = f32 weights in-staging (BF32)
        gemm2h_bt_k<P_F32, false, true, true, true><<<4 * bF2, 256, 0, stream>>>(
            hP, PLN_H, f2 + fd, 0, outs, 0, nullptr, nullptr, offs,
            kD, kFF, kFF, (long)kD * kFF, kSLOTS / 128 / 8,
            4, bF2, PLN_OUTS);
        moe4_rms2h_k<<<kBT, 256, 0, stream>>>(x, outs, PLN_OUTS, slotOf, top2w,
                                              xnP, PLN_XN);
      } else {
        // last layer: single-f16, B = f32 converted in staging (BCONV, swizzled)
        gemm_bt_k<P_F16_RELU, true, true, true, true, true><<<nF1s, 256, 0, stream>>>(
            xnP, f1 + fd, hP, rows, offs, kFF, kD, kD, (long)kFF * kD,
            1.0f / 64.0f, kSLOTS / 128 / 8, 1, nF1s, 0);
        gemm_bt_k<P_F32, true, false, true, true, true><<<4 * bF2, 256, 0, stream>>>(
            hP, f2 + fd, outs, nullptr, offs, kD, kFF, kFF, (long)kD * kFF,
            1.0f, kSLOTS / 128 / 8, 4, bF2, PLN_OUTS);
        moe4_cast_h_k<<<kBT, 256, 0, stream>>>(x, outs, PLN_OUTS, slotOf, top2w, xnP);
      }
      aux_reduce_k<<<1, 256, 0, stream>>>(probs, aux);
    }
    // lm_head: pre-converted f16 weights, swizzled global_load_lds staging
    gemm_bt_k<P_F32, false, false, true, false, false><<<nLM, 256, 0, stream>>>(
        xnP, lmb, out, nullptr, nullptr, kV, kD, kD, 0, 1.0f, kBT / 128,
        1, nLM, 0);
    write_aux_k<<<1, 64, 0, stream>>>(aux, out + (size_t)kBT * kV);
    return;
  }

  // ---------- fallback: f32 path ----------
  off = off_shared;
  float* xnf   = (float*)alloc((size_t)kBT * kD * 4);
  u16*   xnb   = (u16*)  alloc((size_t)kBT * kD * 2);
  float* qkvf32= (float*)alloc((size_t)kBT * 3 * kD * 4);
  float* off32 = (float*)alloc((size_t)kBT * kD * 4);
  float* hbuf  = (float*)alloc((size_t)kSLOTS * kFF * 4);
  u16* hbuf16 = (u16*)hbuf;

  hipMemsetAsync(aux, 0, 4, stream);
  embed_rms_k<<<kBT, 256, 0, stream>>>(idx, wte, wpe, x);
  dim3 gF1s(kSLOTS / 128, kFF / 128);
  dim3 gF2s(kSLOTS / 128, kD / 128);
  for (int li = 0; li < kL; ++li) {
    size_t dd = (size_t)li * kD * kD;
    rmsnorm2_k<<<kBT, 256, 0, stream>>>(x, xnf, xnb);
    dim3 gP(kBT / 128, kD / 128);
    sgemm_bt_k<P_F32, false, false><<<gP, 256, 0, stream>>>(
        xnf, wq + dd, qkvf32, nullptr, nullptr, nullptr, 3 * kD, kD, kD, 0);
    sgemm_bt_k<P_F32, false, false><<<gP, 256, 0, stream>>>(
        xnf, wk + dd, qkvf32 + kD, nullptr, nullptr, nullptr, 3 * kD, kD, kD, 0);
    sgemm_bt_k<P_F32, false, false><<<gP, 256, 0, stream>>>(
        xnf, wv + dd, qkvf32 + 2 * kD, nullptr, nullptr, nullptr, 3 * kD, kD, kD, 0);
    attn_f32_k<<<gAttn, 256, 0, stream>>>(qkvf32, off32, 3 * kD);
    sgemm_bt_k<P_F32_RESID, false, false><<<gP, 256, 0, stream>>>(
        off32, wo + dd, x, x, nullptr, nullptr, kD, kD, kD, 0);
    rmsnorm2_k<<<kBT, 256, 0, stream>>>(x, xnf, xnb);
    hipMemsetAsync(meta, 0, 64, stream);
    gate_topk_k<<<kBT, 256, 0, stream>>>(x, gate + (size_t)li * kE * kD,
                                         probs, top2e, top2w, counts);
    calc_offsets_k<<<1, 64, 0, stream>>>(counts, offs);
    fill_slots_k<<<kBT / 256, 256, 0, stream>>>(top2e, offs, cursors, rows, slotOf);
    size_t fd = (size_t)li * kE * kFF * kD;
    if (li < 2) {
      sgemm_bt_k<P_F32_RELU, true, true><<<gF1s, 256, 0, stream>>>(
          xnf, f1 + fd, hbuf, nullptr, rows, offs, kFF, kD, kD, (long)kFF * kD);
      sgemm_bt_k<P_F32, false, true><<<gF2s, 256, 0, stream>>>(
          hbuf, f2 + fd, outs, nullptr, nullptr, offs, kD, kFF, kFF, (long)kD * kFF);
    } else {
      gemm_bt_k<P_BF16_RELU, true, true, false, true, false><<<nF1s, 256, 0, stream>>>(
          xnb, f1 + fd, hbuf16, rows, offs, kFF, kD, kD, (long)kFF * kD,
          1.0f, kSLOTS / 128, 1, nF1s, 0);
      gemm_bt_k<P_F32, true, false, false, true, false><<<bF2, 256, 0, stream>>>(
          hbuf16, f2 + fd, outs, nullptr, offs, kD, kFF, kFF, (long)kD * kFF,
          1.0f, kSLOTS / 128, 1, bF2, 0);
    }
    hipMemsetAsync(outs + PLN_OUTS, 0, 3 * PLN_OUTS * 4, stream);
    moe_combine4_k<<<kBT, 256, 0, stream>>>(x, outs, PLN_OUTS, slotOf, top2w);
    aux_reduce_k<<<1, 256, 0, stream>>>(probs, aux);
  }
  cast_bf16_k<<<2048, 256, 0, stream>>>(x, xnb, (long)kBT * kD / 4);
  gemm_bt_k<P_F32, false, false, false, true, false><<<nLM, 256, 0, stream>>>(
      xnb, lmh, out, nullptr, nullptr, kV, kD, kD, 0, 1.0f, kBT / 128,
      1, nLM, 0);
  write_aux_k<<<1, 64, 0, stream>>>(aux, out + (size_t)kBT * kV);
}

// Round 18
// 1998.446 us; speedup vs baseline: 1.1818x; 1.0143x over previous
//
#include <hip/hip_runtime.h>

typedef unsigned short u16;
typedef __attribute__((ext_vector_type(4))) float f32x4;
typedef __attribute__((ext_vector_type(8))) __bf16 bf16x8;
typedef __attribute__((ext_vector_type(8))) _Float16 f16x8;
typedef __attribute__((ext_vector_type(4))) unsigned short u16x4;
typedef __attribute__((ext_vector_type(8))) unsigned short u16x8;

constexpr int kT = 1024, kD = 1024, kH = 16, kHD = 64, kL = 3, kE = 8;
constexpr int kFF = 4096, kV = 32000, kBT = 2048, kSLOTS = 5120;

__device__ __forceinline__ u16 f2bf(float f) {
  union { float f; unsigned u; } v; v.f = f;
  unsigned r = v.u + 0x7FFFu + ((v.u >> 16) & 1u);   // RNE
  return (u16)(r >> 16);
}
__device__ __forceinline__ u16 f2h(float x) {
  _Float16 h = (_Float16)x;
  union { _Float16 h; u16 u; } v; v.h = h; return v.u;
}
// uniform-scale fp16 split-2: 64*x = hi + mid + O(2^-11 * |64x - hi|)
__device__ __forceinline__ void split2s(float x, u16& h, u16& m) {
  float xs = x * 64.0f;
  _Float16 hh = (_Float16)xs;
  union { _Float16 h; u16 u; } v; v.h = hh; h = v.u;
  float r = xs - (float)hh;
  union { _Float16 h; u16 u; } w; w.h = (_Float16)r; m = w.u;
}

__device__ __forceinline__ void ld_lds16(const void* g, void* l) {
  __builtin_amdgcn_global_load_lds((const __attribute__((address_space(1))) void*)g,
                                   (__attribute__((address_space(3))) void*)l, 16, 0, 0);
}

#define MFMA16(a, b, c) __builtin_amdgcn_mfma_f32_16x16x32_bf16(a, b, c, 0, 0, 0)
#define MFMAH(a, b, c)  __builtin_amdgcn_mfma_f32_16x16x32_f16(a, b, c, 0, 0, 0)

__device__ __forceinline__ float blockReduceSum256(float v) {
  #pragma unroll
  for (int m = 32; m >= 1; m >>= 1) v += __shfl_xor(v, m);
  __shared__ float sh_[4];
  int w = threadIdx.x >> 6;
  if ((threadIdx.x & 63) == 0) sh_[w] = v;
  __syncthreads();
  v = (sh_[0] + sh_[1]) + (sh_[2] + sh_[3]);
  __syncthreads();
  return v;
}

// ---------------- elementwise / small kernels ----------------

__global__ __launch_bounds__(256) void cast_bf16_k(const float* __restrict__ in,
                                                   u16* __restrict__ out, long n4) {
  long i = (long)blockIdx.x * 256 + threadIdx.x;
  long stride = (long)gridDim.x * 256;
  for (; i < n4; i += stride) {
    f32x4 v = ((const f32x4*)in)[i];
    u16x4 o; o[0] = f2bf(v[0]); o[1] = f2bf(v[1]); o[2] = f2bf(v[2]); o[3] = f2bf(v[3]);
    ((u16x4*)out)[i] = o;
  }
}

__global__ __launch_bounds__(256) void cast_h_k(const float* __restrict__ in,
                                                u16* __restrict__ out, long n4) {
  long i = (long)blockIdx.x * 256 + threadIdx.x;
  long stride = (long)gridDim.x * 256;
  for (; i < n4; i += stride) {
    f32x4 v = ((const f32x4*)in)[i];
    u16x4 o; o[0] = f2h(v[0]); o[1] = f2h(v[1]); o[2] = f2h(v[2]); o[3] = f2h(v[3]);
    ((u16x4*)out)[i] = o;
  }
}

// f32 -> 2 fp16 planes (uniform x64 scale)
__global__ __launch_bounds__(256) void split2h_k(const float* __restrict__ in,
    u16* __restrict__ out, long planeStride, long n4) {
  long i = (long)blockIdx.x * 256 + threadIdx.x;
  long stride = (long)gridDim.x * 256;
  u16* o1 = out + planeStride;
  for (; i < n4; i += stride) {
    f32x4 v = ((const f32x4*)in)[i];
    u16x4 a, b;
    #pragma unroll
    for (int j = 0; j < 4; ++j) {
      u16 h, m; split2s(v[j], h, m);
      a[j] = h; b[j] = m;
    }
    ((u16x4*)out)[i] = a; ((u16x4*)o1)[i] = b;
  }
}

// qkv = p0 + p1 -> 2 fp16 planes (x64 scale)
__global__ __launch_bounds__(256) void qkvcomb_k(const float* __restrict__ a,
    const float* __restrict__ b, u16* __restrict__ oP, long plane, long n4) {
  long i = (long)blockIdx.x * 256 + threadIdx.x;
  long stride = (long)gridDim.x * 256;
  for (; i < n4; i += stride) {
    f32x4 v = ((const f32x4*)a)[i] + ((const f32x4*)b)[i];
    u16x4 hh, mm;
    #pragma unroll
    for (int j = 0; j < 4; ++j) {
      u16 h, m; split2s(v[j], h, m);
      hh[j] = h; mm[j] = m;
    }
    ((u16x4*)oP)[i] = hh;
    ((u16x4*)(oP + plane))[i] = mm;
  }
}

__global__ __launch_bounds__(256) void embed_rms_k(const int* __restrict__ idx,
    const float* __restrict__ wte, const float* __restrict__ wpe, float* __restrict__ x) {
  int tok = blockIdx.x, t = threadIdx.x;
  int id = idx[tok];
  int tt = tok & (kT - 1);
  f32x4 a = ((const f32x4*)(wte + (long)id * kD))[t];
  f32x4 p = ((const f32x4*)(wpe + (long)tt * kD))[t];
  f32x4 vv = a + p;
  float ss = vv[0]*vv[0] + vv[1]*vv[1] + vv[2]*vv[2] + vv[3]*vv[3];
  ss = blockReduceSum256(ss);
  float sc = rsqrtf(ss * (1.0f / kD) + 1e-5f);
  vv *= sc;
  ((f32x4*)(x + (long)tok * kD))[t] = vv;
}

// rmsnorm -> f32 + bf16 (fallback path)
__global__ __launch_bounds__(256) void rmsnorm2_k(const float* __restrict__ x,
    float* __restrict__ xnf, u16* __restrict__ xnb) {
  int tok = blockIdx.x, t = threadIdx.x;
  f32x4 vv = ((const f32x4*)(x + (long)tok * kD))[t];
  float ss = blockReduceSum256(vv[0]*vv[0] + vv[1]*vv[1] + vv[2]*vv[2] + vv[3]*vv[3]);
  float sc = rsqrtf(ss * (1.0f / kD) + 1e-5f);
  vv *= sc;
  ((f32x4*)(xnf + (long)tok * kD))[t] = vv;
  u16x4 o;
  o[0] = f2bf(vv[0]); o[1] = f2bf(vv[1]); o[2] = f2bf(vv[2]); o[3] = f2bf(vv[3]);
  ((u16x4*)(xnb + (long)tok * kD))[t] = o;
}

// rmsnorm -> 2 fp16 planes (fast path, x64 scale)
__global__ __launch_bounds__(256) void rmsnorm2h_k(const float* __restrict__ x,
    u16* __restrict__ xnP, long plane) {
  int tok = blockIdx.x, t = threadIdx.x;
  f32x4 vv = ((const f32x4*)(x + (long)tok * kD))[t];
  float ss = blockReduceSum256(vv[0]*vv[0] + vv[1]*vv[1] + vv[2]*vv[2] + vv[3]*vv[3]);
  float sc = rsqrtf(ss * (1.0f / kD) + 1e-5f);
  vv *= sc;
  u16x4 a, b;
  #pragma unroll
  for (int j = 0; j < 4; ++j) {
    u16 h, m; split2s(vv[j], h, m);
    a[j] = h; b[j] = m;
  }
  long o = (long)tok * kD / 4 + t;
  ((u16x4*)xnP)[o] = a;
  ((u16x4*)(xnP + plane))[o] = b;
}

// x += sum of 4 K-partials; write x; rmsnorm -> 2 fp16 planes
__global__ __launch_bounds__(256) void resid4_rms2h_k(float* __restrict__ x,
    const float* __restrict__ parts, long plane, u16* __restrict__ xnP, long xplane) {
  int tok = blockIdx.x, t = threadIdx.x;
  long o = (long)tok * (kD / 4) + t;
  f32x4 xv = ((f32x4*)x)[o];
  #pragma unroll
  for (int p = 0; p < 4; ++p) xv += ((const f32x4*)(parts + p * plane))[o];
  ((f32x4*)x)[o] = xv;
  float ss = blockReduceSum256(xv[0]*xv[0] + xv[1]*xv[1] + xv[2]*xv[2] + xv[3]*xv[3]);
  float sc = rsqrtf(ss * (1.0f / kD) + 1e-5f);
  f32x4 vv = xv * sc;
  u16x4 a, b;
  #pragma unroll
  for (int j = 0; j < 4; ++j) {
    u16 h, m; split2s(vv[j], h, m);
    a[j] = h; b[j] = m;
  }
  ((u16x4*)xnP)[o] = a;
  ((u16x4*)(xnP + xplane))[o] = b;
}

// x += moe combine (4 K-partials, 2 experts); write x; rmsnorm -> 2 fp16 planes
__global__ __launch_bounds__(256) void moe4_rms2h_k(float* __restrict__ x,
    const float* __restrict__ outsP, long plane, const int* __restrict__ slotOf,
    const float* __restrict__ top2w, u16* __restrict__ xnP, long xplane) {
  int tok = blockIdx.x, t = threadIdx.x;
  int s0 = slotOf[tok*2], s1 = slotOf[tok*2+1];
  float w0 = top2w[tok*2], w1 = top2w[tok*2+1];
  f32x4 a = {0.f,0.f,0.f,0.f}, b = a;
  #pragma unroll
  for (int p = 0; p < 4; ++p) {
    a += ((const f32x4*)(outsP + p * plane + (long)s0 * kD))[t];
    b += ((const f32x4*)(outsP + p * plane + (long)s1 * kD))[t];
  }
  long o = (long)tok * (kD / 4) + t;
  f32x4 xv = ((f32x4*)x)[o];
  xv += a * w0 + b * w1;
  ((f32x4*)x)[o] = xv;
  float ss = blockReduceSum256(xv[0]*xv[0] + xv[1]*xv[1] + xv[2]*xv[2] + xv[3]*xv[3]);
  float sc = rsqrtf(ss * (1.0f / kD) + 1e-5f);
  f32x4 vv = xv * sc;
  u16x4 ha, hb;
  #pragma unroll
  for (int j = 0; j < 4; ++j) {
    u16 h, m; split2s(vv[j], h, m);
    ha[j] = h; hb[j] = m;
  }
  ((u16x4*)xnP)[o] = ha;
  ((u16x4*)(xnP + xplane))[o] = hb;
}

// last layer: x += moe combine; write f16 (unscaled) plane for lm_head
__global__ __launch_bounds__(256) void moe4_cast_h_k(float* __restrict__ x,
    const float* __restrict__ outsP, long plane, const int* __restrict__ slotOf,
    const float* __restrict__ top2w, u16* __restrict__ xn) {
  int tok = blockIdx.x, t = threadIdx.x;
  int s0 = slotOf[tok*2], s1 = slotOf[tok*2+1];
  float w0 = top2w[tok*2], w1 = top2w[tok*2+1];
  f32x4 a = {0.f,0.f,0.f,0.f}, b = a;
  #pragma unroll
  for (int p = 0; p < 4; ++p) {
    a += ((const f32x4*)(outsP + p * plane + (long)s0 * kD))[t];
    b += ((const f32x4*)(outsP + p * plane + (long)s1 * kD))[t];
  }
  long o = (long)tok * (kD / 4) + t;
  f32x4 xv = ((f32x4*)x)[o];
  xv += a * w0 + b * w1;
  u16x4 hv;
  #pragma unroll
  for (int j = 0; j < 4; ++j) hv[j] = f2h(xv[j]);
  ((u16x4*)xn)[o] = hv;
}

// gating in f32 (bf16 would flip top-2 selections on near-ties)
__global__ __launch_bounds__(256) void gate_topk_k(const float* __restrict__ x,
    const float* __restrict__ gate_l, float* __restrict__ probs, int* __restrict__ top2e,
    float* __restrict__ top2w, int* __restrict__ counts) {
  int tok = blockIdx.x, t = threadIdx.x;
  f32x4 xv = ((const f32x4*)(x + (long)tok * kD))[t];
  float ss = blockReduceSum256(xv[0]*xv[0] + xv[1]*xv[1] + xv[2]*xv[2] + xv[3]*xv[3]);
  float sc = rsqrtf(ss * (1.0f / kD) + 1e-5f);
  float a[kE];
  #pragma unroll
  for (int e = 0; e < kE; ++e) {
    f32x4 gv = ((const f32x4*)(gate_l + (long)e * kD))[t];
    a[e] = xv[0]*gv[0] + xv[1]*gv[1] + xv[2]*gv[2] + xv[3]*gv[3];
  }
  __shared__ float sh8[kE][4];
  int w = t >> 6, l = t & 63;
  #pragma unroll
  for (int e = 0; e < kE; ++e) {
    float v = a[e];
    #pragma unroll
    for (int m = 32; m >= 1; m >>= 1) v += __shfl_xor(v, m);
    if (l == 0) sh8[e][w] = v;
  }
  __syncthreads();
  if (t == 0) {
    float lg[kE], mx = -1e30f;
    #pragma unroll
    for (int e = 0; e < kE; ++e) {
      lg[e] = (sh8[e][0] + sh8[e][1] + sh8[e][2] + sh8[e][3]) * sc;
      mx = fmaxf(mx, lg[e]);
    }
    float pe[kE], s = 0.f;
    #pragma unroll
    for (int e = 0; e < kE; ++e) { pe[e] = __expf(lg[e] - mx); s += pe[e]; }
    float inv = 1.f / s;
    int i1 = 0;
    #pragma unroll
    for (int e = 1; e < kE; ++e) if (lg[e] > lg[i1]) i1 = e;
    int i2 = (i1 == 0) ? 1 : 0;
    #pragma unroll
    for (int e = 0; e < kE; ++e) if (e != i1 && lg[e] > lg[i2]) i2 = e;
    #pragma unroll
    for (int e = 0; e < kE; ++e) probs[(long)tok * kE + e] = pe[e] * inv;
    float p1 = pe[i1] * inv, p2 = pe[i2] * inv;
    float wn = p1 + p2;
    top2e[tok*2] = i1; top2e[tok*2+1] = i2;
    top2w[tok*2] = p1 / wn; top2w[tok*2+1] = p2 / wn;
    atomicAdd(&counts[i1], 1); atomicAdd(&counts[i2], 1);
  }
}

// 128-aligned expert offsets (fallback path)
__global__ void calc_offsets_k(const int* __restrict__ counts, int* __restrict__ offsets) {
  if (threadIdx.x == 0) {
    int o = 0;
    #pragma unroll
    for (int e = 0; e < kE; ++e) { offsets[e] = o; o += (counts[e] + 127) & ~127; }
    offsets[kE] = o;
  }
}

// offsets computed in-kernel from counts (block 0 publishes); slots filled
__global__ __launch_bounds__(256) void fill_slots2_k(const int* __restrict__ top2e,
    const int* __restrict__ counts, int* __restrict__ offsets, int* __restrict__ cursors,
    int* __restrict__ rows, int* __restrict__ slotOf) {
  __shared__ int soff[kE + 1];
  if (threadIdx.x == 0) {
    int o = 0;
    #pragma unroll
    for (int e = 0; e < kE; ++e) { soff[e] = o; o += (counts[e] + 127) & ~127; }
    soff[kE] = o;
    if (blockIdx.x == 0) {
      #pragma unroll
      for (int e = 0; e <= kE; ++e) offsets[e] = soff[e];
    }
  }
  __syncthreads();
  int tok = blockIdx.x * 256 + threadIdx.x;
  if (tok >= kBT) return;
  #pragma unroll
  for (int j = 0; j < 2; ++j) {
    int e = top2e[tok*2 + j];
    int pos = atomicAdd(&cursors[e], 1);
    int slot = soff[e] + pos;
    rows[slot] = tok;
    slotOf[tok*2 + j] = slot;
  }
}

// fallback combine (4 partials; unused planes zeroed)
__global__ __launch_bounds__(256) void moe_combine4_k(float* __restrict__ x,
    const float* __restrict__ outsP, long plane, const int* __restrict__ slotOf,
    const float* __restrict__ top2w) {
  int tok = blockIdx.x, t = threadIdx.x;
  int s0 = slotOf[tok*2], s1 = slotOf[tok*2+1];
  float w0 = top2w[tok*2], w1 = top2w[tok*2+1];
  f32x4 a = {0.f,0.f,0.f,0.f}, b = a;
  #pragma unroll
  for (int p = 0; p < 4; ++p) {
    a += ((const f32x4*)(outsP + p * plane + (long)s0 * kD))[t];
    b += ((const f32x4*)(outsP + p * plane + (long)s1 * kD))[t];
  }
  f32x4 xv = ((f32x4*)(x + (long)tok * kD))[t];
  xv += a * w0 + b * w1;
  ((f32x4*)(x + (long)tok * kD))[t] = xv;
}

// all-layer aux: out[0] = 0.01/L * sum_l E * sum_e (mean_t probs3[l])^2
__global__ __launch_bounds__(256) void aux_reduce3_k(const float* __restrict__ probs3,
    long plane, float* __restrict__ outv) {
  int t = threadIdx.x;
  float part[kL][kE] = {};
  for (int i = t; i < kBT; i += 256) {
    #pragma unroll
    for (int l = 0; l < kL; ++l)
      #pragma unroll
      for (int e = 0; e < kE; ++e)
        part[l][e] += probs3[l * plane + (long)i * kE + e];
  }
  __shared__ float sh[kL][kE][4];
  int w = t >> 6, ln = t & 63;
  #pragma unroll
  for (int l = 0; l < kL; ++l)
    #pragma unroll
    for (int e = 0; e < kE; ++e) {
      float v = part[l][e];
      #pragma unroll
      for (int m = 32; m >= 1; m >>= 1) v += __shfl_xor(v, m);
      if (ln == 0) sh[l][e][w] = v;
    }
  __syncthreads();
  if (t == 0) {
    float acc = 0.f;
    #pragma unroll
    for (int l = 0; l < kL; ++l)
      #pragma unroll
      for (int e = 0; e < kE; ++e) {
        float frac = (sh[l][e][0] + sh[l][e][1] + sh[l][e][2] + sh[l][e][3]) * (1.0f / kBT);
        acc += frac * frac;
      }
    outv[0] = 0.01f * (float)kE * acc / (float)kL;
  }
}

__global__ __launch_bounds__(256) void aux_reduce_k(const float* __restrict__ probs,
                                                    float* __restrict__ aux) {
  int t = threadIdx.x;
  float part[kE] = {};
  for (int i = t; i < kBT; i += 256) {
    #pragma unroll
    for (int e = 0; e < kE; ++e) part[e] += probs[(long)i * kE + e];
  }
  __shared__ float sh8[kE][4];
  int w = t >> 6, l = t & 63;
  #pragma unroll
  for (int e = 0; e < kE; ++e) {
    float v = part[e];
    #pragma unroll
    for (int m = 32; m >= 1; m >>= 1) v += __shfl_xor(v, m);
    if (l == 0) sh8[e][w] = v;
  }
  __syncthreads();
  if (t == 0) {
    float acc = 0.f;
    #pragma unroll
    for (int e = 0; e < kE; ++e) {
      float frac = (sh8[e][0] + sh8[e][1] + sh8[e][2] + sh8[e][3]) * (1.0f / kBT);
      acc += frac * frac;
    }
    aux[0] += (float)kE * acc;
  }
}

__global__ void write_aux_k(const float* __restrict__ aux, float* __restrict__ out) {
  if (threadIdx.x == 0) out[0] = 0.01f * aux[0] / (float)kL;
}

enum { P_BF16 = 0, P_BF16_RELU = 1, P_F32 = 2, P_F32_RESID = 3, P_F32_RELU = 4,
       P_SPLIT2_RELU = 5, P_F16_RELU = 6 };

__device__ __forceinline__ int clamp_row(int rv) {
  return ((unsigned)rv < (unsigned)kBT) ? rv : 0;
}

template <bool MPART>
__device__ __forceinline__ void block_mn(int lin, int base, int mArg, int& mb, int& nb) {
  int xcd = lin & 7, c = lin >> 3;
  if (MPART) {
    mb = xcd * mArg + (c % mArg);
    nb = c / mArg;
  } else {
    int swz = xcd * (base >> 3) + c;
    mb = swz % mArg;
    nb = swz / mArg;
  }
}

// ------- fused fp16 split-2 MFMA GEMM (128x128, 256 thr), single accumulator -------

template <int POST, bool GATHER, bool EXPERT, bool MPART, bool BF32>
__global__ __launch_bounds__(256) void gemm2h_bt_k(
    const u16* __restrict__ A0, long planeA,
    const void* __restrict__ Bv, long planeB,
    void* __restrict__ C, long planeC,
    const float* __restrict__ resid,
    const int* __restrict__ rows, const int* __restrict__ offsets,
    int N, int K, int lda, long eBstride, int mArg,
    int kParts, int base, long cPart) {
  constexpr int BM = 128, BK = 32;
  int part = blockIdx.x / base;
  int lin = blockIdx.x % base;
  int mb, nb;
  block_mn<MPART>(lin, base, mArg, mb, nb);
  int m0 = mb * BM, n0 = nb * BM;
  const u16* B0 = (const u16*)Bv;
  const float* Bf = (const float*)Bv;
  if (EXPERT) {
    int total = offsets[kE];
    if (m0 >= total) return;
    int e = 0;
    while (offsets[e + 1] <= m0) ++e;
    if (BF32) Bf += (long)e * eBstride; else B0 += (long)e * eBstride;
  }
  __shared__ __align__(16) u16 Ac[BM][64];
  __shared__ __align__(16) u16 Bc[BM][64];
  int t = threadIdx.x;
  int l = t & 63, lr = l & 15, lg = l >> 4;
  int wid = t >> 6;
  int wm = (wid >> 1) * 64, wn = (wid & 1) * 64;

  long asrc[4], bsrc[4];
  int ldst[4];
  #pragma unroll
  for (int it = 0; it < 4; ++it) {
    int d = it * 256 + t;
    int row = d >> 3, pc = d & 7;
    int lc = pc ^ (row & 7);
    int p = lc >> 2, c = lc & 3;
    int grow = GATHER ? clamp_row(rows[m0 + row]) : (m0 + row);
    asrc[it] = (long)p * planeA + (long)grow * lda + c * 8;
    if (!BF32) bsrc[it] = (long)p * planeB + (long)(n0 + row) * K + c * 8;
    ldst[it] = (it * 256 + (t & ~63)) * 8;
  }
  long bsrcF[2];
  int brow[2], bc[2];
  if (BF32) {
    #pragma unroll
    for (int it = 0; it < 2; ++it) {
      int d = it * 256 + t;
      brow[it] = d >> 2; bc[it] = d & 3;
      bsrcF[it] = (long)(n0 + brow[it]) * K + bc[it] * 8;
    }
  }
  int sa = lr & 7;
  int cH = (lg ^ sa) * 8;
  int cM = ((4 + lg) ^ sa) * 8;

  f32x4 acc[4][4];
  #pragma unroll
  for (int i = 0; i < 4; ++i)
    #pragma unroll
    for (int j = 0; j < 4; ++j) acc[i][j] = 0.f;

  int kStep = K / kParts;
  int kLo = part * kStep, kHi = kLo + kStep;
  for (int k0 = kLo; k0 < kHi; k0 += BK) {
    #pragma unroll
    for (int it = 0; it < 4; ++it) {
      ld_lds16(A0 + asrc[it] + k0, &Ac[0][0] + ldst[it]);
      if (!BF32) ld_lds16(B0 + bsrc[it] + k0, &Bc[0][0] + ldst[it]);
    }
    if (BF32) {
      #pragma unroll
      for (int it = 0; it < 2; ++it) {
        const float* src = Bf + bsrcF[it] + k0;
        f32x4 v0 = *(const f32x4*)src;
        f32x4 v1 = *(const f32x4*)(src + 4);
        u16x8 hi, mi;
        #pragma unroll
        for (int j = 0; j < 4; ++j) {
          u16 h, m; split2s(v0[j], h, m); hi[j] = h; mi[j] = m;
        }
        #pragma unroll
        for (int j = 0; j < 4; ++j) {
          u16 h, m; split2s(v1[j], h, m); hi[4 + j] = h; mi[4 + j] = m;
        }
        int r7 = brow[it] & 7;
        *(u16x8*)&Bc[brow[it]][(bc[it] ^ r7) * 8] = hi;
        *(u16x8*)&Bc[brow[it]][((4 + bc[it]) ^ r7) * 8] = mi;
      }
    }
    __syncthreads();
    f16x8 ah[4], am[4];
    #pragma unroll
    for (int i = 0; i < 4; ++i) {
      ah[i] = *(const f16x8*)&Ac[wm + i*16 + lr][cH];
      am[i] = *(const f16x8*)&Ac[wm + i*16 + lr][cM];
    }
    __builtin_amdgcn_s_setprio(1);
    #pragma unroll
    for (int j = 0; j < 4; ++j) {
      f16x8 bh = *(const f16x8*)&Bc[wn + j*16 + lr][cH];
      f16x8 bm = *(const f16x8*)&Bc[wn + j*16 + lr][cM];
      #pragma unroll
      for (int i = 0; i < 4; ++i) {
        acc[i][j] = MFMAH(ah[i], bh, acc[i][j]);
        acc[i][j] = MFMAH(am[i], bh, acc[i][j]);
        acc[i][j] = MFMAH(ah[i], bm, acc[i][j]);
      }
    }
    __builtin_amdgcn_s_setprio(0);
    __syncthreads();
  }
  float* Cf = (float*)C + (long)part * cPart;
  #pragma unroll
  for (int i = 0; i < 4; ++i) {
    #pragma unroll
    for (int r = 0; r < 4; ++r) {
      long m = m0 + wm + i*16 + lg*4 + r;
      #pragma unroll
      for (int j = 0; j < 4; ++j) {
        int n = n0 + wn + j*16 + lr;
        float val = acc[i][j][r] * (1.0f / 4096.0f);
        if (POST == P_F32) {
          Cf[m * N + n] = val;
        } else if (POST == P_F32_RESID) {
          ((float*)C)[m * N + n] = val + resid[m * N + n];
        } else if (POST == P_SPLIT2_RELU) {
          val = fmaxf(val, 0.f);
          u16 h, mm; split2s(val, h, mm);
          u16* Cp = (u16*)C;
          Cp[m * N + n] = h;
          Cp[planeC + m * N + n] = mm;
        }
      }
    }
  }
}

// ------- wide fused fp16 split-2 GEMM: 128x256 tile, 512 threads, 2m x 4n waves -------

template <int POST, bool GATHER, bool EXPERT, bool BF32>
__global__ __launch_bounds__(512) void gemm2hW_bt_k(
    const u16* __restrict__ A0, long planeA,
    const void* __restrict__ Bv, long planeB,
    void* __restrict__ C, long planeC,
    const int* __restrict__ rows, const int* __restrict__ offsets,
    int N, int K, int lda, long eBstride, int mPerX,
    int kParts, int base, long cPart) {
  constexpr int BM = 128, BN = 256, BK = 32;
  int part = blockIdx.x / base;
  int lin = blockIdx.x % base;
  int xcd = lin & 7, c0 = lin >> 3;
  int m0 = (xcd * mPerX + (c0 % mPerX)) * BM;
  int n0 = (c0 / mPerX) * BN;
  const u16* B0 = (const u16*)Bv;
  const float* Bf = (const float*)Bv;
  if (EXPERT) {
    int total = offsets[kE];
    if (m0 >= total) return;
    int e = 0;
    while (offsets[e + 1] <= m0) ++e;
    if (BF32) Bf += (long)e * eBstride; else B0 += (long)e * eBstride;
  }
  __shared__ __align__(16) u16 Ac[BM][64];
  __shared__ __align__(16) u16 Bc[BN][64];
  int t = threadIdx.x;
  int l = t & 63, lr = l & 15, lg = l >> 4;
  int wid = t >> 6;
  int wm = (wid >> 2) * 64;
  int wn = (wid & 3) * 64;

  long asrc[2], bsrc[4];
  int aldst[2], bldst[4];
  #pragma unroll
  for (int it = 0; it < 2; ++it) {
    int d = it * 512 + t;
    int row = d >> 3, pc = d & 7;
    int lc = pc ^ (row & 7);
    int p = lc >> 2, cc = lc & 3;
    int grow = GATHER ? clamp_row(rows[m0 + row]) : (m0 + row);
    asrc[it] = (long)p * planeA + (long)grow * lda + cc * 8;
    aldst[it] = (it * 512 + (t & ~63)) * 8;
  }
  long bsrcF[2];
  int brow[2], bcc[2];
  if (!BF32) {
    #pragma unroll
    for (int it = 0; it < 4; ++it) {
      int d = it * 512 + t;
      int row = d >> 3, pc = d & 7;
      int lc = pc ^ (row & 7);
      int p = lc >> 2, cc = lc & 3;
      bsrc[it] = (long)p * planeB + (long)(n0 + row) * K + cc * 8;
      bldst[it] = (it * 512 + (t & ~63)) * 8;
    }
  } else {
    #pragma unroll
    for (int it = 0; it < 2; ++it) {
      int d = it * 512 + t;
      brow[it] = d >> 2; bcc[it] = d & 3;
      bsrcF[it] = (long)(n0 + brow[it]) * K + bcc[it] * 8;
    }
  }
  int sa = lr & 7;
  int cH = (lg ^ sa) * 8;
  int cM = ((4 + lg) ^ sa) * 8;

  f32x4 acc[4][4];
  #pragma unroll
  for (int i = 0; i < 4; ++i)
    #pragma unroll
    for (int j = 0; j < 4; ++j) acc[i][j] = 0.f;

  int kStep = K / kParts;
  int kLo = part * kStep, kHi = kLo + kStep;
  for (int k0 = kLo; k0 < kHi; k0 += BK) {
    #pragma unroll
    for (int it = 0; it < 2; ++it)
      ld_lds16(A0 + asrc[it] + k0, &Ac[0][0] + aldst[it]);
    if (!BF32) {
      #pragma unroll
      for (int it = 0; it < 4; ++it)
        ld_lds16(B0 + bsrc[it] + k0, &Bc[0][0] + bldst[it]);
    } else {
      #pragma unroll
      for (int it = 0; it < 2; ++it) {
        const float* src = Bf + bsrcF[it] + k0;
        f32x4 v0 = *(const f32x4*)src;
        f32x4 v1 = *(const f32x4*)(src + 4);
        u16x8 hi, mi;
        #pragma unroll
        for (int j = 0; j < 4; ++j) {
          u16 h, m; split2s(v0[j], h, m); hi[j] = h; mi[j] = m;
        }
        #pragma unroll
        for (int j = 0; j < 4; ++j) {
          u16 h, m; split2s(v1[j], h, m); hi[4 + j] = h; mi[4 + j] = m;
        }
        int r7 = brow[it] & 7;
        *(u16x8*)&Bc[brow[it]][(bcc[it] ^ r7) * 8] = hi;
        *(u16x8*)&Bc[brow[it]][((4 + bcc[it]) ^ r7) * 8] = mi;
      }
    }
    __syncthreads();
    f16x8 ah[4], am[4];
    #pragma unroll
    for (int i = 0; i < 4; ++i) {
      ah[i] = *(const f16x8*)&Ac[wm + i*16 + lr][cH];
      am[i] = *(const f16x8*)&Ac[wm + i*16 + lr][cM];
    }
    __builtin_amdgcn_s_setprio(1);
    #pragma unroll
    for (int j = 0; j < 4; ++j) {
      f16x8 bh = *(const f16x8*)&Bc[wn + j*16 + lr][cH];
      f16x8 bm = *(const f16x8*)&Bc[wn + j*16 + lr][cM];
      #pragma unroll
      for (int i = 0; i < 4; ++i) {
        acc[i][j] = MFMAH(ah[i], bh, acc[i][j]);
        acc[i][j] = MFMAH(am[i], bh, acc[i][j]);
        acc[i][j] = MFMAH(ah[i], bm, acc[i][j]);
      }
    }
    __builtin_amdgcn_s_setprio(0);
    __syncthreads();
  }
  float* Cf = (float*)C + (long)part * cPart;
  #pragma unroll
  for (int i = 0; i < 4; ++i) {
    #pragma unroll
    for (int r = 0; r < 4; ++r) {
      long m = m0 + wm + i*16 + lg*4 + r;
      #pragma unroll
      for (int j = 0; j < 4; ++j) {
        int n = n0 + wn + j*16 + lr;
        float val = acc[i][j][r] * (1.0f / 4096.0f);
        if (POST == P_F32) {
          Cf[m * N + n] = val;
        } else if (POST == P_SPLIT2_RELU) {
          val = fmaxf(val, 0.f);
          u16 h, mm; split2s(val, h, mm);
          u16* Cp = (u16*)C;
          Cp[m * N + n] = h;
          Cp[planeC + m * N + n] = mm;
        }
      }
    }
  }
}

// ---------------- single-plane MFMA GEMM (with optional split-K) ----------------

template <int POST, bool EXPERT, bool GATHER, bool HALF, bool BCONV, bool MPART>
__global__ __launch_bounds__(256) void gemm_bt_k(
    const u16* __restrict__ A, const void* __restrict__ Bv, void* __restrict__ C,
    const int* __restrict__ rows, const int* __restrict__ offsets,
    int N, int K, int lda, long eBstride, float oscale, int mArg,
    int kParts, int base, long cPart) {
  constexpr int BM = 128, BK = 64;
  int part = blockIdx.x / base;
  int lin = blockIdx.x % base;
  int mb, nb;
  block_mn<MPART>(lin, base, mArg, mb, nb);
  int m0 = mb * BM, n0 = nb * BM;
  const float* Bf = (const float*)Bv;
  const u16*   Bh = (const u16*)Bv;
  if (EXPERT) {
    int total = offsets[kE];
    if (m0 >= total) return;
    int e = 0;
    while (offsets[e + 1] <= m0) ++e;
    if (BCONV) Bf += (long)e * eBstride; else Bh += (long)e * eBstride;
  }
  __shared__ __align__(16) u16 As[BM][BK];
  __shared__ __align__(16) u16 Bs[BM][BK];
  int t = threadIdx.x;
  int l = t & 63, lr = l & 15, lg = l >> 4;
  int wid = t >> 6;
  int wm = (wid >> 1) * 64, wn = (wid & 1) * 64;

  long asrc[4], bsrc[4];
  int ldst[4];
  #pragma unroll
  for (int it = 0; it < 4; ++it) {
    int d = it * 256 + t;
    int row = d >> 3, pc = d & 7;
    int c = pc ^ (row & 7);
    int grow = GATHER ? clamp_row(rows[m0 + row]) : (m0 + row);
    asrc[it] = (long)grow * lda + c * 8;
    if (!BCONV) bsrc[it] = (long)(n0 + row) * K + c * 8;
    ldst[it] = (it * 256 + (t & ~63)) * 8;
  }
  long bsrcC[4];
  int bdst[4];
  if (BCONV) {
    #pragma unroll
    for (int it = 0; it < 4; ++it) {
      int d = it * 256 + t;
      int row = d >> 3, lc = d & 7;
      bsrcC[it] = (long)(n0 + row) * K + lc * 8;
      bdst[it] = row * BK + (lc ^ (row & 7)) * 8;
    }
  }
  f32x4 acc[4][4];
  #pragma unroll
  for (int i = 0; i < 4; ++i)
    #pragma unroll
    for (int j = 0; j < 4; ++j) acc[i][j] = 0.f;

  int kStep = K / kParts;
  int kLo = part * kStep, kHi = kLo + kStep;
  for (int k0 = kLo; k0 < kHi; k0 += BK) {
    #pragma unroll
    for (int it = 0; it < 4; ++it)
      ld_lds16(A + asrc[it] + k0, &As[0][0] + ldst[it]);
    if (!BCONV) {
      #pragma unroll
      for (int it = 0; it < 4; ++it)
        ld_lds16(Bh + bsrc[it] + k0, &Bs[0][0] + ldst[it]);
    } else {
      #pragma unroll
      for (int it = 0; it < 4; ++it) {
        const float* src = Bf + bsrcC[it] + k0;
        f32x4 v0 = *(const f32x4*)src;
        f32x4 v1 = *(const f32x4*)(src + 4);
        u16x8 o;
        #pragma unroll
        for (int j = 0; j < 4; ++j) {
          o[j] = HALF ? f2h(v0[j]) : f2bf(v0[j]);
          o[4 + j] = HALF ? f2h(v1[j]) : f2bf(v1[j]);
        }
        *(u16x8*)(&Bs[0][0] + bdst[it]) = o;
      }
    }
    __syncthreads();
    __builtin_amdgcn_s_setprio(1);
    #pragma unroll
    for (int kk = 0; kk < 2; ++kk) {
      int ca = ((kk * 4 + lg) ^ (lr & 7)) * 8;
      #pragma unroll
      for (int i = 0; i < 4; ++i)
        #pragma unroll
        for (int j = 0; j < 4; ++j) {
          if (HALF) {
            f16x8 af = *(const f16x8*)&As[wm + i*16 + lr][ca];
            f16x8 bq = *(const f16x8*)&Bs[wn + j*16 + lr][ca];
            acc[i][j] = MFMAH(af, bq, acc[i][j]);
          } else {
            bf16x8 af = *(const bf16x8*)&As[wm + i*16 + lr][ca];
            bf16x8 bq = *(const bf16x8*)&Bs[wn + j*16 + lr][ca];
            acc[i][j] = MFMA16(af, bq, acc[i][j]);
          }
        }
    }
    __builtin_amdgcn_s_setprio(0);
    __syncthreads();
  }
  #pragma unroll
  for (int i = 0; i < 4; ++i) {
    #pragma unroll
    for (int r = 0; r < 4; ++r) {
      long m = m0 + wm + i*16 + lg*4 + r;
      #pragma unroll
      for (int j = 0; j < 4; ++j) {
        int n = n0 + wn + j*16 + lr;
        float val = acc[i][j][r] * oscale;
        if (POST == P_BF16_RELU)       ((u16*)C)[m * N + n] = f2bf(fmaxf(val, 0.f));
        else if (POST == P_F16_RELU)   ((u16*)C)[m * N + n] = f2h(fmaxf(val, 0.f));
        else if (POST == P_F32)        ((float*)C + (long)part * cPart)[m * N + n] = val;
      }
    }
  }
}

// ---------------- f32 SGEMM (fallback path only) ----------------

template <int POST, bool GATHER, bool EXPERT>
__global__ __launch_bounds__(256) void sgemm_bt_k(
    const float* __restrict__ A, const float* __restrict__ B, float* __restrict__ C,
    const float* __restrict__ resid, const int* __restrict__ rows,
    const int* __restrict__ offsets, int N, int K, int lda, long eBstride) {
  constexpr int BM = 128, BN = 128, BK = 32;
  int m0 = blockIdx.x * BM, n0 = blockIdx.y * BN;
  if (EXPERT) {
    int total = offsets[kE];
    if (m0 >= total) return;
    int e = 0;
    while (offsets[e + 1] <= m0) ++e;
    B += (long)e * eBstride;
  }
  __shared__ float Ast[BK][BM];
  __shared__ float Bst[BK][BN];
  int t = threadIdx.x, tx = t & 15, ty = t >> 4;
  long asrc[4], bsrc[4];
  #pragma unroll
  for (int it = 0; it < 4; ++it) {
    int c = it * 256 + t;
    int row = c >> 3, kc = (c & 7) * 4;
    int gr = GATHER ? clamp_row(rows[m0 + row]) : (m0 + row);
    asrc[it] = (long)gr * lda + kc;
    bsrc[it] = (long)(n0 + row) * K + kc;
  }
  f32x4 accv[8][2];
  #pragma unroll
  for (int i = 0; i < 8; ++i) { accv[i][0] = 0.f; accv[i][1] = 0.f; }

  for (int k0 = 0; k0 < K; k0 += BK) {
    #pragma unroll
    for (int it = 0; it < 4; ++it) {
      int c = it * 256 + t;
      int row = c >> 3, kc = (c & 7) * 4;
      f32x4 av = *(const f32x4*)(A + asrc[it] + k0);
      f32x4 bv = *(const f32x4*)(B + bsrc[it] + k0);
      #pragma unroll
      for (int j = 0; j < 4; ++j) { Ast[kc + j][row] = av[j]; Bst[kc + j][row] = bv[j]; }
    }
    __syncthreads();
    #pragma unroll
    for (int kk = 0; kk < BK; ++kk) {
      f32x4 a0 = *(const f32x4*)&Ast[kk][ty * 4];
      f32x4 a1 = *(const f32x4*)&Ast[kk][64 + ty * 4];
      f32x4 b0 = *(const f32x4*)&Bst[kk][tx * 4];
      f32x4 b1 = *(const f32x4*)&Bst[kk][64 + tx * 4];
      float as[8] = {a0[0], a0[1], a0[2], a0[3], a1[0], a1[1], a1[2], a1[3]};
      #pragma unroll
      for (int i = 0; i < 8; ++i) {
        accv[i][0] += b0 * as[i];
        accv[i][1] += b1 * as[i];
      }
    }
    __syncthreads();
  }
  #pragma unroll
  for (int ih = 0; ih < 2; ++ih)
    #pragma unroll
    for (int i = 0; i < 4; ++i) {
      long m = m0 + ih * 64 + ty * 4 + i;
      #pragma unroll
      for (int jh = 0; jh < 2; ++jh) {
        long n = n0 + jh * 64 + tx * 4;
        f32x4 val = accv[ih * 4 + i][jh];
        if (POST == P_F32_RELU) {
          #pragma unroll
          for (int j = 0; j < 4; ++j) val[j] = fmaxf(val[j], 0.f);
        }
        if (POST == P_F32_RESID) val += *(const f32x4*)&resid[m * N + n];
        *(f32x4*)&C[m * N + n] = val;
      }
    }
}

// ------- MFMA split-2 attention (f32-equivalent accuracy) -------

__global__ __launch_bounds__(256) void attn2h_k(
    const u16* __restrict__ qkvP, long qplane,
    u16* __restrict__ oP, long oplane) {
  int qt = (int)gridDim.x - 1 - (int)blockIdx.x;   // heavy first
  int bh = blockIdx.y;
  int b = bh >> 4, h = bh & 15;
  const int ldq = 3 * kD;
  long hbq = (long)b * kT * ldq + h * kHD;
  long hbo = (long)b * kT * kD + h * kHD;
  int t = threadIdx.x, w = t >> 6, l = t & 63;
  int lr = l & 15, lg = l >> 4;

  __shared__ __align__(16) u16 Ks[2][64][72];
  __shared__ __align__(16) u16 Vt[2][64][72];
  __shared__ __align__(16) u16 Ps[2][4][16][72];

  f16x8 qf0[2], qf1[2];
  {
    long qrow = qt * 64 + w * 16 + lr;
    const u16* qp = qkvP + hbq + qrow * ldq;
    #pragma unroll
    for (int kc = 0; kc < 2; ++kc) {
      qf0[kc] = *(const f16x8*)(qp + kc * 32 + lg * 8);
      qf1[kc] = *(const f16x8*)(qp + qplane + kc * 32 + lg * 8);
    }
  }
  int qg = qt * 64 + w * 16 + lg * 4;

  float mrow[4], lsum[4];
  f32x4 accO[4];
  #pragma unroll
  for (int r = 0; r < 4; ++r) { mrow[r] = -1e30f; lsum[r] = 0.f; }
  #pragma unroll
  for (int j = 0; j < 4; ++j) accO[j] = 0.f;

  for (int it = 0; it <= qt; ++it) {
    #pragma unroll
    for (int p = 0; p < 2; ++p) {
      #pragma unroll
      for (int s = 0; s < 2; ++s) {
        int c = s * 256 + t;
        int row = c >> 3, col = (c & 7) * 8;
        long gi = (long)p * qplane + hbq + (long)(it * 64 + row) * ldq + col;
        *(u16x8*)&Ks[p][row][col] = *(const u16x8*)(qkvP + kD + gi);
        u16x8 vv = *(const u16x8*)(qkvP + 2 * kD + gi);
        #pragma unroll
        for (int j = 0; j < 8; ++j) Vt[p][col + j][row] = vv[j];
      }
    }
    __syncthreads();

    f32x4 s4[4];
    __builtin_amdgcn_s_setprio(1);
    #pragma unroll
    for (int j = 0; j < 4; ++j) {
      f32x4 z = {0.f, 0.f, 0.f, 0.f};
      #pragma unroll
      for (int kc = 0; kc < 2; ++kc) {
        f16x8 kh = *(const f16x8*)&Ks[0][j*16 + lr][kc*32 + lg*8];
        f16x8 km = *(const f16x8*)&Ks[1][j*16 + lr][kc*32 + lg*8];
        z = MFMAH(qf0[kc], kh, z);
        z = MFMAH(qf1[kc], kh, z);
        z = MFMAH(qf0[kc], km, z);
      }
      s4[j] = z;
    }
    __builtin_amdgcn_s_setprio(0);
    #pragma unroll
    for (int j = 0; j < 4; ++j)
      #pragma unroll
      for (int r = 0; r < 4; ++r) {
        float sv = s4[j][r] * (0.125f / 4096.0f);
        if (it * 64 + j * 16 + lr > qg + r) sv = -1e30f;
        s4[j][r] = sv;
      }
    float alpha[4];
    #pragma unroll
    for (int r = 0; r < 4; ++r) {
      float mx = fmaxf(fmaxf(s4[0][r], s4[1][r]), fmaxf(s4[2][r], s4[3][r]));
      mx = fmaxf(mx, __shfl_xor(mx, 1));
      mx = fmaxf(mx, __shfl_xor(mx, 2));
      mx = fmaxf(mx, __shfl_xor(mx, 4));
      mx = fmaxf(mx, __shfl_xor(mx, 8));
      float mi = fmaxf(mrow[r], mx);
      alpha[r] = __expf(mrow[r] - mi);
      mrow[r] = mi;
    }
    float rs[4] = {0.f, 0.f, 0.f, 0.f};
    #pragma unroll
    for (int j = 0; j < 4; ++j)
      #pragma unroll
      for (int r = 0; r < 4; ++r) {
        float p = __expf(s4[j][r] - mrow[r]);
        rs[r] += p;
        u16 hh, mm; split2s(p, hh, mm);
        Ps[0][w][lg*4 + r][j*16 + lr] = hh;
        Ps[1][w][lg*4 + r][j*16 + lr] = mm;
      }
    #pragma unroll
    for (int r = 0; r < 4; ++r) {
      float x2 = rs[r];
      x2 += __shfl_xor(x2, 1);
      x2 += __shfl_xor(x2, 2);
      x2 += __shfl_xor(x2, 4);
      x2 += __shfl_xor(x2, 8);
      lsum[r] = lsum[r] * alpha[r] + x2;
    }
    #pragma unroll
    for (int j = 0; j < 4; ++j)
      #pragma unroll
      for (int r = 0; r < 4; ++r) accO[j][r] *= alpha[r];
    __syncthreads();

    f16x8 ph[2], pm[2];
    #pragma unroll
    for (int kc = 0; kc < 2; ++kc) {
      ph[kc] = *(const f16x8*)&Ps[0][w][lr][kc*32 + lg*8];
      pm[kc] = *(const f16x8*)&Ps[1][w][lr][kc*32 + lg*8];
    }
    __builtin_amdgcn_s_setprio(1);
    #pragma unroll
    for (int j2 = 0; j2 < 4; ++j2) {
      #pragma unroll
      for (int kc = 0; kc < 2; ++kc) {
        f16x8 vh = *(const f16x8*)&Vt[0][j2*16 + lr][kc*32 + lg*8];
        f16x8 vm = *(const f16x8*)&Vt[1][j2*16 + lr][kc*32 + lg*8];
        accO[j2] = MFMAH(ph[kc], vh, accO[j2]);
        accO[j2] = MFMAH(pm[kc], vh, accO[j2]);
        accO[j2] = MFMAH(ph[kc], vm, accO[j2]);
      }
    }
    __builtin_amdgcn_s_setprio(0);
    __syncthreads();
  }
  #pragma unroll
  for (int j2 = 0; j2 < 4; ++j2)
    #pragma unroll
    for (int r = 0; r < 4; ++r) {
      float ov = accO[j2][r] * (1.0f / 4096.0f) / lsum[r];
      long row = qt * 64 + w * 16 + lg * 4 + r;
      long idx = hbo + row * kD + j2 * 16 + lr;
      u16 hh, mm; split2s(ov, hh, mm);
      oP[idx] = hh;
      oP[oplane + idx] = mm;
    }
}

// ---------------- f32 attention (fallback path) ----------------

__global__ __launch_bounds__(256) void attn_f32_k(
    const float* __restrict__ qkv, float* __restrict__ of32, int ldq) {
  int qt = blockIdx.x;
  int bh = blockIdx.y;
  int b = bh >> 4, h = bh & 15;
  long hbq = (long)b * kT * ldq + h * kHD;
  long hbo = (long)b * kT * kD + h * kHD;
  int t = threadIdx.x, qr = t >> 2, sub = t & 3;

  __shared__ float Qs[64][68], Ks[64][68], Vs[64][68], Ps[64][68];

  const float* q = qkv;
  const float* k = qkv + kD;
  const float* v = qkv + 2 * kD;

  #pragma unroll
  for (int it = 0; it < 4; ++it) {
    int c = it * 256 + t, row = c >> 4, c4 = (c & 15) * 4;
    f32x4 qv = *(const f32x4*)(q + hbq + (long)(qt * 64 + row) * ldq + c4);
    #pragma unroll
    for (int j = 0; j < 4; ++j) Qs[row][c4 + j] = qv[j];
  }
  __syncthreads();
  f32x4 qreg[16];
  #pragma unroll
  for (int d4 = 0; d4 < 16; ++d4) qreg[d4] = *(const f32x4*)&Qs[qr][d4 * 4];
  int qg = qt * 64 + qr;

  float mrow = -1e30f, lsum = 0.f;
  f32x4 accO[4];
  #pragma unroll
  for (int i = 0; i < 4; ++i) accO[i] = 0.f;

  for (int itl = 0; itl <= qt; ++itl) {
    #pragma unroll
    for (int it = 0; it < 4; ++it) {
      int c = it * 256 + t, row = c >> 4, c4 = (c & 15) * 4;
      long gi = hbq + (long)(itl * 64 + row) * ldq + c4;
      f32x4 kv = *(const f32x4*)(k + gi);
      f32x4 vv = *(const f32x4*)(v + gi);
      #pragma unroll
      for (int j = 0; j < 4; ++j) { Ks[row][c4 + j] = kv[j]; Vs[row][c4 + j] = vv[j]; }
    }
    __syncthreads();

    float s[16];
    #pragma unroll
    for (int kk = 0; kk < 16; ++kk) {
      int key = kk * 4 + sub;
      f32x4 a = {0.f, 0.f, 0.f, 0.f};
      #pragma unroll
      for (int d4 = 0; d4 < 16; ++d4) a += qreg[d4] * *(const f32x4*)&Ks[key][d4 * 4];
      float sv = (a[0] + a[1] + a[2] + a[3]) * 0.125f;
      if (itl * 64 + key > qg) sv = -1e30f;
      s[kk] = sv;
    }
    float mx = s[0];
    #pragma unroll
    for (int kk = 1; kk < 16; ++kk) mx = fmaxf(mx, s[kk]);
    mx = fmaxf(mx, __shfl_xor(mx, 1));
    mx = fmaxf(mx, __shfl_xor(mx, 2));
    float mi = fmaxf(mrow, mx);
    float alpha = __expf(mrow - mi);
    mrow = mi;
    float rs = 0.f;
    #pragma unroll
    for (int kk = 0; kk < 16; ++kk) {
      float p = __expf(s[kk] - mi);
      rs += p;
      Ps[qr][kk * 4 + sub] = p;
    }
    rs += __shfl_xor(rs, 1);
    rs += __shfl_xor(rs, 2);
    lsum = lsum * alpha + rs;
    #pragma unroll
    for (int i = 0; i < 4; ++i) accO[i] *= alpha;
    #pragma unroll
    for (int key2 = 0; key2 < 64; ++key2) {
      float p = Ps[qr][key2];
      #pragma unroll
      for (int i4 = 0; i4 < 4; ++i4)
        accO[i4] += p * *(const f32x4*)&Vs[key2][sub * 16 + i4 * 4];
    }
    __syncthreads();
  }
  float inv = 1.f / lsum;
  #pragma unroll
  for (int i4 = 0; i4 < 4; ++i4) {
    f32x4 ov = accO[i4] * inv;
    *(f32x4*)(of32 + hbo + (long)qg * kD + sub * 16 + i4 * 4) = ov;
  }
}

// ---------------- host ----------------

extern "C" void kernel_launch(void* const* d_in, const int* in_sizes, int n_in,
                              void* d_out, int out_size, void* d_ws, size_t ws_size,
                              hipStream_t stream) {
  const int*   idx  = (const int*)  d_in[0];
  const float* wte  = (const float*)d_in[1];
  const float* wpe  = (const float*)d_in[2];
  const float* wq   = (const float*)d_in[3];
  const float* wk   = (const float*)d_in[4];
  const float* wv   = (const float*)d_in[5];
  const float* wo   = (const float*)d_in[6];
  const float* gate = (const float*)d_in[7];
  const float* f1   = (const float*)d_in[8];
  const float* f2   = (const float*)d_in[9];
  const float* lmh  = (const float*)d_in[10];
  float* out = (float*)d_out;

  char* ws = (char*)d_ws;
  size_t off = 0;
  auto alloc = [&](size_t b) -> char* {
    char* p = ws + off;
    off += (b + 255) & ~(size_t)255;
    return p;
  };

  constexpr long PLN_XN = (long)kBT * kD;
  constexpr long PLN_Q3 = (long)kBT * 3 * kD;
  constexpr long PLN_QKV = (long)3 * kD * kD;
  constexpr long PLN_WO = (long)kD * kD;
  constexpr long PLN_FF = (long)kE * kFF * kD;
  constexpr long PLN_H = (long)kSLOTS * kFF;
  constexpr long PLN_OUTS = (long)kSLOTS * kD;
  constexpr long PLN_PR = (long)kBT * kE;

  // shared small buffers
  float* x     = (float*)alloc((size_t)kBT * kD * 4);
  float* outs  = (float*)alloc((size_t)4 * PLN_OUTS * 4);   // 4 K-partials
  float* probs3= (float*)alloc((size_t)kL * PLN_PR * 4);    // per-layer probs
  int*   top2e = (int*)  alloc((size_t)kBT * 2 * 4);
  float* top2w = (float*)alloc((size_t)kBT * 2 * 4);
  int*   meta  = (int*)  alloc(64 * 4);
  int* counts = meta; int* cursors = meta + 8; int* offs = meta + 16;
  int*   rows  = (int*)  alloc((size_t)kSLOTS * 4);
  int*   slotOf= (int*)  alloc((size_t)kBT * 2 * 4);
  float* aux   = (float*)alloc(256);
  size_t off_shared = off;

  // fast-path buffers
  u16*   xnP   = (u16*)  alloc((size_t)2 * PLN_XN * 2);
  float* qkvf  = (float*)alloc((size_t)PLN_Q3 * 4);
  u16*   qkvP  = (u16*)  alloc((size_t)2 * PLN_Q3 * 2);
  u16*   ofP   = (u16*)  alloc((size_t)2 * PLN_XN * 2);
  u16*   hP    = (u16*)  alloc((size_t)2 * PLN_H * 2);
  u16*   wqkvP = (u16*)  alloc((size_t)kL * 2 * PLN_QKV * 2);
  u16*   woP   = (u16*)  alloc((size_t)kL * 2 * PLN_WO * 2);
  u16*   lmb   = (u16*)  alloc((size_t)kV * kD * 2);      // f16 lm_head weights
  bool fast = (off <= ws_size);
  float* qkvp1 = (float*)hP;          // alias: hP idle during QKV+attn phase

  dim3 gAttn(kT / 64, 2 * kH);
  // base grids (all % 8 == 0)
  int bQKV = (kBT / 128) * (3 * kD / 128);       // 384,  MPART mPerX=2, kParts=2
  int bWO  = (kBT / 128) * (kD / 128);           // 128,  MPART mPerX=2, kParts=4
  int nF1W = (kSLOTS / 128) * (kFF / 256);       // 640,  W kernel mPerX=5
  int bF2  = (kSLOTS / 128) * (kD / 128);        // 320,  MPART mPerX=5, kParts=4
  int nF1s = (kSLOTS / 128) * (kFF / 128);       // 1280, MPART mPerX=5
  int nLM  = (kBT / 128) * (kV / 128);           // 4000, mBlocks=16

  if (fast) {
    for (int li = 0; li < kL; ++li) {
      u16* dst = wqkvP + (size_t)li * 2 * PLN_QKV;
      split2h_k<<<1024, 256, 0, stream>>>(wq + (size_t)li * kD * kD, dst, PLN_QKV, (long)kD * kD / 4);
      split2h_k<<<1024, 256, 0, stream>>>(wk + (size_t)li * kD * kD, dst + (long)kD * kD, PLN_QKV, (long)kD * kD / 4);
      split2h_k<<<1024, 256, 0, stream>>>(wv + (size_t)li * kD * kD, dst + (long)2 * kD * kD, PLN_QKV, (long)kD * kD / 4);
      split2h_k<<<1024, 256, 0, stream>>>(wo + (size_t)li * kD * kD, woP + (size_t)li * 2 * PLN_WO, PLN_WO, (long)kD * kD / 4);
    }
    cast_h_k<<<4096, 256, 0, stream>>>(lmh, lmb, (long)kV * kD / 4);
    embed_rms_k<<<kBT, 256, 0, stream>>>(idx, wte, wpe, x);
    rmsnorm2h_k<<<kBT, 256, 0, stream>>>(x, xnP, PLN_XN);   // layer-0 QKV input

    for (int li = 0; li < kL; ++li) {
      // QKV: split-K x2 -> qkvf + qkvp1; combine into split-2 planes
      gemm2h_bt_k<P_F32, false, false, true, false><<<2 * bQKV, 256, 0, stream>>>(
          xnP, PLN_XN, wqkvP + (size_t)li * 2 * PLN_QKV, PLN_QKV,
          qkvf, 0, nullptr, nullptr, nullptr, 3 * kD, kD, kD, 0, 2,
          2, bQKV, (long)(qkvp1 - qkvf));
      qkvcomb_k<<<2048, 256, 0, stream>>>(qkvf, qkvp1, qkvP, PLN_Q3, PLN_Q3 / 4);
      attn2h_k<<<gAttn, 256, 0, stream>>>(qkvP, PLN_Q3, ofP, PLN_XN);
      // WO: split-K x4 into outs partials; fused residual+rms+split
      gemm2h_bt_k<P_F32, false, false, true, false><<<4 * bWO, 256, 0, stream>>>(
          ofP, PLN_XN, woP + (size_t)li * 2 * PLN_WO, PLN_WO,
          outs, 0, nullptr, nullptr, nullptr, kD, kD, kD, 0, 2,
          4, bWO, PLN_OUTS);
      resid4_rms2h_k<<<kBT, 256, 0, stream>>>(x, outs, PLN_OUTS, xnP, PLN_XN);
      hipMemsetAsync(meta, 0, 64, stream);
      gate_topk_k<<<kBT, 256, 0, stream>>>(x, gate + (size_t)li * kE * kD,
                                           probs3 + (size_t)li * PLN_PR,
                                           top2e, top2w, counts);
      fill_slots2_k<<<kBT / 256, 256, 0, stream>>>(top2e, counts, offs, cursors,
                                                   rows, slotOf);
      size_t fd = (size_t)li * PLN_FF;
      if (li < 2) {
        gemm2hW_bt_k<P_SPLIT2_RELU, true, true, true><<<nF1W, 512, 0, stream>>>(
            xnP, PLN_XN, f1 + fd, 0, hP, PLN_H, rows, offs,
            kFF, kD, kD, (long)kFF * kD, kSLOTS / 128 / 8,
            1, nF1W, 0);
        gemm2h_bt_k<P_F32, false, true, true, true><<<4 * bF2, 256, 0, stream>>>(
            hP, PLN_H, f2 + fd, 0, outs, 0, nullptr, nullptr, offs,
            kD, kFF, kFF, (long)kD * kFF, kSLOTS / 128 / 8,
            4, bF2, PLN_OUTS);
        moe4_rms2h_k<<<kBT, 256, 0, stream>>>(x, outs, PLN_OUTS, slotOf, top2w,
                                              xnP, PLN_XN);
      } else {
        gemm_bt_k<P_F16_RELU, true, true, true, true, true><<<nF1s, 256, 0, stream>>>(
            xnP, f1 + fd, hP, rows, offs, kFF, kD, kD, (long)kFF * kD,
            1.0f / 64.0f, kSLOTS / 128 / 8, 1, nF1s, 0);
        gemm_bt_k<P_F32, true, false, true, true, true><<<4 * bF2, 256, 0, stream>>>(
            hP, f2 + fd, outs, nullptr, offs, kD, kFF, kFF, (long)kD * kFF,
            1.0f, kSLOTS / 128 / 8, 4, bF2, PLN_OUTS);
        moe4_cast_h_k<<<kBT, 256, 0, stream>>>(x, outs, PLN_OUTS, slotOf, top2w, xnP);
      }
    }
    // lm_head: pre-converted f16 weights, swizzled global_load_lds staging
    gemm_bt_k<P_F32, false, false, true, false, false><<<nLM, 256, 0, stream>>>(
        xnP, lmb, out, nullptr, nullptr, kV, kD, kD, 0, 1.0f, kBT / 128,
        1, nLM, 0);
    aux_reduce3_k<<<1, 256, 0, stream>>>(probs3, PLN_PR, out + (size_t)kBT * kV);
    return;
  }

  // ---------- fallback: f32 path ----------
  off = off_shared;
  float* xnf   = (float*)alloc((size_t)kBT * kD * 4);
  u16*   xnb   = (u16*)  alloc((size_t)kBT * kD * 2);
  float* qkvf32= (float*)alloc((size_t)kBT * 3 * kD * 4);
  float* off32 = (float*)alloc((size_t)kBT * kD * 4);
  float* hbuf  = (float*)alloc((size_t)kSLOTS * kFF * 4);
  u16* hbuf16 = (u16*)hbuf;

  hipMemsetAsync(aux, 0, 4, stream);
  embed_rms_k<<<kBT, 256, 0, stream>>>(idx, wte, wpe, x);
  dim3 gF1s(kSLOTS / 128, kFF / 128);
  dim3 gF2s(kSLOTS / 128, kD / 128);
  for (int li = 0; li < kL; ++li) {
    size_t dd = (size_t)li * kD * kD;
    rmsnorm2_k<<<kBT, 256, 0, stream>>>(x, xnf, xnb);
    dim3 gP(kBT / 128, kD / 128);
    sgemm_bt_k<P_F32, false, false><<<gP, 256, 0, stream>>>(
        xnf, wq + dd, qkvf32, nullptr, nullptr, nullptr, 3 * kD, kD, kD, 0);
    sgemm_bt_k<P_F32, false, false><<<gP, 256, 0, stream>>>(
        xnf, wk + dd, qkvf32 + kD, nullptr, nullptr, nullptr, 3 * kD, kD, kD, 0);
    sgemm_bt_k<P_F32, false, false><<<gP, 256, 0, stream>>>(
        xnf, wv + dd, qkvf32 + 2 * kD, nullptr, nullptr, nullptr, 3 * kD, kD, kD, 0);
    attn_f32_k<<<gAttn, 256, 0, stream>>>(qkvf32, off32, 3 * kD);
    sgemm_bt_k<P_F32_RESID, false, false><<<gP, 256, 0, stream>>>(
        off32, wo + dd, x, x, nullptr, nullptr, kD, kD, kD, 0);
    rmsnorm2_k<<<kBT, 256, 0, stream>>>(x, xnf, xnb);
    hipMemsetAsync(meta, 0, 64, stream);
    gate_topk_k<<<kBT, 256, 0, stream>>>(x, gate + (size_t)li * kE * kD,
                                         probs3, top2e, top2w, counts);
    calc_offsets_k<<<1, 64, 0, stream>>>(counts, offs);
    fill_slots2_k<<<kBT / 256, 256, 0, stream>>>(top2e, counts, offs, cursors,
                                                 rows, slotOf);
    size_t fd = (size_t)li * kE * kFF * kD;
    if (li < 2) {
      sgemm_bt_k<P_F32_RELU, true, true><<<gF1s, 256, 0, stream>>>(
          xnf, f1 + fd, hbuf, nullptr, rows, offs, kFF, kD, kD, (long)kFF * kD);
      sgemm_bt_k<P_F32, false, true><<<gF2s, 256, 0, stream>>>(
          hbuf, f2 + fd, outs, nullptr, nullptr, offs, kD, kFF, kFF, (long)kD * kFF);
    } else {
      gemm_bt_k<P_BF16_RELU, true, true, false, true, false><<<nF1s, 256, 0, stream>>>(
          xnb, f1 + fd, hbuf16, rows, offs, kFF, kD, kD, (long)kFF * kD,
          1.0f, kSLOTS / 128, 1, nF1s, 0);
      gemm_bt_k<P_F32, true, false, false, true, false><<<bF2, 256, 0, stream>>>(
          hbuf16, f2 + fd, outs, nullptr, offs, kD, kFF, kFF, (long)kD * kFF,
          1.0f, kSLOTS / 128, 1, bF2, 0);
    }
    hipMemsetAsync(outs + PLN_OUTS, 0, 3 * PLN_OUTS * 4, stream);
    moe_combine4_k<<<kBT, 256, 0, stream>>>(x, outs, PLN_OUTS, slotOf, top2w);
    aux_reduce_k<<<1, 256, 0, stream>>>(probs3, aux);
  }
  cast_bf16_k<<<2048, 256, 0, stream>>>(x, xnb, (long)kBT * kD / 4);
  gemm_bt_k<P_F32, false, false, false, true, false><<<nLM, 256, 0, stream>>>(
      xnb, lmh, out, nullptr, nullptr, kV, kD, kD, 0, 1.0f, kBT / 128,
      1, nLM, 0);
  write_aux_k<<<1, 64, 0, stream>>>(aux, out + (size_t)kBT * kV);
}

// Round 19
// 1903.445 us; speedup vs baseline: 1.2408x; 1.0499x over previous
//
#include <hip/hip_runtime.h>

typedef unsigned short u16;
typedef __attribute__((ext_vector_type(4))) float f32x4;
typedef __attribute__((ext_vector_type(8))) __bf16 bf16x8;
typedef __attribute__((ext_vector_type(8))) _Float16 f16x8;
typedef __attribute__((ext_vector_type(4))) unsigned short u16x4;
typedef __attribute__((ext_vector_type(8))) unsigned short u16x8;

constexpr int kT = 1024, kD = 1024, kH = 16, kHD = 64, kL = 3, kE = 8;
constexpr int kFF = 4096, kV = 32000, kBT = 2048, kSLOTS = 5120;

__device__ __forceinline__ u16 f2bf(float f) {
  union { float f; unsigned u; } v; v.f = f;
  unsigned r = v.u + 0x7FFFu + ((v.u >> 16) & 1u);   // RNE
  return (u16)(r >> 16);
}
__device__ __forceinline__ u16 f2h(float x) {
  _Float16 h = (_Float16)x;
  union { _Float16 h; u16 u; } v; v.h = h; return v.u;
}
// uniform-scale fp16 split-2: 64*x = hi + mid + O(2^-11 * |64x - hi|)
__device__ __forceinline__ void split2s(float x, u16& h, u16& m) {
  float xs = x * 64.0f;
  _Float16 hh = (_Float16)xs;
  union { _Float16 h; u16 u; } v; v.h = hh; h = v.u;
  float r = xs - (float)hh;
  union { _Float16 h; u16 u; } w; w.h = (_Float16)r; m = w.u;
}

__device__ __forceinline__ void ld_lds16(const void* g, void* l) {
  __builtin_amdgcn_global_load_lds((const __attribute__((address_space(1))) void*)g,
                                   (__attribute__((address_space(3))) void*)l, 16, 0, 0);
}

#define MFMA16(a, b, c) __builtin_amdgcn_mfma_f32_16x16x32_bf16(a, b, c, 0, 0, 0)
#define MFMAH(a, b, c)  __builtin_amdgcn_mfma_f32_16x16x32_f16(a, b, c, 0, 0, 0)

__device__ __forceinline__ float blockReduceSum256(float v) {
  #pragma unroll
  for (int m = 32; m >= 1; m >>= 1) v += __shfl_xor(v, m);
  __shared__ float sh_[4];
  int w = threadIdx.x >> 6;
  if ((threadIdx.x & 63) == 0) sh_[w] = v;
  __syncthreads();
  v = (sh_[0] + sh_[1]) + (sh_[2] + sh_[3]);
  __syncthreads();
  return v;
}

// ---------------- elementwise / small kernels ----------------

__global__ __launch_bounds__(256) void cast_bf16_k(const float* __restrict__ in,
                                                   u16* __restrict__ out, long n4) {
  long i = (long)blockIdx.x * 256 + threadIdx.x;
  long stride = (long)gridDim.x * 256;
  for (; i < n4; i += stride) {
    f32x4 v = ((const f32x4*)in)[i];
    u16x4 o; o[0] = f2bf(v[0]); o[1] = f2bf(v[1]); o[2] = f2bf(v[2]); o[3] = f2bf(v[3]);
    ((u16x4*)out)[i] = o;
  }
}

__global__ __launch_bounds__(256) void cast_h_k(const float* __restrict__ in,
                                                u16* __restrict__ out, long n4) {
  long i = (long)blockIdx.x * 256 + threadIdx.x;
  long stride = (long)gridDim.x * 256;
  for (; i < n4; i += stride) {
    f32x4 v = ((const f32x4*)in)[i];
    u16x4 o; o[0] = f2h(v[0]); o[1] = f2h(v[1]); o[2] = f2h(v[2]); o[3] = f2h(v[3]);
    ((u16x4*)out)[i] = o;
  }
}

// f32 -> 2 fp16 planes (uniform x64 scale)
__global__ __launch_bounds__(256) void split2h_k(const float* __restrict__ in,
    u16* __restrict__ out, long planeStride, long n4) {
  long i = (long)blockIdx.x * 256 + threadIdx.x;
  long stride = (long)gridDim.x * 256;
  u16* o1 = out + planeStride;
  for (; i < n4; i += stride) {
    f32x4 v = ((const f32x4*)in)[i];
    u16x4 a, b;
    #pragma unroll
    for (int j = 0; j < 4; ++j) {
      u16 h, m; split2s(v[j], h, m);
      a[j] = h; b[j] = m;
    }
    ((u16x4*)out)[i] = a; ((u16x4*)o1)[i] = b;
  }
}

// qkv = p0 + p1 -> 2 fp16 planes (x64 scale)
__global__ __launch_bounds__(256) void qkvcomb_k(const float* __restrict__ a,
    const float* __restrict__ b, u16* __restrict__ oP, long plane, long n4) {
  long i = (long)blockIdx.x * 256 + threadIdx.x;
  long stride = (long)gridDim.x * 256;
  for (; i < n4; i += stride) {
    f32x4 v = ((const f32x4*)a)[i] + ((const f32x4*)b)[i];
    u16x4 hh, mm;
    #pragma unroll
    for (int j = 0; j < 4; ++j) {
      u16 h, m; split2s(v[j], h, m);
      hh[j] = h; mm[j] = m;
    }
    ((u16x4*)oP)[i] = hh;
    ((u16x4*)(oP + plane))[i] = mm;
  }
}

__global__ __launch_bounds__(256) void embed_rms_k(const int* __restrict__ idx,
    const float* __restrict__ wte, const float* __restrict__ wpe, float* __restrict__ x) {
  int tok = blockIdx.x, t = threadIdx.x;
  int id = idx[tok];
  int tt = tok & (kT - 1);
  f32x4 a = ((const f32x4*)(wte + (long)id * kD))[t];
  f32x4 p = ((const f32x4*)(wpe + (long)tt * kD))[t];
  f32x4 vv = a + p;
  float ss = vv[0]*vv[0] + vv[1]*vv[1] + vv[2]*vv[2] + vv[3]*vv[3];
  ss = blockReduceSum256(ss);
  float sc = rsqrtf(ss * (1.0f / kD) + 1e-5f);
  vv *= sc;
  ((f32x4*)(x + (long)tok * kD))[t] = vv;
}

// rmsnorm -> f32 + bf16 (fallback path)
__global__ __launch_bounds__(256) void rmsnorm2_k(const float* __restrict__ x,
    float* __restrict__ xnf, u16* __restrict__ xnb) {
  int tok = blockIdx.x, t = threadIdx.x;
  f32x4 vv = ((const f32x4*)(x + (long)tok * kD))[t];
  float ss = blockReduceSum256(vv[0]*vv[0] + vv[1]*vv[1] + vv[2]*vv[2] + vv[3]*vv[3]);
  float sc = rsqrtf(ss * (1.0f / kD) + 1e-5f);
  vv *= sc;
  ((f32x4*)(xnf + (long)tok * kD))[t] = vv;
  u16x4 o;
  o[0] = f2bf(vv[0]); o[1] = f2bf(vv[1]); o[2] = f2bf(vv[2]); o[3] = f2bf(vv[3]);
  ((u16x4*)(xnb + (long)tok * kD))[t] = o;
}

// rmsnorm -> 2 fp16 planes (fast path, x64 scale)
__global__ __launch_bounds__(256) void rmsnorm2h_k(const float* __restrict__ x,
    u16* __restrict__ xnP, long plane) {
  int tok = blockIdx.x, t = threadIdx.x;
  f32x4 vv = ((const f32x4*)(x + (long)tok * kD))[t];
  float ss = blockReduceSum256(vv[0]*vv[0] + vv[1]*vv[1] + vv[2]*vv[2] + vv[3]*vv[3]);
  float sc = rsqrtf(ss * (1.0f / kD) + 1e-5f);
  vv *= sc;
  u16x4 a, b;
  #pragma unroll
  for (int j = 0; j < 4; ++j) {
    u16 h, m; split2s(vv[j], h, m);
    a[j] = h; b[j] = m;
  }
  long o = (long)tok * kD / 4 + t;
  ((u16x4*)xnP)[o] = a;
  ((u16x4*)(xnP + plane))[o] = b;
}

// x += sum of 4 K-partials; write x; rmsnorm -> 2 fp16 planes
__global__ __launch_bounds__(256) void resid4_rms2h_k(float* __restrict__ x,
    const float* __restrict__ parts, long plane, u16* __restrict__ xnP, long xplane) {
  int tok = blockIdx.x, t = threadIdx.x;
  long o = (long)tok * (kD / 4) + t;
  f32x4 xv = ((f32x4*)x)[o];
  #pragma unroll
  for (int p = 0; p < 4; ++p) xv += ((const f32x4*)(parts + p * plane))[o];
  ((f32x4*)x)[o] = xv;
  float ss = blockReduceSum256(xv[0]*xv[0] + xv[1]*xv[1] + xv[2]*xv[2] + xv[3]*xv[3]);
  float sc = rsqrtf(ss * (1.0f / kD) + 1e-5f);
  f32x4 vv = xv * sc;
  u16x4 a, b;
  #pragma unroll
  for (int j = 0; j < 4; ++j) {
    u16 h, m; split2s(vv[j], h, m);
    a[j] = h; b[j] = m;
  }
  ((u16x4*)xnP)[o] = a;
  ((u16x4*)(xnP + xplane))[o] = b;
}

// x += moe combine (4 K-partials, 2 experts); write x; rmsnorm -> 2 fp16 planes
__global__ __launch_bounds__(256) void moe4_rms2h_k(float* __restrict__ x,
    const float* __restrict__ outsP, long plane, const int* __restrict__ slotOf,
    const float* __restrict__ top2w, u16* __restrict__ xnP, long xplane) {
  int tok = blockIdx.x, t = threadIdx.x;
  int s0 = slotOf[tok*2], s1 = slotOf[tok*2+1];
  float w0 = top2w[tok*2], w1 = top2w[tok*2+1];
  f32x4 a = {0.f,0.f,0.f,0.f}, b = a;
  #pragma unroll
  for (int p = 0; p < 4; ++p) {
    a += ((const f32x4*)(outsP + p * plane + (long)s0 * kD))[t];
    b += ((const f32x4*)(outsP + p * plane + (long)s1 * kD))[t];
  }
  long o = (long)tok * (kD / 4) + t;
  f32x4 xv = ((f32x4*)x)[o];
  xv += a * w0 + b * w1;
  ((f32x4*)x)[o] = xv;
  float ss = blockReduceSum256(xv[0]*xv[0] + xv[1]*xv[1] + xv[2]*xv[2] + xv[3]*xv[3]);
  float sc = rsqrtf(ss * (1.0f / kD) + 1e-5f);
  f32x4 vv = xv * sc;
  u16x4 ha, hb;
  #pragma unroll
  for (int j = 0; j < 4; ++j) {
    u16 h, m; split2s(vv[j], h, m);
    ha[j] = h; hb[j] = m;
  }
  ((u16x4*)xnP)[o] = ha;
  ((u16x4*)(xnP + xplane))[o] = hb;
}

// last layer: x += moe combine; write f16 (unscaled) plane for lm_head
__global__ __launch_bounds__(256) void moe4_cast_h_k(float* __restrict__ x,
    const float* __restrict__ outsP, long plane, const int* __restrict__ slotOf,
    const float* __restrict__ top2w, u16* __restrict__ xn) {
  int tok = blockIdx.x, t = threadIdx.x;
  int s0 = slotOf[tok*2], s1 = slotOf[tok*2+1];
  float w0 = top2w[tok*2], w1 = top2w[tok*2+1];
  f32x4 a = {0.f,0.f,0.f,0.f}, b = a;
  #pragma unroll
  for (int p = 0; p < 4; ++p) {
    a += ((const f32x4*)(outsP + p * plane + (long)s0 * kD))[t];
    b += ((const f32x4*)(outsP + p * plane + (long)s1 * kD))[t];
  }
  long o = (long)tok * (kD / 4) + t;
  f32x4 xv = ((f32x4*)x)[o];
  xv += a * w0 + b * w1;
  u16x4 hv;
  #pragma unroll
  for (int j = 0; j < 4; ++j) hv[j] = f2h(xv[j]);
  ((u16x4*)xn)[o] = hv;
}

// gating in f32 (bf16 would flip top-2 selections on near-ties)
__global__ __launch_bounds__(256) void gate_topk_k(const float* __restrict__ x,
    const float* __restrict__ gate_l, float* __restrict__ probs, int* __restrict__ top2e,
    float* __restrict__ top2w, int* __restrict__ counts) {
  int tok = blockIdx.x, t = threadIdx.x;
  f32x4 xv = ((const f32x4*)(x + (long)tok * kD))[t];
  float ss = blockReduceSum256(xv[0]*xv[0] + xv[1]*xv[1] + xv[2]*xv[2] + xv[3]*xv[3]);
  float sc = rsqrtf(ss * (1.0f / kD) + 1e-5f);
  float a[kE];
  #pragma unroll
  for (int e = 0; e < kE; ++e) {
    f32x4 gv = ((const f32x4*)(gate_l + (long)e * kD))[t];
    a[e] = xv[0]*gv[0] + xv[1]*gv[1] + xv[2]*gv[2] + xv[3]*gv[3];
  }
  __shared__ float sh8[kE][4];
  int w = t >> 6, l = t & 63;
  #pragma unroll
  for (int e = 0; e < kE; ++e) {
    float v = a[e];
    #pragma unroll
    for (int m = 32; m >= 1; m >>= 1) v += __shfl_xor(v, m);
    if (l == 0) sh8[e][w] = v;
  }
  __syncthreads();
  if (t == 0) {
    float lg[kE], mx = -1e30f;
    #pragma unroll
    for (int e = 0; e < kE; ++e) {
      lg[e] = (sh8[e][0] + sh8[e][1] + sh8[e][2] + sh8[e][3]) * sc;
      mx = fmaxf(mx, lg[e]);
    }
    float pe[kE], s = 0.f;
    #pragma unroll
    for (int e = 0; e < kE; ++e) { pe[e] = __expf(lg[e] - mx); s += pe[e]; }
    float inv = 1.f / s;
    int i1 = 0;
    #pragma unroll
    for (int e = 1; e < kE; ++e) if (lg[e] > lg[i1]) i1 = e;
    int i2 = (i1 == 0) ? 1 : 0;
    #pragma unroll
    for (int e = 0; e < kE; ++e) if (e != i1 && lg[e] > lg[i2]) i2 = e;
    #pragma unroll
    for (int e = 0; e < kE; ++e) probs[(long)tok * kE + e] = pe[e] * inv;
    float p1 = pe[i1] * inv, p2 = pe[i2] * inv;
    float wn = p1 + p2;
    top2e[tok*2] = i1; top2e[tok*2+1] = i2;
    top2w[tok*2] = p1 / wn; top2w[tok*2+1] = p2 / wn;
    atomicAdd(&counts[i1], 1); atomicAdd(&counts[i2], 1);
  }
}

// 128-aligned expert offsets (fallback path)
__global__ void calc_offsets_k(const int* __restrict__ counts, int* __restrict__ offsets) {
  if (threadIdx.x == 0) {
    int o = 0;
    #pragma unroll
    for (int e = 0; e < kE; ++e) { offsets[e] = o; o += (counts[e] + 127) & ~127; }
    offsets[kE] = o;
  }
}

// offsets computed in-kernel from counts (block 0 publishes); slots filled
__global__ __launch_bounds__(256) void fill_slots2_k(const int* __restrict__ top2e,
    const int* __restrict__ counts, int* __restrict__ offsets, int* __restrict__ cursors,
    int* __restrict__ rows, int* __restrict__ slotOf) {
  __shared__ int soff[kE + 1];
  if (threadIdx.x == 0) {
    int o = 0;
    #pragma unroll
    for (int e = 0; e < kE; ++e) { soff[e] = o; o += (counts[e] + 127) & ~127; }
    soff[kE] = o;
    if (blockIdx.x == 0) {
      #pragma unroll
      for (int e = 0; e <= kE; ++e) offsets[e] = soff[e];
    }
  }
  __syncthreads();
  int tok = blockIdx.x * 256 + threadIdx.x;
  if (tok >= kBT) return;
  #pragma unroll
  for (int j = 0; j < 2; ++j) {
    int e = top2e[tok*2 + j];
    int pos = atomicAdd(&cursors[e], 1);
    int slot = soff[e] + pos;
    rows[slot] = tok;
    slotOf[tok*2 + j] = slot;
  }
}

// fallback combine (4 partials; unused planes zeroed)
__global__ __launch_bounds__(256) void moe_combine4_k(float* __restrict__ x,
    const float* __restrict__ outsP, long plane, const int* __restrict__ slotOf,
    const float* __restrict__ top2w) {
  int tok = blockIdx.x, t = threadIdx.x;
  int s0 = slotOf[tok*2], s1 = slotOf[tok*2+1];
  float w0 = top2w[tok*2], w1 = top2w[tok*2+1];
  f32x4 a = {0.f,0.f,0.f,0.f}, b = a;
  #pragma unroll
  for (int p = 0; p < 4; ++p) {
    a += ((const f32x4*)(outsP + p * plane + (long)s0 * kD))[t];
    b += ((const f32x4*)(outsP + p * plane + (long)s1 * kD))[t];
  }
  f32x4 xv = ((f32x4*)(x + (long)tok * kD))[t];
  xv += a * w0 + b * w1;
  ((f32x4*)(x + (long)tok * kD))[t] = xv;
}

// all-layer aux: out[0] = 0.01/L * sum_l E * sum_e (mean_t probs3[l])^2
__global__ __launch_bounds__(256) void aux_reduce3_k(const float* __restrict__ probs3,
    long plane, float* __restrict__ outv) {
  int t = threadIdx.x;
  float part[kL][kE] = {};
  for (int i = t; i < kBT; i += 256) {
    #pragma unroll
    for (int l = 0; l < kL; ++l)
      #pragma unroll
      for (int e = 0; e < kE; ++e)
        part[l][e] += probs3[l * plane + (long)i * kE + e];
  }
  __shared__ float sh[kL][kE][4];
  int w = t >> 6, ln = t & 63;
  #pragma unroll
  for (int l = 0; l < kL; ++l)
    #pragma unroll
    for (int e = 0; e < kE; ++e) {
      float v = part[l][e];
      #pragma unroll
      for (int m = 32; m >= 1; m >>= 1) v += __shfl_xor(v, m);
      if (ln == 0) sh[l][e][w] = v;
    }
  __syncthreads();
  if (t == 0) {
    float acc = 0.f;
    #pragma unroll
    for (int l = 0; l < kL; ++l)
      #pragma unroll
      for (int e = 0; e < kE; ++e) {
        float frac = (sh[l][e][0] + sh[l][e][1] + sh[l][e][2] + sh[l][e][3]) * (1.0f / kBT);
        acc += frac * frac;
      }
    outv[0] = 0.01f * (float)kE * acc / (float)kL;
  }
}

__global__ __launch_bounds__(256) void aux_reduce_k(const float* __restrict__ probs,
                                                    float* __restrict__ aux) {
  int t = threadIdx.x;
  float part[kE] = {};
  for (int i = t; i < kBT; i += 256) {
    #pragma unroll
    for (int e = 0; e < kE; ++e) part[e] += probs[(long)i * kE + e];
  }
  __shared__ float sh8[kE][4];
  int w = t >> 6, l = t & 63;
  #pragma unroll
  for (int e = 0; e < kE; ++e) {
    float v = part[e];
    #pragma unroll
    for (int m = 32; m >= 1; m >>= 1) v += __shfl_xor(v, m);
    if (l == 0) sh8[e][w] = v;
  }
  __syncthreads();
  if (t == 0) {
    float acc = 0.f;
    #pragma unroll
    for (int e = 0; e < kE; ++e) {
      float frac = (sh8[e][0] + sh8[e][1] + sh8[e][2] + sh8[e][3]) * (1.0f / kBT);
      acc += frac * frac;
    }
    aux[0] += (float)kE * acc;
  }
}

__global__ void write_aux_k(const float* __restrict__ aux, float* __restrict__ out) {
  if (threadIdx.x == 0) out[0] = 0.01f * aux[0] / (float)kL;
}

enum { P_BF16 = 0, P_BF16_RELU = 1, P_F32 = 2, P_F32_RESID = 3, P_F32_RELU = 4,
       P_SPLIT2_RELU = 5, P_F16_RELU = 6 };

__device__ __forceinline__ int clamp_row(int rv) {
  return ((unsigned)rv < (unsigned)kBT) ? rv : 0;
}

template <bool MPART>
__device__ __forceinline__ void block_mn(int lin, int base, int mArg, int& mb, int& nb) {
  int xcd = lin & 7, c = lin >> 3;
  if (MPART) {
    mb = xcd * mArg + (c % mArg);
    nb = c / mArg;
  } else {
    int swz = xcd * (base >> 3) + c;
    mb = swz % mArg;
    nb = swz / mArg;
  }
}

// ------- fused fp16 split-2 MFMA GEMM (128x128, 256 thr), single accumulator -------
// BF32: B is f32; registers hold the NEXT k-step's B tile (prefetched one
// iteration ahead, issued alongside A's global_load_lds so HBM latency
// overlaps the convert phase + barrier drain).

template <int POST, bool GATHER, bool EXPERT, bool MPART, bool BF32>
__global__ __launch_bounds__(256) void gemm2h_bt_k(
    const u16* __restrict__ A0, long planeA,
    const void* __restrict__ Bv, long planeB,
    void* __restrict__ C, long planeC,
    const float* __restrict__ resid,
    const int* __restrict__ rows, const int* __restrict__ offsets,
    int N, int K, int lda, long eBstride, int mArg,
    int kParts, int base, long cPart) {
  constexpr int BM = 128, BK = 32;
  int part = blockIdx.x / base;
  int lin = blockIdx.x % base;
  int mb, nb;
  block_mn<MPART>(lin, base, mArg, mb, nb);
  int m0 = mb * BM, n0 = nb * BM;
  const u16* B0 = (const u16*)Bv;
  const float* Bf = (const float*)Bv;
  if (EXPERT) {
    int total = offsets[kE];
    if (m0 >= total) return;
    int e = 0;
    while (offsets[e + 1] <= m0) ++e;
    if (BF32) Bf += (long)e * eBstride; else B0 += (long)e * eBstride;
  }
  __shared__ __align__(16) u16 Ac[BM][64];
  __shared__ __align__(16) u16 Bc[BM][64];
  int t = threadIdx.x;
  int l = t & 63, lr = l & 15, lg = l >> 4;
  int wid = t >> 6;
  int wm = (wid >> 1) * 64, wn = (wid & 1) * 64;

  long asrc[4], bsrc[4];
  int ldst[4];
  #pragma unroll
  for (int it = 0; it < 4; ++it) {
    int d = it * 256 + t;
    int row = d >> 3, pc = d & 7;
    int lc = pc ^ (row & 7);
    int p = lc >> 2, c = lc & 3;
    int grow = GATHER ? clamp_row(rows[m0 + row]) : (m0 + row);
    asrc[it] = (long)p * planeA + (long)grow * lda + c * 8;
    if (!BF32) bsrc[it] = (long)p * planeB + (long)(n0 + row) * K + c * 8;
    ldst[it] = (it * 256 + (t & ~63)) * 8;
  }
  long bsrcF[2];
  int brow[2], bc[2];
  if (BF32) {
    #pragma unroll
    for (int it = 0; it < 2; ++it) {
      int d = it * 256 + t;
      brow[it] = d >> 2; bc[it] = d & 3;
      bsrcF[it] = (long)(n0 + brow[it]) * K + bc[it] * 8;
    }
  }
  int sa = lr & 7;
  int cH = (lg ^ sa) * 8;
  int cM = ((4 + lg) ^ sa) * 8;

  f32x4 acc[4][4];
  #pragma unroll
  for (int i = 0; i < 4; ++i)
    #pragma unroll
    for (int j = 0; j < 4; ++j) acc[i][j] = 0.f;

  int kStep = K / kParts;
  int kLo = part * kStep, kHi = kLo + kStep;

  f32x4 pv0[2], pv1[2];
  if (BF32) {
    #pragma unroll
    for (int it = 0; it < 2; ++it) {
      const float* src = Bf + bsrcF[it] + kLo;
      pv0[it] = *(const f32x4*)src;
      pv1[it] = *(const f32x4*)(src + 4);
    }
  }
  for (int k0 = kLo; k0 < kHi; k0 += BK) {
    bool pf = BF32 && (k0 + BK < kHi);
    #pragma unroll
    for (int it = 0; it < 4; ++it) {
      ld_lds16(A0 + asrc[it] + k0, &Ac[0][0] + ldst[it]);
      if (!BF32) ld_lds16(B0 + bsrc[it] + k0, &Bc[0][0] + ldst[it]);
    }
    f32x4 nv0[2], nv1[2];
    if (pf) {
      #pragma unroll
      for (int it = 0; it < 2; ++it) {
        const float* src = Bf + bsrcF[it] + k0 + BK;
        nv0[it] = *(const f32x4*)src;
        nv1[it] = *(const f32x4*)(src + 4);
      }
    }
    if (BF32) {
      #pragma unroll
      for (int it = 0; it < 2; ++it) {
        u16x8 hi, mi;
        #pragma unroll
        for (int j = 0; j < 4; ++j) {
          u16 h, m; split2s(pv0[it][j], h, m); hi[j] = h; mi[j] = m;
        }
        #pragma unroll
        for (int j = 0; j < 4; ++j) {
          u16 h, m; split2s(pv1[it][j], h, m); hi[4 + j] = h; mi[4 + j] = m;
        }
        int r7 = brow[it] & 7;
        *(u16x8*)&Bc[brow[it]][(bc[it] ^ r7) * 8] = hi;
        *(u16x8*)&Bc[brow[it]][((4 + bc[it]) ^ r7) * 8] = mi;
      }
    }
    __syncthreads();
    f16x8 ah[4], am[4];
    #pragma unroll
    for (int i = 0; i < 4; ++i) {
      ah[i] = *(const f16x8*)&Ac[wm + i*16 + lr][cH];
      am[i] = *(const f16x8*)&Ac[wm + i*16 + lr][cM];
    }
    __builtin_amdgcn_s_setprio(1);
    #pragma unroll
    for (int j = 0; j < 4; ++j) {
      f16x8 bh = *(const f16x8*)&Bc[wn + j*16 + lr][cH];
      f16x8 bm = *(const f16x8*)&Bc[wn + j*16 + lr][cM];
      #pragma unroll
      for (int i = 0; i < 4; ++i) {
        acc[i][j] = MFMAH(ah[i], bh, acc[i][j]);
        acc[i][j] = MFMAH(am[i], bh, acc[i][j]);
        acc[i][j] = MFMAH(ah[i], bm, acc[i][j]);
      }
    }
    __builtin_amdgcn_s_setprio(0);
    __syncthreads();
    if (pf) {
      #pragma unroll
      for (int it = 0; it < 2; ++it) { pv0[it] = nv0[it]; pv1[it] = nv1[it]; }
    }
  }
  float* Cf = (float*)C + (long)part * cPart;
  #pragma unroll
  for (int i = 0; i < 4; ++i) {
    #pragma unroll
    for (int r = 0; r < 4; ++r) {
      long m = m0 + wm + i*16 + lg*4 + r;
      #pragma unroll
      for (int j = 0; j < 4; ++j) {
        int n = n0 + wn + j*16 + lr;
        float val = acc[i][j][r] * (1.0f / 4096.0f);
        if (POST == P_F32) {
          Cf[m * N + n] = val;
        } else if (POST == P_F32_RESID) {
          ((float*)C)[m * N + n] = val + resid[m * N + n];
        } else if (POST == P_SPLIT2_RELU) {
          val = fmaxf(val, 0.f);
          u16 h, mm; split2s(val, h, mm);
          u16* Cp = (u16*)C;
          Cp[m * N + n] = h;
          Cp[planeC + m * N + n] = mm;
        }
      }
    }
  }
}

// ------- wide fused fp16 split-2 GEMM: 128x256 tile, 512 threads, 2m x 4n waves -------

template <int POST, bool GATHER, bool EXPERT, bool BF32>
__global__ __launch_bounds__(512) void gemm2hW_bt_k(
    const u16* __restrict__ A0, long planeA,
    const void* __restrict__ Bv, long planeB,
    void* __restrict__ C, long planeC,
    const int* __restrict__ rows, const int* __restrict__ offsets,
    int N, int K, int lda, long eBstride, int mPerX,
    int kParts, int base, long cPart) {
  constexpr int BM = 128, BN = 256, BK = 32;
  int part = blockIdx.x / base;
  int lin = blockIdx.x % base;
  int xcd = lin & 7, c0 = lin >> 3;
  int m0 = (xcd * mPerX + (c0 % mPerX)) * BM;
  int n0 = (c0 / mPerX) * BN;
  const u16* B0 = (const u16*)Bv;
  const float* Bf = (const float*)Bv;
  if (EXPERT) {
    int total = offsets[kE];
    if (m0 >= total) return;
    int e = 0;
    while (offsets[e + 1] <= m0) ++e;
    if (BF32) Bf += (long)e * eBstride; else B0 += (long)e * eBstride;
  }
  __shared__ __align__(16) u16 Ac[BM][64];
  __shared__ __align__(16) u16 Bc[BN][64];
  int t = threadIdx.x;
  int l = t & 63, lr = l & 15, lg = l >> 4;
  int wid = t >> 6;
  int wm = (wid >> 2) * 64;
  int wn = (wid & 3) * 64;

  long asrc[2], bsrc[4];
  int aldst[2], bldst[4];
  #pragma unroll
  for (int it = 0; it < 2; ++it) {
    int d = it * 512 + t;
    int row = d >> 3, pc = d & 7;
    int lc = pc ^ (row & 7);
    int p = lc >> 2, cc = lc & 3;
    int grow = GATHER ? clamp_row(rows[m0 + row]) : (m0 + row);
    asrc[it] = (long)p * planeA + (long)grow * lda + cc * 8;
    aldst[it] = (it * 512 + (t & ~63)) * 8;
  }
  long bsrcF[2];
  int brow[2], bcc[2];
  if (!BF32) {
    #pragma unroll
    for (int it = 0; it < 4; ++it) {
      int d = it * 512 + t;
      int row = d >> 3, pc = d & 7;
      int lc = pc ^ (row & 7);
      int p = lc >> 2, cc = lc & 3;
      bsrc[it] = (long)p * planeB + (long)(n0 + row) * K + cc * 8;
      bldst[it] = (it * 512 + (t & ~63)) * 8;
    }
  } else {
    #pragma unroll
    for (int it = 0; it < 2; ++it) {
      int d = it * 512 + t;
      brow[it] = d >> 2; bcc[it] = d & 3;
      bsrcF[it] = (long)(n0 + brow[it]) * K + bcc[it] * 8;
    }
  }
  int sa = lr & 7;
  int cH = (lg ^ sa) * 8;
  int cM = ((4 + lg) ^ sa) * 8;

  f32x4 acc[4][4];
  #pragma unroll
  for (int i = 0; i < 4; ++i)
    #pragma unroll
    for (int j = 0; j < 4; ++j) acc[i][j] = 0.f;

  int kStep = K / kParts;
  int kLo = part * kStep, kHi = kLo + kStep;

  f32x4 pv0[2], pv1[2];
  if (BF32) {
    #pragma unroll
    for (int it = 0; it < 2; ++it) {
      const float* src = Bf + bsrcF[it] + kLo;
      pv0[it] = *(const f32x4*)src;
      pv1[it] = *(const f32x4*)(src + 4);
    }
  }
  for (int k0 = kLo; k0 < kHi; k0 += BK) {
    bool pf = BF32 && (k0 + BK < kHi);
    #pragma unroll
    for (int it = 0; it < 2; ++it)
      ld_lds16(A0 + asrc[it] + k0, &Ac[0][0] + aldst[it]);
    if (!BF32) {
      #pragma unroll
      for (int it = 0; it < 4; ++it)
        ld_lds16(B0 + bsrc[it] + k0, &Bc[0][0] + bldst[it]);
    }
    f32x4 nv0[2], nv1[2];
    if (pf) {
      #pragma unroll
      for (int it = 0; it < 2; ++it) {
        const float* src = Bf + bsrcF[it] + k0 + BK;
        nv0[it] = *(const f32x4*)src;
        nv1[it] = *(const f32x4*)(src + 4);
      }
    }
    if (BF32) {
      #pragma unroll
      for (int it = 0; it < 2; ++it) {
        u16x8 hi, mi;
        #pragma unroll
        for (int j = 0; j < 4; ++j) {
          u16 h, m; split2s(pv0[it][j], h, m); hi[j] = h; mi[j] = m;
        }
        #pragma unroll
        for (int j = 0; j < 4; ++j) {
          u16 h, m; split2s(pv1[it][j], h, m); hi[4 + j] = h; mi[4 + j] = m;
        }
        int r7 = brow[it] & 7;
        *(u16x8*)&Bc[brow[it]][(bcc[it] ^ r7) * 8] = hi;
        *(u16x8*)&Bc[brow[it]][((4 + bcc[it]) ^ r7) * 8] = mi;
      }
    }
    __syncthreads();
    f16x8 ah[4], am[4];
    #pragma unroll
    for (int i = 0; i < 4; ++i) {
      ah[i] = *(const f16x8*)&Ac[wm + i*16 + lr][cH];
      am[i] = *(const f16x8*)&Ac[wm + i*16 + lr][cM];
    }
    __builtin_amdgcn_s_setprio(1);
    #pragma unroll
    for (int j = 0; j < 4; ++j) {
      f16x8 bh = *(const f16x8*)&Bc[wn + j*16 + lr][cH];
      f16x8 bm = *(const f16x8*)&Bc[wn + j*16 + lr][cM];
      #pragma unroll
      for (int i = 0; i < 4; ++i) {
        acc[i][j] = MFMAH(ah[i], bh, acc[i][j]);
        acc[i][j] = MFMAH(am[i], bh, acc[i][j]);
        acc[i][j] = MFMAH(ah[i], bm, acc[i][j]);
      }
    }
    __builtin_amdgcn_s_setprio(0);
    __syncthreads();
    if (pf) {
      #pragma unroll
      for (int it = 0; it < 2; ++it) { pv0[it] = nv0[it]; pv1[it] = nv1[it]; }
    }
  }
  float* Cf = (float*)C + (long)part * cPart;
  #pragma unroll
  for (int i = 0; i < 4; ++i) {
    #pragma unroll
    for (int r = 0; r < 4; ++r) {
      long m = m0 + wm + i*16 + lg*4 + r;
      #pragma unroll
      for (int j = 0; j < 4; ++j) {
        int n = n0 + wn + j*16 + lr;
        float val = acc[i][j][r] * (1.0f / 4096.0f);
        if (POST == P_F32) {
          Cf[m * N + n] = val;
        } else if (POST == P_SPLIT2_RELU) {
          val = fmaxf(val, 0.f);
          u16 h, mm; split2s(val, h, mm);
          u16* Cp = (u16*)C;
          Cp[m * N + n] = h;
          Cp[planeC + m * N + n] = mm;
        }
      }
    }
  }
}

// ---------------- single-plane MFMA GEMM (with optional split-K) ----------------

template <int POST, bool EXPERT, bool GATHER, bool HALF, bool BCONV, bool MPART>
__global__ __launch_bounds__(256) void gemm_bt_k(
    const u16* __restrict__ A, const void* __restrict__ Bv, void* __restrict__ C,
    const int* __restrict__ rows, const int* __restrict__ offsets,
    int N, int K, int lda, long eBstride, float oscale, int mArg,
    int kParts, int base, long cPart) {
  constexpr int BM = 128, BK = 64;
  int part = blockIdx.x / base;
  int lin = blockIdx.x % base;
  int mb, nb;
  block_mn<MPART>(lin, base, mArg, mb, nb);
  int m0 = mb * BM, n0 = nb * BM;
  const float* Bf = (const float*)Bv;
  const u16*   Bh = (const u16*)Bv;
  if (EXPERT) {
    int total = offsets[kE];
    if (m0 >= total) return;
    int e = 0;
    while (offsets[e + 1] <= m0) ++e;
    if (BCONV) Bf += (long)e * eBstride; else Bh += (long)e * eBstride;
  }
  __shared__ __align__(16) u16 As[BM][BK];
  __shared__ __align__(16) u16 Bs[BM][BK];
  int t = threadIdx.x;
  int l = t & 63, lr = l & 15, lg = l >> 4;
  int wid = t >> 6;
  int wm = (wid >> 1) * 64, wn = (wid & 1) * 64;

  long asrc[4], bsrc[4];
  int ldst[4];
  #pragma unroll
  for (int it = 0; it < 4; ++it) {
    int d = it * 256 + t;
    int row = d >> 3, pc = d & 7;
    int c = pc ^ (row & 7);
    int grow = GATHER ? clamp_row(rows[m0 + row]) : (m0 + row);
    asrc[it] = (long)grow * lda + c * 8;
    if (!BCONV) bsrc[it] = (long)(n0 + row) * K + c * 8;
    ldst[it] = (it * 256 + (t & ~63)) * 8;
  }
  long bsrcC[4];
  int bdst[4];
  if (BCONV) {
    #pragma unroll
    for (int it = 0; it < 4; ++it) {
      int d = it * 256 + t;
      int row = d >> 3, lc = d & 7;
      bsrcC[it] = (long)(n0 + row) * K + lc * 8;
      bdst[it] = row * BK + (lc ^ (row & 7)) * 8;
    }
  }
  f32x4 acc[4][4];
  #pragma unroll
  for (int i = 0; i < 4; ++i)
    #pragma unroll
    for (int j = 0; j < 4; ++j) acc[i][j] = 0.f;

  int kStep = K / kParts;
  int kLo = part * kStep, kHi = kLo + kStep;
  for (int k0 = kLo; k0 < kHi; k0 += BK) {
    #pragma unroll
    for (int it = 0; it < 4; ++it)
      ld_lds16(A + asrc[it] + k0, &As[0][0] + ldst[it]);
    if (!BCONV) {
      #pragma unroll
      for (int it = 0; it < 4; ++it)
        ld_lds16(Bh + bsrc[it] + k0, &Bs[0][0] + ldst[it]);
    } else {
      #pragma unroll
      for (int it = 0; it < 4; ++it) {
        const float* src = Bf + bsrcC[it] + k0;
        f32x4 v0 = *(const f32x4*)src;
        f32x4 v1 = *(const f32x4*)(src + 4);
        u16x8 o;
        #pragma unroll
        for (int j = 0; j < 4; ++j) {
          o[j] = HALF ? f2h(v0[j]) : f2bf(v0[j]);
          o[4 + j] = HALF ? f2h(v1[j]) : f2bf(v1[j]);
        }
        *(u16x8*)(&Bs[0][0] + bdst[it]) = o;
      }
    }
    __syncthreads();
    __builtin_amdgcn_s_setprio(1);
    #pragma unroll
    for (int kk = 0; kk < 2; ++kk) {
      int ca = ((kk * 4 + lg) ^ (lr & 7)) * 8;
      #pragma unroll
      for (int i = 0; i < 4; ++i)
        #pragma unroll
        for (int j = 0; j < 4; ++j) {
          if (HALF) {
            f16x8 af = *(const f16x8*)&As[wm + i*16 + lr][ca];
            f16x8 bq = *(const f16x8*)&Bs[wn + j*16 + lr][ca];
            acc[i][j] = MFMAH(af, bq, acc[i][j]);
          } else {
            bf16x8 af = *(const bf16x8*)&As[wm + i*16 + lr][ca];
            bf16x8 bq = *(const bf16x8*)&Bs[wn + j*16 + lr][ca];
            acc[i][j] = MFMA16(af, bq, acc[i][j]);
          }
        }
    }
    __builtin_amdgcn_s_setprio(0);
    __syncthreads();
  }
  #pragma unroll
  for (int i = 0; i < 4; ++i) {
    #pragma unroll
    for (int r = 0; r < 4; ++r) {
      long m = m0 + wm + i*16 + lg*4 + r;
      #pragma unroll
      for (int j = 0; j < 4; ++j) {
        int n = n0 + wn + j*16 + lr;
        float val = acc[i][j][r] * oscale;
        if (POST == P_BF16_RELU)       ((u16*)C)[m * N + n] = f2bf(fmaxf(val, 0.f));
        else if (POST == P_F16_RELU)   ((u16*)C)[m * N + n] = f2h(fmaxf(val, 0.f));
        else if (POST == P_F32)        ((float*)C + (long)part * cPart)[m * N + n] = val;
      }
    }
  }
}

// ---------------- f32 SGEMM (fallback path only) ----------------

template <int POST, bool GATHER, bool EXPERT>
__global__ __launch_bounds__(256) void sgemm_bt_k(
    const float* __restrict__ A, const float* __restrict__ B, float* __restrict__ C,
    const float* __restrict__ resid, const int* __restrict__ rows,
    const int* __restrict__ offsets, int N, int K, int lda, long eBstride) {
  constexpr int BM = 128, BN = 128, BK = 32;
  int m0 = blockIdx.x * BM, n0 = blockIdx.y * BN;
  if (EXPERT) {
    int total = offsets[kE];
    if (m0 >= total) return;
    int e = 0;
    while (offsets[e + 1] <= m0) ++e;
    B += (long)e * eBstride;
  }
  __shared__ float Ast[BK][BM];
  __shared__ float Bst[BK][BN];
  int t = threadIdx.x, tx = t & 15, ty = t >> 4;
  long asrc[4], bsrc[4];
  #pragma unroll
  for (int it = 0; it < 4; ++it) {
    int c = it * 256 + t;
    int row = c >> 3, kc = (c & 7) * 4;
    int gr = GATHER ? clamp_row(rows[m0 + row]) : (m0 + row);
    asrc[it] = (long)gr * lda + kc;
    bsrc[it] = (long)(n0 + row) * K + kc;
  }
  f32x4 accv[8][2];
  #pragma unroll
  for (int i = 0; i < 8; ++i) { accv[i][0] = 0.f; accv[i][1] = 0.f; }

  for (int k0 = 0; k0 < K; k0 += BK) {
    #pragma unroll
    for (int it = 0; it < 4; ++it) {
      int c = it * 256 + t;
      int row = c >> 3, kc = (c & 7) * 4;
      f32x4 av = *(const f32x4*)(A + asrc[it] + k0);
      f32x4 bv = *(const f32x4*)(B + bsrc[it] + k0);
      #pragma unroll
      for (int j = 0; j < 4; ++j) { Ast[kc + j][row] = av[j]; Bst[kc + j][row] = bv[j]; }
    }
    __syncthreads();
    #pragma unroll
    for (int kk = 0; kk < BK; ++kk) {
      f32x4 a0 = *(const f32x4*)&Ast[kk][ty * 4];
      f32x4 a1 = *(const f32x4*)&Ast[kk][64 + ty * 4];
      f32x4 b0 = *(const f32x4*)&Bst[kk][tx * 4];
      f32x4 b1 = *(const f32x4*)&Bst[kk][64 + tx * 4];
      float as[8] = {a0[0], a0[1], a0[2], a0[3], a1[0], a1[1], a1[2], a1[3]};
      #pragma unroll
      for (int i = 0; i < 8; ++i) {
        accv[i][0] += b0 * as[i];
        accv[i][1] += b1 * as[i];
      }
    }
    __syncthreads();
  }
  #pragma unroll
  for (int ih = 0; ih < 2; ++ih)
    #pragma unroll
    for (int i = 0; i < 4; ++i) {
      long m = m0 + ih * 64 + ty * 4 + i;
      #pragma unroll
      for (int jh = 0; jh < 2; ++jh) {
        long n = n0 + jh * 64 + tx * 4;
        f32x4 val = accv[ih * 4 + i][jh];
        if (POST == P_F32_RELU) {
          #pragma unroll
          for (int j = 0; j < 4; ++j) val[j] = fmaxf(val[j], 0.f);
        }
        if (POST == P_F32_RESID) val += *(const f32x4*)&resid[m * N + n];
        *(f32x4*)&C[m * N + n] = val;
      }
    }
}

// ------- MFMA split-2 attention (f32-equivalent accuracy) -------

__global__ __launch_bounds__(256) void attn2h_k(
    const u16* __restrict__ qkvP, long qplane,
    u16* __restrict__ oP, long oplane) {
  int qt = (int)gridDim.x - 1 - (int)blockIdx.x;   // heavy first
  int bh = blockIdx.y;
  int b = bh >> 4, h = bh & 15;
  const int ldq = 3 * kD;
  long hbq = (long)b * kT * ldq + h * kHD;
  long hbo = (long)b * kT * kD + h * kHD;
  int t = threadIdx.x, w = t >> 6, l = t & 63;
  int lr = l & 15, lg = l >> 4;

  __shared__ __align__(16) u16 Ks[2][64][72];
  __shared__ __align__(16) u16 Vt[2][64][72];
  __shared__ __align__(16) u16 Ps[2][4][16][72];

  f16x8 qf0[2], qf1[2];
  {
    long qrow = qt * 64 + w * 16 + lr;
    const u16* qp = qkvP + hbq + qrow * ldq;
    #pragma unroll
    for (int kc = 0; kc < 2; ++kc) {
      qf0[kc] = *(const f16x8*)(qp + kc * 32 + lg * 8);
      qf1[kc] = *(const f16x8*)(qp + qplane + kc * 32 + lg * 8);
    }
  }
  int qg = qt * 64 + w * 16 + lg * 4;

  float mrow[4], lsum[4];
  f32x4 accO[4];
  #pragma unroll
  for (int r = 0; r < 4; ++r) { mrow[r] = -1e30f; lsum[r] = 0.f; }
  #pragma unroll
  for (int j = 0; j < 4; ++j) accO[j] = 0.f;

  for (int it = 0; it <= qt; ++it) {
    #pragma unroll
    for (int p = 0; p < 2; ++p) {
      #pragma unroll
      for (int s = 0; s < 2; ++s) {
        int c = s * 256 + t;
        int row = c >> 3, col = (c & 7) * 8;
        long gi = (long)p * qplane + hbq + (long)(it * 64 + row) * ldq + col;
        *(u16x8*)&Ks[p][row][col] = *(const u16x8*)(qkvP + kD + gi);
        u16x8 vv = *(const u16x8*)(qkvP + 2 * kD + gi);
        #pragma unroll
        for (int j = 0; j < 8; ++j) Vt[p][col + j][row] = vv[j];
      }
    }
    __syncthreads();

    f32x4 s4[4];
    __builtin_amdgcn_s_setprio(1);
    #pragma unroll
    for (int j = 0; j < 4; ++j) {
      f32x4 z = {0.f, 0.f, 0.f, 0.f};
      #pragma unroll
      for (int kc = 0; kc < 2; ++kc) {
        f16x8 kh = *(const f16x8*)&Ks[0][j*16 + lr][kc*32 + lg*8];
        f16x8 km = *(const f16x8*)&Ks[1][j*16 + lr][kc*32 + lg*8];
        z = MFMAH(qf0[kc], kh, z);
        z = MFMAH(qf1[kc], kh, z);
        z = MFMAH(qf0[kc], km, z);
      }
      s4[j] = z;
    }
    __builtin_amdgcn_s_setprio(0);
    #pragma unroll
    for (int j = 0; j < 4; ++j)
      #pragma unroll
      for (int r = 0; r < 4; ++r) {
        float sv = s4[j][r] * (0.125f / 4096.0f);
        if (it * 64 + j * 16 + lr > qg + r) sv = -1e30f;
        s4[j][r] = sv;
      }
    float alpha[4];
    #pragma unroll
    for (int r = 0; r < 4; ++r) {
      float mx = fmaxf(fmaxf(s4[0][r], s4[1][r]), fmaxf(s4[2][r], s4[3][r]));
      mx = fmaxf(mx, __shfl_xor(mx, 1));
      mx = fmaxf(mx, __shfl_xor(mx, 2));
      mx = fmaxf(mx, __shfl_xor(mx, 4));
      mx = fmaxf(mx, __shfl_xor(mx, 8));
      float mi = fmaxf(mrow[r], mx);
      alpha[r] = __expf(mrow[r] - mi);
      mrow[r] = mi;
    }
    float rs[4] = {0.f, 0.f, 0.f, 0.f};
    #pragma unroll
    for (int j = 0; j < 4; ++j)
      #pragma unroll
      for (int r = 0; r < 4; ++r) {
        float p = __expf(s4[j][r] - mrow[r]);
        rs[r] += p;
        u16 hh, mm; split2s(p, hh, mm);
        Ps[0][w][lg*4 + r][j*16 + lr] = hh;
        Ps[1][w][lg*4 + r][j*16 + lr] = mm;
      }
    #pragma unroll
    for (int r = 0; r < 4; ++r) {
      float x2 = rs[r];
      x2 += __shfl_xor(x2, 1);
      x2 += __shfl_xor(x2, 2);
      x2 += __shfl_xor(x2, 4);
      x2 += __shfl_xor(x2, 8);
      lsum[r] = lsum[r] * alpha[r] + x2;
    }
    #pragma unroll
    for (int j = 0; j < 4; ++j)
      #pragma unroll
      for (int r = 0; r < 4; ++r) accO[j][r] *= alpha[r];
    __syncthreads();

    f16x8 ph[2], pm[2];
    #pragma unroll
    for (int kc = 0; kc < 2; ++kc) {
      ph[kc] = *(const f16x8*)&Ps[0][w][lr][kc*32 + lg*8];
      pm[kc] = *(const f16x8*)&Ps[1][w][lr][kc*32 + lg*8];
    }
    __builtin_amdgcn_s_setprio(1);
    #pragma unroll
    for (int j2 = 0; j2 < 4; ++j2) {
      #pragma unroll
      for (int kc = 0; kc < 2; ++kc) {
        f16x8 vh = *(const f16x8*)&Vt[0][j2*16 + lr][kc*32 + lg*8];
        f16x8 vm = *(const f16x8*)&Vt[1][j2*16 + lr][kc*32 + lg*8];
        accO[j2] = MFMAH(ph[kc], vh, accO[j2]);
        accO[j2] = MFMAH(pm[kc], vh, accO[j2]);
        accO[j2] = MFMAH(ph[kc], vm, accO[j2]);
      }
    }
    __builtin_amdgcn_s_setprio(0);
    __syncthreads();
  }
  #pragma unroll
  for (int j2 = 0; j2 < 4; ++j2)
    #pragma unroll
    for (int r = 0; r < 4; ++r) {
      float ov = accO[j2][r] * (1.0f / 4096.0f) / lsum[r];
      long row = qt * 64 + w * 16 + lg * 4 + r;
      long idx = hbo + row * kD + j2 * 16 + lr;
      u16 hh, mm; split2s(ov, hh, mm);
      oP[idx] = hh;
      oP[oplane + idx] = mm;
    }
}

// ---------------- f32 attention (fallback path) ----------------

__global__ __launch_bounds__(256) void attn_f32_k(
    const float* __restrict__ qkv, float* __restrict__ of32, int ldq) {
  int qt = blockIdx.x;
  int bh = blockIdx.y;
  int b = bh >> 4, h = bh & 15;
  long hbq = (long)b * kT * ldq + h * kHD;
  long hbo = (long)b * kT * kD + h * kHD;
  int t = threadIdx.x, qr = t >> 2, sub = t & 3;

  __shared__ float Qs[64][68], Ks[64][68], Vs[64][68], Ps[64][68];

  const float* q = qkv;
  const float* k = qkv + kD;
  const float* v = qkv + 2 * kD;

  #pragma unroll
  for (int it = 0; it < 4; ++it) {
    int c = it * 256 + t, row = c >> 4, c4 = (c & 15) * 4;
    f32x4 qv = *(const f32x4*)(q + hbq + (long)(qt * 64 + row) * ldq + c4);
    #pragma unroll
    for (int j = 0; j < 4; ++j) Qs[row][c4 + j] = qv[j];
  }
  __syncthreads();
  f32x4 qreg[16];
  #pragma unroll
  for (int d4 = 0; d4 < 16; ++d4) qreg[d4] = *(const f32x4*)&Qs[qr][d4 * 4];
  int qg = qt * 64 + qr;

  float mrow = -1e30f, lsum = 0.f;
  f32x4 accO[4];
  #pragma unroll
  for (int i = 0; i < 4; ++i) accO[i] = 0.f;

  for (int itl = 0; itl <= qt; ++itl) {
    #pragma unroll
    for (int it = 0; it < 4; ++it) {
      int c = it * 256 + t, row = c >> 4, c4 = (c & 15) * 4;
      long gi = hbq + (long)(itl * 64 + row) * ldq + c4;
      f32x4 kv = *(const f32x4*)(k + gi);
      f32x4 vv = *(const f32x4*)(v + gi);
      #pragma unroll
      for (int j = 0; j < 4; ++j) { Ks[row][c4 + j] = kv[j]; Vs[row][c4 + j] = vv[j]; }
    }
    __syncthreads();

    float s[16];
    #pragma unroll
    for (int kk = 0; kk < 16; ++kk) {
      int key = kk * 4 + sub;
      f32x4 a = {0.f, 0.f, 0.f, 0.f};
      #pragma unroll
      for (int d4 = 0; d4 < 16; ++d4) a += qreg[d4] * *(const f32x4*)&Ks[key][d4 * 4];
      float sv = (a[0] + a[1] + a[2] + a[3]) * 0.125f;
      if (itl * 64 + key > qg) sv = -1e30f;
      s[kk] = sv;
    }
    float mx = s[0];
    #pragma unroll
    for (int kk = 1; kk < 16; ++kk) mx = fmaxf(mx, s[kk]);
    mx = fmaxf(mx, __shfl_xor(mx, 1));
    mx = fmaxf(mx, __shfl_xor(mx, 2));
    float mi = fmaxf(mrow, mx);
    float alpha = __expf(mrow - mi);
    mrow = mi;
    float rs = 0.f;
    #pragma unroll
    for (int kk = 0; kk < 16; ++kk) {
      float p = __expf(s[kk] - mi);
      rs += p;
      Ps[qr][kk * 4 + sub] = p;
    }
    rs += __shfl_xor(rs, 1);
    rs += __shfl_xor(rs, 2);
    lsum = lsum * alpha + rs;
    #pragma unroll
    for (int i = 0; i < 4; ++i) accO[i] *= alpha;
    #pragma unroll
    for (int key2 = 0; key2 < 64; ++key2) {
      float p = Ps[qr][key2];
      #pragma unroll
      for (int i4 = 0; i4 < 4; ++i4)
        accO[i4] += p * *(const f32x4*)&Vs[key2][sub * 16 + i4 * 4];
    }
    __syncthreads();
  }
  float inv = 1.f / lsum;
  #pragma unroll
  for (int i4 = 0; i4 < 4; ++i4) {
    f32x4 ov = accO[i4] * inv;
    *(f32x4*)(of32 + hbo + (long)qg * kD + sub * 16 + i4 * 4) = ov;
  }
}

// ---------------- host ----------------

extern "C" void kernel_launch(void* const* d_in, const int* in_sizes, int n_in,
                              void* d_out, int out_size, void* d_ws, size_t ws_size,
                              hipStream_t stream) {
  const int*   idx  = (const int*)  d_in[0];
  const float* wte  = (const float*)d_in[1];
  const float* wpe  = (const float*)d_in[2];
  const float* wq   = (const float*)d_in[3];
  const float* wk   = (const float*)d_in[4];
  const float* wv   = (const float*)d_in[5];
  const float* wo   = (const float*)d_in[6];
  const float* gate = (const float*)d_in[7];
  const float* f1   = (const float*)d_in[8];
  const float* f2   = (const float*)d_in[9];
  const float* lmh  = (const float*)d_in[10];
  float* out = (float*)d_out;

  char* ws = (char*)d_ws;
  size_t off = 0;
  auto alloc = [&](size_t b) -> char* {
    char* p = ws + off;
    off += (b + 255) & ~(size_t)255;
    return p;
  };

  constexpr long PLN_XN = (long)kBT * kD;
  constexpr long PLN_Q3 = (long)kBT * 3 * kD;
  constexpr long PLN_QKV = (long)3 * kD * kD;
  constexpr long PLN_WO = (long)kD * kD;
  constexpr long PLN_FF = (long)kE * kFF * kD;
  constexpr long PLN_H = (long)kSLOTS * kFF;
  constexpr long PLN_OUTS = (long)kSLOTS * kD;
  constexpr long PLN_PR = (long)kBT * kE;

  // shared small buffers
  float* x     = (float*)alloc((size_t)kBT * kD * 4);
  float* outs  = (float*)alloc((size_t)4 * PLN_OUTS * 4);   // 4 K-partials
  float* probs3= (float*)alloc((size_t)kL * PLN_PR * 4);    // per-layer probs
  int*   top2e = (int*)  alloc((size_t)kBT * 2 * 4);
  float* top2w = (float*)alloc((size_t)kBT * 2 * 4);
  int*   meta  = (int*)  alloc(64 * 4);
  int* counts = meta; int* cursors = meta + 8; int* offs = meta + 16;
  int*   rows  = (int*)  alloc((size_t)kSLOTS * 4);
  int*   slotOf= (int*)  alloc((size_t)kBT * 2 * 4);
  float* aux   = (float*)alloc(256);
  size_t off_shared = off;

  // fast-path buffers
  u16*   xnP   = (u16*)  alloc((size_t)2 * PLN_XN * 2);
  float* qkvf  = (float*)alloc((size_t)PLN_Q3 * 4);
  u16*   qkvP  = (u16*)  alloc((size_t)2 * PLN_Q3 * 2);
  u16*   ofP   = (u16*)  alloc((size_t)2 * PLN_XN * 2);
  u16*   hP    = (u16*)  alloc((size_t)2 * PLN_H * 2);
  u16*   wqkvP = (u16*)  alloc((size_t)kL * 2 * PLN_QKV * 2);
  u16*   woP   = (u16*)  alloc((size_t)kL * 2 * PLN_WO * 2);
  u16*   lmb   = (u16*)  alloc((size_t)kV * kD * 2);      // f16 lm_head weights
  bool fast = (off <= ws_size);
  float* qkvp1 = (float*)hP;          // alias: hP idle during QKV+attn phase

  dim3 gAttn(kT / 64, 2 * kH);
  // base grids (all % 8 == 0)
  int bQKV = (kBT / 128) * (3 * kD / 128);       // 384,  MPART mPerX=2, kParts=2
  int bWO  = (kBT / 128) * (kD / 128);           // 128,  MPART mPerX=2, kParts=4
  int nF1W = (kSLOTS / 128) * (kFF / 256);       // 640,  W kernel mPerX=5
  int bF2  = (kSLOTS / 128) * (kD / 128);        // 320,  MPART mPerX=5, kParts=4
  int nF1s = (kSLOTS / 128) * (kFF / 128);       // 1280, MPART mPerX=5
  int nLM  = (kBT / 128) * (kV / 128);           // 4000, mBlocks=16

  if (fast) {
    for (int li = 0; li < kL; ++li) {
      u16* dst = wqkvP + (size_t)li * 2 * PLN_QKV;
      split2h_k<<<1024, 256, 0, stream>>>(wq + (size_t)li * kD * kD, dst, PLN_QKV, (long)kD * kD / 4);
      split2h_k<<<1024, 256, 0, stream>>>(wk + (size_t)li * kD * kD, dst + (long)kD * kD, PLN_QKV, (long)kD * kD / 4);
      split2h_k<<<1024, 256, 0, stream>>>(wv + (size_t)li * kD * kD, dst + (long)2 * kD * kD, PLN_QKV, (long)kD * kD / 4);
      split2h_k<<<1024, 256, 0, stream>>>(wo + (size_t)li * kD * kD, woP + (size_t)li * 2 * PLN_WO, PLN_WO, (long)kD * kD / 4);
    }
    cast_h_k<<<4096, 256, 0, stream>>>(lmh, lmb, (long)kV * kD / 4);
    embed_rms_k<<<kBT, 256, 0, stream>>>(idx, wte, wpe, x);
    rmsnorm2h_k<<<kBT, 256, 0, stream>>>(x, xnP, PLN_XN);   // layer-0 QKV input

    for (int li = 0; li < kL; ++li) {
      // QKV: split-K x2 -> qkvf + qkvp1; combine into split-2 planes
      gemm2h_bt_k<P_F32, false, false, true, false><<<2 * bQKV, 256, 0, stream>>>(
          xnP, PLN_XN, wqkvP + (size_t)li * 2 * PLN_QKV, PLN_QKV,
          qkvf, 0, nullptr, nullptr, nullptr, 3 * kD, kD, kD, 0, 2,
          2, bQKV, (long)(qkvp1 - qkvf));
      qkvcomb_k<<<2048, 256, 0, stream>>>(qkvf, qkvp1, qkvP, PLN_Q3, PLN_Q3 / 4);
      attn2h_k<<<gAttn, 256, 0, stream>>>(qkvP, PLN_Q3, ofP, PLN_XN);
      // WO: split-K x4 into outs partials; fused residual+rms+split
      gemm2h_bt_k<P_F32, false, false, true, false><<<4 * bWO, 256, 0, stream>>>(
          ofP, PLN_XN, woP + (size_t)li * 2 * PLN_WO, PLN_WO,
          outs, 0, nullptr, nullptr, nullptr, kD, kD, kD, 0, 2,
          4, bWO, PLN_OUTS);
      resid4_rms2h_k<<<kBT, 256, 0, stream>>>(x, outs, PLN_OUTS, xnP, PLN_XN);
      hipMemsetAsync(meta, 0, 64, stream);
      gate_topk_k<<<kBT, 256, 0, stream>>>(x, gate + (size_t)li * kE * kD,
                                           probs3 + (size_t)li * PLN_PR,
                                           top2e, top2w, counts);
      fill_slots2_k<<<kBT / 256, 256, 0, stream>>>(top2e, counts, offs, cursors,
                                                   rows, slotOf);
      size_t fd = (size_t)li * PLN_FF;
      if (li < 2) {
        gemm2hW_bt_k<P_SPLIT2_RELU, true, true, true><<<nF1W, 512, 0, stream>>>(
            xnP, PLN_XN, f1 + fd, 0, hP, PLN_H, rows, offs,
            kFF, kD, kD, (long)kFF * kD, kSLOTS / 128 / 8,
            1, nF1W, 0);
        gemm2h_bt_k<P_F32, false, true, true, true><<<4 * bF2, 256, 0, stream>>>(
            hP, PLN_H, f2 + fd, 0, outs, 0, nullptr, nullptr, offs,
            kD, kFF, kFF, (long)kD * kFF, kSLOTS / 128 / 8,
            4, bF2, PLN_OUTS);
        moe4_rms2h_k<<<kBT, 256, 0, stream>>>(x, outs, PLN_OUTS, slotOf, top2w,
                                              xnP, PLN_XN);
      } else {
        gemm_bt_k<P_F16_RELU, true, true, true, true, true><<<nF1s, 256, 0, stream>>>(
            xnP, f1 + fd, hP, rows, offs, kFF, kD, kD, (long)kFF * kD,
            1.0f / 64.0f, kSLOTS / 128 / 8, 1, nF1s, 0);
        gemm_bt_k<P_F32, true, false, true, true, true><<<4 * bF2, 256, 0, stream>>>(
            hP, f2 + fd, outs, nullptr, offs, kD, kFF, kFF, (long)kD * kFF,
            1.0f, kSLOTS / 128 / 8, 4, bF2, PLN_OUTS);
        moe4_cast_h_k<<<kBT, 256, 0, stream>>>(x, outs, PLN_OUTS, slotOf, top2w, xnP);
      }
    }
    // lm_head: pre-converted f16 weights, swizzled global_load_lds staging
    gemm_bt_k<P_F32, false, false, true, false, false><<<nLM, 256, 0, stream>>>(
        xnP, lmb, out, nullptr, nullptr, kV, kD, kD, 0, 1.0f, kBT / 128,
        1, nLM, 0);
    aux_reduce3_k<<<1, 256, 0, stream>>>(probs3, PLN_PR, out + (size_t)kBT * kV);
    return;
  }

  // ---------- fallback: f32 path ----------
  off = off_shared;
  float* xnf   = (float*)alloc((size_t)kBT * kD * 4);
  u16*   xnb   = (u16*)  alloc((size_t)kBT * kD * 2);
  float* qkvf32= (float*)alloc((size_t)kBT * 3 * kD * 4);
  float* off32 = (float*)alloc((size_t)kBT * kD * 4);
  float* hbuf  = (float*)alloc((size_t)kSLOTS * kFF * 4);
  u16* hbuf16 = (u16*)hbuf;

  hipMemsetAsync(aux, 0, 4, stream);
  embed_rms_k<<<kBT, 256, 0, stream>>>(idx, wte, wpe, x);
  dim3 gF1s(kSLOTS / 128, kFF / 128);
  dim3 gF2s(kSLOTS / 128, kD / 128);
  for (int li = 0; li < kL; ++li) {
    size_t dd = (size_t)li * kD * kD;
    rmsnorm2_k<<<kBT, 256, 0, stream>>>(x, xnf, xnb);
    dim3 gP(kBT / 128, kD / 128);
    sgemm_bt_k<P_F32, false, false><<<gP, 256, 0, stream>>>(
        xnf, wq + dd, qkvf32, nullptr, nullptr, nullptr, 3 * kD, kD, kD, 0);
    sgemm_bt_k<P_F32, false, false><<<gP, 256, 0, stream>>>(
        xnf, wk + dd, qkvf32 + kD, nullptr, nullptr, nullptr, 3 * kD, kD, kD, 0);
    sgemm_bt_k<P_F32, false, false><<<gP, 256, 0, stream>>>(
        xnf, wv + dd, qkvf32 + 2 * kD, nullptr, nullptr, nullptr, 3 * kD, kD, kD, 0);
    attn_f32_k<<<gAttn, 256, 0, stream>>>(qkvf32, off32, 3 * kD);
    sgemm_bt_k<P_F32_RESID, false, false><<<gP, 256, 0, stream>>>(
        off32, wo + dd, x, x, nullptr, nullptr, kD, kD, kD, 0);
    rmsnorm2_k<<<kBT, 256, 0, stream>>>(x, xnf, xnb);
    hipMemsetAsync(meta, 0, 64, stream);
    gate_topk_k<<<kBT, 256, 0, stream>>>(x, gate + (size_t)li * kE * kD,
                                         probs3, top2e, top2w, counts);
    calc_offsets_k<<<1, 64, 0, stream>>>(counts, offs);
    fill_slots2_k<<<kBT / 256, 256, 0, stream>>>(top2e, counts, offs, cursors,
                                                 rows, slotOf);
    size_t fd = (size_t)li * kE * kFF * kD;
    if (li < 2) {
      sgemm_bt_k<P_F32_RELU, true, true><<<gF1s, 256, 0, stream>>>(
          xnf, f1 + fd, hbuf, nullptr, rows, offs, kFF, kD, kD, (long)kFF * kD);
      sgemm_bt_k<P_F32, false, true><<<gF2s, 256, 0, stream>>>(
          hbuf, f2 + fd, outs, nullptr, nullptr, offs, kD, kFF, kFF, (long)kD * kFF);
    } else {
      gemm_bt_k<P_BF16_RELU, true, true, false, true, false><<<nF1s, 256, 0, stream>>>(
          xnb, f1 + fd, hbuf16, rows, offs, kFF, kD, kD, (long)kFF * kD,
          1.0f, kSLOTS / 128, 1, nF1s, 0);
      gemm_bt_k<P_F32, true, false, false, true, false><<<bF2, 256, 0, stream>>>(
          hbuf16, f2 + fd, outs, nullptr, offs, kD, kFF, kFF, (long)kD * kFF,
          1.0f, kSLOTS / 128, 1, bF2, 0);
    }
    hipMemsetAsync(outs + PLN_OUTS, 0, 3 * PLN_OUTS * 4, stream);
    moe_combine4_k<<<kBT, 256, 0, stream>>>(x, outs, PLN_OUTS, slotOf, top2w);
    aux_reduce_k<<<1, 256, 0, stream>>>(probs3, aux);
  }
  cast_bf16_k<<<2048, 256, 0, stream>>>(x, xnb, (long)kBT * kD / 4);
  gemm_bt_k<P_F32, false, false, false, true, false><<<nLM, 256, 0, stream>>>(
      xnb, lmh, out, nullptr, nullptr, kV, kD, kD, 0, 1.0f, kBT / 128,
      1, nLM, 0);
  write_aux_k<<<1, 64, 0, stream>>>(aux, out + (size_t)kBT * kV);
}

// Round 20
// 1842.345 us; speedup vs baseline: 1.2819x; 1.0332x over previous
//
#include <hip/hip_runtime.h>

typedef unsigned short u16;
typedef __attribute__((ext_vector_type(4))) float f32x4;
typedef __attribute__((ext_vector_type(8))) __bf16 bf16x8;
typedef __attribute__((ext_vector_type(8))) _Float16 f16x8;
typedef __attribute__((ext_vector_type(4))) unsigned short u16x4;
typedef __attribute__((ext_vector_type(8))) unsigned short u16x8;

constexpr int kT = 1024, kD = 1024, kH = 16, kHD = 64, kL = 3, kE = 8;
constexpr int kFF = 4096, kV = 32000, kBT = 2048, kSLOTS = 5120;

__device__ __forceinline__ u16 f2bf(float f) {
  union { float f; unsigned u; } v; v.f = f;
  unsigned r = v.u + 0x7FFFu + ((v.u >> 16) & 1u);   // RNE
  return (u16)(r >> 16);
}
__device__ __forceinline__ u16 f2h(float x) {
  _Float16 h = (_Float16)x;
  union { _Float16 h; u16 u; } v; v.h = h; return v.u;
}
// uniform-scale fp16 split-2: 64*x = hi + mid + O(2^-11 * |64x - hi|)
__device__ __forceinline__ void split2s(float x, u16& h, u16& m) {
  float xs = x * 64.0f;
  _Float16 hh = (_Float16)xs;
  union { _Float16 h; u16 u; } v; v.h = hh; h = v.u;
  float r = xs - (float)hh;
  union { _Float16 h; u16 u; } w; w.h = (_Float16)r; m = w.u;
}

__device__ __forceinline__ void ld_lds16(const void* g, void* l) {
  __builtin_amdgcn_global_load_lds((const __attribute__((address_space(1))) void*)g,
                                   (__attribute__((address_space(3))) void*)l, 16, 0, 0);
}

#define MFMA16(a, b, c) __builtin_amdgcn_mfma_f32_16x16x32_bf16(a, b, c, 0, 0, 0)
#define MFMAH(a, b, c)  __builtin_amdgcn_mfma_f32_16x16x32_f16(a, b, c, 0, 0, 0)

__device__ __forceinline__ float blockReduceSum256(float v) {
  #pragma unroll
  for (int m = 32; m >= 1; m >>= 1) v += __shfl_xor(v, m);
  __shared__ float sh_[4];
  int w = threadIdx.x >> 6;
  if ((threadIdx.x & 63) == 0) sh_[w] = v;
  __syncthreads();
  v = (sh_[0] + sh_[1]) + (sh_[2] + sh_[3]);
  __syncthreads();
  return v;
}

// ---------------- elementwise / small kernels ----------------

__global__ __launch_bounds__(256) void cast_bf16_k(const float* __restrict__ in,
                                                   u16* __restrict__ out, long n4) {
  long i = (long)blockIdx.x * 256 + threadIdx.x;
  long stride = (long)gridDim.x * 256;
  for (; i < n4; i += stride) {
    f32x4 v = ((const f32x4*)in)[i];
    u16x4 o; o[0] = f2bf(v[0]); o[1] = f2bf(v[1]); o[2] = f2bf(v[2]); o[3] = f2bf(v[3]);
    ((u16x4*)out)[i] = o;
  }
}

__global__ __launch_bounds__(256) void cast_h_k(const float* __restrict__ in,
                                                u16* __restrict__ out, long n4) {
  long i = (long)blockIdx.x * 256 + threadIdx.x;
  long stride = (long)gridDim.x * 256;
  for (; i < n4; i += stride) {
    f32x4 v = ((const f32x4*)in)[i];
    u16x4 o; o[0] = f2h(v[0]); o[1] = f2h(v[1]); o[2] = f2h(v[2]); o[3] = f2h(v[3]);
    ((u16x4*)out)[i] = o;
  }
}

// qkv = p0 + p1 -> 2 fp16 planes (x64 scale)
__global__ __launch_bounds__(256) void qkvcomb_k(const float* __restrict__ a,
    const float* __restrict__ b, u16* __restrict__ oP, long plane, long n4) {
  long i = (long)blockIdx.x * 256 + threadIdx.x;
  long stride = (long)gridDim.x * 256;
  for (; i < n4; i += stride) {
    f32x4 v = ((const f32x4*)a)[i] + ((const f32x4*)b)[i];
    u16x4 hh, mm;
    #pragma unroll
    for (int j = 0; j < 4; ++j) {
      u16 h, m; split2s(v[j], h, m);
      hh[j] = h; mm[j] = m;
    }
    ((u16x4*)oP)[i] = hh;
    ((u16x4*)(oP + plane))[i] = mm;
  }
}

__global__ __launch_bounds__(256) void embed_rms_k(const int* __restrict__ idx,
    const float* __restrict__ wte, const float* __restrict__ wpe, float* __restrict__ x) {
  int tok = blockIdx.x, t = threadIdx.x;
  int id = idx[tok];
  int tt = tok & (kT - 1);
  f32x4 a = ((const f32x4*)(wte + (long)id * kD))[t];
  f32x4 p = ((const f32x4*)(wpe + (long)tt * kD))[t];
  f32x4 vv = a + p;
  float ss = vv[0]*vv[0] + vv[1]*vv[1] + vv[2]*vv[2] + vv[3]*vv[3];
  ss = blockReduceSum256(ss);
  float sc = rsqrtf(ss * (1.0f / kD) + 1e-5f);
  vv *= sc;
  ((f32x4*)(x + (long)tok * kD))[t] = vv;
}

// rmsnorm -> f32 + bf16 (fallback path)
__global__ __launch_bounds__(256) void rmsnorm2_k(const float* __restrict__ x,
    float* __restrict__ xnf, u16* __restrict__ xnb) {
  int tok = blockIdx.x, t = threadIdx.x;
  f32x4 vv = ((const f32x4*)(x + (long)tok * kD))[t];
  float ss = blockReduceSum256(vv[0]*vv[0] + vv[1]*vv[1] + vv[2]*vv[2] + vv[3]*vv[3]);
  float sc = rsqrtf(ss * (1.0f / kD) + 1e-5f);
  vv *= sc;
  ((f32x4*)(xnf + (long)tok * kD))[t] = vv;
  u16x4 o;
  o[0] = f2bf(vv[0]); o[1] = f2bf(vv[1]); o[2] = f2bf(vv[2]); o[3] = f2bf(vv[3]);
  ((u16x4*)(xnb + (long)tok * kD))[t] = o;
}

// rmsnorm -> 2 fp16 planes (fast path, x64 scale)
__global__ __launch_bounds__(256) void rmsnorm2h_k(const float* __restrict__ x,
    u16* __restrict__ xnP, long plane) {
  int tok = blockIdx.x, t = threadIdx.x;
  f32x4 vv = ((const f32x4*)(x + (long)tok * kD))[t];
  float ss = blockReduceSum256(vv[0]*vv[0] + vv[1]*vv[1] + vv[2]*vv[2] + vv[3]*vv[3]);
  float sc = rsqrtf(ss * (1.0f / kD) + 1e-5f);
  vv *= sc;
  u16x4 a, b;
  #pragma unroll
  for (int j = 0; j < 4; ++j) {
    u16 h, m; split2s(vv[j], h, m);
    a[j] = h; b[j] = m;
  }
  long o = (long)tok * kD / 4 + t;
  ((u16x4*)xnP)[o] = a;
  ((u16x4*)(xnP + plane))[o] = b;
}

// x += sum of 4 K-partials; write x; rmsnorm -> 2 fp16 planes
__global__ __launch_bounds__(256) void resid4_rms2h_k(float* __restrict__ x,
    const float* __restrict__ parts, long plane, u16* __restrict__ xnP, long xplane) {
  int tok = blockIdx.x, t = threadIdx.x;
  long o = (long)tok * (kD / 4) + t;
  f32x4 xv = ((f32x4*)x)[o];
  #pragma unroll
  for (int p = 0; p < 4; ++p) xv += ((const f32x4*)(parts + p * plane))[o];
  ((f32x4*)x)[o] = xv;
  float ss = blockReduceSum256(xv[0]*xv[0] + xv[1]*xv[1] + xv[2]*xv[2] + xv[3]*xv[3]);
  float sc = rsqrtf(ss * (1.0f / kD) + 1e-5f);
  f32x4 vv = xv * sc;
  u16x4 a, b;
  #pragma unroll
  for (int j = 0; j < 4; ++j) {
    u16 h, m; split2s(vv[j], h, m);
    a[j] = h; b[j] = m;
  }
  ((u16x4*)xnP)[o] = a;
  ((u16x4*)(xnP + xplane))[o] = b;
}

// x += moe combine (4 K-partials, 2 experts); write x; rmsnorm -> 2 fp16 planes
__global__ __launch_bounds__(256) void moe4_rms2h_k(float* __restrict__ x,
    const float* __restrict__ outsP, long plane, const int* __restrict__ slotOf,
    const float* __restrict__ top2w, u16* __restrict__ xnP, long xplane) {
  int tok = blockIdx.x, t = threadIdx.x;
  int s0 = slotOf[tok*2], s1 = slotOf[tok*2+1];
  float w0 = top2w[tok*2], w1 = top2w[tok*2+1];
  f32x4 a = {0.f,0.f,0.f,0.f}, b = a;
  #pragma unroll
  for (int p = 0; p < 4; ++p) {
    a += ((const f32x4*)(outsP + p * plane + (long)s0 * kD))[t];
    b += ((const f32x4*)(outsP + p * plane + (long)s1 * kD))[t];
  }
  long o = (long)tok * (kD / 4) + t;
  f32x4 xv = ((f32x4*)x)[o];
  xv += a * w0 + b * w1;
  ((f32x4*)x)[o] = xv;
  float ss = blockReduceSum256(xv[0]*xv[0] + xv[1]*xv[1] + xv[2]*xv[2] + xv[3]*xv[3]);
  float sc = rsqrtf(ss * (1.0f / kD) + 1e-5f);
  f32x4 vv = xv * sc;
  u16x4 ha, hb;
  #pragma unroll
  for (int j = 0; j < 4; ++j) {
    u16 h, m; split2s(vv[j], h, m);
    ha[j] = h; hb[j] = m;
  }
  ((u16x4*)xnP)[o] = ha;
  ((u16x4*)(xnP + xplane))[o] = hb;
}

// last layer: x += moe combine; write f16 (unscaled) plane for lm_head
__global__ __launch_bounds__(256) void moe4_cast_h_k(float* __restrict__ x,
    const float* __restrict__ outsP, long plane, const int* __restrict__ slotOf,
    const float* __restrict__ top2w, u16* __restrict__ xn) {
  int tok = blockIdx.x, t = threadIdx.x;
  int s0 = slotOf[tok*2], s1 = slotOf[tok*2+1];
  float w0 = top2w[tok*2], w1 = top2w[tok*2+1];
  f32x4 a = {0.f,0.f,0.f,0.f}, b = a;
  #pragma unroll
  for (int p = 0; p < 4; ++p) {
    a += ((const f32x4*)(outsP + p * plane + (long)s0 * kD))[t];
    b += ((const f32x4*)(outsP + p * plane + (long)s1 * kD))[t];
  }
  long o = (long)tok * (kD / 4) + t;
  f32x4 xv = ((f32x4*)x)[o];
  xv += a * w0 + b * w1;
  u16x4 hv;
  #pragma unroll
  for (int j = 0; j < 4; ++j) hv[j] = f2h(xv[j]);
  ((u16x4*)xn)[o] = hv;
}

// gating in f32 (bf16 would flip top-2 selections on near-ties)
__global__ __launch_bounds__(256) void gate_topk_k(const float* __restrict__ x,
    const float* __restrict__ gate_l, float* __restrict__ probs, int* __restrict__ top2e,
    float* __restrict__ top2w, int* __restrict__ counts) {
  int tok = blockIdx.x, t = threadIdx.x;
  f32x4 xv = ((const f32x4*)(x + (long)tok * kD))[t];
  float ss = blockReduceSum256(xv[0]*xv[0] + xv[1]*xv[1] + xv[2]*xv[2] + xv[3]*xv[3]);
  float sc = rsqrtf(ss * (1.0f / kD) + 1e-5f);
  float a[kE];
  #pragma unroll
  for (int e = 0; e < kE; ++e) {
    f32x4 gv = ((const f32x4*)(gate_l + (long)e * kD))[t];
    a[e] = xv[0]*gv[0] + xv[1]*gv[1] + xv[2]*gv[2] + xv[3]*gv[3];
  }
  __shared__ float sh8[kE][4];
  int w = t >> 6, l = t & 63;
  #pragma unroll
  for (int e = 0; e < kE; ++e) {
    float v = a[e];
    #pragma unroll
    for (int m = 32; m >= 1; m >>= 1) v += __shfl_xor(v, m);
    if (l == 0) sh8[e][w] = v;
  }
  __syncthreads();
  if (t == 0) {
    float lg[kE], mx = -1e30f;
    #pragma unroll
    for (int e = 0; e < kE; ++e) {
      lg[e] = (sh8[e][0] + sh8[e][1] + sh8[e][2] + sh8[e][3]) * sc;
      mx = fmaxf(mx, lg[e]);
    }
    float pe[kE], s = 0.f;
    #pragma unroll
    for (int e = 0; e < kE; ++e) { pe[e] = __expf(lg[e] - mx); s += pe[e]; }
    float inv = 1.f / s;
    int i1 = 0;
    #pragma unroll
    for (int e = 1; e < kE; ++e) if (lg[e] > lg[i1]) i1 = e;
    int i2 = (i1 == 0) ? 1 : 0;
    #pragma unroll
    for (int e = 0; e < kE; ++e) if (e != i1 && lg[e] > lg[i2]) i2 = e;
    #pragma unroll
    for (int e = 0; e < kE; ++e) probs[(long)tok * kE + e] = pe[e] * inv;
    float p1 = pe[i1] * inv, p2 = pe[i2] * inv;
    float wn = p1 + p2;
    top2e[tok*2] = i1; top2e[tok*2+1] = i2;
    top2w[tok*2] = p1 / wn; top2w[tok*2+1] = p2 / wn;
    atomicAdd(&counts[i1], 1); atomicAdd(&counts[i2], 1);
  }
}

// 128-aligned expert offsets (fallback path)
__global__ void calc_offsets_k(const int* __restrict__ counts, int* __restrict__ offsets) {
  if (threadIdx.x == 0) {
    int o = 0;
    #pragma unroll
    for (int e = 0; e < kE; ++e) { offsets[e] = o; o += (counts[e] + 127) & ~127; }
    offsets[kE] = o;
  }
}

// offsets computed in-kernel from counts (block 0 publishes); slots filled
__global__ __launch_bounds__(256) void fill_slots2_k(const int* __restrict__ top2e,
    const int* __restrict__ counts, int* __restrict__ offsets, int* __restrict__ cursors,
    int* __restrict__ rows, int* __restrict__ slotOf) {
  __shared__ int soff[kE + 1];
  if (threadIdx.x == 0) {
    int o = 0;
    #pragma unroll
    for (int e = 0; e < kE; ++e) { soff[e] = o; o += (counts[e] + 127) & ~127; }
    soff[kE] = o;
    if (blockIdx.x == 0) {
      #pragma unroll
      for (int e = 0; e <= kE; ++e) offsets[e] = soff[e];
    }
  }
  __syncthreads();
  int tok = blockIdx.x * 256 + threadIdx.x;
  if (tok >= kBT) return;
  #pragma unroll
  for (int j = 0; j < 2; ++j) {
    int e = top2e[tok*2 + j];
    int pos = atomicAdd(&cursors[e], 1);
    int slot = soff[e] + pos;
    rows[slot] = tok;
    slotOf[tok*2 + j] = slot;
  }
}

// fallback combine (4 partials; unused planes zeroed)
__global__ __launch_bounds__(256) void moe_combine4_k(float* __restrict__ x,
    const float* __restrict__ outsP, long plane, const int* __restrict__ slotOf,
    const float* __restrict__ top2w) {
  int tok = blockIdx.x, t = threadIdx.x;
  int s0 = slotOf[tok*2], s1 = slotOf[tok*2+1];
  float w0 = top2w[tok*2], w1 = top2w[tok*2+1];
  f32x4 a = {0.f,0.f,0.f,0.f}, b = a;
  #pragma unroll
  for (int p = 0; p < 4; ++p) {
    a += ((const f32x4*)(outsP + p * plane + (long)s0 * kD))[t];
    b += ((const f32x4*)(outsP + p * plane + (long)s1 * kD))[t];
  }
  f32x4 xv = ((f32x4*)(x + (long)tok * kD))[t];
  xv += a * w0 + b * w1;
  ((f32x4*)(x + (long)tok * kD))[t] = xv;
}

// all-layer aux: out[0] = 0.01/L * sum_l E * sum_e (mean_t probs3[l])^2
__global__ __launch_bounds__(256) void aux_reduce3_k(const float* __restrict__ probs3,
    long plane, float* __restrict__ outv) {
  int t = threadIdx.x;
  float part[kL][kE] = {};
  for (int i = t; i < kBT; i += 256) {
    #pragma unroll
    for (int l = 0; l < kL; ++l)
      #pragma unroll
      for (int e = 0; e < kE; ++e)
        part[l][e] += probs3[l * plane + (long)i * kE + e];
  }
  __shared__ float sh[kL][kE][4];
  int w = t >> 6, ln = t & 63;
  #pragma unroll
  for (int l = 0; l < kL; ++l)
    #pragma unroll
    for (int e = 0; e < kE; ++e) {
      float v = part[l][e];
      #pragma unroll
      for (int m = 32; m >= 1; m >>= 1) v += __shfl_xor(v, m);
      if (ln == 0) sh[l][e][w] = v;
    }
  __syncthreads();
  if (t == 0) {
    float acc = 0.f;
    #pragma unroll
    for (int l = 0; l < kL; ++l)
      #pragma unroll
      for (int e = 0; e < kE; ++e) {
        float frac = (sh[l][e][0] + sh[l][e][1] + sh[l][e][2] + sh[l][e][3]) * (1.0f / kBT);
        acc += frac * frac;
      }
    outv[0] = 0.01f * (float)kE * acc / (float)kL;
  }
}

__global__ __launch_bounds__(256) void aux_reduce_k(const float* __restrict__ probs,
                                                    float* __restrict__ aux) {
  int t = threadIdx.x;
  float part[kE] = {};
  for (int i = t; i < kBT; i += 256) {
    #pragma unroll
    for (int e = 0; e < kE; ++e) part[e] += probs[(long)i * kE + e];
  }
  __shared__ float sh8[kE][4];
  int w = t >> 6, l = t & 63;
  #pragma unroll
  for (int e = 0; e < kE; ++e) {
    float v = part[e];
    #pragma unroll
    for (int m = 32; m >= 1; m >>= 1) v += __shfl_xor(v, m);
    if (l == 0) sh8[e][w] = v;
  }
  __syncthreads();
  if (t == 0) {
    float acc = 0.f;
    #pragma unroll
    for (int e = 0; e < kE; ++e) {
      float frac = (sh8[e][0] + sh8[e][1] + sh8[e][2] + sh8[e][3]) * (1.0f / kBT);
      acc += frac * frac;
    }
    aux[0] += (float)kE * acc;
  }
}

__global__ void write_aux_k(const float* __restrict__ aux, float* __restrict__ out) {
  if (threadIdx.x == 0) out[0] = 0.01f * aux[0] / (float)kL;
}

enum { P_BF16 = 0, P_BF16_RELU = 1, P_F32 = 2, P_F32_RESID = 3, P_F32_RELU = 4,
       P_SPLIT2_RELU = 5, P_F16_RELU = 6 };

__device__ __forceinline__ int clamp_row(int rv) {
  return ((unsigned)rv < (unsigned)kBT) ? rv : 0;
}

template <bool MPART>
__device__ __forceinline__ void block_mn(int lin, int base, int mArg, int& mb, int& nb) {
  int xcd = lin & 7, c = lin >> 3;
  if (MPART) {
    mb = xcd * mArg + (c % mArg);
    nb = c / mArg;
  } else {
    int swz = xcd * (base >> 3) + c;
    mb = swz % mArg;
    nb = swz / mArg;
  }
}

// ------- fused fp16 split-2 MFMA GEMM (128x128, 256 thr), single accumulator -------
// BF32: B is f32; staged via registers (one k-step prefetch) + split2s + swizzled
// ds_write. QKV3: three f32 B tensors (wq/wk/wv) selected by n0>>10 — replaces the
// pre-converted concatenated plane with direct in-staging conversion.

template <int POST, bool GATHER, bool EXPERT, bool MPART, bool BF32, bool QKV3 = false>
__global__ __launch_bounds__(256) void gemm2h_bt_k(
    const u16* __restrict__ A0, long planeA,
    const void* __restrict__ Bv, const void* __restrict__ Bv1, const void* __restrict__ Bv2,
    long planeB,
    void* __restrict__ C, long planeC,
    const float* __restrict__ resid,
    const int* __restrict__ rows, const int* __restrict__ offsets,
    int N, int K, int lda, long eBstride, int mArg,
    int kParts, int base, long cPart) {
  constexpr int BM = 128, BK = 32;
  int part = blockIdx.x / base;
  int lin = blockIdx.x % base;
  int mb, nb;
  block_mn<MPART>(lin, base, mArg, mb, nb);
  int m0 = mb * BM, n0 = nb * BM;
  const u16* B0 = (const u16*)Bv;
  const float* Bf = (const float*)Bv;
  if (EXPERT) {
    int total = offsets[kE];
    if (m0 >= total) return;
    int e = 0;
    while (offsets[e + 1] <= m0) ++e;
    if (BF32) Bf += (long)e * eBstride; else B0 += (long)e * eBstride;
  }
  __shared__ __align__(16) u16 Ac[BM][64];
  __shared__ __align__(16) u16 Bc[BM][64];
  int t = threadIdx.x;
  int l = t & 63, lr = l & 15, lg = l >> 4;
  int wid = t >> 6;
  int wm = (wid >> 1) * 64, wn = (wid & 1) * 64;

  long asrc[4], bsrc[4];
  int ldst[4];
  #pragma unroll
  for (int it = 0; it < 4; ++it) {
    int d = it * 256 + t;
    int row = d >> 3, pc = d & 7;
    int lc = pc ^ (row & 7);
    int p = lc >> 2, c = lc & 3;
    int grow = GATHER ? clamp_row(rows[m0 + row]) : (m0 + row);
    asrc[it] = (long)p * planeA + (long)grow * lda + c * 8;
    if (!BF32) bsrc[it] = (long)p * planeB + (long)(n0 + row) * K + c * 8;
    ldst[it] = (it * 256 + (t & ~63)) * 8;
  }
  long bsrcF[2];
  int brow[2], bc[2];
  if (BF32) {
    if (QKV3) {
      int ts = n0 >> 10;
      Bf = (ts == 0) ? (const float*)Bv : (ts == 1) ? (const float*)Bv1
                                                    : (const float*)Bv2;
    }
    int nB = QKV3 ? (n0 & 1023) : n0;
    #pragma unroll
    for (int it = 0; it < 2; ++it) {
      int d = it * 256 + t;
      brow[it] = d >> 2; bc[it] = d & 3;
      bsrcF[it] = (long)(nB + brow[it]) * K + bc[it] * 8;
    }
  }
  int sa = lr & 7;
  int cH = (lg ^ sa) * 8;
  int cM = ((4 + lg) ^ sa) * 8;

  f32x4 acc[4][4];
  #pragma unroll
  for (int i = 0; i < 4; ++i)
    #pragma unroll
    for (int j = 0; j < 4; ++j) acc[i][j] = 0.f;

  int kStep = K / kParts;
  int kLo = part * kStep, kHi = kLo + kStep;

  f32x4 pv0[2], pv1[2];
  if (BF32) {
    #pragma unroll
    for (int it = 0; it < 2; ++it) {
      const float* src = Bf + bsrcF[it] + kLo;
      pv0[it] = *(const f32x4*)src;
      pv1[it] = *(const f32x4*)(src + 4);
    }
  }
  for (int k0 = kLo; k0 < kHi; k0 += BK) {
    bool pf = BF32 && (k0 + BK < kHi);
    #pragma unroll
    for (int it = 0; it < 4; ++it) {
      ld_lds16(A0 + asrc[it] + k0, &Ac[0][0] + ldst[it]);
      if (!BF32) ld_lds16(B0 + bsrc[it] + k0, &Bc[0][0] + ldst[it]);
    }
    f32x4 nv0[2], nv1[2];
    if (pf) {
      #pragma unroll
      for (int it = 0; it < 2; ++it) {
        const float* src = Bf + bsrcF[it] + k0 + BK;
        nv0[it] = *(const f32x4*)src;
        nv1[it] = *(const f32x4*)(src + 4);
      }
    }
    if (BF32) {
      #pragma unroll
      for (int it = 0; it < 2; ++it) {
        u16x8 hi, mi;
        #pragma unroll
        for (int j = 0; j < 4; ++j) {
          u16 h, m; split2s(pv0[it][j], h, m); hi[j] = h; mi[j] = m;
        }
        #pragma unroll
        for (int j = 0; j < 4; ++j) {
          u16 h, m; split2s(pv1[it][j], h, m); hi[4 + j] = h; mi[4 + j] = m;
        }
        int r7 = brow[it] & 7;
        *(u16x8*)&Bc[brow[it]][(bc[it] ^ r7) * 8] = hi;
        *(u16x8*)&Bc[brow[it]][((4 + bc[it]) ^ r7) * 8] = mi;
      }
    }
    __syncthreads();
    f16x8 ah[4], am[4];
    #pragma unroll
    for (int i = 0; i < 4; ++i) {
      ah[i] = *(const f16x8*)&Ac[wm + i*16 + lr][cH];
      am[i] = *(const f16x8*)&Ac[wm + i*16 + lr][cM];
    }
    __builtin_amdgcn_s_setprio(1);
    #pragma unroll
    for (int j = 0; j < 4; ++j) {
      f16x8 bh = *(const f16x8*)&Bc[wn + j*16 + lr][cH];
      f16x8 bm = *(const f16x8*)&Bc[wn + j*16 + lr][cM];
      #pragma unroll
      for (int i = 0; i < 4; ++i) {
        acc[i][j] = MFMAH(ah[i], bh, acc[i][j]);
        acc[i][j] = MFMAH(am[i], bh, acc[i][j]);
        acc[i][j] = MFMAH(ah[i], bm, acc[i][j]);
      }
    }
    __builtin_amdgcn_s_setprio(0);
    __syncthreads();
    if (pf) {
      #pragma unroll
      for (int it = 0; it < 2; ++it) { pv0[it] = nv0[it]; pv1[it] = nv1[it]; }
    }
  }
  float* Cf = (float*)C + (long)part * cPart;
  #pragma unroll
  for (int i = 0; i < 4; ++i) {
    #pragma unroll
    for (int r = 0; r < 4; ++r) {
      long m = m0 + wm + i*16 + lg*4 + r;
      #pragma unroll
      for (int j = 0; j < 4; ++j) {
        int n = n0 + wn + j*16 + lr;
        float val = acc[i][j][r] * (1.0f / 4096.0f);
        if (POST == P_F32) {
          Cf[m * N + n] = val;
        } else if (POST == P_F32_RESID) {
          ((float*)C)[m * N + n] = val + resid[m * N + n];
        } else if (POST == P_SPLIT2_RELU) {
          val = fmaxf(val, 0.f);
          u16 h, mm; split2s(val, h, mm);
          u16* Cp = (u16*)C;
          Cp[m * N + n] = h;
          Cp[planeC + m * N + n] = mm;
        }
      }
    }
  }
}

// ------- wide fused fp16 split-2 GEMM: 128x256 tile, 512 threads, 2m x 4n waves -------

template <int POST, bool GATHER, bool EXPERT, bool BF32>
__global__ __launch_bounds__(512) void gemm2hW_bt_k(
    const u16* __restrict__ A0, long planeA,
    const void* __restrict__ Bv, long planeB,
    void* __restrict__ C, long planeC,
    const int* __restrict__ rows, const int* __restrict__ offsets,
    int N, int K, int lda, long eBstride, int mPerX,
    int kParts, int base, long cPart) {
  constexpr int BM = 128, BN = 256, BK = 32;
  int part = blockIdx.x / base;
  int lin = blockIdx.x % base;
  int xcd = lin & 7, c0 = lin >> 3;
  int m0 = (xcd * mPerX + (c0 % mPerX)) * BM;
  int n0 = (c0 / mPerX) * BN;
  const u16* B0 = (const u16*)Bv;
  const float* Bf = (const float*)Bv;
  if (EXPERT) {
    int total = offsets[kE];
    if (m0 >= total) return;
    int e = 0;
    while (offsets[e + 1] <= m0) ++e;
    if (BF32) Bf += (long)e * eBstride; else B0 += (long)e * eBstride;
  }
  __shared__ __align__(16) u16 Ac[BM][64];
  __shared__ __align__(16) u16 Bc[BN][64];
  int t = threadIdx.x;
  int l = t & 63, lr = l & 15, lg = l >> 4;
  int wid = t >> 6;
  int wm = (wid >> 2) * 64;
  int wn = (wid & 3) * 64;

  long asrc[2], bsrc[4];
  int aldst[2], bldst[4];
  #pragma unroll
  for (int it = 0; it < 2; ++it) {
    int d = it * 512 + t;
    int row = d >> 3, pc = d & 7;
    int lc = pc ^ (row & 7);
    int p = lc >> 2, cc = lc & 3;
    int grow = GATHER ? clamp_row(rows[m0 + row]) : (m0 + row);
    asrc[it] = (long)p * planeA + (long)grow * lda + cc * 8;
    aldst[it] = (it * 512 + (t & ~63)) * 8;
  }
  long bsrcF[2];
  int brow[2], bcc[2];
  if (!BF32) {
    #pragma unroll
    for (int it = 0; it < 4; ++it) {
      int d = it * 512 + t;
      int row = d >> 3, pc = d & 7;
      int lc = pc ^ (row & 7);
      int p = lc >> 2, cc = lc & 3;
      bsrc[it] = (long)p * planeB + (long)(n0 + row) * K + cc * 8;
      bldst[it] = (it * 512 + (t & ~63)) * 8;
    }
  } else {
    #pragma unroll
    for (int it = 0; it < 2; ++it) {
      int d = it * 512 + t;
      brow[it] = d >> 2; bcc[it] = d & 3;
      bsrcF[it] = (long)(n0 + brow[it]) * K + bcc[it] * 8;
    }
  }
  int sa = lr & 7;
  int cH = (lg ^ sa) * 8;
  int cM = ((4 + lg) ^ sa) * 8;

  f32x4 acc[4][4];
  #pragma unroll
  for (int i = 0; i < 4; ++i)
    #pragma unroll
    for (int j = 0; j < 4; ++j) acc[i][j] = 0.f;

  int kStep = K / kParts;
  int kLo = part * kStep, kHi = kLo + kStep;

  f32x4 pv0[2], pv1[2];
  if (BF32) {
    #pragma unroll
    for (int it = 0; it < 2; ++it) {
      const float* src = Bf + bsrcF[it] + kLo;
      pv0[it] = *(const f32x4*)src;
      pv1[it] = *(const f32x4*)(src + 4);
    }
  }
  for (int k0 = kLo; k0 < kHi; k0 += BK) {
    bool pf = BF32 && (k0 + BK < kHi);
    #pragma unroll
    for (int it = 0; it < 2; ++it)
      ld_lds16(A0 + asrc[it] + k0, &Ac[0][0] + aldst[it]);
    if (!BF32) {
      #pragma unroll
      for (int it = 0; it < 4; ++it)
        ld_lds16(B0 + bsrc[it] + k0, &Bc[0][0] + bldst[it]);
    }
    f32x4 nv0[2], nv1[2];
    if (pf) {
      #pragma unroll
      for (int it = 0; it < 2; ++it) {
        const float* src = Bf + bsrcF[it] + k0 + BK;
        nv0[it] = *(const f32x4*)src;
        nv1[it] = *(const f32x4*)(src + 4);
      }
    }
    if (BF32) {
      #pragma unroll
      for (int it = 0; it < 2; ++it) {
        u16x8 hi, mi;
        #pragma unroll
        for (int j = 0; j < 4; ++j) {
          u16 h, m; split2s(pv0[it][j], h, m); hi[j] = h; mi[j] = m;
        }
        #pragma unroll
        for (int j = 0; j < 4; ++j) {
          u16 h, m; split2s(pv1[it][j], h, m); hi[4 + j] = h; mi[4 + j] = m;
        }
        int r7 = brow[it] & 7;
        *(u16x8*)&Bc[brow[it]][(bcc[it] ^ r7) * 8] = hi;
        *(u16x8*)&Bc[brow[it]][((4 + bcc[it]) ^ r7) * 8] = mi;
      }
    }
    __syncthreads();
    f16x8 ah[4], am[4];
    #pragma unroll
    for (int i = 0; i < 4; ++i) {
      ah[i] = *(const f16x8*)&Ac[wm + i*16 + lr][cH];
      am[i] = *(const f16x8*)&Ac[wm + i*16 + lr][cM];
    }
    __builtin_amdgcn_s_setprio(1);
    #pragma unroll
    for (int j = 0; j < 4; ++j) {
      f16x8 bh = *(const f16x8*)&Bc[wn + j*16 + lr][cH];
      f16x8 bm = *(const f16x8*)&Bc[wn + j*16 + lr][cM];
      #pragma unroll
      for (int i = 0; i < 4; ++i) {
        acc[i][j] = MFMAH(ah[i], bh, acc[i][j]);
        acc[i][j] = MFMAH(am[i], bh, acc[i][j]);
        acc[i][j] = MFMAH(ah[i], bm, acc[i][j]);
      }
    }
    __builtin_amdgcn_s_setprio(0);
    __syncthreads();
    if (pf) {
      #pragma unroll
      for (int it = 0; it < 2; ++it) { pv0[it] = nv0[it]; pv1[it] = nv1[it]; }
    }
  }
  float* Cf = (float*)C + (long)part * cPart;
  #pragma unroll
  for (int i = 0; i < 4; ++i) {
    #pragma unroll
    for (int r = 0; r < 4; ++r) {
      long m = m0 + wm + i*16 + lg*4 + r;
      #pragma unroll
      for (int j = 0; j < 4; ++j) {
        int n = n0 + wn + j*16 + lr;
        float val = acc[i][j][r] * (1.0f / 4096.0f);
        if (POST == P_F32) {
          Cf[m * N + n] = val;
        } else if (POST == P_SPLIT2_RELU) {
          val = fmaxf(val, 0.f);
          u16 h, mm; split2s(val, h, mm);
          u16* Cp = (u16*)C;
          Cp[m * N + n] = h;
          Cp[planeC + m * N + n] = mm;
        }
      }
    }
  }
}

// ---------------- single-plane MFMA GEMM (with optional split-K) ----------------

template <int POST, bool EXPERT, bool GATHER, bool HALF, bool BCONV, bool MPART>
__global__ __launch_bounds__(256) void gemm_bt_k(
    const u16* __restrict__ A, const void* __restrict__ Bv, void* __restrict__ C,
    const int* __restrict__ rows, const int* __restrict__ offsets,
    int N, int K, int lda, long eBstride, float oscale, int mArg,
    int kParts, int base, long cPart) {
  constexpr int BM = 128, BK = 64;
  int part = blockIdx.x / base;
  int lin = blockIdx.x % base;
  int mb, nb;
  block_mn<MPART>(lin, base, mArg, mb, nb);
  int m0 = mb * BM, n0 = nb * BM;
  const float* Bf = (const float*)Bv;
  const u16*   Bh = (const u16*)Bv;
  if (EXPERT) {
    int total = offsets[kE];
    if (m0 >= total) return;
    int e = 0;
    while (offsets[e + 1] <= m0) ++e;
    if (BCONV) Bf += (long)e * eBstride; else Bh += (long)e * eBstride;
  }
  __shared__ __align__(16) u16 As[BM][BK];
  __shared__ __align__(16) u16 Bs[BM][BK];
  int t = threadIdx.x;
  int l = t & 63, lr = l & 15, lg = l >> 4;
  int wid = t >> 6;
  int wm = (wid >> 1) * 64, wn = (wid & 1) * 64;

  long asrc[4], bsrc[4];
  int ldst[4];
  #pragma unroll
  for (int it = 0; it < 4; ++it) {
    int d = it * 256 + t;
    int row = d >> 3, pc = d & 7;
    int c = pc ^ (row & 7);
    int grow = GATHER ? clamp_row(rows[m0 + row]) : (m0 + row);
    asrc[it] = (long)grow * lda + c * 8;
    if (!BCONV) bsrc[it] = (long)(n0 + row) * K + c * 8;
    ldst[it] = (it * 256 + (t & ~63)) * 8;
  }
  long bsrcC[4];
  int bdst[4];
  if (BCONV) {
    #pragma unroll
    for (int it = 0; it < 4; ++it) {
      int d = it * 256 + t;
      int row = d >> 3, lc = d & 7;
      bsrcC[it] = (long)(n0 + row) * K + lc * 8;
      bdst[it] = row * BK + (lc ^ (row & 7)) * 8;
    }
  }
  f32x4 acc[4][4];
  #pragma unroll
  for (int i = 0; i < 4; ++i)
    #pragma unroll
    for (int j = 0; j < 4; ++j) acc[i][j] = 0.f;

  int kStep = K / kParts;
  int kLo = part * kStep, kHi = kLo + kStep;
  for (int k0 = kLo; k0 < kHi; k0 += BK) {
    #pragma unroll
    for (int it = 0; it < 4; ++it)
      ld_lds16(A + asrc[it] + k0, &As[0][0] + ldst[it]);
    if (!BCONV) {
      #pragma unroll
      for (int it = 0; it < 4; ++it)
        ld_lds16(Bh + bsrc[it] + k0, &Bs[0][0] + ldst[it]);
    } else {
      #pragma unroll
      for (int it = 0; it < 4; ++it) {
        const float* src = Bf + bsrcC[it] + k0;
        f32x4 v0 = *(const f32x4*)src;
        f32x4 v1 = *(const f32x4*)(src + 4);
        u16x8 o;
        #pragma unroll
        for (int j = 0; j < 4; ++j) {
          o[j] = HALF ? f2h(v0[j]) : f2bf(v0[j]);
          o[4 + j] = HALF ? f2h(v1[j]) : f2bf(v1[j]);
        }
        *(u16x8*)(&Bs[0][0] + bdst[it]) = o;
      }
    }
    __syncthreads();
    __builtin_amdgcn_s_setprio(1);
    #pragma unroll
    for (int kk = 0; kk < 2; ++kk) {
      int ca = ((kk * 4 + lg) ^ (lr & 7)) * 8;
      #pragma unroll
      for (int i = 0; i < 4; ++i)
        #pragma unroll
        for (int j = 0; j < 4; ++j) {
          if (HALF) {
            f16x8 af = *(const f16x8*)&As[wm + i*16 + lr][ca];
            f16x8 bq = *(const f16x8*)&Bs[wn + j*16 + lr][ca];
            acc[i][j] = MFMAH(af, bq, acc[i][j]);
          } else {
            bf16x8 af = *(const bf16x8*)&As[wm + i*16 + lr][ca];
            bf16x8 bq = *(const bf16x8*)&Bs[wn + j*16 + lr][ca];
            acc[i][j] = MFMA16(af, bq, acc[i][j]);
          }
        }
    }
    __builtin_amdgcn_s_setprio(0);
    __syncthreads();
  }
  #pragma unroll
  for (int i = 0; i < 4; ++i) {
    #pragma unroll
    for (int r = 0; r < 4; ++r) {
      long m = m0 + wm + i*16 + lg*4 + r;
      #pragma unroll
      for (int j = 0; j < 4; ++j) {
        int n = n0 + wn + j*16 + lr;
        float val = acc[i][j][r] * oscale;
        if (POST == P_BF16_RELU)       ((u16*)C)[m * N + n] = f2bf(fmaxf(val, 0.f));
        else if (POST == P_F16_RELU)   ((u16*)C)[m * N + n] = f2h(fmaxf(val, 0.f));
        else if (POST == P_F32)        ((float*)C + (long)part * cPart)[m * N + n] = val;
      }
    }
  }
}

// ---------------- f32 SGEMM (fallback path only) ----------------

template <int POST, bool GATHER, bool EXPERT>
__global__ __launch_bounds__(256) void sgemm_bt_k(
    const float* __restrict__ A, const float* __restrict__ B, float* __restrict__ C,
    const float* __restrict__ resid, const int* __restrict__ rows,
    const int* __restrict__ offsets, int N, int K, int lda, long eBstride) {
  constexpr int BM = 128, BN = 128, BK = 32;
  int m0 = blockIdx.x * BM, n0 = blockIdx.y * BN;
  if (EXPERT) {
    int total = offsets[kE];
    if (m0 >= total) return;
    int e = 0;
    while (offsets[e + 1] <= m0) ++e;
    B += (long)e * eBstride;
  }
  __shared__ float Ast[BK][BM];
  __shared__ float Bst[BK][BN];
  int t = threadIdx.x, tx = t & 15, ty = t >> 4;
  long asrc[4], bsrc[4];
  #pragma unroll
  for (int it = 0; it < 4; ++it) {
    int c = it * 256 + t;
    int row = c >> 3, kc = (c & 7) * 4;
    int gr = GATHER ? clamp_row(rows[m0 + row]) : (m0 + row);
    asrc[it] = (long)gr * lda + kc;
    bsrc[it] = (long)(n0 + row) * K + kc;
  }
  f32x4 accv[8][2];
  #pragma unroll
  for (int i = 0; i < 8; ++i) { accv[i][0] = 0.f; accv[i][1] = 0.f; }

  for (int k0 = 0; k0 < K; k0 += BK) {
    #pragma unroll
    for (int it = 0; it < 4; ++it) {
      int c = it * 256 + t;
      int row = c >> 3, kc = (c & 7) * 4;
      f32x4 av = *(const f32x4*)(A + asrc[it] + k0);
      f32x4 bv = *(const f32x4*)(B + bsrc[it] + k0);
      #pragma unroll
      for (int j = 0; j < 4; ++j) { Ast[kc + j][row] = av[j]; Bst[kc + j][row] = bv[j]; }
    }
    __syncthreads();
    #pragma unroll
    for (int kk = 0; kk < BK; ++kk) {
      f32x4 a0 = *(const f32x4*)&Ast[kk][ty * 4];
      f32x4 a1 = *(const f32x4*)&Ast[kk][64 + ty * 4];
      f32x4 b0 = *(const f32x4*)&Bst[kk][tx * 4];
      f32x4 b1 = *(const f32x4*)&Bst[kk][64 + tx * 4];
      float as[8] = {a0[0], a0[1], a0[2], a0[3], a1[0], a1[1], a1[2], a1[3]};
      #pragma unroll
      for (int i = 0; i < 8; ++i) {
        accv[i][0] += b0 * as[i];
        accv[i][1] += b1 * as[i];
      }
    }
    __syncthreads();
  }
  #pragma unroll
  for (int ih = 0; ih < 2; ++ih)
    #pragma unroll
    for (int i = 0; i < 4; ++i) {
      long m = m0 + ih * 64 + ty * 4 + i;
      #pragma unroll
      for (int jh = 0; jh < 2; ++jh) {
        long n = n0 + jh * 64 + tx * 4;
        f32x4 val = accv[ih * 4 + i][jh];
        if (POST == P_F32_RELU) {
          #pragma unroll
          for (int j = 0; j < 4; ++j) val[j] = fmaxf(val[j], 0.f);
        }
        if (POST == P_F32_RESID) val += *(const f32x4*)&resid[m * N + n];
        *(f32x4*)&C[m * N + n] = val;
      }
    }
}

// ------- MFMA split-2 attention (f32-equivalent accuracy) -------

__global__ __launch_bounds__(256) void attn2h_k(
    const u16* __restrict__ qkvP, long qplane,
    u16* __restrict__ oP, long oplane) {
  int qt = (int)gridDim.x - 1 - (int)blockIdx.x;   // heavy first
  int bh = blockIdx.y;
  int b = bh >> 4, h = bh & 15;
  const int ldq = 3 * kD;
  long hbq = (long)b * kT * ldq + h * kHD;
  long hbo = (long)b * kT * kD + h * kHD;
  int t = threadIdx.x, w = t >> 6, l = t & 63;
  int lr = l & 15, lg = l >> 4;

  __shared__ __align__(16) u16 Ks[2][64][72];
  __shared__ __align__(16) u16 Vt[2][64][72];
  __shared__ __align__(16) u16 Ps[2][4][16][72];

  f16x8 qf0[2], qf1[2];
  {
    long qrow = qt * 64 + w * 16 + lr;
    const u16* qp = qkvP + hbq + qrow * ldq;
    #pragma unroll
    for (int kc = 0; kc < 2; ++kc) {
      qf0[kc] = *(const f16x8*)(qp + kc * 32 + lg * 8);
      qf1[kc] = *(const f16x8*)(qp + qplane + kc * 32 + lg * 8);
    }
  }
  int qg = qt * 64 + w * 16 + lg * 4;

  float mrow[4], lsum[4];
  f32x4 accO[4];
  #pragma unroll
  for (int r = 0; r < 4; ++r) { mrow[r] = -1e30f; lsum[r] = 0.f; }
  #pragma unroll
  for (int j = 0; j < 4; ++j) accO[j] = 0.f;

  for (int it = 0; it <= qt; ++it) {
    #pragma unroll
    for (int p = 0; p < 2; ++p) {
      #pragma unroll
      for (int s = 0; s < 2; ++s) {
        int c = s * 256 + t;
        int row = c >> 3, col = (c & 7) * 8;
        long gi = (long)p * qplane + hbq + (long)(it * 64 + row) * ldq + col;
        *(u16x8*)&Ks[p][row][col] = *(const u16x8*)(qkvP + kD + gi);
        u16x8 vv = *(const u16x8*)(qkvP + 2 * kD + gi);
        #pragma unroll
        for (int j = 0; j < 8; ++j) Vt[p][col + j][row] = vv[j];
      }
    }
    __syncthreads();

    f32x4 s4[4];
    __builtin_amdgcn_s_setprio(1);
    #pragma unroll
    for (int j = 0; j < 4; ++j) {
      f32x4 z = {0.f, 0.f, 0.f, 0.f};
      #pragma unroll
      for (int kc = 0; kc < 2; ++kc) {
        f16x8 kh = *(const f16x8*)&Ks[0][j*16 + lr][kc*32 + lg*8];
        f16x8 km = *(const f16x8*)&Ks[1][j*16 + lr][kc*32 + lg*8];
        z = MFMAH(qf0[kc], kh, z);
        z = MFMAH(qf1[kc], kh, z);
        z = MFMAH(qf0[kc], km, z);
      }
      s4[j] = z;
    }
    __builtin_amdgcn_s_setprio(0);
    #pragma unroll
    for (int j = 0; j < 4; ++j)
      #pragma unroll
      for (int r = 0; r < 4; ++r) {
        float sv = s4[j][r] * (0.125f / 4096.0f);
        if (it * 64 + j * 16 + lr > qg + r) sv = -1e30f;
        s4[j][r] = sv;
      }
    float alpha[4];
    #pragma unroll
    for (int r = 0; r < 4; ++r) {
      float mx = fmaxf(fmaxf(s4[0][r], s4[1][r]), fmaxf(s4[2][r], s4[3][r]));
      mx = fmaxf(mx, __shfl_xor(mx, 1));
      mx = fmaxf(mx, __shfl_xor(mx, 2));
      mx = fmaxf(mx, __shfl_xor(mx, 4));
      mx = fmaxf(mx, __shfl_xor(mx, 8));
      float mi = fmaxf(mrow[r], mx);
      alpha[r] = __expf(mrow[r] - mi);
      mrow[r] = mi;
    }
    float rs[4] = {0.f, 0.f, 0.f, 0.f};
    #pragma unroll
    for (int j = 0; j < 4; ++j)
      #pragma unroll
      for (int r = 0; r < 4; ++r) {
        float p = __expf(s4[j][r] - mrow[r]);
        rs[r] += p;
        u16 hh, mm; split2s(p, hh, mm);
        Ps[0][w][lg*4 + r][j*16 + lr] = hh;
        Ps[1][w][lg*4 + r][j*16 + lr] = mm;
      }
    #pragma unroll
    for (int r = 0; r < 4; ++r) {
      float x2 = rs[r];
      x2 += __shfl_xor(x2, 1);
      x2 += __shfl_xor(x2, 2);
      x2 += __shfl_xor(x2, 4);
      x2 += __shfl_xor(x2, 8);
      lsum[r] = lsum[r] * alpha[r] + x2;
    }
    #pragma unroll
    for (int j = 0; j < 4; ++j)
      #pragma unroll
      for (int r = 0; r < 4; ++r) accO[j][r] *= alpha[r];
    __syncthreads();

    f16x8 ph[2], pm[2];
    #pragma unroll
    for (int kc = 0; kc < 2; ++kc) {
      ph[kc] = *(const f16x8*)&Ps[0][w][lr][kc*32 + lg*8];
      pm[kc] = *(const f16x8*)&Ps[1][w][lr][kc*32 + lg*8];
    }
    __builtin_amdgcn_s_setprio(1);
    #pragma unroll
    for (int j2 = 0; j2 < 4; ++j2) {
      #pragma unroll
      for (int kc = 0; kc < 2; ++kc) {
        f16x8 vh = *(const f16x8*)&Vt[0][j2*16 + lr][kc*32 + lg*8];
        f16x8 vm = *(const f16x8*)&Vt[1][j2*16 + lr][kc*32 + lg*8];
        accO[j2] = MFMAH(ph[kc], vh, accO[j2]);
        accO[j2] = MFMAH(pm[kc], vh, accO[j2]);
        accO[j2] = MFMAH(ph[kc], vm, accO[j2]);
      }
    }
    __builtin_amdgcn_s_setprio(0);
    __syncthreads();
  }
  #pragma unroll
  for (int j2 = 0; j2 < 4; ++j2)
    #pragma unroll
    for (int r = 0; r < 4; ++r) {
      float ov = accO[j2][r] * (1.0f / 4096.0f) / lsum[r];
      long row = qt * 64 + w * 16 + lg * 4 + r;
      long idx = hbo + row * kD + j2 * 16 + lr;
      u16 hh, mm; split2s(ov, hh, mm);
      oP[idx] = hh;
      oP[oplane + idx] = mm;
    }
}

// ---------------- f32 attention (fallback path) ----------------

__global__ __launch_bounds__(256) void attn_f32_k(
    const float* __restrict__ qkv, float* __restrict__ of32, int ldq) {
  int qt = blockIdx.x;
  int bh = blockIdx.y;
  int b = bh >> 4, h = bh & 15;
  long hbq = (long)b * kT * ldq + h * kHD;
  long hbo = (long)b * kT * kD + h * kHD;
  int t = threadIdx.x, qr = t >> 2, sub = t & 3;

  __shared__ float Qs[64][68], Ks[64][68], Vs[64][68], Ps[64][68];

  const float* q = qkv;
  const float* k = qkv + kD;
  const float* v = qkv + 2 * kD;

  #pragma unroll
  for (int it = 0; it < 4; ++it) {
    int c = it * 256 + t, row = c >> 4, c4 = (c & 15) * 4;
    f32x4 qv = *(const f32x4*)(q + hbq + (long)(qt * 64 + row) * ldq + c4);
    #pragma unroll
    for (int j = 0; j < 4; ++j) Qs[row][c4 + j] = qv[j];
  }
  __syncthreads();
  f32x4 qreg[16];
  #pragma unroll
  for (int d4 = 0; d4 < 16; ++d4) qreg[d4] = *(const f32x4*)&Qs[qr][d4 * 4];
  int qg = qt * 64 + qr;

  float mrow = -1e30f, lsum = 0.f;
  f32x4 accO[4];
  #pragma unroll
  for (int i = 0; i < 4; ++i) accO[i] = 0.f;

  for (int itl = 0; itl <= qt; ++itl) {
    #pragma unroll
    for (int it = 0; it < 4; ++it) {
      int c = it * 256 + t, row = c >> 4, c4 = (c & 15) * 4;
      long gi = hbq + (long)(itl * 64 + row) * ldq + c4;
      f32x4 kv = *(const f32x4*)(k + gi);
      f32x4 vv = *(const f32x4*)(v + gi);
      #pragma unroll
      for (int j = 0; j < 4; ++j) { Ks[row][c4 + j] = kv[j]; Vs[row][c4 + j] = vv[j]; }
    }
    __syncthreads();

    float s[16];
    #pragma unroll
    for (int kk = 0; kk < 16; ++kk) {
      int key = kk * 4 + sub;
      f32x4 a = {0.f, 0.f, 0.f, 0.f};
      #pragma unroll
      for (int d4 = 0; d4 < 16; ++d4) a += qreg[d4] * *(const f32x4*)&Ks[key][d4 * 4];
      float sv = (a[0] + a[1] + a[2] + a[3]) * 0.125f;
      if (itl * 64 + key > qg) sv = -1e30f;
      s[kk] = sv;
    }
    float mx = s[0];
    #pragma unroll
    for (int kk = 1; kk < 16; ++kk) mx = fmaxf(mx, s[kk]);
    mx = fmaxf(mx, __shfl_xor(mx, 1));
    mx = fmaxf(mx, __shfl_xor(mx, 2));
    float mi = fmaxf(mrow, mx);
    float alpha = __expf(mrow - mi);
    mrow = mi;
    float rs = 0.f;
    #pragma unroll
    for (int kk = 0; kk < 16; ++kk) {
      float p = __expf(s[kk] - mi);
      rs += p;
      Ps[qr][kk * 4 + sub] = p;
    }
    rs += __shfl_xor(rs, 1);
    rs += __shfl_xor(rs, 2);
    lsum = lsum * alpha + rs;
    #pragma unroll
    for (int i = 0; i < 4; ++i) accO[i] *= alpha;
    #pragma unroll
    for (int key2 = 0; key2 < 64; ++key2) {
      float p = Ps[qr][key2];
      #pragma unroll
      for (int i4 = 0; i4 < 4; ++i4)
        accO[i4] += p * *(const f32x4*)&Vs[key2][sub * 16 + i4 * 4];
    }
    __syncthreads();
  }
  float inv = 1.f / lsum;
  #pragma unroll
  for (int i4 = 0; i4 < 4; ++i4) {
    f32x4 ov = accO[i4] * inv;
    *(f32x4*)(of32 + hbo + (long)qg * kD + sub * 16 + i4 * 4) = ov;
  }
}

// ---------------- host ----------------

extern "C" void kernel_launch(void* const* d_in, const int* in_sizes, int n_in,
                              void* d_out, int out_size, void* d_ws, size_t ws_size,
                              hipStream_t stream) {
  const int*   idx  = (const int*)  d_in[0];
  const float* wte  = (const float*)d_in[1];
  const float* wpe  = (const float*)d_in[2];
  const float* wq   = (const float*)d_in[3];
  const float* wk   = (const float*)d_in[4];
  const float* wv   = (const float*)d_in[5];
  const float* wo   = (const float*)d_in[6];
  const float* gate = (const float*)d_in[7];
  const float* f1   = (const float*)d_in[8];
  const float* f2   = (const float*)d_in[9];
  const float* lmh  = (const float*)d_in[10];
  float* out = (float*)d_out;

  char* ws = (char*)d_ws;
  size_t off = 0;
  auto alloc = [&](size_t b) -> char* {
    char* p = ws + off;
    off += (b + 255) & ~(size_t)255;
    return p;
  };

  constexpr long PLN_XN = (long)kBT * kD;
  constexpr long PLN_Q3 = (long)kBT * 3 * kD;
  constexpr long PLN_FF = (long)kE * kFF * kD;
  constexpr long PLN_H = (long)kSLOTS * kFF;
  constexpr long PLN_OUTS = (long)kSLOTS * kD;
  constexpr long PLN_PR = (long)kBT * kE;

  // shared small buffers
  float* x     = (float*)alloc((size_t)kBT * kD * 4);
  float* outs  = (float*)alloc((size_t)4 * PLN_OUTS * 4);   // 4 K-partials
  float* probs3= (float*)alloc((size_t)kL * PLN_PR * 4);    // per-layer probs
  int*   top2e = (int*)  alloc((size_t)kBT * 2 * 4);
  float* top2w = (float*)alloc((size_t)kBT * 2 * 4);
  int*   meta  = (int*)  alloc(64 * 4);
  int* counts = meta; int* cursors = meta + 8; int* offs = meta + 16;
  int*   rows  = (int*)  alloc((size_t)kSLOTS * 4);
  int*   slotOf= (int*)  alloc((size_t)kBT * 2 * 4);
  float* aux   = (float*)alloc(256);
  size_t off_shared = off;

  // fast-path buffers
  u16*   xnP   = (u16*)  alloc((size_t)2 * PLN_XN * 2);
  float* qkvf  = (float*)alloc((size_t)PLN_Q3 * 4);
  u16*   qkvP  = (u16*)  alloc((size_t)2 * PLN_Q3 * 2);
  u16*   ofP   = (u16*)  alloc((size_t)2 * PLN_XN * 2);
  u16*   hP    = (u16*)  alloc((size_t)2 * PLN_H * 2);
  u16*   lmb   = (u16*)  alloc((size_t)kV * kD * 2);      // f16 lm_head weights
  bool fast = (off <= ws_size);
  float* qkvp1 = (float*)hP;          // alias: hP idle during QKV+attn phase

  dim3 gAttn(kT / 64, 2 * kH);
  // base grids (all % 8 == 0)
  int bQKV = (kBT / 128) * (3 * kD / 128);       // 384,  MPART mPerX=2, kParts=2
  int bWO  = (kBT / 128) * (kD / 128);           // 128,  MPART mPerX=2, kParts=4
  int nF1W = (kSLOTS / 128) * (kFF / 256);       // 640,  W kernel mPerX=5
  int bF2  = (kSLOTS / 128) * (kD / 128);        // 320,  MPART mPerX=5, kParts=4
  int nF1s = (kSLOTS / 128) * (kFF / 128);       // 1280, MPART mPerX=5
  int nLM  = (kBT / 128) * (kV / 128);           // 4000, mBlocks=16

  if (fast) {
    cast_h_k<<<4096, 256, 0, stream>>>(lmh, lmb, (long)kV * kD / 4);
    embed_rms_k<<<kBT, 256, 0, stream>>>(idx, wte, wpe, x);
    rmsnorm2h_k<<<kBT, 256, 0, stream>>>(x, xnP, PLN_XN);   // layer-0 QKV input

    for (int li = 0; li < kL; ++li) {
      size_t dd = (size_t)li * kD * kD;
      // QKV: direct f32 weights (QKV3 in-staging split-2), split-K x2
      gemm2h_bt_k<P_F32, false, false, true, true, true><<<2 * bQKV, 256, 0, stream>>>(
          xnP, PLN_XN, wq + dd, wk + dd, wv + dd, 0,
          qkvf, 0, nullptr, nullptr, nullptr, 3 * kD, kD, kD, 0, 2,
          2, bQKV, (long)(qkvp1 - qkvf));
      qkvcomb_k<<<2048, 256, 0, stream>>>(qkvf, qkvp1, qkvP, PLN_Q3, PLN_Q3 / 4);
      attn2h_k<<<gAttn, 256, 0, stream>>>(qkvP, PLN_Q3, ofP, PLN_XN);
      // WO: direct f32 weights (BF32), split-K x4; fused residual+rms+split
      gemm2h_bt_k<P_F32, false, false, true, true><<<4 * bWO, 256, 0, stream>>>(
          ofP, PLN_XN, wo + dd, nullptr, nullptr, 0,
          outs, 0, nullptr, nullptr, nullptr, kD, kD, kD, 0, 2,
          4, bWO, PLN_OUTS);
      resid4_rms2h_k<<<kBT, 256, 0, stream>>>(x, outs, PLN_OUTS, xnP, PLN_XN);
      hipMemsetAsync(meta, 0, 64, stream);
      gate_topk_k<<<kBT, 256, 0, stream>>>(x, gate + (size_t)li * kE * kD,
                                           probs3 + (size_t)li * PLN_PR,
                                           top2e, top2w, counts);
      fill_slots2_k<<<kBT / 256, 256, 0, stream>>>(top2e, counts, offs, cursors,
                                                   rows, slotOf);
      size_t fd = (size_t)li * PLN_FF;
      if (li < 2) {
        gemm2hW_bt_k<P_SPLIT2_RELU, true, true, true><<<nF1W, 512, 0, stream>>>(
            xnP, PLN_XN, f1 + fd, 0, hP, PLN_H, rows, offs,
            kFF, kD, kD, (long)kFF * kD, kSLOTS / 128 / 8,
            1, nF1W, 0);
        gemm2h_bt_k<P_F32, false, true, true, true><<<4 * bF2, 256, 0, stream>>>(
            hP, PLN_H, f2 + fd, nullptr, nullptr, 0, outs, 0, nullptr, nullptr, offs,
            kD, kFF, kFF, (long)kD * kFF, kSLOTS / 128 / 8,
            4, bF2, PLN_OUTS);
        moe4_rms2h_k<<<kBT, 256, 0, stream>>>(x, outs, PLN_OUTS, slotOf, top2w,
                                              xnP, PLN_XN);
      } else {
        gemm_bt_k<P_F16_RELU, true, true, true, true, true><<<nF1s, 256, 0, stream>>>(
            xnP, f1 + fd, hP, rows, offs, kFF, kD, kD, (long)kFF * kD,
            1.0f / 64.0f, kSLOTS / 128 / 8, 1, nF1s, 0);
        gemm_bt_k<P_F32, true, false, true, true, true><<<4 * bF2, 256, 0, stream>>>(
            hP, f2 + fd, outs, nullptr, offs, kD, kFF, kFF, (long)kD * kFF,
            1.0f, kSLOTS / 128 / 8, 4, bF2, PLN_OUTS);
        moe4_cast_h_k<<<kBT, 256, 0, stream>>>(x, outs, PLN_OUTS, slotOf, top2w, xnP);
      }
    }
    // lm_head: pre-converted f16 weights, swizzled global_load_lds staging
    gemm_bt_k<P_F32, false, false, true, false, false><<<nLM, 256, 0, stream>>>(
        xnP, lmb, out, nullptr, nullptr, kV, kD, kD, 0, 1.0f, kBT / 128,
        1, nLM, 0);
    aux_reduce3_k<<<1, 256, 0, stream>>>(probs3, PLN_PR, out + (size_t)kBT * kV);
    return;
  }

  // ---------- fallback: f32 path ----------
  off = off_shared;
  float* xnf   = (float*)alloc((size_t)kBT * kD * 4);
  u16*   xnb   = (u16*)  alloc((size_t)kBT * kD * 2);
  float* qkvf32= (float*)alloc((size_t)kBT * 3 * kD * 4);
  float* off32 = (float*)alloc((size_t)kBT * kD * 4);
  float* hbuf  = (float*)alloc((size_t)kSLOTS * kFF * 4);
  u16* hbuf16 = (u16*)hbuf;

  hipMemsetAsync(aux, 0, 4, stream);
  embed_rms_k<<<kBT, 256, 0, stream>>>(idx, wte, wpe, x);
  dim3 gF1s(kSLOTS / 128, kFF / 128);
  dim3 gF2s(kSLOTS / 128, kD / 128);
  for (int li = 0; li < kL; ++li) {
    size_t dd = (size_t)li * kD * kD;
    rmsnorm2_k<<<kBT, 256, 0, stream>>>(x, xnf, xnb);
    dim3 gP(kBT / 128, kD / 128);
    sgemm_bt_k<P_F32, false, false><<<gP, 256, 0, stream>>>(
        xnf, wq + dd, qkvf32, nullptr, nullptr, nullptr, 3 * kD, kD, kD, 0);
    sgemm_bt_k<P_F32, false, false><<<gP, 256, 0, stream>>>(
        xnf, wk + dd, qkvf32 + kD, nullptr, nullptr, nullptr, 3 * kD, kD, kD, 0);
    sgemm_bt_k<P_F32, false, false><<<gP, 256, 0, stream>>>(
        xnf, wv + dd, qkvf32 + 2 * kD, nullptr, nullptr, nullptr, 3 * kD, kD, kD, 0);
    attn_f32_k<<<gAttn, 256, 0, stream>>>(qkvf32, off32, 3 * kD);
    sgemm_bt_k<P_F32_RESID, false, false><<<gP, 256, 0, stream>>>(
        off32, wo + dd, x, x, nullptr, nullptr, kD, kD, kD, 0);
    rmsnorm2_k<<<kBT, 256, 0, stream>>>(x, xnf, xnb);
    hipMemsetAsync(meta, 0, 64, stream);
    gate_topk_k<<<kBT, 256, 0, stream>>>(x, gate + (size_t)li * kE * kD,
                                         probs3, top2e, top2w, counts);
    calc_offsets_k<<<1, 64, 0, stream>>>(counts, offs);
    fill_slots2_k<<<kBT / 256, 256, 0, stream>>>(top2e, counts, offs, cursors,
                                                 rows, slotOf);
    size_t fd = (size_t)li * kE * kFF * kD;
    if (li < 2) {
      sgemm_bt_k<P_F32_RELU, true, true><<<gF1s, 256, 0, stream>>>(
          xnf, f1 + fd, hbuf, nullptr, rows, offs, kFF, kD, kD, (long)kFF * kD);
      sgemm_bt_k<P_F32, false, true><<<gF2s, 256, 0, stream>>>(
          hbuf, f2 + fd, outs, nullptr, nullptr, offs, kD, kFF, kFF, (long)kD * kFF);
    } else {
      gemm_bt_k<P_BF16_RELU, true, true, false, true, false><<<nF1s, 256, 0, stream>>>(
          xnb, f1 + fd, hbuf16, rows, offs, kFF, kD, kD, (long)kFF * kD,
          1.0f, kSLOTS / 128, 1, nF1s, 0);
      gemm_bt_k<P_F32, true, false, false, true, false><<<bF2, 256, 0, stream>>>(
          hbuf16, f2 + fd, outs, nullptr, offs, kD, kFF, kFF, (long)kD * kFF,
          1.0f, kSLOTS / 128, 1, bF2, 0);
    }
    hipMemsetAsync(outs + PLN_OUTS, 0, 3 * PLN_OUTS * 4, stream);
    moe_combine4_k<<<kBT, 256, 0, stream>>>(x, outs, PLN_OUTS, slotOf, top2w);
    aux_reduce_k<<<1, 256, 0, stream>>>(probs3, aux);
  }
  cast_bf16_k<<<2048, 256, 0, stream>>>(x, xnb, (long)kBT * kD / 4);
  gemm_bt_k<P_F32, false, false, false, true, false><<<nLM, 256, 0, stream>>>(
      xnb, lmh, out, nullptr, nullptr, kV, kD, kD, 0, 1.0f, kBT / 128,
      1, nLM, 0);
  write_aux_k<<<1, 64, 0, stream>>>(aux, out + (size_t)kBT * kV);
}

// Round 21
// 1783.896 us; speedup vs baseline: 1.3239x; 1.0328x over previous
//
#include <hip/hip_runtime.h>

typedef unsigned short u16;
typedef __attribute__((ext_vector_type(4))) float f32x4;
typedef __attribute__((ext_vector_type(8))) __bf16 bf16x8;
typedef __attribute__((ext_vector_type(8))) _Float16 f16x8;
typedef __attribute__((ext_vector_type(4))) unsigned short u16x4;
typedef __attribute__((ext_vector_type(8))) unsigned short u16x8;

constexpr int kT = 1024, kD = 1024, kH = 16, kHD = 64, kL = 3, kE = 8;
constexpr int kFF = 4096, kV = 32000, kBT = 2048, kSLOTS = 5120;

__device__ __forceinline__ u16 f2bf(float f) {
  union { float f; unsigned u; } v; v.f = f;
  unsigned r = v.u + 0x7FFFu + ((v.u >> 16) & 1u);   // RNE
  return (u16)(r >> 16);
}
__device__ __forceinline__ u16 f2h(float x) {
  _Float16 h = (_Float16)x;
  union { _Float16 h; u16 u; } v; v.h = h; return v.u;
}
// uniform-scale fp16 split-2: 64*x = hi + mid + O(2^-11 * |64x - hi|)
__device__ __forceinline__ void split2s(float x, u16& h, u16& m) {
  float xs = x * 64.0f;
  _Float16 hh = (_Float16)xs;
  union { _Float16 h; u16 u; } v; v.h = hh; h = v.u;
  float r = xs - (float)hh;
  union { _Float16 h; u16 u; } w; w.h = (_Float16)r; m = w.u;
}

__device__ __forceinline__ void ld_lds16(const void* g, void* l) {
  __builtin_amdgcn_global_load_lds((const __attribute__((address_space(1))) void*)g,
                                   (__attribute__((address_space(3))) void*)l, 16, 0, 0);
}

#define MFMA16(a, b, c) __builtin_amdgcn_mfma_f32_16x16x32_bf16(a, b, c, 0, 0, 0)
#define MFMAH(a, b, c)  __builtin_amdgcn_mfma_f32_16x16x32_f16(a, b, c, 0, 0, 0)

__device__ __forceinline__ float blockReduceSum256(float v) {
  #pragma unroll
  for (int m = 32; m >= 1; m >>= 1) v += __shfl_xor(v, m);
  __shared__ float sh_[4];
  int w = threadIdx.x >> 6;
  if ((threadIdx.x & 63) == 0) sh_[w] = v;
  __syncthreads();
  v = (sh_[0] + sh_[1]) + (sh_[2] + sh_[3]);
  __syncthreads();
  return v;
}

// ---------------- elementwise / small kernels ----------------

__global__ __launch_bounds__(256) void cast_bf16_k(const float* __restrict__ in,
                                                   u16* __restrict__ out, long n4) {
  long i = (long)blockIdx.x * 256 + threadIdx.x;
  long stride = (long)gridDim.x * 256;
  for (; i < n4; i += stride) {
    f32x4 v = ((const f32x4*)in)[i];
    u16x4 o; o[0] = f2bf(v[0]); o[1] = f2bf(v[1]); o[2] = f2bf(v[2]); o[3] = f2bf(v[3]);
    ((u16x4*)out)[i] = o;
  }
}

// qkv = p0 + p1 -> 2 fp16 planes (x64 scale)
__global__ __launch_bounds__(256) void qkvcomb_k(const float* __restrict__ a,
    const float* __restrict__ b, u16* __restrict__ oP, long plane, long n4) {
  long i = (long)blockIdx.x * 256 + threadIdx.x;
  long stride = (long)gridDim.x * 256;
  for (; i < n4; i += stride) {
    f32x4 v = ((const f32x4*)a)[i] + ((const f32x4*)b)[i];
    u16x4 hh, mm;
    #pragma unroll
    for (int j = 0; j < 4; ++j) {
      u16 h, m; split2s(v[j], h, m);
      hh[j] = h; mm[j] = m;
    }
    ((u16x4*)oP)[i] = hh;
    ((u16x4*)(oP + plane))[i] = mm;
  }
}

__global__ __launch_bounds__(256) void embed_rms_k(const int* __restrict__ idx,
    const float* __restrict__ wte, const float* __restrict__ wpe, float* __restrict__ x) {
  int tok = blockIdx.x, t = threadIdx.x;
  int id = idx[tok];
  int tt = tok & (kT - 1);
  f32x4 a = ((const f32x4*)(wte + (long)id * kD))[t];
  f32x4 p = ((const f32x4*)(wpe + (long)tt * kD))[t];
  f32x4 vv = a + p;
  float ss = vv[0]*vv[0] + vv[1]*vv[1] + vv[2]*vv[2] + vv[3]*vv[3];
  ss = blockReduceSum256(ss);
  float sc = rsqrtf(ss * (1.0f / kD) + 1e-5f);
  vv *= sc;
  ((f32x4*)(x + (long)tok * kD))[t] = vv;
}

// rmsnorm -> f32 + bf16 (fallback path)
__global__ __launch_bounds__(256) void rmsnorm2_k(const float* __restrict__ x,
    float* __restrict__ xnf, u16* __restrict__ xnb) {
  int tok = blockIdx.x, t = threadIdx.x;
  f32x4 vv = ((const f32x4*)(x + (long)tok * kD))[t];
  float ss = blockReduceSum256(vv[0]*vv[0] + vv[1]*vv[1] + vv[2]*vv[2] + vv[3]*vv[3]);
  float sc = rsqrtf(ss * (1.0f / kD) + 1e-5f);
  vv *= sc;
  ((f32x4*)(xnf + (long)tok * kD))[t] = vv;
  u16x4 o;
  o[0] = f2bf(vv[0]); o[1] = f2bf(vv[1]); o[2] = f2bf(vv[2]); o[3] = f2bf(vv[3]);
  ((u16x4*)(xnb + (long)tok * kD))[t] = o;
}

// rmsnorm -> 2 fp16 planes (fast path, x64 scale)
__global__ __launch_bounds__(256) void rmsnorm2h_k(const float* __restrict__ x,
    u16* __restrict__ xnP, long plane) {
  int tok = blockIdx.x, t = threadIdx.x;
  f32x4 vv = ((const f32x4*)(x + (long)tok * kD))[t];
  float ss = blockReduceSum256(vv[0]*vv[0] + vv[1]*vv[1] + vv[2]*vv[2] + vv[3]*vv[3]);
  float sc = rsqrtf(ss * (1.0f / kD) + 1e-5f);
  vv *= sc;
  u16x4 a, b;
  #pragma unroll
  for (int j = 0; j < 4; ++j) {
    u16 h, m; split2s(vv[j], h, m);
    a[j] = h; b[j] = m;
  }
  long o = (long)tok * kD / 4 + t;
  ((u16x4*)xnP)[o] = a;
  ((u16x4*)(xnP + plane))[o] = b;
}

// x += sum of 4 K-partials; write x; rmsnorm -> 2 fp16 planes
__global__ __launch_bounds__(256) void resid4_rms2h_k(float* __restrict__ x,
    const float* __restrict__ parts, long plane, u16* __restrict__ xnP, long xplane) {
  int tok = blockIdx.x, t = threadIdx.x;
  long o = (long)tok * (kD / 4) + t;
  f32x4 xv = ((f32x4*)x)[o];
  #pragma unroll
  for (int p = 0; p < 4; ++p) xv += ((const f32x4*)(parts + p * plane))[o];
  ((f32x4*)x)[o] = xv;
  float ss = blockReduceSum256(xv[0]*xv[0] + xv[1]*xv[1] + xv[2]*xv[2] + xv[3]*xv[3]);
  float sc = rsqrtf(ss * (1.0f / kD) + 1e-5f);
  f32x4 vv = xv * sc;
  u16x4 a, b;
  #pragma unroll
  for (int j = 0; j < 4; ++j) {
    u16 h, m; split2s(vv[j], h, m);
    a[j] = h; b[j] = m;
  }
  ((u16x4*)xnP)[o] = a;
  ((u16x4*)(xnP + xplane))[o] = b;
}

// x += moe combine (4 K-partials, 2 experts); write x; rmsnorm -> 2 fp16 planes
__global__ __launch_bounds__(256) void moe4_rms2h_k(float* __restrict__ x,
    const float* __restrict__ outsP, long plane, const int* __restrict__ slotOf,
    const float* __restrict__ top2w, u16* __restrict__ xnP, long xplane) {
  int tok = blockIdx.x, t = threadIdx.x;
  int s0 = slotOf[tok*2], s1 = slotOf[tok*2+1];
  float w0 = top2w[tok*2], w1 = top2w[tok*2+1];
  f32x4 a = {0.f,0.f,0.f,0.f}, b = a;
  #pragma unroll
  for (int p = 0; p < 4; ++p) {
    a += ((const f32x4*)(outsP + p * plane + (long)s0 * kD))[t];
    b += ((const f32x4*)(outsP + p * plane + (long)s1 * kD))[t];
  }
  long o = (long)tok * (kD / 4) + t;
  f32x4 xv = ((f32x4*)x)[o];
  xv += a * w0 + b * w1;
  ((f32x4*)x)[o] = xv;
  float ss = blockReduceSum256(xv[0]*xv[0] + xv[1]*xv[1] + xv[2]*xv[2] + xv[3]*xv[3]);
  float sc = rsqrtf(ss * (1.0f / kD) + 1e-5f);
  f32x4 vv = xv * sc;
  u16x4 ha, hb;
  #pragma unroll
  for (int j = 0; j < 4; ++j) {
    u16 h, m; split2s(vv[j], h, m);
    ha[j] = h; hb[j] = m;
  }
  ((u16x4*)xnP)[o] = ha;
  ((u16x4*)(xnP + xplane))[o] = hb;
}

// last layer: x += moe combine; write f16 (unscaled) plane for lm_head
__global__ __launch_bounds__(256) void moe4_cast_h_k(float* __restrict__ x,
    const float* __restrict__ outsP, long plane, const int* __restrict__ slotOf,
    const float* __restrict__ top2w, u16* __restrict__ xn) {
  int tok = blockIdx.x, t = threadIdx.x;
  int s0 = slotOf[tok*2], s1 = slotOf[tok*2+1];
  float w0 = top2w[tok*2], w1 = top2w[tok*2+1];
  f32x4 a = {0.f,0.f,0.f,0.f}, b = a;
  #pragma unroll
  for (int p = 0; p < 4; ++p) {
    a += ((const f32x4*)(outsP + p * plane + (long)s0 * kD))[t];
    b += ((const f32x4*)(outsP + p * plane + (long)s1 * kD))[t];
  }
  long o = (long)tok * (kD / 4) + t;
  f32x4 xv = ((f32x4*)x)[o];
  xv += a * w0 + b * w1;
  u16x4 hv;
  #pragma unroll
  for (int j = 0; j < 4; ++j) hv[j] = f2h(xv[j]);
  ((u16x4*)xn)[o] = hv;
}

// gating in f32 (bf16 would flip top-2 selections on near-ties)
__global__ __launch_bounds__(256) void gate_topk_k(const float* __restrict__ x,
    const float* __restrict__ gate_l, float* __restrict__ probs, int* __restrict__ top2e,
    float* __restrict__ top2w, int* __restrict__ counts) {
  int tok = blockIdx.x, t = threadIdx.x;
  f32x4 xv = ((const f32x4*)(x + (long)tok * kD))[t];
  float ss = blockReduceSum256(xv[0]*xv[0] + xv[1]*xv[1] + xv[2]*xv[2] + xv[3]*xv[3]);
  float sc = rsqrtf(ss * (1.0f / kD) + 1e-5f);
  float a[kE];
  #pragma unroll
  for (int e = 0; e < kE; ++e) {
    f32x4 gv = ((const f32x4*)(gate_l + (long)e * kD))[t];
    a[e] = xv[0]*gv[0] + xv[1]*gv[1] + xv[2]*gv[2] + xv[3]*gv[3];
  }
  __shared__ float sh8[kE][4];
  int w = t >> 6, l = t & 63;
  #pragma unroll
  for (int e = 0; e < kE; ++e) {
    float v = a[e];
    #pragma unroll
    for (int m = 32; m >= 1; m >>= 1) v += __shfl_xor(v, m);
    if (l == 0) sh8[e][w] = v;
  }
  __syncthreads();
  if (t == 0) {
    float lg[kE], mx = -1e30f;
    #pragma unroll
    for (int e = 0; e < kE; ++e) {
      lg[e] = (sh8[e][0] + sh8[e][1] + sh8[e][2] + sh8[e][3]) * sc;
      mx = fmaxf(mx, lg[e]);
    }
    float pe[kE], s = 0.f;
    #pragma unroll
    for (int e = 0; e < kE; ++e) { pe[e] = __expf(lg[e] - mx); s += pe[e]; }
    float inv = 1.f / s;
    int i1 = 0;
    #pragma unroll
    for (int e = 1; e < kE; ++e) if (lg[e] > lg[i1]) i1 = e;
    int i2 = (i1 == 0) ? 1 : 0;
    #pragma unroll
    for (int e = 0; e < kE; ++e) if (e != i1 && lg[e] > lg[i2]) i2 = e;
    #pragma unroll
    for (int e = 0; e < kE; ++e) probs[(long)tok * kE + e] = pe[e] * inv;
    float p1 = pe[i1] * inv, p2 = pe[i2] * inv;
    float wn = p1 + p2;
    top2e[tok*2] = i1; top2e[tok*2+1] = i2;
    top2w[tok*2] = p1 / wn; top2w[tok*2+1] = p2 / wn;
    atomicAdd(&counts[i1], 1); atomicAdd(&counts[i2], 1);
  }
}

// 128-aligned expert offsets (fallback path)
__global__ void calc_offsets_k(const int* __restrict__ counts, int* __restrict__ offsets) {
  if (threadIdx.x == 0) {
    int o = 0;
    #pragma unroll
    for (int e = 0; e < kE; ++e) { offsets[e] = o; o += (counts[e] + 127) & ~127; }
    offsets[kE] = o;
  }
}

// offsets computed in-kernel from counts (block 0 publishes); slots filled
__global__ __launch_bounds__(256) void fill_slots2_k(const int* __restrict__ top2e,
    const int* __restrict__ counts, int* __restrict__ offsets, int* __restrict__ cursors,
    int* __restrict__ rows, int* __restrict__ slotOf) {
  __shared__ int soff[kE + 1];
  if (threadIdx.x == 0) {
    int o = 0;
    #pragma unroll
    for (int e = 0; e < kE; ++e) { soff[e] = o; o += (counts[e] + 127) & ~127; }
    soff[kE] = o;
    if (blockIdx.x == 0) {
      #pragma unroll
      for (int e = 0; e <= kE; ++e) offsets[e] = soff[e];
    }
  }
  __syncthreads();
  int tok = blockIdx.x * 256 + threadIdx.x;
  if (tok >= kBT) return;
  #pragma unroll
  for (int j = 0; j < 2; ++j) {
    int e = top2e[tok*2 + j];
    int pos = atomicAdd(&cursors[e], 1);
    int slot = soff[e] + pos;
    rows[slot] = tok;
    slotOf[tok*2 + j] = slot;
  }
}

// fallback combine (4 partials; unused planes zeroed)
__global__ __launch_bounds__(256) void moe_combine4_k(float* __restrict__ x,
    const float* __restrict__ outsP, long plane, const int* __restrict__ slotOf,
    const float* __restrict__ top2w) {
  int tok = blockIdx.x, t = threadIdx.x;
  int s0 = slotOf[tok*2], s1 = slotOf[tok*2+1];
  float w0 = top2w[tok*2], w1 = top2w[tok*2+1];
  f32x4 a = {0.f,0.f,0.f,0.f}, b = a;
  #pragma unroll
  for (int p = 0; p < 4; ++p) {
    a += ((const f32x4*)(outsP + p * plane + (long)s0 * kD))[t];
    b += ((const f32x4*)(outsP + p * plane + (long)s1 * kD))[t];
  }
  f32x4 xv = ((f32x4*)(x + (long)tok * kD))[t];
  xv += a * w0 + b * w1;
  ((f32x4*)(x + (long)tok * kD))[t] = xv;
}

// all-layer aux: out[0] = 0.01/L * sum_l E * sum_e (mean_t probs3[l])^2
__global__ __launch_bounds__(256) void aux_reduce3_k(const float* __restrict__ probs3,
    long plane, float* __restrict__ outv) {
  int t = threadIdx.x;
  float part[kL][kE] = {};
  for (int i = t; i < kBT; i += 256) {
    #pragma unroll
    for (int l = 0; l < kL; ++l)
      #pragma unroll
      for (int e = 0; e < kE; ++e)
        part[l][e] += probs3[l * plane + (long)i * kE + e];
  }
  __shared__ float sh[kL][kE][4];
  int w = t >> 6, ln = t & 63;
  #pragma unroll
  for (int l = 0; l < kL; ++l)
    #pragma unroll
    for (int e = 0; e < kE; ++e) {
      float v = part[l][e];
      #pragma unroll
      for (int m = 32; m >= 1; m >>= 1) v += __shfl_xor(v, m);
      if (ln == 0) sh[l][e][w] = v;
    }
  __syncthreads();
  if (t == 0) {
    float acc = 0.f;
    #pragma unroll
    for (int l = 0; l < kL; ++l)
      #pragma unroll
      for (int e = 0; e < kE; ++e) {
        float frac = (sh[l][e][0] + sh[l][e][1] + sh[l][e][2] + sh[l][e][3]) * (1.0f / kBT);
        acc += frac * frac;
      }
    outv[0] = 0.01f * (float)kE * acc / (float)kL;
  }
}

__global__ __launch_bounds__(256) void aux_reduce_k(const float* __restrict__ probs,
                                                    float* __restrict__ aux) {
  int t = threadIdx.x;
  float part[kE] = {};
  for (int i = t; i < kBT; i += 256) {
    #pragma unroll
    for (int e = 0; e < kE; ++e) part[e] += probs[(long)i * kE + e];
  }
  __shared__ float sh8[kE][4];
  int w = t >> 6, l = t & 63;
  #pragma unroll
  for (int e = 0; e < kE; ++e) {
    float v = part[e];
    #pragma unroll
    for (int m = 32; m >= 1; m >>= 1) v += __shfl_xor(v, m);
    if (l == 0) sh8[e][w] = v;
  }
  __syncthreads();
  if (t == 0) {
    float acc = 0.f;
    #pragma unroll
    for (int e = 0; e < kE; ++e) {
      float frac = (sh8[e][0] + sh8[e][1] + sh8[e][2] + sh8[e][3]) * (1.0f / kBT);
      acc += frac * frac;
    }
    aux[0] += (float)kE * acc;
  }
}

__global__ void write_aux_k(const float* __restrict__ aux, float* __restrict__ out) {
  if (threadIdx.x == 0) out[0] = 0.01f * aux[0] / (float)kL;
}

enum { P_BF16 = 0, P_BF16_RELU = 1, P_F32 = 2, P_F32_RESID = 3, P_F32_RELU = 4,
       P_SPLIT2_RELU = 5, P_F16_RELU = 6 };

__device__ __forceinline__ int clamp_row(int rv) {
  return ((unsigned)rv < (unsigned)kBT) ? rv : 0;
}

template <bool MPART>
__device__ __forceinline__ void block_mn(int lin, int base, int mArg, int& mb, int& nb) {
  int xcd = lin & 7, c = lin >> 3;
  if (MPART) {
    mb = xcd * mArg + (c % mArg);
    nb = c / mArg;
  } else {
    int swz = xcd * (base >> 3) + c;
    mb = swz % mArg;
    nb = swz / mArg;
  }
}

// ------- fused fp16 split-2 MFMA GEMM (128x128, 256 thr), single accumulator -------
// BF32: B is f32; staged via registers (one k-step prefetch) + split2s + swizzled
// ds_write. QKV3: three f32 B tensors (wq/wk/wv) selected by n0>>10.

template <int POST, bool GATHER, bool EXPERT, bool MPART, bool BF32, bool QKV3 = false>
__global__ __launch_bounds__(256) void gemm2h_bt_k(
    const u16* __restrict__ A0, long planeA,
    const void* __restrict__ Bv, const void* __restrict__ Bv1, const void* __restrict__ Bv2,
    long planeB,
    void* __restrict__ C, long planeC,
    const float* __restrict__ resid,
    const int* __restrict__ rows, const int* __restrict__ offsets,
    int N, int K, int lda, long eBstride, int mArg,
    int kParts, int base, long cPart) {
  constexpr int BM = 128, BK = 32;
  int part = blockIdx.x / base;
  int lin = blockIdx.x % base;
  int mb, nb;
  block_mn<MPART>(lin, base, mArg, mb, nb);
  int m0 = mb * BM, n0 = nb * BM;
  const u16* B0 = (const u16*)Bv;
  const float* Bf = (const float*)Bv;
  if (EXPERT) {
    int total = offsets[kE];
    if (m0 >= total) return;
    int e = 0;
    while (offsets[e + 1] <= m0) ++e;
    if (BF32) Bf += (long)e * eBstride; else B0 += (long)e * eBstride;
  }
  __shared__ __align__(16) u16 Ac[BM][64];
  __shared__ __align__(16) u16 Bc[BM][64];
  int t = threadIdx.x;
  int l = t & 63, lr = l & 15, lg = l >> 4;
  int wid = t >> 6;
  int wm = (wid >> 1) * 64, wn = (wid & 1) * 64;

  long asrc[4], bsrc[4];
  int ldst[4];
  #pragma unroll
  for (int it = 0; it < 4; ++it) {
    int d = it * 256 + t;
    int row = d >> 3, pc = d & 7;
    int lc = pc ^ (row & 7);
    int p = lc >> 2, c = lc & 3;
    int grow = GATHER ? clamp_row(rows[m0 + row]) : (m0 + row);
    asrc[it] = (long)p * planeA + (long)grow * lda + c * 8;
    if (!BF32) bsrc[it] = (long)p * planeB + (long)(n0 + row) * K + c * 8;
    ldst[it] = (it * 256 + (t & ~63)) * 8;
  }
  long bsrcF[2];
  int brow[2], bc[2];
  if (BF32) {
    if (QKV3) {
      int ts = n0 >> 10;
      Bf = (ts == 0) ? (const float*)Bv : (ts == 1) ? (const float*)Bv1
                                                    : (const float*)Bv2;
    }
    int nB = QKV3 ? (n0 & 1023) : n0;
    #pragma unroll
    for (int it = 0; it < 2; ++it) {
      int d = it * 256 + t;
      brow[it] = d >> 2; bc[it] = d & 3;
      bsrcF[it] = (long)(nB + brow[it]) * K + bc[it] * 8;
    }
  }
  int sa = lr & 7;
  int cH = (lg ^ sa) * 8;
  int cM = ((4 + lg) ^ sa) * 8;

  f32x4 acc[4][4];
  #pragma unroll
  for (int i = 0; i < 4; ++i)
    #pragma unroll
    for (int j = 0; j < 4; ++j) acc[i][j] = 0.f;

  int kStep = K / kParts;
  int kLo = part * kStep, kHi = kLo + kStep;

  f32x4 pv0[2], pv1[2];
  if (BF32) {
    #pragma unroll
    for (int it = 0; it < 2; ++it) {
      const float* src = Bf + bsrcF[it] + kLo;
      pv0[it] = *(const f32x4*)src;
      pv1[it] = *(const f32x4*)(src + 4);
    }
  }
  for (int k0 = kLo; k0 < kHi; k0 += BK) {
    bool pf = BF32 && (k0 + BK < kHi);
    #pragma unroll
    for (int it = 0; it < 4; ++it) {
      ld_lds16(A0 + asrc[it] + k0, &Ac[0][0] + ldst[it]);
      if (!BF32) ld_lds16(B0 + bsrc[it] + k0, &Bc[0][0] + ldst[it]);
    }
    f32x4 nv0[2], nv1[2];
    if (pf) {
      #pragma unroll
      for (int it = 0; it < 2; ++it) {
        const float* src = Bf + bsrcF[it] + k0 + BK;
        nv0[it] = *(const f32x4*)src;
        nv1[it] = *(const f32x4*)(src + 4);
      }
    }
    if (BF32) {
      #pragma unroll
      for (int it = 0; it < 2; ++it) {
        u16x8 hi, mi;
        #pragma unroll
        for (int j = 0; j < 4; ++j) {
          u16 h, m; split2s(pv0[it][j], h, m); hi[j] = h; mi[j] = m;
        }
        #pragma unroll
        for (int j = 0; j < 4; ++j) {
          u16 h, m; split2s(pv1[it][j], h, m); hi[4 + j] = h; mi[4 + j] = m;
        }
        int r7 = brow[it] & 7;
        *(u16x8*)&Bc[brow[it]][(bc[it] ^ r7) * 8] = hi;
        *(u16x8*)&Bc[brow[it]][((4 + bc[it]) ^ r7) * 8] = mi;
      }
    }
    __syncthreads();
    f16x8 ah[4], am[4];
    #pragma unroll
    for (int i = 0; i < 4; ++i) {
      ah[i] = *(const f16x8*)&Ac[wm + i*16 + lr][cH];
      am[i] = *(const f16x8*)&Ac[wm + i*16 + lr][cM];
    }
    __builtin_amdgcn_s_setprio(1);
    #pragma unroll
    for (int j = 0; j < 4; ++j) {
      f16x8 bh = *(const f16x8*)&Bc[wn + j*16 + lr][cH];
      f16x8 bm = *(const f16x8*)&Bc[wn + j*16 + lr][cM];
      #pragma unroll
      for (int i = 0; i < 4; ++i) {
        acc[i][j] = MFMAH(ah[i], bh, acc[i][j]);
        acc[i][j] = MFMAH(am[i], bh, acc[i][j]);
        acc[i][j] = MFMAH(ah[i], bm, acc[i][j]);
      }
    }
    __builtin_amdgcn_s_setprio(0);
    __syncthreads();
    if (pf) {
      #pragma unroll
      for (int it = 0; it < 2; ++it) { pv0[it] = nv0[it]; pv1[it] = nv1[it]; }
    }
  }
  float* Cf = (float*)C + (long)part * cPart;
  #pragma unroll
  for (int i = 0; i < 4; ++i) {
    #pragma unroll
    for (int r = 0; r < 4; ++r) {
      long m = m0 + wm + i*16 + lg*4 + r;
      #pragma unroll
      for (int j = 0; j < 4; ++j) {
        int n = n0 + wn + j*16 + lr;
        float val = acc[i][j][r] * (1.0f / 4096.0f);
        if (POST == P_F32) {
          Cf[m * N + n] = val;
        } else if (POST == P_F32_RESID) {
          ((float*)C)[m * N + n] = val + resid[m * N + n];
        } else if (POST == P_SPLIT2_RELU) {
          val = fmaxf(val, 0.f);
          u16 h, mm; split2s(val, h, mm);
          u16* Cp = (u16*)C;
          Cp[m * N + n] = h;
          Cp[planeC + m * N + n] = mm;
        }
      }
    }
  }
}

// ------- wide fused fp16 split-2 GEMM: 128x256 tile, 512 threads, 2m x 4n waves -------

template <int POST, bool GATHER, bool EXPERT, bool BF32>
__global__ __launch_bounds__(512) void gemm2hW_bt_k(
    const u16* __restrict__ A0, long planeA,
    const void* __restrict__ Bv, long planeB,
    void* __restrict__ C, long planeC,
    const int* __restrict__ rows, const int* __restrict__ offsets,
    int N, int K, int lda, long eBstride, int mPerX,
    int kParts, int base, long cPart) {
  constexpr int BM = 128, BN = 256, BK = 32;
  int part = blockIdx.x / base;
  int lin = blockIdx.x % base;
  int xcd = lin & 7, c0 = lin >> 3;
  int m0 = (xcd * mPerX + (c0 % mPerX)) * BM;
  int n0 = (c0 / mPerX) * BN;
  const u16* B0 = (const u16*)Bv;
  const float* Bf = (const float*)Bv;
  if (EXPERT) {
    int total = offsets[kE];
    if (m0 >= total) return;
    int e = 0;
    while (offsets[e + 1] <= m0) ++e;
    if (BF32) Bf += (long)e * eBstride; else B0 += (long)e * eBstride;
  }
  __shared__ __align__(16) u16 Ac[BM][64];
  __shared__ __align__(16) u16 Bc[BN][64];
  int t = threadIdx.x;
  int l = t & 63, lr = l & 15, lg = l >> 4;
  int wid = t >> 6;
  int wm = (wid >> 2) * 64;
  int wn = (wid & 3) * 64;

  long asrc[2], bsrc[4];
  int aldst[2], bldst[4];
  #pragma unroll
  for (int it = 0; it < 2; ++it) {
    int d = it * 512 + t;
    int row = d >> 3, pc = d & 7;
    int lc = pc ^ (row & 7);
    int p = lc >> 2, cc = lc & 3;
    int grow = GATHER ? clamp_row(rows[m0 + row]) : (m0 + row);
    asrc[it] = (long)p * planeA + (long)grow * lda + cc * 8;
    aldst[it] = (it * 512 + (t & ~63)) * 8;
  }
  long bsrcF[2];
  int brow[2], bcc[2];
  if (!BF32) {
    #pragma unroll
    for (int it = 0; it < 4; ++it) {
      int d = it * 512 + t;
      int row = d >> 3, pc = d & 7;
      int lc = pc ^ (row & 7);
      int p = lc >> 2, cc = lc & 3;
      bsrc[it] = (long)p * planeB + (long)(n0 + row) * K + cc * 8;
      bldst[it] = (it * 512 + (t & ~63)) * 8;
    }
  } else {
    #pragma unroll
    for (int it = 0; it < 2; ++it) {
      int d = it * 512 + t;
      brow[it] = d >> 2; bcc[it] = d & 3;
      bsrcF[it] = (long)(n0 + brow[it]) * K + bcc[it] * 8;
    }
  }
  int sa = lr & 7;
  int cH = (lg ^ sa) * 8;
  int cM = ((4 + lg) ^ sa) * 8;

  f32x4 acc[4][4];
  #pragma unroll
  for (int i = 0; i < 4; ++i)
    #pragma unroll
    for (int j = 0; j < 4; ++j) acc[i][j] = 0.f;

  int kStep = K / kParts;
  int kLo = part * kStep, kHi = kLo + kStep;

  f32x4 pv0[2], pv1[2];
  if (BF32) {
    #pragma unroll
    for (int it = 0; it < 2; ++it) {
      const float* src = Bf + bsrcF[it] + kLo;
      pv0[it] = *(const f32x4*)src;
      pv1[it] = *(const f32x4*)(src + 4);
    }
  }
  for (int k0 = kLo; k0 < kHi; k0 += BK) {
    bool pf = BF32 && (k0 + BK < kHi);
    #pragma unroll
    for (int it = 0; it < 2; ++it)
      ld_lds16(A0 + asrc[it] + k0, &Ac[0][0] + aldst[it]);
    if (!BF32) {
      #pragma unroll
      for (int it = 0; it < 4; ++it)
        ld_lds16(B0 + bsrc[it] + k0, &Bc[0][0] + bldst[it]);
    }
    f32x4 nv0[2], nv1[2];
    if (pf) {
      #pragma unroll
      for (int it = 0; it < 2; ++it) {
        const float* src = Bf + bsrcF[it] + k0 + BK;
        nv0[it] = *(const f32x4*)src;
        nv1[it] = *(const f32x4*)(src + 4);
      }
    }
    if (BF32) {
      #pragma unroll
      for (int it = 0; it < 2; ++it) {
        u16x8 hi, mi;
        #pragma unroll
        for (int j = 0; j < 4; ++j) {
          u16 h, m; split2s(pv0[it][j], h, m); hi[j] = h; mi[j] = m;
        }
        #pragma unroll
        for (int j = 0; j < 4; ++j) {
          u16 h, m; split2s(pv1[it][j], h, m); hi[4 + j] = h; mi[4 + j] = m;
        }
        int r7 = brow[it] & 7;
        *(u16x8*)&Bc[brow[it]][(bcc[it] ^ r7) * 8] = hi;
        *(u16x8*)&Bc[brow[it]][((4 + bcc[it]) ^ r7) * 8] = mi;
      }
    }
    __syncthreads();
    f16x8 ah[4], am[4];
    #pragma unroll
    for (int i = 0; i < 4; ++i) {
      ah[i] = *(const f16x8*)&Ac[wm + i*16 + lr][cH];
      am[i] = *(const f16x8*)&Ac[wm + i*16 + lr][cM];
    }
    __builtin_amdgcn_s_setprio(1);
    #pragma unroll
    for (int j = 0; j < 4; ++j) {
      f16x8 bh = *(const f16x8*)&Bc[wn + j*16 + lr][cH];
      f16x8 bm = *(const f16x8*)&Bc[wn + j*16 + lr][cM];
      #pragma unroll
      for (int i = 0; i < 4; ++i) {
        acc[i][j] = MFMAH(ah[i], bh, acc[i][j]);
        acc[i][j] = MFMAH(am[i], bh, acc[i][j]);
        acc[i][j] = MFMAH(ah[i], bm, acc[i][j]);
      }
    }
    __builtin_amdgcn_s_setprio(0);
    __syncthreads();
    if (pf) {
      #pragma unroll
      for (int it = 0; it < 2; ++it) { pv0[it] = nv0[it]; pv1[it] = nv1[it]; }
    }
  }
  float* Cf = (float*)C + (long)part * cPart;
  #pragma unroll
  for (int i = 0; i < 4; ++i) {
    #pragma unroll
    for (int r = 0; r < 4; ++r) {
      long m = m0 + wm + i*16 + lg*4 + r;
      #pragma unroll
      for (int j = 0; j < 4; ++j) {
        int n = n0 + wn + j*16 + lr;
        float val = acc[i][j][r] * (1.0f / 4096.0f);
        if (POST == P_F32) {
          Cf[m * N + n] = val;
        } else if (POST == P_SPLIT2_RELU) {
          val = fmaxf(val, 0.f);
          u16 h, mm; split2s(val, h, mm);
          u16* Cp = (u16*)C;
          Cp[m * N + n] = h;
          Cp[planeC + m * N + n] = mm;
        }
      }
    }
  }
}

// ---------------- single-plane MFMA GEMM (with optional split-K) ----------------
// BCONV staging now register-prefetched one k-step ahead (same pipeline as BF32).

template <int POST, bool EXPERT, bool GATHER, bool HALF, bool BCONV, bool MPART>
__global__ __launch_bounds__(256) void gemm_bt_k(
    const u16* __restrict__ A, const void* __restrict__ Bv, void* __restrict__ C,
    const int* __restrict__ rows, const int* __restrict__ offsets,
    int N, int K, int lda, long eBstride, float oscale, int mArg,
    int kParts, int base, long cPart) {
  constexpr int BM = 128, BK = 64;
  int part = blockIdx.x / base;
  int lin = blockIdx.x % base;
  int mb, nb;
  block_mn<MPART>(lin, base, mArg, mb, nb);
  int m0 = mb * BM, n0 = nb * BM;
  const float* Bf = (const float*)Bv;
  const u16*   Bh = (const u16*)Bv;
  if (EXPERT) {
    int total = offsets[kE];
    if (m0 >= total) return;
    int e = 0;
    while (offsets[e + 1] <= m0) ++e;
    if (BCONV) Bf += (long)e * eBstride; else Bh += (long)e * eBstride;
  }
  __shared__ __align__(16) u16 As[BM][BK];
  __shared__ __align__(16) u16 Bs[BM][BK];
  int t = threadIdx.x;
  int l = t & 63, lr = l & 15, lg = l >> 4;
  int wid = t >> 6;
  int wm = (wid >> 1) * 64, wn = (wid & 1) * 64;

  long asrc[4], bsrc[4];
  int ldst[4];
  #pragma unroll
  for (int it = 0; it < 4; ++it) {
    int d = it * 256 + t;
    int row = d >> 3, pc = d & 7;
    int c = pc ^ (row & 7);
    int grow = GATHER ? clamp_row(rows[m0 + row]) : (m0 + row);
    asrc[it] = (long)grow * lda + c * 8;
    if (!BCONV) bsrc[it] = (long)(n0 + row) * K + c * 8;
    ldst[it] = (it * 256 + (t & ~63)) * 8;
  }
  long bsrcC[4];
  int bdst[4];
  if (BCONV) {
    #pragma unroll
    for (int it = 0; it < 4; ++it) {
      int d = it * 256 + t;
      int row = d >> 3, lc = d & 7;
      bsrcC[it] = (long)(n0 + row) * K + lc * 8;
      bdst[it] = row * BK + (lc ^ (row & 7)) * 8;
    }
  }
  f32x4 acc[4][4];
  #pragma unroll
  for (int i = 0; i < 4; ++i)
    #pragma unroll
    for (int j = 0; j < 4; ++j) acc[i][j] = 0.f;

  int kStep = K / kParts;
  int kLo = part * kStep, kHi = kLo + kStep;

  f32x4 pv0[4], pv1[4];
  if (BCONV) {
    #pragma unroll
    for (int it = 0; it < 4; ++it) {
      const float* src = Bf + bsrcC[it] + kLo;
      pv0[it] = *(const f32x4*)src;
      pv1[it] = *(const f32x4*)(src + 4);
    }
  }
  for (int k0 = kLo; k0 < kHi; k0 += BK) {
    bool pf = BCONV && (k0 + BK < kHi);
    #pragma unroll
    for (int it = 0; it < 4; ++it)
      ld_lds16(A + asrc[it] + k0, &As[0][0] + ldst[it]);
    if (!BCONV) {
      #pragma unroll
      for (int it = 0; it < 4; ++it)
        ld_lds16(Bh + bsrc[it] + k0, &Bs[0][0] + ldst[it]);
    }
    f32x4 nv0[4], nv1[4];
    if (pf) {
      #pragma unroll
      for (int it = 0; it < 4; ++it) {
        const float* src = Bf + bsrcC[it] + k0 + BK;
        nv0[it] = *(const f32x4*)src;
        nv1[it] = *(const f32x4*)(src + 4);
      }
    }
    if (BCONV) {
      #pragma unroll
      for (int it = 0; it < 4; ++it) {
        u16x8 o;
        #pragma unroll
        for (int j = 0; j < 4; ++j) {
          o[j] = HALF ? f2h(pv0[it][j]) : f2bf(pv0[it][j]);
          o[4 + j] = HALF ? f2h(pv1[it][j]) : f2bf(pv1[it][j]);
        }
        *(u16x8*)(&Bs[0][0] + bdst[it]) = o;
      }
    }
    __syncthreads();
    __builtin_amdgcn_s_setprio(1);
    #pragma unroll
    for (int kk = 0; kk < 2; ++kk) {
      int ca = ((kk * 4 + lg) ^ (lr & 7)) * 8;
      #pragma unroll
      for (int i = 0; i < 4; ++i)
        #pragma unroll
        for (int j = 0; j < 4; ++j) {
          if (HALF) {
            f16x8 af = *(const f16x8*)&As[wm + i*16 + lr][ca];
            f16x8 bq = *(const f16x8*)&Bs[wn + j*16 + lr][ca];
            acc[i][j] = MFMAH(af, bq, acc[i][j]);
          } else {
            bf16x8 af = *(const bf16x8*)&As[wm + i*16 + lr][ca];
            bf16x8 bq = *(const bf16x8*)&Bs[wn + j*16 + lr][ca];
            acc[i][j] = MFMA16(af, bq, acc[i][j]);
          }
        }
    }
    __builtin_amdgcn_s_setprio(0);
    __syncthreads();
    if (pf) {
      #pragma unroll
      for (int it = 0; it < 4; ++it) { pv0[it] = nv0[it]; pv1[it] = nv1[it]; }
    }
  }
  #pragma unroll
  for (int i = 0; i < 4; ++i) {
    #pragma unroll
    for (int r = 0; r < 4; ++r) {
      long m = m0 + wm + i*16 + lg*4 + r;
      #pragma unroll
      for (int j = 0; j < 4; ++j) {
        int n = n0 + wn + j*16 + lr;
        float val = acc[i][j][r] * oscale;
        if (POST == P_BF16_RELU)       ((u16*)C)[m * N + n] = f2bf(fmaxf(val, 0.f));
        else if (POST == P_F16_RELU)   ((u16*)C)[m * N + n] = f2h(fmaxf(val, 0.f));
        else if (POST == P_F32)        ((float*)C + (long)part * cPart)[m * N + n] = val;
      }
    }
  }
}

// ---------------- f32 SGEMM (fallback path only) ----------------

template <int POST, bool GATHER, bool EXPERT>
__global__ __launch_bounds__(256) void sgemm_bt_k(
    const float* __restrict__ A, const float* __restrict__ B, float* __restrict__ C,
    const float* __restrict__ resid, const int* __restrict__ rows,
    const int* __restrict__ offsets, int N, int K, int lda, long eBstride) {
  constexpr int BM = 128, BN = 128, BK = 32;
  int m0 = blockIdx.x * BM, n0 = blockIdx.y * BN;
  if (EXPERT) {
    int total = offsets[kE];
    if (m0 >= total) return;
    int e = 0;
    while (offsets[e + 1] <= m0) ++e;
    B += (long)e * eBstride;
  }
  __shared__ float Ast[BK][BM];
  __shared__ float Bst[BK][BN];
  int t = threadIdx.x, tx = t & 15, ty = t >> 4;
  long asrc[4], bsrc[4];
  #pragma unroll
  for (int it = 0; it < 4; ++it) {
    int c = it * 256 + t;
    int row = c >> 3, kc = (c & 7) * 4;
    int gr = GATHER ? clamp_row(rows[m0 + row]) : (m0 + row);
    asrc[it] = (long)gr * lda + kc;
    bsrc[it] = (long)(n0 + row) * K + kc;
  }
  f32x4 accv[8][2];
  #pragma unroll
  for (int i = 0; i < 8; ++i) { accv[i][0] = 0.f; accv[i][1] = 0.f; }

  for (int k0 = 0; k0 < K; k0 += BK) {
    #pragma unroll
    for (int it = 0; it < 4; ++it) {
      int c = it * 256 + t;
      int row = c >> 3, kc = (c & 7) * 4;
      f32x4 av = *(const f32x4*)(A + asrc[it] + k0);
      f32x4 bv = *(const f32x4*)(B + bsrc[it] + k0);
      #pragma unroll
      for (int j = 0; j < 4; ++j) { Ast[kc + j][row] = av[j]; Bst[kc + j][row] = bv[j]; }
    }
    __syncthreads();
    #pragma unroll
    for (int kk = 0; kk < BK; ++kk) {
      f32x4 a0 = *(const f32x4*)&Ast[kk][ty * 4];
      f32x4 a1 = *(const f32x4*)&Ast[kk][64 + ty * 4];
      f32x4 b0 = *(const f32x4*)&Bst[kk][tx * 4];
      f32x4 b1 = *(const f32x4*)&Bst[kk][64 + tx * 4];
      float as[8] = {a0[0], a0[1], a0[2], a0[3], a1[0], a1[1], a1[2], a1[3]};
      #pragma unroll
      for (int i = 0; i < 8; ++i) {
        accv[i][0] += b0 * as[i];
        accv[i][1] += b1 * as[i];
      }
    }
    __syncthreads();
  }
  #pragma unroll
  for (int ih = 0; ih < 2; ++ih)
    #pragma unroll
    for (int i = 0; i < 4; ++i) {
      long m = m0 + ih * 64 + ty * 4 + i;
      #pragma unroll
      for (int jh = 0; jh < 2; ++jh) {
        long n = n0 + jh * 64 + tx * 4;
        f32x4 val = accv[ih * 4 + i][jh];
        if (POST == P_F32_RELU) {
          #pragma unroll
          for (int j = 0; j < 4; ++j) val[j] = fmaxf(val[j], 0.f);
        }
        if (POST == P_F32_RESID) val += *(const f32x4*)&resid[m * N + n];
        *(f32x4*)&C[m * N + n] = val;
      }
    }
}

// ------- MFMA split-2 attention (f32-equivalent accuracy) -------

__global__ __launch_bounds__(256) void attn2h_k(
    const u16* __restrict__ qkvP, long qplane,
    u16* __restrict__ oP, long oplane) {
  int qt = (int)gridDim.x - 1 - (int)blockIdx.x;   // heavy first
  int bh = blockIdx.y;
  int b = bh >> 4, h = bh & 15;
  const int ldq = 3 * kD;
  long hbq = (long)b * kT * ldq + h * kHD;
  long hbo = (long)b * kT * kD + h * kHD;
  int t = threadIdx.x, w = t >> 6, l = t & 63;
  int lr = l & 15, lg = l >> 4;

  __shared__ __align__(16) u16 Ks[2][64][72];
  __shared__ __align__(16) u16 Vt[2][64][72];
  __shared__ __align__(16) u16 Ps[2][4][16][72];

  f16x8 qf0[2], qf1[2];
  {
    long qrow = qt * 64 + w * 16 + lr;
    const u16* qp = qkvP + hbq + qrow * ldq;
    #pragma unroll
    for (int kc = 0; kc < 2; ++kc) {
      qf0[kc] = *(const f16x8*)(qp + kc * 32 + lg * 8);
      qf1[kc] = *(const f16x8*)(qp + qplane + kc * 32 + lg * 8);
    }
  }
  int qg = qt * 64 + w * 16 + lg * 4;

  float mrow[4], lsum[4];
  f32x4 accO[4];
  #pragma unroll
  for (int r = 0; r < 4; ++r) { mrow[r] = -1e30f; lsum[r] = 0.f; }
  #pragma unroll
  for (int j = 0; j < 4; ++j) accO[j] = 0.f;

  for (int it = 0; it <= qt; ++it) {
    #pragma unroll
    for (int p = 0; p < 2; ++p) {
      #pragma unroll
      for (int s = 0; s < 2; ++s) {
        int c = s * 256 + t;
        int row = c >> 3, col = (c & 7) * 8;
        long gi = (long)p * qplane + hbq + (long)(it * 64 + row) * ldq + col;
        *(u16x8*)&Ks[p][row][col] = *(const u16x8*)(qkvP + kD + gi);
        u16x8 vv = *(const u16x8*)(qkvP + 2 * kD + gi);
        #pragma unroll
        for (int j = 0; j < 8; ++j) Vt[p][col + j][row] = vv[j];
      }
    }
    __syncthreads();

    f32x4 s4[4];
    __builtin_amdgcn_s_setprio(1);
    #pragma unroll
    for (int j = 0; j < 4; ++j) {
      f32x4 z = {0.f, 0.f, 0.f, 0.f};
      #pragma unroll
      for (int kc = 0; kc < 2; ++kc) {
        f16x8 kh = *(const f16x8*)&Ks[0][j*16 + lr][kc*32 + lg*8];
        f16x8 km = *(const f16x8*)&Ks[1][j*16 + lr][kc*32 + lg*8];
        z = MFMAH(qf0[kc], kh, z);
        z = MFMAH(qf1[kc], kh, z);
        z = MFMAH(qf0[kc], km, z);
      }
      s4[j] = z;
    }
    __builtin_amdgcn_s_setprio(0);
    #pragma unroll
    for (int j = 0; j < 4; ++j)
      #pragma unroll
      for (int r = 0; r < 4; ++r) {
        float sv = s4[j][r] * (0.125f / 4096.0f);
        if (it * 64 + j * 16 + lr > qg + r) sv = -1e30f;
        s4[j][r] = sv;
      }
    float alpha[4];
    #pragma unroll
    for (int r = 0; r < 4; ++r) {
      float mx = fmaxf(fmaxf(s4[0][r], s4[1][r]), fmaxf(s4[2][r], s4[3][r]));
      mx = fmaxf(mx, __shfl_xor(mx, 1));
      mx = fmaxf(mx, __shfl_xor(mx, 2));
      mx = fmaxf(mx, __shfl_xor(mx, 4));
      mx = fmaxf(mx, __shfl_xor(mx, 8));
      float mi = fmaxf(mrow[r], mx);
      alpha[r] = __expf(mrow[r] - mi);
      mrow[r] = mi;
    }
    float rs[4] = {0.f, 0.f, 0.f, 0.f};
    #pragma unroll
    for (int j = 0; j < 4; ++j)
      #pragma unroll
      for (int r = 0; r < 4; ++r) {
        float p = __expf(s4[j][r] - mrow[r]);
        rs[r] += p;
        u16 hh, mm; split2s(p, hh, mm);
        Ps[0][w][lg*4 + r][j*16 + lr] = hh;
        Ps[1][w][lg*4 + r][j*16 + lr] = mm;
      }
    #pragma unroll
    for (int r = 0; r < 4; ++r) {
      float x2 = rs[r];
      x2 += __shfl_xor(x2, 1);
      x2 += __shfl_xor(x2, 2);
      x2 += __shfl_xor(x2, 4);
      x2 += __shfl_xor(x2, 8);
      lsum[r] = lsum[r] * alpha[r] + x2;
    }
    #pragma unroll
    for (int j = 0; j < 4; ++j)
      #pragma unroll
      for (int r = 0; r < 4; ++r) accO[j][r] *= alpha[r];
    __syncthreads();

    f16x8 ph[2], pm[2];
    #pragma unroll
    for (int kc = 0; kc < 2; ++kc) {
      ph[kc] = *(const f16x8*)&Ps[0][w][lr][kc*32 + lg*8];
      pm[kc] = *(const f16x8*)&Ps[1][w][lr][kc*32 + lg*8];
    }
    __builtin_amdgcn_s_setprio(1);
    #pragma unroll
    for (int j2 = 0; j2 < 4; ++j2) {
      #pragma unroll
      for (int kc = 0; kc < 2; ++kc) {
        f16x8 vh = *(const f16x8*)&Vt[0][j2*16 + lr][kc*32 + lg*8];
        f16x8 vm = *(const f16x8*)&Vt[1][j2*16 + lr][kc*32 + lg*8];
        accO[j2] = MFMAH(ph[kc], vh, accO[j2]);
        accO[j2] = MFMAH(pm[kc], vh, accO[j2]);
        accO[j2] = MFMAH(ph[kc], vm, accO[j2]);
      }
    }
    __builtin_amdgcn_s_setprio(0);
    __syncthreads();
  }
  #pragma unroll
  for (int j2 = 0; j2 < 4; ++j2)
    #pragma unroll
    for (int r = 0; r < 4; ++r) {
      float ov = accO[j2][r] * (1.0f / 4096.0f) / lsum[r];
      long row = qt * 64 + w * 16 + lg * 4 + r;
      long idx = hbo + row * kD + j2 * 16 + lr;
      u16 hh, mm; split2s(ov, hh, mm);
      oP[idx] = hh;
      oP[oplane + idx] = mm;
    }
}

// ---------------- f32 attention (fallback path) ----------------

__global__ __launch_bounds__(256) void attn_f32_k(
    const float* __restrict__ qkv, float* __restrict__ of32, int ldq) {
  int qt = blockIdx.x;
  int bh = blockIdx.y;
  int b = bh >> 4, h = bh & 15;
  long hbq = (long)b * kT * ldq + h * kHD;
  long hbo = (long)b * kT * kD + h * kHD;
  int t = threadIdx.x, qr = t >> 2, sub = t & 3;

  __shared__ float Qs[64][68], Ks[64][68], Vs[64][68], Ps[64][68];

  const float* q = qkv;
  const float* k = qkv + kD;
  const float* v = qkv + 2 * kD;

  #pragma unroll
  for (int it = 0; it < 4; ++it) {
    int c = it * 256 + t, row = c >> 4, c4 = (c & 15) * 4;
    f32x4 qv = *(const f32x4*)(q + hbq + (long)(qt * 64 + row) * ldq + c4);
    #pragma unroll
    for (int j = 0; j < 4; ++j) Qs[row][c4 + j] = qv[j];
  }
  __syncthreads();
  f32x4 qreg[16];
  #pragma unroll
  for (int d4 = 0; d4 < 16; ++d4) qreg[d4] = *(const f32x4*)&Qs[qr][d4 * 4];
  int qg = qt * 64 + qr;

  float mrow = -1e30f, lsum = 0.f;
  f32x4 accO[4];
  #pragma unroll
  for (int i = 0; i < 4; ++i) accO[i] = 0.f;

  for (int itl = 0; itl <= qt; ++itl) {
    #pragma unroll
    for (int it = 0; it < 4; ++it) {
      int c = it * 256 + t, row = c >> 4, c4 = (c & 15) * 4;
      long gi = hbq + (long)(itl * 64 + row) * ldq + c4;
      f32x4 kv = *(const f32x4*)(k + gi);
      f32x4 vv = *(const f32x4*)(v + gi);
      #pragma unroll
      for (int j = 0; j < 4; ++j) { Ks[row][c4 + j] = kv[j]; Vs[row][c4 + j] = vv[j]; }
    }
    __syncthreads();

    float s[16];
    #pragma unroll
    for (int kk = 0; kk < 16; ++kk) {
      int key = kk * 4 + sub;
      f32x4 a = {0.f, 0.f, 0.f, 0.f};
      #pragma unroll
      for (int d4 = 0; d4 < 16; ++d4) a += qreg[d4] * *(const f32x4*)&Ks[key][d4 * 4];
      float sv = (a[0] + a[1] + a[2] + a[3]) * 0.125f;
      if (itl * 64 + key > qg) sv = -1e30f;
      s[kk] = sv;
    }
    float mx = s[0];
    #pragma unroll
    for (int kk = 1; kk < 16; ++kk) mx = fmaxf(mx, s[kk]);
    mx = fmaxf(mx, __shfl_xor(mx, 1));
    mx = fmaxf(mx, __shfl_xor(mx, 2));
    float mi = fmaxf(mrow, mx);
    float alpha = __expf(mrow - mi);
    mrow = mi;
    float rs = 0.f;
    #pragma unroll
    for (int kk = 0; kk < 16; ++kk) {
      float p = __expf(s[kk] - mi);
      rs += p;
      Ps[qr][kk * 4 + sub] = p;
    }
    rs += __shfl_xor(rs, 1);
    rs += __shfl_xor(rs, 2);
    lsum = lsum * alpha + rs;
    #pragma unroll
    for (int i = 0; i < 4; ++i) accO[i] *= alpha;
    #pragma unroll
    for (int key2 = 0; key2 < 64; ++key2) {
      float p = Ps[qr][key2];
      #pragma unroll
      for (int i4 = 0; i4 < 4; ++i4)
        accO[i4] += p * *(const f32x4*)&Vs[key2][sub * 16 + i4 * 4];
    }
    __syncthreads();
  }
  float inv = 1.f / lsum;
  #pragma unroll
  for (int i4 = 0; i4 < 4; ++i4) {
    f32x4 ov = accO[i4] * inv;
    *(f32x4*)(of32 + hbo + (long)qg * kD + sub * 16 + i4 * 4) = ov;
  }
}

// ---------------- host ----------------

extern "C" void kernel_launch(void* const* d_in, const int* in_sizes, int n_in,
                              void* d_out, int out_size, void* d_ws, size_t ws_size,
                              hipStream_t stream) {
  const int*   idx  = (const int*)  d_in[0];
  const float* wte  = (const float*)d_in[1];
  const float* wpe  = (const float*)d_in[2];
  const float* wq   = (const float*)d_in[3];
  const float* wk   = (const float*)d_in[4];
  const float* wv   = (const float*)d_in[5];
  const float* wo   = (const float*)d_in[6];
  const float* gate = (const float*)d_in[7];
  const float* f1   = (const float*)d_in[8];
  const float* f2   = (const float*)d_in[9];
  const float* lmh  = (const float*)d_in[10];
  float* out = (float*)d_out;

  char* ws = (char*)d_ws;
  size_t off = 0;
  auto alloc = [&](size_t b) -> char* {
    char* p = ws + off;
    off += (b + 255) & ~(size_t)255;
    return p;
  };

  constexpr long PLN_XN = (long)kBT * kD;
  constexpr long PLN_Q3 = (long)kBT * 3 * kD;
  constexpr long PLN_FF = (long)kE * kFF * kD;
  constexpr long PLN_H = (long)kSLOTS * kFF;
  constexpr long PLN_OUTS = (long)kSLOTS * kD;
  constexpr long PLN_PR = (long)kBT * kE;

  // shared small buffers
  float* x     = (float*)alloc((size_t)kBT * kD * 4);
  float* outs  = (float*)alloc((size_t)4 * PLN_OUTS * 4);   // 4 K-partials
  float* probs3= (float*)alloc((size_t)kL * PLN_PR * 4);    // per-layer probs
  int*   top2e = (int*)  alloc((size_t)kBT * 2 * 4);
  float* top2w = (float*)alloc((size_t)kBT * 2 * 4);
  int*   meta  = (int*)  alloc(64 * 4);
  int* counts = meta; int* cursors = meta + 8; int* offs = meta + 16;
  int*   rows  = (int*)  alloc((size_t)kSLOTS * 4);
  int*   slotOf= (int*)  alloc((size_t)kBT * 2 * 4);
  float* aux   = (float*)alloc(256);
  size_t off_shared = off;

  // fast-path buffers
  u16*   xnP   = (u16*)  alloc((size_t)2 * PLN_XN * 2);
  float* qkvf  = (float*)alloc((size_t)PLN_Q3 * 4);
  u16*   qkvP  = (u16*)  alloc((size_t)2 * PLN_Q3 * 2);
  u16*   ofP   = (u16*)  alloc((size_t)2 * PLN_XN * 2);
  u16*   hP    = (u16*)  alloc((size_t)2 * PLN_H * 2);
  bool fast = (off <= ws_size);
  float* qkvp1 = (float*)hP;          // alias: hP idle during QKV+attn phase

  dim3 gAttn(kT / 64, 2 * kH);
  // base grids (all % 8 == 0)
  int bQKV = (kBT / 128) * (3 * kD / 128);       // 384,  MPART mPerX=2, kParts=2
  int bWO  = (kBT / 128) * (kD / 128);           // 128,  MPART mPerX=2, kParts=4
  int nF1W = (kSLOTS / 128) * (kFF / 256);       // 640,  W kernel mPerX=5
  int bF2  = (kSLOTS / 128) * (kD / 128);        // 320,  MPART mPerX=5, kParts=4
  int nF1s = (kSLOTS / 128) * (kFF / 128);       // 1280, MPART mPerX=5
  int nLM  = (kBT / 128) * (kV / 128);           // 4000, mBlocks=16

  if (fast) {
    embed_rms_k<<<kBT, 256, 0, stream>>>(idx, wte, wpe, x);
    rmsnorm2h_k<<<kBT, 256, 0, stream>>>(x, xnP, PLN_XN);   // layer-0 QKV input

    for (int li = 0; li < kL; ++li) {
      size_t dd = (size_t)li * kD * kD;
      // QKV: direct f32 weights (QKV3 in-staging split-2), split-K x2
      gemm2h_bt_k<P_F32, false, false, true, true, true><<<2 * bQKV, 256, 0, stream>>>(
          xnP, PLN_XN, wq + dd, wk + dd, wv + dd, 0,
          qkvf, 0, nullptr, nullptr, nullptr, 3 * kD, kD, kD, 0, 2,
          2, bQKV, (long)(qkvp1 - qkvf));
      qkvcomb_k<<<2048, 256, 0, stream>>>(qkvf, qkvp1, qkvP, PLN_Q3, PLN_Q3 / 4);
      attn2h_k<<<gAttn, 256, 0, stream>>>(qkvP, PLN_Q3, ofP, PLN_XN);
      // WO: direct f32 weights (BF32), split-K x4; fused residual+rms+split
      gemm2h_bt_k<P_F32, false, false, true, true><<<4 * bWO, 256, 0, stream>>>(
          ofP, PLN_XN, wo + dd, nullptr, nullptr, 0,
          outs, 0, nullptr, nullptr, nullptr, kD, kD, kD, 0, 2,
          4, bWO, PLN_OUTS);
      resid4_rms2h_k<<<kBT, 256, 0, stream>>>(x, outs, PLN_OUTS, xnP, PLN_XN);
      hipMemsetAsync(meta, 0, 64, stream);
      gate_topk_k<<<kBT, 256, 0, stream>>>(x, gate + (size_t)li * kE * kD,
                                           probs3 + (size_t)li * PLN_PR,
                                           top2e, top2w, counts);
      fill_slots2_k<<<kBT / 256, 256, 0, stream>>>(top2e, counts, offs, cursors,
                                                   rows, slotOf);
      size_t fd = (size_t)li * PLN_FF;
      if (li < 2) {
        gemm2hW_bt_k<P_SPLIT2_RELU, true, true, true><<<nF1W, 512, 0, stream>>>(
            xnP, PLN_XN, f1 + fd, 0, hP, PLN_H, rows, offs,
            kFF, kD, kD, (long)kFF * kD, kSLOTS / 128 / 8,
            1, nF1W, 0);
        gemm2h_bt_k<P_F32, false, true, true, true><<<4 * bF2, 256, 0, stream>>>(
            hP, PLN_H, f2 + fd, nullptr, nullptr, 0, outs, 0, nullptr, nullptr, offs,
            kD, kFF, kFF, (long)kD * kFF, kSLOTS / 128 / 8,
            4, bF2, PLN_OUTS);
        moe4_rms2h_k<<<kBT, 256, 0, stream>>>(x, outs, PLN_OUTS, slotOf, top2w,
                                              xnP, PLN_XN);
      } else {
        gemm_bt_k<P_F16_RELU, true, true, true, true, true><<<nF1s, 256, 0, stream>>>(
            xnP, f1 + fd, hP, rows, offs, kFF, kD, kD, (long)kFF * kD,
            1.0f / 64.0f, kSLOTS / 128 / 8, 1, nF1s, 0);
        gemm_bt_k<P_F32, true, false, true, true, true><<<4 * bF2, 256, 0, stream>>>(
            hP, f2 + fd, outs, nullptr, offs, kD, kFF, kFF, (long)kD * kFF,
            1.0f, kSLOTS / 128 / 8, 4, bF2, PLN_OUTS);
        moe4_cast_h_k<<<kBT, 256, 0, stream>>>(x, outs, PLN_OUTS, slotOf, top2w, xnP);
      }
    }
    // lm_head: direct f32 weights (BCONV+prefetch, swizzled staging)
    gemm_bt_k<P_F32, false, false, true, true, false><<<nLM, 256, 0, stream>>>(
        xnP, lmh, out, nullptr, nullptr, kV, kD, kD, 0, 1.0f, kBT / 128,
        1, nLM, 0);
    aux_reduce3_k<<<1, 256, 0, stream>>>(probs3, PLN_PR, out + (size_t)kBT * kV);
    return;
  }

  // ---------- fallback: f32 path ----------
  off = off_shared;
  float* xnf   = (float*)alloc((size_t)kBT * kD * 4);
  u16*   xnb   = (u16*)  alloc((size_t)kBT * kD * 2);
  float* qkvf32= (float*)alloc((size_t)kBT * 3 * kD * 4);
  float* off32 = (float*)alloc((size_t)kBT * kD * 4);
  float* hbuf  = (float*)alloc((size_t)kSLOTS * kFF * 4);
  u16* hbuf16 = (u16*)hbuf;

  hipMemsetAsync(aux, 0, 4, stream);
  embed_rms_k<<<kBT, 256, 0, stream>>>(idx, wte, wpe, x);
  dim3 gF1s(kSLOTS / 128, kFF / 128);
  dim3 gF2s(kSLOTS / 128, kD / 128);
  for (int li = 0; li < kL; ++li) {
    size_t dd = (size_t)li * kD * kD;
    rmsnorm2_k<<<kBT, 256, 0, stream>>>(x, xnf, xnb);
    dim3 gP(kBT / 128, kD / 128);
    sgemm_bt_k<P_F32, false, false><<<gP, 256, 0, stream>>>(
        xnf, wq + dd, qkvf32, nullptr, nullptr, nullptr, 3 * kD, kD, kD, 0);
    sgemm_bt_k<P_F32, false, false><<<gP, 256, 0, stream>>>(
        xnf, wk + dd, qkvf32 + kD, nullptr, nullptr, nullptr, 3 * kD, kD, kD, 0);
    sgemm_bt_k<P_F32, false, false><<<gP, 256, 0, stream>>>(
        xnf, wv + dd, qkvf32 + 2 * kD, nullptr, nullptr, nullptr, 3 * kD, kD, kD, 0);
    attn_f32_k<<<gAttn, 256, 0, stream>>>(qkvf32, off32, 3 * kD);
    sgemm_bt_k<P_F32_RESID, false, false><<<gP, 256, 0, stream>>>(
        off32, wo + dd, x, x, nullptr, nullptr, kD, kD, kD, 0);
    rmsnorm2_k<<<kBT, 256, 0, stream>>>(x, xnf, xnb);
    hipMemsetAsync(meta, 0, 64, stream);
    gate_topk_k<<<kBT, 256, 0, stream>>>(x, gate + (size_t)li * kE * kD,
                                         probs3, top2e, top2w, counts);
    calc_offsets_k<<<1, 64, 0, stream>>>(counts, offs);
    fill_slots2_k<<<kBT / 256, 256, 0, stream>>>(top2e, counts, offs, cursors,
                                                 rows, slotOf);
    size_t fd = (size_t)li * kE * kFF * kD;
    if (li < 2) {
      sgemm_bt_k<P_F32_RELU, true, true><<<gF1s, 256, 0, stream>>>(
          xnf, f1 + fd, hbuf, nullptr, rows, offs, kFF, kD, kD, (long)kFF * kD);
      sgemm_bt_k<P_F32, false, true><<<gF2s, 256, 0, stream>>>(
          hbuf, f2 + fd, outs, nullptr, nullptr, offs, kD, kFF, kFF, (long)kD * kFF);
    } else {
      gemm_bt_k<P_BF16_RELU, true, true, false, true, false><<<nF1s, 256, 0, stream>>>(
          xnb, f1 + fd, hbuf16, rows, offs, kFF, kD, kD, (long)kFF * kD,
          1.0f, kSLOTS / 128, 1, nF1s, 0);
      gemm_bt_k<P_F32, true, false, false, true, false><<<bF2, 256, 0, stream>>>(
          hbuf16, f2 + fd, outs, nullptr, offs, kD, kFF, kFF, (long)kD * kFF,
          1.0f, kSLOTS / 128, 1, bF2, 0);
    }
    hipMemsetAsync(outs + PLN_OUTS, 0, 3 * PLN_OUTS * 4, stream);
    moe_combine4_k<<<kBT, 256, 0, stream>>>(x, outs, PLN_OUTS, slotOf, top2w);
    aux_reduce_k<<<1, 256, 0, stream>>>(probs3, aux);
  }
  cast_bf16_k<<<2048, 256, 0, stream>>>(x, xnb, (long)kBT * kD / 4);
  gemm_bt_k<P_F32, false, false, false, true, false><<<nLM, 256, 0, stream>>>(
      xnb, lmh, out, nullptr, nullptr, kV, kD, kD, 0, 1.0f, kBT / 128,
      1, nLM, 0);
  write_aux_k<<<1, 64, 0, stream>>>(aux, out + (size_t)kBT * kV);
}